// Round 6
// baseline (5672.324 us; speedup 1.0000x reference)
//
#include <hip/hip_runtime.h>
#include <math.h>

#define Bq 512
#define Tq 64
#define Hq 450
#define Lq 56
#define Vq 780
#define Mq 8
#define TBq 32768
#define Sq 32770
#define HP 480          // bf16 row stride (mult of 32)
#define F32S 464        // f32 row stride
#define NPB 130         // 130*256 = 33280 rows
#define NPCAP 12288     // compacted pred rows cap
#define NSCAP 20480     // compacted stop rows cap
#define CH2 4096        // pred score chunk rows
#define NCH2 3
#define NBLK 256        // persistent scan grid (1/CU; >=2 blocks/CU capacity)

using bf16x8 = __attribute__((ext_vector_type(8))) __bf16;
using f32x4  = __attribute__((ext_vector_type(4))) float;

__device__ __forceinline__ ushort f2bf(float f){
    union { float f; unsigned u; } c; c.f = f;
    unsigned u = c.u;
    return (ushort)((u + 0x7FFFu + ((u >> 16) & 1u)) >> 16);
}
__device__ __forceinline__ float bf2f(ushort h){
    union { unsigned u; float f; } c; c.u = ((unsigned)h) << 16;
    return c.f;
}
__device__ __forceinline__ unsigned pk2(float a, float b){
    return (unsigned)f2bf(a) | ((unsigned)f2bf(b) << 16);
}
__device__ __forceinline__ float sigmf(float x){
    return __builtin_amdgcn_rcpf(1.f + __expf(-x));
}
__device__ __forceinline__ float tanhfast(float x){
    float e2 = __expf(2.f * x);
    return 1.f - 2.f * __builtin_amdgcn_rcpf(e2 + 1.f);
}

// ---------- device-scope grid barrier (NBLK co-resident blocks) ----------
// Each block's ACQ_REL arrival write-backs its XCD L2 (release); the exit
// ACQUIRE invalidates -> cross-XCD visibility of all plain stores.
__device__ __forceinline__ void gbar(int* bar){
    __syncthreads();
    if (threadIdx.x == 0){
        int gen = __hip_atomic_load(&bar[1], __ATOMIC_RELAXED, __HIP_MEMORY_SCOPE_AGENT);
        int old = __hip_atomic_fetch_add(&bar[0], 1, __ATOMIC_ACQ_REL, __HIP_MEMORY_SCOPE_AGENT);
        if (old == NBLK - 1){
            __hip_atomic_store(&bar[0], 0, __ATOMIC_RELAXED, __HIP_MEMORY_SCOPE_AGENT);
            __hip_atomic_store(&bar[1], gen + 1, __ATOMIC_RELEASE, __HIP_MEMORY_SCOPE_AGENT);
        } else {
            while (__hip_atomic_load(&bar[1], __ATOMIC_RELAXED, __HIP_MEMORY_SCOPE_AGENT) == gen)
                __builtin_amdgcn_s_sleep(1);
            (void)__hip_atomic_load(&bar[1], __ATOMIC_ACQUIRE, __HIP_MEMORY_SCOPE_AGENT);
        }
    }
    __syncthreads();
}

// ---------- fused converter: 14 jobs by blockIdx.y ----------
__global__ void convAll_k(
    const float* __restrict__ emb, const float* __restrict__ tree,
    const float* __restrict__ Wz, const float* __restrict__ Wr,
    const float* __restrict__ Ur, const float* __restrict__ Wh,
    const float* __restrict__ Wm, const float* __restrict__ U, const float* __restrict__ Wo,
    ushort* embb, ushort* treeb, ushort* WzX, ushort* WzS, ushort* WrB,
    ushort* WhX, ushort* WhG, ushort* UrB, ushort* WHp, ushort* UXp,
    ushort* UOp, ushort* WOp, ushort* WLp, ushort* ULp)
{
    int job = blockIdx.y, n = blockIdx.x;
    const float* src; ushort* dst; int Npad, Nsrc, Ksrc, Kpad, len, off;
    switch(job){
      case 0:  src=emb;  dst=embb; Npad=896; Nsrc=780; Ksrc=450; Kpad=480; len=450; off=0;   break;
      case 1:  src=tree; dst=treeb;Npad=512; Nsrc=512; Ksrc=56;  Kpad=64;  len=56;  off=0;   break;
      case 2:  src=Wz;   dst=WzX;  Npad=512; Nsrc=450; Ksrc=900; Kpad=480; len=450; off=0;   break;
      case 3:  src=Wz;   dst=WzS;  Npad=512; Nsrc=450; Ksrc=900; Kpad=480; len=450; off=450; break;
      case 4:  src=Wr;   dst=WrB;  Npad=512; Nsrc=450; Ksrc=450; Kpad=480; len=450; off=0;   break;
      case 5:  src=Wh;   dst=WhX;  Npad=512; Nsrc=450; Ksrc=900; Kpad=480; len=450; off=0;   break;
      case 6:  src=Wh;   dst=WhG;  Npad=512; Nsrc=450; Ksrc=900; Kpad=480; len=450; off=450; break;
      case 7:  src=Ur;   dst=UrB;  Npad=512; Nsrc=450; Ksrc=450; Kpad=480; len=450; off=0;   break;
      case 8:  src=Wm;   dst=WHp;  Npad=512; Nsrc=450; Ksrc=506; Kpad=480; len=450; off=0;   break;
      case 9:  src=U;    dst=UXp;  Npad=512; Nsrc=450; Ksrc=956; Kpad=480; len=450; off=0;   break;
      case 10: src=U;    dst=UOp;  Npad=512; Nsrc=450; Ksrc=956; Kpad=480; len=450; off=450; break;
      case 11: src=Wo;   dst=WOp;  Npad=832; Nsrc=780; Ksrc=450; Kpad=480; len=450; off=0;   break;
      case 12: src=Wm;   dst=WLp;  Npad=512; Nsrc=450; Ksrc=506; Kpad=64;  len=56;  off=450; break;
      default: src=U;    dst=ULp;  Npad=512; Nsrc=450; Ksrc=956; Kpad=64;  len=56;  off=900; break;
    }
    if (n >= Npad) return;
    for (int k = threadIdx.x; k < Kpad; k += blockDim.x){
        float v = 0.f;
        if (n < Nsrc && k < len) v = src[(size_t)n*Ksrc + off + k];
        dst[(size_t)n*Kpad + k] = f2bf(v);
    }
}

// ---------- double-buffered MFMA GEMM body: C(128x64) tile ----------
template<class APtr>
__device__ __forceinline__ void mgemm2(APtr&& aptr, const ushort* __restrict__ Bw, int ldb,
                                       int KT, int col0, f32x4 acc[4][2])
{
    __shared__ __align__(16) char As[2][128*80];
    __shared__ __align__(16) char Bs[2][64*80];
    const int tid = threadIdx.x;
    const int lane = tid & 63;
    const int w = tid >> 6, wm = w >> 1, wn = w & 1;
    const int ac = (tid & 3) * 8;
    const size_t boff = (size_t)(col0 + (tid >> 2)) * ldb;
    uint4 ra0, ra1, rb;
    auto ld = [&](int k0){
        ra0 = *(const uint4*)(aptr(0, k0) + ac);
        ra1 = *(const uint4*)(aptr(1, k0) + ac);
        rb  = *(const uint4*)(Bw + boff + k0 + ac);
    };
    const int wr_a0 = (tid>>2)*80 + (tid&3)*16;
    const int wr_a1 = ((tid>>2)+64)*80 + (tid&3)*16;
    const int wr_b  = (tid>>2)*80 + (tid&3)*16;
    const int rd_a  = (wm*64 + (lane&15))*80 + (lane>>4)*16;
    const int rd_b  = (wn*32 + (lane&15))*80 + (lane>>4)*16;
    ld(0);
    *(uint4*)(As[0]+wr_a0) = ra0; *(uint4*)(As[0]+wr_a1) = ra1; *(uint4*)(Bs[0]+wr_b) = rb;
#pragma unroll
    for (int f=0;f<4;f++)
#pragma unroll
        for (int g=0;g<2;g++) acc[f][g] = (f32x4){0.f,0.f,0.f,0.f};
    __syncthreads();
    for (int kt=0; kt<KT; ++kt){
        const int cur = kt & 1;
        if (kt+1 < KT) ld((kt+1)*32);
        bf16x8 bF[2];
#pragma unroll
        for (int g=0; g<2; g++) bF[g] = *(const bf16x8*)(Bs[cur] + rd_b + g*16*80);
#pragma unroll
        for (int f=0; f<4; f++){
            bf16x8 aF = *(const bf16x8*)(As[cur] + rd_a + f*16*80);
#pragma unroll
            for (int g=0; g<2; g++)
                acc[f][g] = __builtin_amdgcn_mfma_f32_16x16x32_bf16(aF, bF[g], acc[f][g], 0, 0, 0);
        }
        if (kt+1 < KT){
            *(uint4*)(As[cur^1]+wr_a0) = ra0; *(uint4*)(As[cur^1]+wr_a1) = ra1;
            *(uint4*)(Bs[cur^1]+wr_b) = rb;
        }
        __syncthreads();
    }
}

#define EPI_PRE  const int lane = threadIdx.x & 63; const int w_ = threadIdx.x >> 6; \
                 const int wm = w_ >> 1, wn = w_ & 1;

// ---------- precompute GEMM body ----------
__device__ __forceinline__ void pre_body(const ushort* __restrict__ A, int lda,
    const ushort* __restrict__ Bw, const float* __restrict__ bias,
    float* __restrict__ out, int Mr, int KT)
{
    const int row0 = blockIdx.y*128, col0 = blockIdx.x*64;
    const int tid = threadIdx.x;
    const ushort* p0 = A + (size_t)(row0 + (tid>>2))*lda;
    const ushort* p1 = p0 + (size_t)64*lda;
    f32x4 acc[4][2];
    mgemm2([&](int which,int k0){ return (which?p1:p0)+k0; }, Bw, lda, KT, col0, acc);
    EPI_PRE
#pragma unroll
    for (int f=0; f<4; f++)
#pragma unroll
      for (int g=0; g<2; g++){
        int col = col0 + wn*32 + g*16 + (lane & 15);
        if (col >= F32S) continue;
        float bb = 0.f;
        if (col < Hq && bias) bb = bias[col];
#pragma unroll
        for (int j=0; j<4; j++){
            int row = row0 + wm*64 + f*16 + ((lane>>4)<<2) + j;
            if (row < Mr) out[(size_t)row*F32S + col] = (col < Hq) ? acc[f][g][j] + bb : 0.f;
        }
      }
}

__global__ __launch_bounds__(256) void preE_k(
    const ushort* __restrict__ embb,
    const ushort* __restrict__ WzX, const ushort* __restrict__ WrB,
    const ushort* __restrict__ WhX, const ushort* __restrict__ UXp,
    const float* __restrict__ bz, const float* __restrict__ br,
    const float* __restrict__ bh, const float* __restrict__ bU,
    float* __restrict__ EZ, float* __restrict__ ER,
    float* __restrict__ EH, float* __restrict__ EU)
{
    const ushort* Bw; const float* bias; float* out;
    switch(blockIdx.z){
      case 0:  Bw=WzX; bias=bz; out=EZ; break;
      case 1:  Bw=WrB; bias=br; out=ER; break;
      case 2:  Bw=WhX; bias=bh; out=EH; break;
      default: Bw=UXp; bias=bU; out=EU; break;
    }
    pre_body(embb, HP, Bw, bias, out, Vq, 15);
}

__global__ __launch_bounds__(256) void preT_k(
    const ushort* __restrict__ treeb,
    const ushort* __restrict__ WLp, const ushort* __restrict__ ULp,
    const float* __restrict__ bW, float* __restrict__ TP, float* __restrict__ TU)
{
    const ushort* Bw = blockIdx.z ? ULp : WLp;
    const float* bias = blockIdx.z ? nullptr : bW;
    float* out = blockIdx.z ? TU : TP;
    pre_body(treeb, 64, Bw, bias, out, Bq, 2);
}

// ---------- compaction: count / scan / fill ----------
__device__ __forceinline__ bool cmask(int which, int gr,
    const int* __restrict__ valid, const int* __restrict__ dir)
{
    if (which == 0) return (gr < Bq) ? true : (valid[gr-Bq] && dir[gr-Bq]);
    return (gr < TBq) ? (valid[gr] != 0) : true;
}
__global__ void cnt_k(const int* __restrict__ valid, const int* __restrict__ dir,
                      int* __restrict__ cnts)
{
    int which = blockIdx.y;
    int gr = blockIdx.x*256 + threadIdx.x;
    bool m = cmask(which, gr, valid, dir);
    unsigned long long bal = __ballot(m);
    if ((threadIdx.x & 63) == 0)
        atomicAdd(&cnts[which*NPB + blockIdx.x], (int)__popcll(bal));
}
__global__ void scan_k(const int* __restrict__ cnts, int* __restrict__ offs,
                       int* __restrict__ totals)
{
    if (threadIdx.x == 0){
        int a = 0;
        for (int i=0;i<NPB;i++){ offs[i] = a; a += cnts[i]; }
        totals[0] = a;
        int b = 0;
        for (int i=0;i<NPB;i++){ offs[NPB+i] = b; b += cnts[NPB+i]; }
        totals[1] = b;
    }
}
__global__ void fill_k(const int* __restrict__ valid, const int* __restrict__ dir,
                       const int* __restrict__ offs, int* __restrict__ listp,
                       int* __restrict__ lists)
{
    __shared__ int woff[4];
    int which = blockIdx.y;
    int gr = blockIdx.x*256 + threadIdx.x;
    bool m = cmask(which, gr, valid, dir);
    unsigned long long bal = __ballot(m);
    int lane = threadIdx.x & 63, wv = threadIdx.x >> 6;
    if (lane == 0) woff[wv] = (int)__popcll(bal);
    __syncthreads();
    int prev = 0;
    for (int i=0;i<wv;i++) prev += woff[i];
    if (m){
        int rank = prev + (int)__popcll(bal & ((1ull << lane) - 1ull));
        int pos = offs[which*NPB + blockIdx.x] + rank;
        if (which == 0){ if (pos < NPCAP) listp[pos] = gr; }
        else           { if (pos < NSCAP) lists[pos] = gr; }
    }
}

// ---------- persistent scan: 256 blocks, 64 steps, 3 phases/step ----------
// Phase A: 30720 gather tasks (row x 8-col chunk), 120 per block.
// Phase B: twin GEMM (z,h) 32x32 tiles, 16x16 grid = 256 blocks, blend epilogue.
// Phase C: Ur GEMM 32x32 tiles = 256 blocks.
__global__ __launch_bounds__(256, 1) void scan_coop(
    const int* __restrict__ x_wid, const int* __restrict__ h_nei_idx,
    const int* __restrict__ valid,
    const float* __restrict__ ER, const float* __restrict__ EZ, const float* __restrict__ EH,
    const ushort* __restrict__ WzS, const ushort* __restrict__ WhG, const ushort* __restrict__ UrB,
    ushort* __restrict__ hbuf, ushort* __restrict__ uhbuf,
    ushort* __restrict__ sumh, ushort* __restrict__ gated, ushort* __restrict__ nh,
    int* __restrict__ bar)
{
    __shared__ __align__(16) char smem[20480];
    char* Az = smem;           // 2 buf x 32 rows x 80B
    char* Ag = smem + 5120;
    char* Bz = smem + 10240;
    char* Bg = smem + 15360;
    const int tid = threadIdx.x;
    const int blk = blockIdx.x;
    const int lane = tid & 63;
    const int wv = tid >> 6, wr = wv >> 1, wc = wv & 1;
    const int rows0 = (blk >> 4) * 32, cols0 = (blk & 15) * 32;
    const bool isA = tid < 128;
    const int slot = isA ? tid : tid - 128;
    const int lrow = slot >> 2;          // 0..31
    const int kc8  = (slot & 3) * 8;     // elem offset in 32-wide k slab
    const int wrOff = lrow*80 + (slot&3)*16;
    const int rdA = (wr*16 + (lane&15))*80 + (lane>>4)*16;
    const int rdB = (wc*16 + (lane&15))*80 + (lane>>4)*16;
    // phase A task (tid<120)
    const int task = blk*120 + tid;
    const int ga_b = task / 60;
    const int ga_c = task - ga_b*60;
    // phase B/C load pointers
    const ushort* aSrcZ = sumh  + (size_t)(rows0+lrow)*HP + kc8;
    const ushort* aSrcG = gated + (size_t)(rows0+lrow)*HP + kc8;
    const ushort* bSrcZ = WzS + (size_t)(cols0+lrow)*HP + kc8;
    const ushort* bSrcG = WhG + (size_t)(cols0+lrow)*HP + kc8;
    const ushort* aSrcN = nh  + (size_t)(rows0+lrow)*HP + kc8;
    const ushort* bSrcU = UrB + (size_t)(cols0+lrow)*HP + kc8;

    for (int t = 0; t < Tq; ++t){
        // ======== phase A: gather sum_h & gated ========
        if (tid < 120){
            const int b = ga_b, c = ga_c;
            const int j0 = c*8;
            const int base = t*Bq + b;
            uint4 so, go;
            if (c < 57){
                const int wid = x_wid[base];
                const int* ip = h_nei_idx + (size_t)base*Mq;
                float er[8];
                const float* erp = ER + (size_t)wid*F32S + j0;
                {
                    float4 e0 = *(const float4*)(erp);
                    float4 e1 = *(const float4*)(erp+4);
                    er[0]=e0.x; er[1]=e0.y; er[2]=e0.z; er[3]=e0.w;
                    er[4]=e1.x; er[5]=e1.y; er[6]=e1.z; er[7]=e1.w;
                }
                float sh[8] = {0,0,0,0,0,0,0,0};
                float gt[8] = {0,0,0,0,0,0,0,0};
#pragma unroll
                for (int m=0;m<Mq;m++){
                    int ix = ip[m];
                    uint4 hv = *(const uint4*)(hbuf  + (size_t)ix*HP + j0);
                    uint4 uv = *(const uint4*)(uhbuf + (size_t)ix*HP + j0);
                    unsigned hw[4] = {hv.x,hv.y,hv.z,hv.w};
                    unsigned uw[4] = {uv.x,uv.y,uv.z,uv.w};
#pragma unroll
                    for (int e=0;e<8;e++){
                        float h = bf2f((ushort)((hw[e>>1] >> ((e&1)*16)) & 0xffff));
                        float u = bf2f((ushort)((uw[e>>1] >> ((e&1)*16)) & 0xffff));
                        sh[e] += h;
                        gt[e] += h * sigmf(er[e] + u);
                    }
                }
                so.x = pk2(sh[0],sh[1]); so.y = pk2(sh[2],sh[3]);
                so.z = pk2(sh[4],sh[5]); so.w = pk2(sh[6],sh[7]);
                go.x = pk2(gt[0],gt[1]); go.y = pk2(gt[2],gt[3]);
                go.z = pk2(gt[4],gt[5]); go.w = pk2(gt[6],gt[7]);
            } else {
                so = (uint4){0,0,0,0}; go = (uint4){0,0,0,0};
            }
            *(uint4*)(sumh  + (size_t)b*HP + j0) = so;
            *(uint4*)(gated + (size_t)b*HP + j0) = go;
        }
        gbar(bar);
        // ======== phase B: twin 32x32 GEMM + GRU blend ========
        {
            uint4 r0, r1;
            f32x4 accZ = (f32x4){0,0,0,0}, accH = (f32x4){0,0,0,0};
            if (isA){ r0 = *(const uint4*)(aSrcZ); r1 = *(const uint4*)(aSrcG); }
            else    { r0 = *(const uint4*)(bSrcZ); r1 = *(const uint4*)(bSrcG); }
            if (isA){ *(uint4*)(Az+wrOff)=r0; *(uint4*)(Ag+wrOff)=r1; }
            else    { *(uint4*)(Bz+wrOff)=r0; *(uint4*)(Bg+wrOff)=r1; }
            __syncthreads();
            for (int kt=0; kt<15; ++kt){
                const int cb = (kt&1)*2560;
                if (kt < 14){
                    int k0 = (kt+1)*32;
                    if (isA){ r0 = *(const uint4*)(aSrcZ+k0); r1 = *(const uint4*)(aSrcG+k0); }
                    else    { r0 = *(const uint4*)(bSrcZ+k0); r1 = *(const uint4*)(bSrcG+k0); }
                }
                bf16x8 az_ = *(const bf16x8*)(Az + cb + rdA);
                bf16x8 ag_ = *(const bf16x8*)(Ag + cb + rdA);
                bf16x8 bz_ = *(const bf16x8*)(Bz + cb + rdB);
                bf16x8 bg_ = *(const bf16x8*)(Bg + cb + rdB);
                accZ = __builtin_amdgcn_mfma_f32_16x16x32_bf16(az_, bz_, accZ, 0, 0, 0);
                accH = __builtin_amdgcn_mfma_f32_16x16x32_bf16(ag_, bg_, accH, 0, 0, 0);
                if (kt < 14){
                    const int nb = ((kt&1)^1)*2560;
                    if (isA){ *(uint4*)(Az+nb+wrOff)=r0; *(uint4*)(Ag+nb+wrOff)=r1; }
                    else    { *(uint4*)(Bz+nb+wrOff)=r0; *(uint4*)(Bg+nb+wrOff)=r1; }
                }
                __syncthreads();
            }
            const int col = cols0 + wc*16 + (lane & 15);
            if (col < Hq){
#pragma unroll
                for (int j=0; j<4; j++){
                    int b = rows0 + wr*16 + ((lane>>4)<<2) + j;
                    int base = t*Bq + b;
                    int wid = x_wid[base];
                    float z  = sigmf(accZ[j] + EZ[(size_t)wid*F32S + col]);
                    float ht = tanhfast(accH[j] + EH[(size_t)wid*F32S + col]);
                    float sh = bf2f(sumh[(size_t)b*HP + col]);
                    ushort o = f2bf((1.f - z)*sh + z*ht);
                    nh[(size_t)b*HP + col] = o;
                    if (valid[base]) hbuf[(size_t)(1 + base)*HP + col] = o;
                }
            }
        }
        gbar(bar);
        // ======== phase C: uh = nh @ Ur^T (32x32 tiles) ========
        {
            uint4 r0;
            f32x4 acc = (f32x4){0,0,0,0};
            r0 = isA ? *(const uint4*)(aSrcN) : *(const uint4*)(bSrcU);
            if (isA) *(uint4*)(Az+wrOff)=r0; else *(uint4*)(Bz+wrOff)=r0;
            __syncthreads();
            for (int kt=0; kt<15; ++kt){
                const int cb = (kt&1)*2560;
                if (kt < 14){
                    int k0 = (kt+1)*32;
                    r0 = isA ? *(const uint4*)(aSrcN+k0) : *(const uint4*)(bSrcU+k0);
                }
                bf16x8 aF = *(const bf16x8*)(Az + cb + rdA);
                bf16x8 bF = *(const bf16x8*)(Bz + cb + rdB);
                acc = __builtin_amdgcn_mfma_f32_16x16x32_bf16(aF, bF, acc, 0, 0, 0);
                if (kt < 14){
                    const int nb = ((kt&1)^1)*2560;
                    if (isA) *(uint4*)(Az+nb+wrOff)=r0; else *(uint4*)(Bz+nb+wrOff)=r0;
                }
                __syncthreads();
            }
            const int col = cols0 + wc*16 + (lane & 15);
            if (col < Hq){
#pragma unroll
                for (int j=0; j<4; j++){
                    int b = rows0 + wr*16 + ((lane>>4)<<2) + j;
                    int base = t*Bq + b;
                    if (valid[base]) uhbuf[(size_t)(1 + base)*HP + col] = f2bf(acc[j]);
                }
            }
        }
        gbar(bar);
    }
}

// ---------- pred GEMM1 (compacted rows) ----------
__global__ __launch_bounds__(256) void pred1c_k(const int* __restrict__ np_,
    const int* __restrict__ listp, const ushort* __restrict__ hbuf,
    const float* __restrict__ TP, const ushort* __restrict__ WHp,
    ushort* __restrict__ pv)
{
    const int np = *np_;
    const int row0 = blockIdx.y*128;
    if (row0 >= np) return;
    const int col0 = blockIdx.x*64;
    const int tid = threadIdx.x;
    int i0 = row0 + (tid>>2), i1 = i0 + 64;
    int g0 = (i0 < np) ? listp[i0] : 0;
    int g1 = (i1 < np) ? listp[i1] : 0;
    const ushort* p0 = (g0 < Bq) ? hbuf : hbuf + (size_t)(1 + g0 - Bq)*HP;  // hbuf row0 = zeros
    const ushort* p1 = (g1 < Bq) ? hbuf : hbuf + (size_t)(1 + g1 - Bq)*HP;
    f32x4 acc[4][2];
    mgemm2([&](int which,int k0){ return (which?p1:p0)+k0; }, WHp, HP, 15, col0, acc);
    EPI_PRE
#pragma unroll
    for (int f=0; f<4; f++)
#pragma unroll
      for (int g=0; g<2; g++){
        int col = col0 + wn*32 + g*16 + (lane & 15);
        if (col >= HP) continue;
#pragma unroll
        for (int j=0; j<4; j++){
            int i = row0 + wm*64 + f*16 + ((lane>>4)<<2) + j;
            if (i >= np) continue;
            int gr = listp[i];
            int b = (gr < Bq) ? gr : ((gr - Bq) & (Bq-1));
            float v = 0.f;
            if (col < Hq) v = fmaxf(acc[f][g][j] + TP[(size_t)b*F32S + col], 0.f);
            pv[(size_t)i*HP + col] = f2bf(v);
        }
      }
}

// ---------- pred GEMM2 ----------
__global__ __launch_bounds__(256) void pred2c_k(int cs, const int* __restrict__ np_,
    const ushort* __restrict__ pv, const ushort* __restrict__ WOp,
    const float* __restrict__ bWo, float* __restrict__ scores)
{
    const int np = *np_;
    const int row0 = blockIdx.y*128;
    if (cs + row0 >= np) return;
    const int col0 = blockIdx.x*64;
    const int tid = threadIdx.x;
    const ushort* p0 = pv + (size_t)(cs + row0 + (tid>>2))*HP;
    const ushort* p1 = p0 + (size_t)64*HP;
    f32x4 acc[4][2];
    mgemm2([&](int which,int k0){ return (which?p1:p0)+k0; }, WOp, HP, 15, col0, acc);
    EPI_PRE
#pragma unroll
    for (int f=0; f<4; f++)
#pragma unroll
      for (int g=0; g<2; g++){
        int col = col0 + wn*32 + g*16 + (lane & 15);
        if (col >= Vq) continue;
        float bc = bWo[col];
#pragma unroll
        for (int j=0; j<4; j++){
            int r = row0 + wm*64 + f*16 + ((lane>>4)<<2) + j;
            scores[(size_t)r*832 + col] = acc[f][g][j] + bc;
        }
      }
}

// ---------- pred reduce: wave-per-row ----------
__global__ __launch_bounds__(256) void predred_k(int cs, const int* __restrict__ np_,
    const int* __restrict__ listp, const float* __restrict__ scores,
    const int* __restrict__ pred_wid, const int* __restrict__ root_wid,
    float* __restrict__ accv)
{
    const int np = *np_;
    int nrows = np - cs; if (nrows > CH2) nrows = CH2;
    const int lane = threadIdx.x & 63, wv = threadIdx.x >> 6;
    const int wid_g = blockIdx.x*4 + wv, nw = gridDim.x*4;
    float ce = 0.f, hit = 0.f, cnt = 0.f;
    for (int r = wid_g; r < nrows; r += nw){
        const float* sc = scores + (size_t)r*832;
        int gr = listp[cs + r];
        int tgt = (gr < Bq) ? root_wid[gr] : pred_wid[gr - Bq];
        float vals[13];
        float bv = -INFINITY, tv = 0.f; int bi = 0;
#pragma unroll
        for (int q=0; q<13; q++){
            int j = lane + q*64;
            float v = (j < Vq) ? sc[j] : -INFINITY;
            vals[q] = v;
            if (v > bv){ bv = v; bi = j; }
            if (j == tgt) tv = v;
        }
#pragma unroll
        for (int off=32; off; off>>=1){
            float ov = __shfl_xor(bv, off); int oi = __shfl_xor(bi, off);
            if (ov > bv || (ov == bv && oi < bi)){ bv = ov; bi = oi; }
        }
        float s = 0.f;
#pragma unroll
        for (int q=0; q<13; q++){
            int j = lane + q*64;
            if (j < Vq) s += __expf(vals[q] - bv);
        }
#pragma unroll
        for (int off=32; off; off>>=1) s += __shfl_xor(s, off);
#pragma unroll
        for (int off=32; off; off>>=1) tv += __shfl_xor(tv, off);
        if (lane == 0){
            ce += bv + logf(s) - tv;
            hit += (bi == tgt) ? 1.f : 0.f;
            cnt += 1.f;
        }
    }
    __shared__ float L[3][4];
    if (lane == 0){ L[0][wv] = ce; L[1][wv] = hit; L[2][wv] = cnt; }
    __syncthreads();
    if (threadIdx.x == 0){
        float a = L[0][0]+L[0][1]+L[0][2]+L[0][3];
        float b = L[1][0]+L[1][1]+L[1][2]+L[1][3];
        float c = L[2][0]+L[2][1]+L[2][2]+L[2][3];
        if (c != 0.f){
            atomicAdd(&accv[0], a);
            atomicAdd(&accv[1], b);
            atomicAdd(&accv[2], c);
        }
    }
}

// ---------- stop: cur_o gather (compacted) ----------
__global__ void curo_c(const int* __restrict__ ns_, const int* __restrict__ lists,
                       const int* __restrict__ o_nei_idx, const int* __restrict__ root_o_nei,
                       const ushort* __restrict__ hbuf, ushort* __restrict__ curo)
{
    int i = blockIdx.x;
    if (i >= *ns_) return;
    int gr = lists[i];
    int j0 = threadIdx.x * 4;
    if (j0 >= HP) return;
    int idx[Mq];
    if (gr < TBq){
        int tt = gr >> 9;
#pragma unroll
        for (int m=0;m<Mq;m++){
            int ix = o_nei_idx[(size_t)gr*Mq + m];
            idx[m] = (ix <= tt*Bq) ? ix : 0;   // slots written before step tt; row 0 is zero
        }
    } else {
#pragma unroll
        for (int m=0;m<Mq;m++) idx[m] = root_o_nei[(size_t)(gr-TBq)*Mq + m];
    }
    float s0=0,s1=0,s2=0,s3=0;
#pragma unroll
    for (int m=0;m<Mq;m++){
        uint2 v = *(const uint2*)(hbuf + (size_t)idx[m]*HP + j0);
        s0 += bf2f((ushort)(v.x & 0xffff)); s1 += bf2f((ushort)(v.x >> 16));
        s2 += bf2f((ushort)(v.y & 0xffff)); s3 += bf2f((ushort)(v.y >> 16));
    }
    uint2 o; o.x = pk2(s0, s1); o.y = pk2(s2, s3);
    *(uint2*)(curo + (size_t)i*HP + j0) = o;
}

// ---------- stop GEMM (compacted) + fused Us-dot ----------
__global__ __launch_bounds__(256) void stopc_k(const int* __restrict__ ns_,
    const int* __restrict__ lists, const int* __restrict__ x_wid,
    const int* __restrict__ root_wid, const ushort* __restrict__ curo,
    const ushort* __restrict__ UOp, const float* __restrict__ EU,
    const float* __restrict__ TU, const float* __restrict__ Usf,
    float* __restrict__ ss)
{
    const int ns = *ns_;
    const int row0 = blockIdx.y*128;
    if (row0 >= ns) return;
    const int col0 = blockIdx.x*64;
    const int tid = threadIdx.x;
    const ushort* p0 = curo + (size_t)(row0 + (tid>>2))*HP;
    const ushort* p1 = p0 + (size_t)64*HP;
    f32x4 acc[4][2];
    mgemm2([&](int which,int k0){ return (which?p1:p0)+k0; }, UOp, HP, 15, col0, acc);
    EPI_PRE
#pragma unroll
    for (int f=0; f<4; f++){
#pragma unroll
        for (int j=0; j<4; j++){
            int i = row0 + wm*64 + f*16 + ((lane>>4)<<2) + j;
            float p = 0.f;
            if (i < ns){
                int gr = lists[i];
                int wid = (gr < TBq) ? x_wid[gr] : root_wid[gr - TBq];
                int b   = (gr < TBq) ? (gr & (Bq-1)) : (gr - TBq);
                const float* eu = EU + (size_t)wid*F32S;
                const float* tu = TU + (size_t)b*F32S;
#pragma unroll
                for (int g=0; g<2; g++){
                    int col = col0 + wn*32 + g*16 + (lane & 15);
                    if (col < Hq)
                        p += fmaxf(acc[f][g][j] + eu[col] + tu[col], 0.f) * Usf[col];
                }
            }
            p += __shfl_xor(p, 1); p += __shfl_xor(p, 2);
            p += __shfl_xor(p, 4); p += __shfl_xor(p, 8);
            if ((lane & 15) == 0 && i < ns) atomicAdd(&ss[i], p);
        }
    }
}

__global__ void stopfin_k(const int* __restrict__ ns_, const int* __restrict__ lists,
    const float* __restrict__ ss, const float* __restrict__ bUs,
    const int* __restrict__ direction, float* __restrict__ accv)
{
    const int ns = *ns_;
    int i = blockIdx.x*256 + threadIdx.x;
    float bce = 0.f, hit = 0.f, c = 0.f;
    if (i < ns){
        int gr = lists[i];
        float s = ss[i] + bUs[0];
        float stgt = (gr < TBq) ? (float)direction[gr] : 0.f;
        bce = fmaxf(s,0.f) - s*stgt + log1pf(__expf(-fabsf(s)));
        hit = ((((s >= 0.f) ? 1.f : 0.f) == stgt) ? 1.f : 0.f);
        c = 1.f;
    }
    for (int off=32; off; off>>=1){
        bce += __shfl_down(bce, off);
        hit += __shfl_down(hit, off);
        c   += __shfl_down(c,   off);
    }
    if ((threadIdx.x & 63) == 0 && c != 0.f){
        atomicAdd(&accv[3], bce);
        atomicAdd(&accv[4], hit);
        atomicAdd(&accv[5], c);
    }
}

__global__ void finalize_k(const float* __restrict__ accv, float* __restrict__ out){
    if (threadIdx.x == 0){
        out[0] = accv[0] / (float)Bq;
        out[1] = accv[3] / (float)Bq;
        out[2] = accv[1] / accv[2];
        out[3] = accv[4] / accv[5];
    }
}

extern "C" void kernel_launch(void* const* d_in, const int* in_sizes, int n_in,
                              void* d_out, int out_size, void* d_ws, size_t ws_size,
                              hipStream_t stream) {
    (void)in_sizes; (void)n_in; (void)out_size; (void)ws_size;
    const float* tree_vecs = (const float*)d_in[0];
    const int*   x_wid     = (const int*)d_in[1];
    const int*   pred_wid  = (const int*)d_in[2];
    const int*   root_wid  = (const int*)d_in[3];
    const int*   h_nei_idx = (const int*)d_in[4];
    const int*   o_nei_idx = (const int*)d_in[5];
    const int*   root_o_nei= (const int*)d_in[6];
    const int*   valid     = (const int*)d_in[7];
    const int*   direction = (const int*)d_in[8];
    const float* emb       = (const float*)d_in[9];
    const float* Wz        = (const float*)d_in[10];
    const float* bz        = (const float*)d_in[11];
    const float* Wr        = (const float*)d_in[12];
    const float* br        = (const float*)d_in[13];
    const float* Ur        = (const float*)d_in[14];
    const float* Wh        = (const float*)d_in[15];
    const float* bh        = (const float*)d_in[16];
    const float* Wm        = (const float*)d_in[17];
    const float* bW        = (const float*)d_in[18];
    const float* U         = (const float*)d_in[19];
    const float* bU        = (const float*)d_in[20];
    const float* Wo        = (const float*)d_in[21];
    const float* bWo       = (const float*)d_in[22];
    const float* Us        = (const float*)d_in[23];
    const float* bUs       = (const float*)d_in[24];

    char* w = (char*)d_ws; size_t off = 0;
    auto alloc = [&](size_t bytes)->void*{ void* p = w + off; off += (bytes + 255) & ~(size_t)255; return p; };

    ushort* hbuf  = (ushort*)alloc((size_t)Sq*HP*2);
    ushort* uhbuf = (ushort*)alloc((size_t)Sq*HP*2);
    ushort* embb  = (ushort*)alloc((size_t)896*HP*2);
    ushort* treeb = (ushort*)alloc((size_t)Bq*64*2);
    ushort* WzX   = (ushort*)alloc((size_t)512*HP*2);
    ushort* WzS   = (ushort*)alloc((size_t)512*HP*2);
    ushort* WrB   = (ushort*)alloc((size_t)512*HP*2);
    ushort* WhX   = (ushort*)alloc((size_t)512*HP*2);
    ushort* WhG   = (ushort*)alloc((size_t)512*HP*2);
    ushort* UrB   = (ushort*)alloc((size_t)512*HP*2);
    ushort* WHp   = (ushort*)alloc((size_t)512*HP*2);
    ushort* UXp   = (ushort*)alloc((size_t)512*HP*2);
    ushort* UOp   = (ushort*)alloc((size_t)512*HP*2);
    ushort* WOp   = (ushort*)alloc((size_t)832*HP*2);
    ushort* WLp   = (ushort*)alloc((size_t)512*64*2);
    ushort* ULp   = (ushort*)alloc((size_t)512*64*2);
    float*  EZ    = (float*)alloc((size_t)Vq*F32S*4);
    float*  ER    = (float*)alloc((size_t)Vq*F32S*4);
    float*  EH    = (float*)alloc((size_t)Vq*F32S*4);
    float*  EU    = (float*)alloc((size_t)Vq*F32S*4);
    float*  TP    = (float*)alloc((size_t)Bq*F32S*4);
    float*  TU    = (float*)alloc((size_t)Bq*F32S*4);
    ushort* sumh  = (ushort*)alloc((size_t)Bq*HP*2);
    ushort* gated = (ushort*)alloc((size_t)Bq*HP*2);
    ushort* nh    = (ushort*)alloc((size_t)Bq*HP*2);
    ushort* pv    = (ushort*)alloc((size_t)NPCAP*HP*2);
    float*  scores= (float*)alloc((size_t)CH2*832*4);
    float*  ss    = (float*)alloc((size_t)NSCAP*4);
    int*    listp = (int*)alloc((size_t)NPCAP*4);
    int*    lists = (int*)alloc((size_t)NSCAP*4);
    int*    meta  = (int*)alloc((size_t)(NPB*4 + 2 + 2 + 16)*4);
    int*    cnts  = meta;            // [2*NPB]
    int*    offs  = meta + 2*NPB;    // [2*NPB]
    int*    tot   = meta + 4*NPB;    // [2]
    int*    bar   = meta + 4*NPB + 2;// [2]
    float*  accv  = (float*)(meta + 4*NPB + 4);
    ushort* curo  = pv;              // stop phase reuses pv/scores region

    hipMemsetAsync(hbuf,  0, (size_t)Sq*HP*2, stream);
    hipMemsetAsync(nh,    0, (size_t)Bq*HP*2, stream);
    hipMemsetAsync(ss,    0, (size_t)NSCAP*4, stream);
    hipMemsetAsync(meta,  0, (size_t)(NPB*4 + 2 + 2 + 16)*4, stream);

    // ---- conversions (1 launch) ----
    convAll_k<<<dim3(896,14), 128, 0, stream>>>(
        emb, tree_vecs, Wz, Wr, Ur, Wh, Wm, U, Wo,
        embb, treeb, WzX, WzS, WrB, WhX, WhG, UrB, WHp, UXp, UOp, WOp, WLp, ULp);

    // ---- precomputes (2 launches) ----
    preE_k<<<dim3(8,7,4), 256, 0, stream>>>(embb, WzX, WrB, WhX, UXp,
                                            bz, br, bh, bU, EZ, ER, EH, EU);
    preT_k<<<dim3(8,4,2), 256, 0, stream>>>(treeb, WLp, ULp, bW, TP, TU);

    // ---- row compaction ----
    cnt_k <<<dim3(NPB,2), 256, 0, stream>>>(valid, direction, cnts);
    scan_k<<<1, 64, 0, stream>>>(cnts, offs, tot);
    fill_k<<<dim3(NPB,2), 256, 0, stream>>>(valid, direction, offs, listp, lists);

    // ---- persistent scan: 1 launch, 64 steps, 256 blocks ----
    scan_coop<<<NBLK, 256, 0, stream>>>(x_wid, h_nei_idx, valid, ER, EZ, EH,
                                        WzS, WhG, UrB, hbuf, uhbuf,
                                        sumh, gated, nh, bar);

    // ---- pred phase (compacted) ----
    pred1c_k<<<dim3(8, NPCAP/128), 256, 0, stream>>>(tot, listp, hbuf, TP, WHp, pv);
    for (int c=0; c<NCH2; c++){
        int cs = c*CH2;
        pred2c_k<<<dim3(13, CH2/128), 256, 0, stream>>>(cs, tot, pv, WOp, bWo, scores);
        predred_k<<<256, 256, 0, stream>>>(cs, tot, listp, scores, pred_wid, root_wid, accv);
    }

    // ---- stop phase (compacted) ----
    curo_c<<<NSCAP, 128, 0, stream>>>(tot+1, lists, o_nei_idx, root_o_nei, hbuf, curo);
    stopc_k<<<dim3(8, NSCAP/128), 256, 0, stream>>>(tot+1, lists, x_wid, root_wid,
                                                    curo, UOp, EU, TU, Us, ss);
    stopfin_k<<<NSCAP/256, 256, 0, stream>>>(tot+1, lists, ss, bUs, direction, accv);

    finalize_k<<<1, 64, 0, stream>>>(accv, (float*)d_out);
}

// Round 10
// 4336.103 us; speedup vs baseline: 1.3082x; 1.3082x over previous
//
#include <hip/hip_runtime.h>
#include <math.h>

#define Bq 512
#define Tq 64
#define Hq 450
#define Lq 56
#define Vq 780
#define Mq 8
#define TBq 32768
#define Sq 32770
#define HP 480          // bf16 row stride (mult of 32)
#define F32S 464        // f32 row stride
#define NPB 130         // 130*256 = 33280 rows
#define NPCAP 12288     // compacted pred rows cap
#define NSCAP 20480     // compacted stop rows cap
#define CH2 4096        // pred score chunk rows
#define NCH2 3
#define SLAB 16         // rows per step_k block

using bf16x8 = __attribute__((ext_vector_type(8))) __bf16;
using f32x4  = __attribute__((ext_vector_type(4))) float;
using u32x4  = __attribute__((ext_vector_type(4))) unsigned;

__device__ __forceinline__ ushort f2bf(float f){
    union { float f; unsigned u; } c; c.f = f;
    unsigned u = c.u;
    return (ushort)((u + 0x7FFFu + ((u >> 16) & 1u)) >> 16);
}
__device__ __forceinline__ float bf2f(ushort h){
    union { unsigned u; float f; } c; c.u = ((unsigned)h) << 16;
    return c.f;
}
__device__ __forceinline__ unsigned pk2(float a, float b){
    return (unsigned)f2bf(a) | ((unsigned)f2bf(b) << 16);
}
__device__ __forceinline__ float sigmf(float x){
    return __builtin_amdgcn_rcpf(1.f + __expf(-x));
}
__device__ __forceinline__ float tanhfast(float x){
    float e2 = __expf(2.f * x);
    return 1.f - 2.f * __builtin_amdgcn_rcpf(e2 + 1.f);
}

// ---------- fused converter: 14 jobs by blockIdx.y ----------
__global__ void convAll_k(
    const float* __restrict__ emb, const float* __restrict__ tree,
    const float* __restrict__ Wz, const float* __restrict__ Wr,
    const float* __restrict__ Ur, const float* __restrict__ Wh,
    const float* __restrict__ Wm, const float* __restrict__ U, const float* __restrict__ Wo,
    ushort* embb, ushort* treeb, ushort* WzX, ushort* WzS, ushort* WrB,
    ushort* WhX, ushort* WhG, ushort* UrB, ushort* WHp, ushort* UXp,
    ushort* UOp, ushort* WOp, ushort* WLp, ushort* ULp)
{
    int job = blockIdx.y, n = blockIdx.x;
    const float* src; ushort* dst; int Npad, Nsrc, Ksrc, Kpad, len, off;
    switch(job){
      case 0:  src=emb;  dst=embb; Npad=896; Nsrc=780; Ksrc=450; Kpad=480; len=450; off=0;   break;
      case 1:  src=tree; dst=treeb;Npad=512; Nsrc=512; Ksrc=56;  Kpad=64;  len=56;  off=0;   break;
      case 2:  src=Wz;   dst=WzX;  Npad=512; Nsrc=450; Ksrc=900; Kpad=480; len=450; off=0;   break;
      case 3:  src=Wz;   dst=WzS;  Npad=512; Nsrc=450; Ksrc=900; Kpad=480; len=450; off=450; break;
      case 4:  src=Wr;   dst=WrB;  Npad=512; Nsrc=450; Ksrc=450; Kpad=480; len=450; off=0;   break;
      case 5:  src=Wh;   dst=WhX;  Npad=512; Nsrc=450; Ksrc=900; Kpad=480; len=450; off=0;   break;
      case 6:  src=Wh;   dst=WhG;  Npad=512; Nsrc=450; Ksrc=900; Kpad=480; len=450; off=450; break;
      case 7:  src=Ur;   dst=UrB;  Npad=512; Nsrc=450; Ksrc=450; Kpad=480; len=450; off=0;   break;
      case 8:  src=Wm;   dst=WHp;  Npad=512; Nsrc=450; Ksrc=506; Kpad=480; len=450; off=0;   break;
      case 9:  src=U;    dst=UXp;  Npad=512; Nsrc=450; Ksrc=956; Kpad=480; len=450; off=0;   break;
      case 10: src=U;    dst=UOp;  Npad=512; Nsrc=450; Ksrc=956; Kpad=480; len=450; off=450; break;
      case 11: src=Wo;   dst=WOp;  Npad=832; Nsrc=780; Ksrc=450; Kpad=480; len=450; off=0;   break;
      case 12: src=Wm;   dst=WLp;  Npad=512; Nsrc=450; Ksrc=506; Kpad=64;  len=56;  off=450; break;
      default: src=U;    dst=ULp;  Npad=512; Nsrc=450; Ksrc=956; Kpad=64;  len=56;  off=900; break;
    }
    if (n >= Npad) return;
    for (int k = threadIdx.x; k < Kpad; k += blockDim.x){
        float v = 0.f;
        if (n < Nsrc && k < len) v = src[(size_t)n*Ksrc + off + k];
        dst[(size_t)n*Kpad + k] = f2bf(v);
    }
}

// ---------- double-buffered MFMA GEMM body: C(128x64) tile ----------
template<class APtr>
__device__ __forceinline__ void mgemm2(APtr&& aptr, const ushort* __restrict__ Bw, int ldb,
                                       int KT, int col0, f32x4 acc[4][2])
{
    __shared__ __align__(16) char As[2][128*80];
    __shared__ __align__(16) char Bs[2][64*80];
    const int tid = threadIdx.x;
    const int lane = tid & 63;
    const int w = tid >> 6, wm = w >> 1, wn = w & 1;
    const int ac = (tid & 3) * 8;
    const size_t boff = (size_t)(col0 + (tid >> 2)) * ldb;
    u32x4 ra0, ra1, rb;
    auto ld = [&](int k0){
        ra0 = *(const u32x4*)(aptr(0, k0) + ac);
        ra1 = *(const u32x4*)(aptr(1, k0) + ac);
        rb  = *(const u32x4*)(Bw + boff + k0 + ac);
    };
    const int wr_a0 = (tid>>2)*80 + (tid&3)*16;
    const int wr_a1 = ((tid>>2)+64)*80 + (tid&3)*16;
    const int wr_b  = (tid>>2)*80 + (tid&3)*16;
    const int rd_a  = (wm*64 + (lane&15))*80 + (lane>>4)*16;
    const int rd_b  = (wn*32 + (lane&15))*80 + (lane>>4)*16;
    ld(0);
    *(u32x4*)(As[0]+wr_a0) = ra0; *(u32x4*)(As[0]+wr_a1) = ra1; *(u32x4*)(Bs[0]+wr_b) = rb;
#pragma unroll
    for (int f=0;f<4;f++)
#pragma unroll
        for (int g=0;g<2;g++) acc[f][g] = (f32x4){0.f,0.f,0.f,0.f};
    __syncthreads();
    for (int kt=0; kt<KT; ++kt){
        const int cur = kt & 1;
        if (kt+1 < KT) ld((kt+1)*32);
        bf16x8 bF[2];
#pragma unroll
        for (int g=0; g<2; g++) bF[g] = *(const bf16x8*)(Bs[cur] + rd_b + g*16*80);
#pragma unroll
        for (int f=0; f<4; f++){
            bf16x8 aF = *(const bf16x8*)(As[cur] + rd_a + f*16*80);
#pragma unroll
            for (int g=0; g<2; g++)
                acc[f][g] = __builtin_amdgcn_mfma_f32_16x16x32_bf16(aF, bF[g], acc[f][g], 0, 0, 0);
        }
        if (kt+1 < KT){
            *(u32x4*)(As[cur^1]+wr_a0) = ra0; *(u32x4*)(As[cur^1]+wr_a1) = ra1;
            *(u32x4*)(Bs[cur^1]+wr_b) = rb;
        }
        __syncthreads();
    }
}

#define EPI_PRE  const int lane = threadIdx.x & 63; const int w_ = threadIdx.x >> 6; \
                 const int wm = w_ >> 1, wn = w_ & 1;

// ---------- precompute GEMM body ----------
__device__ __forceinline__ void pre_body(const ushort* __restrict__ A, int lda,
    const ushort* __restrict__ Bw, const float* __restrict__ bias,
    float* __restrict__ out, int Mr, int KT)
{
    const int row0 = blockIdx.y*128, col0 = blockIdx.x*64;
    const int tid = threadIdx.x;
    const ushort* p0 = A + (size_t)(row0 + (tid>>2))*lda;
    const ushort* p1 = p0 + (size_t)64*lda;
    f32x4 acc[4][2];
    mgemm2([&](int which,int k0){ return (which?p1:p0)+k0; }, Bw, lda, KT, col0, acc);
    EPI_PRE
#pragma unroll
    for (int f=0; f<4; f++)
#pragma unroll
      for (int g=0; g<2; g++){
        int col = col0 + wn*32 + g*16 + (lane & 15);
        if (col >= F32S) continue;
        float bb = 0.f;
        if (col < Hq && bias) bb = bias[col];
#pragma unroll
        for (int j=0; j<4; j++){
            int row = row0 + wm*64 + f*16 + ((lane>>4)<<2) + j;
            if (row < Mr) out[(size_t)row*F32S + col] = (col < Hq) ? acc[f][g][j] + bb : 0.f;
        }
      }
}

__global__ __launch_bounds__(256) void preE_k(
    const ushort* __restrict__ embb,
    const ushort* __restrict__ WzX, const ushort* __restrict__ WrB,
    const ushort* __restrict__ WhX, const ushort* __restrict__ UXp,
    const float* __restrict__ bz, const float* __restrict__ br,
    const float* __restrict__ bh, const float* __restrict__ bU,
    float* __restrict__ EZ, float* __restrict__ ER,
    float* __restrict__ EH, float* __restrict__ EU)
{
    const ushort* Bw; const float* bias; float* out;
    switch(blockIdx.z){
      case 0:  Bw=WzX; bias=bz; out=EZ; break;
      case 1:  Bw=WrB; bias=br; out=ER; break;
      case 2:  Bw=WhX; bias=bh; out=EH; break;
      default: Bw=UXp; bias=bU; out=EU; break;
    }
    pre_body(embb, HP, Bw, bias, out, Vq, 15);
}

__global__ __launch_bounds__(256) void preT_k(
    const ushort* __restrict__ treeb,
    const ushort* __restrict__ WLp, const ushort* __restrict__ ULp,
    const float* __restrict__ bW, float* __restrict__ TP, float* __restrict__ TU)
{
    const ushort* Bw = blockIdx.z ? ULp : WLp;
    const float* bias = blockIdx.z ? nullptr : bW;
    float* out = blockIdx.z ? TU : TP;
    pre_body(treeb, 64, Bw, bias, out, Bq, 2);
}

// ---------- compaction: count / scan / fill ----------
__device__ __forceinline__ bool cmask(int which, int gr,
    const int* __restrict__ valid, const int* __restrict__ dir)
{
    if (which == 0) return (gr < Bq) ? true : (valid[gr-Bq] && dir[gr-Bq]);
    return (gr < TBq) ? (valid[gr] != 0) : true;
}
__global__ void cnt_k(const int* __restrict__ valid, const int* __restrict__ dir,
                      int* __restrict__ cnts)
{
    int which = blockIdx.y;
    int gr = blockIdx.x*256 + threadIdx.x;
    bool m = cmask(which, gr, valid, dir);
    unsigned long long bal = __ballot(m);
    if ((threadIdx.x & 63) == 0)
        atomicAdd(&cnts[which*NPB + blockIdx.x], (int)__popcll(bal));
}
__global__ void scan_k(const int* __restrict__ cnts, int* __restrict__ offs,
                       int* __restrict__ totals)
{
    if (threadIdx.x == 0){
        int a = 0;
        for (int i=0;i<NPB;i++){ offs[i] = a; a += cnts[i]; }
        totals[0] = a;
        int b = 0;
        for (int i=0;i<NPB;i++){ offs[NPB+i] = b; b += cnts[NPB+i]; }
        totals[1] = b;
    }
}
__global__ void fill_k(const int* __restrict__ valid, const int* __restrict__ dir,
                       const int* __restrict__ offs, int* __restrict__ listp,
                       int* __restrict__ lists)
{
    __shared__ int woff[4];
    int which = blockIdx.y;
    int gr = blockIdx.x*256 + threadIdx.x;
    bool m = cmask(which, gr, valid, dir);
    unsigned long long bal = __ballot(m);
    int lane = threadIdx.x & 63, wv = threadIdx.x >> 6;
    if (lane == 0) woff[wv] = (int)__popcll(bal);
    __syncthreads();
    int prev = 0;
    for (int i=0;i<wv;i++) prev += woff[i];
    if (m){
        int rank = prev + (int)__popcll(bal & ((1ull << lane) - 1ull));
        int pos = offs[which*NPB + blockIdx.x] + rank;
        if (which == 0){ if (pos < NPCAP) listp[pos] = gr; }
        else           { if (pos < NSCAP) lists[pos] = gr; }
    }
}

// ---------- fused scan step: one launch per t, NO grid barrier ----------
// Each block owns a 16-row slab and computes ALL 512 output cols for it:
// gather -> LDS; twin GEMM + blend -> nh in LDS (+hbuf); Ur GEMM -> uhbuf.
// Cross-step coherence comes from kernel launch boundaries. LDS rows are
// 1024B with 16B-slot XOR swizzle (byte ^= (row&7)<<4) for conflict-free
// ds_read_b128 (G4).
__global__ __launch_bounds__(256, 1) void step_k(int t,
    const int* __restrict__ x_wid, const int* __restrict__ h_nei_idx,
    const int* __restrict__ valid,
    const float* __restrict__ ER, const float* __restrict__ EZ, const float* __restrict__ EH,
    const ushort* __restrict__ WzS, const ushort* __restrict__ WhG, const ushort* __restrict__ UrB,
    ushort* __restrict__ hbuf, ushort* __restrict__ uhbuf)
{
    __shared__ __align__(16) char sumhL[SLAB*1024];
    __shared__ __align__(16) char gatedL[SLAB*1024];
    __shared__ __align__(16) char nhL[SLAB*1024];
    const int tid = threadIdx.x, lane = tid & 63, wv = tid >> 6;
    const int R0 = blockIdx.x * SLAB;

    // ---- phase A: gather own-slab sum_h & gated into LDS ----
    for (int task = tid; task < SLAB*60; task += 256){
        const int r = task / 60;
        const int c = task - r*60;
        const int j0 = c*8;
        u32x4 so, go;
        if (c < 57){
            const int base = t*Bq + R0 + r;
            const int wid = x_wid[base];
            const int* ip = h_nei_idx + (size_t)base*Mq;
            int idx[Mq];
#pragma unroll
            for (int m=0;m<Mq;m++) idx[m] = ip[m];
            float er[8];
            { const float* erp = ER + (size_t)wid*F32S + j0;
              float4 e0 = *(const float4*)erp, e1 = *(const float4*)(erp+4);
              er[0]=e0.x;er[1]=e0.y;er[2]=e0.z;er[3]=e0.w;
              er[4]=e1.x;er[5]=e1.y;er[6]=e1.z;er[7]=e1.w; }
            float sh[8] = {0,0,0,0,0,0,0,0};
            float gt[8] = {0,0,0,0,0,0,0,0};
#pragma unroll
            for (int m=0;m<Mq;m++){
                u32x4 hv = *(const u32x4*)(hbuf  + (size_t)idx[m]*HP + j0);
                u32x4 uv = *(const u32x4*)(uhbuf + (size_t)idx[m]*HP + j0);
#pragma unroll
                for (int e=0;e<8;e++){
                    float h = bf2f((ushort)((hv[e>>1] >> ((e&1)*16)) & 0xffff));
                    float u = bf2f((ushort)((uv[e>>1] >> ((e&1)*16)) & 0xffff));
                    sh[e] += h;
                    gt[e] += h * sigmf(er[e] + u);
                }
            }
            so[0]=pk2(sh[0],sh[1]); so[1]=pk2(sh[2],sh[3]);
            so[2]=pk2(sh[4],sh[5]); so[3]=pk2(sh[6],sh[7]);
            go[0]=pk2(gt[0],gt[1]); go[1]=pk2(gt[2],gt[3]);
            go[2]=pk2(gt[4],gt[5]); go[3]=pk2(gt[6],gt[7]);
        } else {
            so = (u32x4){0,0,0,0}; go = (u32x4){0,0,0,0};
        }
        const int off = (c*16) ^ ((r&7)<<4);
        *(u32x4*)(sumhL  + r*1024 + off) = so;
        *(u32x4*)(gatedL + r*1024 + off) = go;
    }
    __syncthreads();

    // ---- phase B: twin 16x512 GEMM (K=480) + GRU blend ----
    const int arow = lane & 15;     // A row / output col-within-tile
    const int kh = lane >> 4;       // k-half group / output row group
    f32x4 accZ[8], accH[8];
#pragma unroll
    for (int nt=0; nt<8; ++nt){ accZ[nt]=(f32x4){0,0,0,0}; accH[nt]=(f32x4){0,0,0,0}; }
    for (int kt=0; kt<15; ++kt){
        const int aoff = (kt*64 + kh*16) ^ ((arow&7)<<4);
        bf16x8 aZ = *(const bf16x8*)(sumhL  + arow*1024 + aoff);
        bf16x8 aG = *(const bf16x8*)(gatedL + arow*1024 + aoff);
        const int kb = kt*32 + kh*8;
#pragma unroll
        for (int nt=0; nt<8; ++nt){
            const int col = wv*128 + nt*16 + arow;
            bf16x8 bZ = *(const bf16x8*)(WzS + (size_t)col*HP + kb);
            bf16x8 bG = *(const bf16x8*)(WhG + (size_t)col*HP + kb);
            accZ[nt] = __builtin_amdgcn_mfma_f32_16x16x32_bf16(aZ, bZ, accZ[nt], 0, 0, 0);
            accH[nt] = __builtin_amdgcn_mfma_f32_16x16x32_bf16(aG, bG, accH[nt], 0, 0, 0);
        }
    }
#pragma unroll
    for (int nt=0; nt<8; ++nt){
        const int col = wv*128 + nt*16 + arow;   // C/D: col = lane&15 (+tile), row = kh*4+j
        if (col < 480){
#pragma unroll
            for (int j=0; j<4; j++){
                const int r = kh*4 + j;
                const int base = t*Bq + R0 + r;
                ushort o = 0;
                if (col < Hq){
                    const int wid = x_wid[base];
                    float z  = sigmf(accZ[nt][j] + EZ[(size_t)wid*F32S + col]);
                    float ht = tanhfast(accH[nt][j] + EH[(size_t)wid*F32S + col]);
                    const int sb = col*2;
                    const int soff = r*1024 + ((sb & 0x3F0) ^ ((r&7)<<4)) + (sb & 0xF);
                    float sh = bf2f(*(const ushort*)(sumhL + soff));
                    o = f2bf((1.f - z)*sh + z*ht);
                    if (valid[base]) hbuf[(size_t)(1 + base)*HP + col] = o;
                }
                const int nb = col*2;
                *(ushort*)(nhL + r*1024 + ((nb & 0x3F0) ^ ((r&7)<<4)) + (nb & 0xF)) = o;
            }
        }
    }
    __syncthreads();

    // ---- phase C: uh = nh @ Ur^T (16x512, K=480) ----
    f32x4 accU[8];
#pragma unroll
    for (int nt=0; nt<8; ++nt) accU[nt]=(f32x4){0,0,0,0};
    for (int kt=0; kt<15; ++kt){
        const int aoff = (kt*64 + kh*16) ^ ((arow&7)<<4);
        bf16x8 aN = *(const bf16x8*)(nhL + arow*1024 + aoff);
        const int kb = kt*32 + kh*8;
#pragma unroll
        for (int nt=0; nt<8; ++nt){
            const int col = wv*128 + nt*16 + arow;
            bf16x8 bU = *(const bf16x8*)(UrB + (size_t)col*HP + kb);
            accU[nt] = __builtin_amdgcn_mfma_f32_16x16x32_bf16(aN, bU, accU[nt], 0, 0, 0);
        }
    }
#pragma unroll
    for (int nt=0; nt<8; ++nt){
        const int col = wv*128 + nt*16 + arow;
        if (col < Hq){
#pragma unroll
            for (int j=0; j<4; j++){
                const int r = kh*4 + j;
                const int base = t*Bq + R0 + r;
                if (valid[base]) uhbuf[(size_t)(1 + base)*HP + col] = f2bf(accU[nt][j]);
            }
        }
    }
}

// ---------- pred GEMM1 (compacted rows) ----------
__global__ __launch_bounds__(256) void pred1c_k(const int* __restrict__ np_,
    const int* __restrict__ listp, const ushort* __restrict__ hbuf,
    const float* __restrict__ TP, const ushort* __restrict__ WHp,
    ushort* __restrict__ pv)
{
    const int np = *np_;
    const int row0 = blockIdx.y*128;
    if (row0 >= np) return;
    const int col0 = blockIdx.x*64;
    const int tid = threadIdx.x;
    int i0 = row0 + (tid>>2), i1 = i0 + 64;
    int g0 = (i0 < np) ? listp[i0] : 0;
    int g1 = (i1 < np) ? listp[i1] : 0;
    const ushort* p0 = (g0 < Bq) ? hbuf : hbuf + (size_t)(1 + g0 - Bq)*HP;  // hbuf row0 = zeros
    const ushort* p1 = (g1 < Bq) ? hbuf : hbuf + (size_t)(1 + g1 - Bq)*HP;
    f32x4 acc[4][2];
    mgemm2([&](int which,int k0){ return (which?p1:p0)+k0; }, WHp, HP, 15, col0, acc);
    EPI_PRE
#pragma unroll
    for (int f=0; f<4; f++)
#pragma unroll
      for (int g=0; g<2; g++){
        int col = col0 + wn*32 + g*16 + (lane & 15);
        if (col >= HP) continue;
#pragma unroll
        for (int j=0; j<4; j++){
            int i = row0 + wm*64 + f*16 + ((lane>>4)<<2) + j;
            if (i >= np) continue;
            int gr = listp[i];
            int b = (gr < Bq) ? gr : ((gr - Bq) & (Bq-1));
            float v = 0.f;
            if (col < Hq) v = fmaxf(acc[f][g][j] + TP[(size_t)b*F32S + col], 0.f);
            pv[(size_t)i*HP + col] = f2bf(v);
        }
      }
}

// ---------- pred GEMM2 ----------
__global__ __launch_bounds__(256) void pred2c_k(int cs, const int* __restrict__ np_,
    const ushort* __restrict__ pv, const ushort* __restrict__ WOp,
    const float* __restrict__ bWo, float* __restrict__ scores)
{
    const int np = *np_;
    const int row0 = blockIdx.y*128;
    if (cs + row0 >= np) return;
    const int col0 = blockIdx.x*64;
    const int tid = threadIdx.x;
    const ushort* p0 = pv + (size_t)(cs + row0 + (tid>>2))*HP;
    const ushort* p1 = p0 + (size_t)64*HP;
    f32x4 acc[4][2];
    mgemm2([&](int which,int k0){ return (which?p1:p0)+k0; }, WOp, HP, 15, col0, acc);
    EPI_PRE
#pragma unroll
    for (int f=0; f<4; f++)
#pragma unroll
      for (int g=0; g<2; g++){
        int col = col0 + wn*32 + g*16 + (lane & 15);
        if (col >= Vq) continue;
        float bc = bWo[col];
#pragma unroll
        for (int j=0; j<4; j++){
            int r = row0 + wm*64 + f*16 + ((lane>>4)<<2) + j;
            scores[(size_t)r*832 + col] = acc[f][g][j] + bc;
        }
      }
}

// ---------- pred reduce: wave-per-row ----------
__global__ __launch_bounds__(256) void predred_k(int cs, const int* __restrict__ np_,
    const int* __restrict__ listp, const float* __restrict__ scores,
    const int* __restrict__ pred_wid, const int* __restrict__ root_wid,
    float* __restrict__ accv)
{
    const int np = *np_;
    int nrows = np - cs; if (nrows > CH2) nrows = CH2;
    const int lane = threadIdx.x & 63, wv = threadIdx.x >> 6;
    const int wid_g = blockIdx.x*4 + wv, nw = gridDim.x*4;
    float ce = 0.f, hit = 0.f, cnt = 0.f;
    for (int r = wid_g; r < nrows; r += nw){
        const float* sc = scores + (size_t)r*832;
        int gr = listp[cs + r];
        int tgt = (gr < Bq) ? root_wid[gr] : pred_wid[gr - Bq];
        float vals[13];
        float bv = -INFINITY, tv = 0.f; int bi = 0;
#pragma unroll
        for (int q=0; q<13; q++){
            int j = lane + q*64;
            float v = (j < Vq) ? sc[j] : -INFINITY;
            vals[q] = v;
            if (v > bv){ bv = v; bi = j; }
            if (j == tgt) tv = v;
        }
#pragma unroll
        for (int off=32; off; off>>=1){
            float ov = __shfl_xor(bv, off); int oi = __shfl_xor(bi, off);
            if (ov > bv || (ov == bv && oi < bi)){ bv = ov; bi = oi; }
        }
        float s = 0.f;
#pragma unroll
        for (int q=0; q<13; q++){
            int j = lane + q*64;
            if (j < Vq) s += __expf(vals[q] - bv);
        }
#pragma unroll
        for (int off=32; off; off>>=1) s += __shfl_xor(s, off);
#pragma unroll
        for (int off=32; off; off>>=1) tv += __shfl_xor(tv, off);
        if (lane == 0){
            ce += bv + logf(s) - tv;
            hit += (bi == tgt) ? 1.f : 0.f;
            cnt += 1.f;
        }
    }
    __shared__ float L[3][4];
    if (lane == 0){ L[0][wv] = ce; L[1][wv] = hit; L[2][wv] = cnt; }
    __syncthreads();
    if (threadIdx.x == 0){
        float a = L[0][0]+L[0][1]+L[0][2]+L[0][3];
        float b = L[1][0]+L[1][1]+L[1][2]+L[1][3];
        float c = L[2][0]+L[2][1]+L[2][2]+L[2][3];
        if (c != 0.f){
            atomicAdd(&accv[0], a);
            atomicAdd(&accv[1], b);
            atomicAdd(&accv[2], c);
        }
    }
}

// ---------- stop: cur_o gather (compacted) ----------
__global__ void curo_c(const int* __restrict__ ns_, const int* __restrict__ lists,
                       const int* __restrict__ o_nei_idx, const int* __restrict__ root_o_nei,
                       const ushort* __restrict__ hbuf, ushort* __restrict__ curo)
{
    int i = blockIdx.x;
    if (i >= *ns_) return;
    int gr = lists[i];
    int j0 = threadIdx.x * 4;
    if (j0 >= HP) return;
    int idx[Mq];
    if (gr < TBq){
        int tt = gr >> 9;
#pragma unroll
        for (int m=0;m<Mq;m++){
            int ix = o_nei_idx[(size_t)gr*Mq + m];
            idx[m] = (ix <= tt*Bq) ? ix : 0;   // slots written before step tt; row 0 is zero
        }
    } else {
#pragma unroll
        for (int m=0;m<Mq;m++) idx[m] = root_o_nei[(size_t)(gr-TBq)*Mq + m];
    }
    float s0=0,s1=0,s2=0,s3=0;
#pragma unroll
    for (int m=0;m<Mq;m++){
        uint2 v = *(const uint2*)(hbuf + (size_t)idx[m]*HP + j0);
        s0 += bf2f((ushort)(v.x & 0xffff)); s1 += bf2f((ushort)(v.x >> 16));
        s2 += bf2f((ushort)(v.y & 0xffff)); s3 += bf2f((ushort)(v.y >> 16));
    }
    uint2 o; o.x = pk2(s0, s1); o.y = pk2(s2, s3);
    *(uint2*)(curo + (size_t)i*HP + j0) = o;
}

// ---------- stop GEMM (compacted) + fused Us-dot ----------
__global__ __launch_bounds__(256) void stopc_k(const int* __restrict__ ns_,
    const int* __restrict__ lists, const int* __restrict__ x_wid,
    const int* __restrict__ root_wid, const ushort* __restrict__ curo,
    const ushort* __restrict__ UOp, const float* __restrict__ EU,
    const float* __restrict__ TU, const float* __restrict__ Usf,
    float* __restrict__ ss)
{
    const int ns = *ns_;
    const int row0 = blockIdx.y*128;
    if (row0 >= ns) return;
    const int col0 = blockIdx.x*64;
    const int tid = threadIdx.x;
    const ushort* p0 = curo + (size_t)(row0 + (tid>>2))*HP;
    const ushort* p1 = p0 + (size_t)64*HP;
    f32x4 acc[4][2];
    mgemm2([&](int which,int k0){ return (which?p1:p0)+k0; }, UOp, HP, 15, col0, acc);
    EPI_PRE
#pragma unroll
    for (int f=0; f<4; f++){
#pragma unroll
        for (int j=0; j<4; j++){
            int i = row0 + wm*64 + f*16 + ((lane>>4)<<2) + j;
            float p = 0.f;
            if (i < ns){
                int gr = lists[i];
                int wid = (gr < TBq) ? x_wid[gr] : root_wid[gr - TBq];
                int b   = (gr < TBq) ? (gr & (Bq-1)) : (gr - TBq);
                const float* eu = EU + (size_t)wid*F32S;
                const float* tu = TU + (size_t)b*F32S;
#pragma unroll
                for (int g=0; g<2; g++){
                    int col = col0 + wn*32 + g*16 + (lane & 15);
                    if (col < Hq)
                        p += fmaxf(acc[f][g][j] + eu[col] + tu[col], 0.f) * Usf[col];
                }
            }
            p += __shfl_xor(p, 1); p += __shfl_xor(p, 2);
            p += __shfl_xor(p, 4); p += __shfl_xor(p, 8);
            if ((lane & 15) == 0 && i < ns) atomicAdd(&ss[i], p);
        }
    }
}

__global__ void stopfin_k(const int* __restrict__ ns_, const int* __restrict__ lists,
    const float* __restrict__ ss, const float* __restrict__ bUs,
    const int* __restrict__ direction, float* __restrict__ accv)
{
    const int ns = *ns_;
    int i = blockIdx.x*256 + threadIdx.x;
    float bce = 0.f, hit = 0.f, c = 0.f;
    if (i < ns){
        int gr = lists[i];
        float s = ss[i] + bUs[0];
        float stgt = (gr < TBq) ? (float)direction[gr] : 0.f;
        bce = fmaxf(s,0.f) - s*stgt + log1pf(__expf(-fabsf(s)));
        hit = ((((s >= 0.f) ? 1.f : 0.f) == stgt) ? 1.f : 0.f);
        c = 1.f;
    }
    for (int off=32; off; off>>=1){
        bce += __shfl_down(bce, off);
        hit += __shfl_down(hit, off);
        c   += __shfl_down(c,   off);
    }
    if ((threadIdx.x & 63) == 0 && c != 0.f){
        atomicAdd(&accv[3], bce);
        atomicAdd(&accv[4], hit);
        atomicAdd(&accv[5], c);
    }
}

__global__ void finalize_k(const float* __restrict__ accv, float* __restrict__ out){
    if (threadIdx.x == 0){
        out[0] = accv[0] / (float)Bq;
        out[1] = accv[3] / (float)Bq;
        out[2] = accv[1] / accv[2];
        out[3] = accv[4] / accv[5];
    }
}

extern "C" void kernel_launch(void* const* d_in, const int* in_sizes, int n_in,
                              void* d_out, int out_size, void* d_ws, size_t ws_size,
                              hipStream_t stream) {
    (void)in_sizes; (void)n_in; (void)out_size; (void)ws_size;
    const float* tree_vecs = (const float*)d_in[0];
    const int*   x_wid     = (const int*)d_in[1];
    const int*   pred_wid  = (const int*)d_in[2];
    const int*   root_wid  = (const int*)d_in[3];
    const int*   h_nei_idx = (const int*)d_in[4];
    const int*   o_nei_idx = (const int*)d_in[5];
    const int*   root_o_nei= (const int*)d_in[6];
    const int*   valid     = (const int*)d_in[7];
    const int*   direction = (const int*)d_in[8];
    const float* emb       = (const float*)d_in[9];
    const float* Wz        = (const float*)d_in[10];
    const float* bz        = (const float*)d_in[11];
    const float* Wr        = (const float*)d_in[12];
    const float* br        = (const float*)d_in[13];
    const float* Ur        = (const float*)d_in[14];
    const float* Wh        = (const float*)d_in[15];
    const float* bh        = (const float*)d_in[16];
    const float* Wm        = (const float*)d_in[17];
    const float* bW        = (const float*)d_in[18];
    const float* U         = (const float*)d_in[19];
    const float* bU        = (const float*)d_in[20];
    const float* Wo        = (const float*)d_in[21];
    const float* bWo       = (const float*)d_in[22];
    const float* Us        = (const float*)d_in[23];
    const float* bUs       = (const float*)d_in[24];

    char* w = (char*)d_ws; size_t off = 0;
    auto alloc = [&](size_t bytes)->void*{ void* p = w + off; off += (bytes + 255) & ~(size_t)255; return p; };

    ushort* hbuf  = (ushort*)alloc((size_t)Sq*HP*2);
    ushort* uhbuf = (ushort*)alloc((size_t)Sq*HP*2);
    ushort* embb  = (ushort*)alloc((size_t)896*HP*2);
    ushort* treeb = (ushort*)alloc((size_t)Bq*64*2);
    ushort* WzX   = (ushort*)alloc((size_t)512*HP*2);
    ushort* WzS   = (ushort*)alloc((size_t)512*HP*2);
    ushort* WrB   = (ushort*)alloc((size_t)512*HP*2);
    ushort* WhX   = (ushort*)alloc((size_t)512*HP*2);
    ushort* WhG   = (ushort*)alloc((size_t)512*HP*2);
    ushort* UrB   = (ushort*)alloc((size_t)512*HP*2);
    ushort* WHp   = (ushort*)alloc((size_t)512*HP*2);
    ushort* UXp   = (ushort*)alloc((size_t)512*HP*2);
    ushort* UOp   = (ushort*)alloc((size_t)512*HP*2);
    ushort* WOp   = (ushort*)alloc((size_t)832*HP*2);
    ushort* WLp   = (ushort*)alloc((size_t)512*64*2);
    ushort* ULp   = (ushort*)alloc((size_t)512*64*2);
    float*  EZ    = (float*)alloc((size_t)Vq*F32S*4);
    float*  ER    = (float*)alloc((size_t)Vq*F32S*4);
    float*  EH    = (float*)alloc((size_t)Vq*F32S*4);
    float*  EU    = (float*)alloc((size_t)Vq*F32S*4);
    float*  TP    = (float*)alloc((size_t)Bq*F32S*4);
    float*  TU    = (float*)alloc((size_t)Bq*F32S*4);
    ushort* pv    = (ushort*)alloc((size_t)NPCAP*HP*2);
    float*  scores= (float*)alloc((size_t)CH2*832*4);
    float*  ss    = (float*)alloc((size_t)NSCAP*4);
    int*    listp = (int*)alloc((size_t)NPCAP*4);
    int*    lists = (int*)alloc((size_t)NSCAP*4);
    int*    meta  = (int*)alloc((size_t)(NPB*4 + 2 + 16)*4);
    int*    cnts  = meta;            // [2*NPB]
    int*    offs  = meta + 2*NPB;    // [2*NPB]
    int*    tot   = meta + 4*NPB;    // [2]
    float*  accv  = (float*)(meta + 4*NPB + 2);
    ushort* curo  = pv;              // stop phase reuses pv/scores region

    (void)hipMemsetAsync(hbuf,  0, (size_t)Sq*HP*2, stream);
    (void)hipMemsetAsync(uhbuf, 0, (size_t)Sq*HP*2, stream);
    (void)hipMemsetAsync(ss,    0, (size_t)NSCAP*4, stream);
    (void)hipMemsetAsync(meta,  0, (size_t)(NPB*4 + 2 + 16)*4, stream);

    // ---- conversions (1 launch) ----
    convAll_k<<<dim3(896,14), 128, 0, stream>>>(
        emb, tree_vecs, Wz, Wr, Ur, Wh, Wm, U, Wo,
        embb, treeb, WzX, WzS, WrB, WhX, WhG, UrB, WHp, UXp, UOp, WOp, WLp, ULp);

    // ---- precomputes (2 launches) ----
    preE_k<<<dim3(8,7,4), 256, 0, stream>>>(embb, WzX, WrB, WhX, UXp,
                                            bz, br, bh, bU, EZ, ER, EH, EU);
    preT_k<<<dim3(8,4,2), 256, 0, stream>>>(treeb, WLp, ULp, bW, TP, TU);

    // ---- row compaction ----
    cnt_k <<<dim3(NPB,2), 256, 0, stream>>>(valid, direction, cnts);
    scan_k<<<1, 64, 0, stream>>>(cnts, offs, tot);
    fill_k<<<dim3(NPB,2), 256, 0, stream>>>(valid, direction, offs, listp, lists);

    // ---- sequential scan: ONE fused kernel per step ----
    for (int t=0; t<Tq; t++)
        step_k<<<Bq/SLAB, 256, 0, stream>>>(t, x_wid, h_nei_idx, valid, ER, EZ, EH,
                                            WzS, WhG, UrB, hbuf, uhbuf);

    // ---- pred phase (compacted) ----
    pred1c_k<<<dim3(8, NPCAP/128), 256, 0, stream>>>(tot, listp, hbuf, TP, WHp, pv);
    for (int c=0; c<NCH2; c++){
        int cs = c*CH2;
        pred2c_k<<<dim3(13, CH2/128), 256, 0, stream>>>(cs, tot, pv, WOp, bWo, scores);
        predred_k<<<256, 256, 0, stream>>>(cs, tot, listp, scores, pred_wid, root_wid, accv);
    }

    // ---- stop phase (compacted) ----
    curo_c<<<NSCAP, 128, 0, stream>>>(tot+1, lists, o_nei_idx, root_o_nei, hbuf, curo);
    stopc_k<<<dim3(8, NSCAP/128), 256, 0, stream>>>(tot+1, lists, x_wid, root_wid,
                                                    curo, UOp, EU, TU, Us, ss);
    stopfin_k<<<NSCAP/256, 256, 0, stream>>>(tot+1, lists, ss, bUs, direction, accv);

    finalize_k<<<1, 64, 0, stream>>>(accv, (float*)d_out);
}

// Round 11
// 3951.523 us; speedup vs baseline: 1.4355x; 1.0973x over previous
//
#include <hip/hip_runtime.h>
#include <math.h>

#define Bq 512
#define Tq 64
#define Hq 450
#define Lq 56
#define Vq 780
#define Mq 8
#define TBq 32768
#define Sq 32770
#define HP 480          // bf16 row stride (mult of 32)
#define F32S 464        // f32 row stride
#define NPB 130         // 130*256 = 33280 rows
#define NPCAP 12288     // compacted pred rows cap
#define NSCAP 20480     // compacted stop rows cap
#define CH2 4096        // pred score chunk rows
#define NCH2 3
#define SLAB 16         // rows per gemm_step_k block

using bf16x8 = __attribute__((ext_vector_type(8))) __bf16;
using f32x4  = __attribute__((ext_vector_type(4))) float;
using u32x4  = __attribute__((ext_vector_type(4))) unsigned;

__device__ __forceinline__ ushort f2bf(float f){
    union { float f; unsigned u; } c; c.f = f;
    unsigned u = c.u;
    return (ushort)((u + 0x7FFFu + ((u >> 16) & 1u)) >> 16);
}
__device__ __forceinline__ float bf2f(ushort h){
    union { unsigned u; float f; } c; c.u = ((unsigned)h) << 16;
    return c.f;
}
__device__ __forceinline__ unsigned pk2(float a, float b){
    return (unsigned)f2bf(a) | ((unsigned)f2bf(b) << 16);
}
__device__ __forceinline__ float sigmf(float x){
    return __builtin_amdgcn_rcpf(1.f + __expf(-x));
}
__device__ __forceinline__ float tanhfast(float x){
    float e2 = __expf(2.f * x);
    return 1.f - 2.f * __builtin_amdgcn_rcpf(e2 + 1.f);
}

// ---------- fused converter: 14 jobs by blockIdx.y ----------
__global__ void convAll_k(
    const float* __restrict__ emb, const float* __restrict__ tree,
    const float* __restrict__ Wz, const float* __restrict__ Wr,
    const float* __restrict__ Ur, const float* __restrict__ Wh,
    const float* __restrict__ Wm, const float* __restrict__ U, const float* __restrict__ Wo,
    ushort* embb, ushort* treeb, ushort* WzX, ushort* WzS, ushort* WrB,
    ushort* WhX, ushort* WhG, ushort* UrB, ushort* WHp, ushort* UXp,
    ushort* UOp, ushort* WOp, ushort* WLp, ushort* ULp)
{
    int job = blockIdx.y, n = blockIdx.x;
    const float* src; ushort* dst; int Npad, Nsrc, Ksrc, Kpad, len, off;
    switch(job){
      case 0:  src=emb;  dst=embb; Npad=896; Nsrc=780; Ksrc=450; Kpad=480; len=450; off=0;   break;
      case 1:  src=tree; dst=treeb;Npad=512; Nsrc=512; Ksrc=56;  Kpad=64;  len=56;  off=0;   break;
      case 2:  src=Wz;   dst=WzX;  Npad=512; Nsrc=450; Ksrc=900; Kpad=480; len=450; off=0;   break;
      case 3:  src=Wz;   dst=WzS;  Npad=512; Nsrc=450; Ksrc=900; Kpad=480; len=450; off=450; break;
      case 4:  src=Wr;   dst=WrB;  Npad=512; Nsrc=450; Ksrc=450; Kpad=480; len=450; off=0;   break;
      case 5:  src=Wh;   dst=WhX;  Npad=512; Nsrc=450; Ksrc=900; Kpad=480; len=450; off=0;   break;
      case 6:  src=Wh;   dst=WhG;  Npad=512; Nsrc=450; Ksrc=900; Kpad=480; len=450; off=450; break;
      case 7:  src=Ur;   dst=UrB;  Npad=512; Nsrc=450; Ksrc=450; Kpad=480; len=450; off=0;   break;
      case 8:  src=Wm;   dst=WHp;  Npad=512; Nsrc=450; Ksrc=506; Kpad=480; len=450; off=0;   break;
      case 9:  src=U;    dst=UXp;  Npad=512; Nsrc=450; Ksrc=956; Kpad=480; len=450; off=0;   break;
      case 10: src=U;    dst=UOp;  Npad=512; Nsrc=450; Ksrc=956; Kpad=480; len=450; off=450; break;
      case 11: src=Wo;   dst=WOp;  Npad=832; Nsrc=780; Ksrc=450; Kpad=480; len=450; off=0;   break;
      case 12: src=Wm;   dst=WLp;  Npad=512; Nsrc=450; Ksrc=506; Kpad=64;  len=56;  off=450; break;
      default: src=U;    dst=ULp;  Npad=512; Nsrc=450; Ksrc=956; Kpad=64;  len=56;  off=900; break;
    }
    if (n >= Npad) return;
    for (int k = threadIdx.x; k < Kpad; k += blockDim.x){
        float v = 0.f;
        if (n < Nsrc && k < len) v = src[(size_t)n*Ksrc + off + k];
        dst[(size_t)n*Kpad + k] = f2bf(v);
    }
}

// ---------- double-buffered MFMA GEMM body: C(128x64) tile ----------
template<class APtr>
__device__ __forceinline__ void mgemm2(APtr&& aptr, const ushort* __restrict__ Bw, int ldb,
                                       int KT, int col0, f32x4 acc[4][2])
{
    __shared__ __align__(16) char As[2][128*80];
    __shared__ __align__(16) char Bs[2][64*80];
    const int tid = threadIdx.x;
    const int lane = tid & 63;
    const int w = tid >> 6, wm = w >> 1, wn = w & 1;
    const int ac = (tid & 3) * 8;
    const size_t boff = (size_t)(col0 + (tid >> 2)) * ldb;
    u32x4 ra0, ra1, rb;
    auto ld = [&](int k0){
        ra0 = *(const u32x4*)(aptr(0, k0) + ac);
        ra1 = *(const u32x4*)(aptr(1, k0) + ac);
        rb  = *(const u32x4*)(Bw + boff + k0 + ac);
    };
    const int wr_a0 = (tid>>2)*80 + (tid&3)*16;
    const int wr_a1 = ((tid>>2)+64)*80 + (tid&3)*16;
    const int wr_b  = (tid>>2)*80 + (tid&3)*16;
    const int rd_a  = (wm*64 + (lane&15))*80 + (lane>>4)*16;
    const int rd_b  = (wn*32 + (lane&15))*80 + (lane>>4)*16;
    ld(0);
    *(u32x4*)(As[0]+wr_a0) = ra0; *(u32x4*)(As[0]+wr_a1) = ra1; *(u32x4*)(Bs[0]+wr_b) = rb;
#pragma unroll
    for (int f=0;f<4;f++)
#pragma unroll
        for (int g=0;g<2;g++) acc[f][g] = (f32x4){0.f,0.f,0.f,0.f};
    __syncthreads();
    for (int kt=0; kt<KT; ++kt){
        const int cur = kt & 1;
        if (kt+1 < KT) ld((kt+1)*32);
        bf16x8 bF[2];
#pragma unroll
        for (int g=0; g<2; g++) bF[g] = *(const bf16x8*)(Bs[cur] + rd_b + g*16*80);
#pragma unroll
        for (int f=0; f<4; f++){
            bf16x8 aF = *(const bf16x8*)(As[cur] + rd_a + f*16*80);
#pragma unroll
            for (int g=0; g<2; g++)
                acc[f][g] = __builtin_amdgcn_mfma_f32_16x16x32_bf16(aF, bF[g], acc[f][g], 0, 0, 0);
        }
        if (kt+1 < KT){
            *(u32x4*)(As[cur^1]+wr_a0) = ra0; *(u32x4*)(As[cur^1]+wr_a1) = ra1;
            *(u32x4*)(Bs[cur^1]+wr_b) = rb;
        }
        __syncthreads();
    }
}

#define EPI_PRE  const int lane = threadIdx.x & 63; const int w_ = threadIdx.x >> 6; \
                 const int wm = w_ >> 1, wn = w_ & 1;

// ---------- precompute GEMM body ----------
__device__ __forceinline__ void pre_body(const ushort* __restrict__ A, int lda,
    const ushort* __restrict__ Bw, const float* __restrict__ bias,
    float* __restrict__ out, int Mr, int KT)
{
    const int row0 = blockIdx.y*128, col0 = blockIdx.x*64;
    const int tid = threadIdx.x;
    const ushort* p0 = A + (size_t)(row0 + (tid>>2))*lda;
    const ushort* p1 = p0 + (size_t)64*lda;
    f32x4 acc[4][2];
    mgemm2([&](int which,int k0){ return (which?p1:p0)+k0; }, Bw, lda, KT, col0, acc);
    EPI_PRE
#pragma unroll
    for (int f=0; f<4; f++)
#pragma unroll
      for (int g=0; g<2; g++){
        int col = col0 + wn*32 + g*16 + (lane & 15);
        if (col >= F32S) continue;
        float bb = 0.f;
        if (col < Hq && bias) bb = bias[col];
#pragma unroll
        for (int j=0; j<4; j++){
            int row = row0 + wm*64 + f*16 + ((lane>>4)<<2) + j;
            if (row < Mr) out[(size_t)row*F32S + col] = (col < Hq) ? acc[f][g][j] + bb : 0.f;
        }
      }
}

__global__ __launch_bounds__(256) void preE_k(
    const ushort* __restrict__ embb,
    const ushort* __restrict__ WzX, const ushort* __restrict__ WrB,
    const ushort* __restrict__ WhX, const ushort* __restrict__ UXp,
    const float* __restrict__ bz, const float* __restrict__ br,
    const float* __restrict__ bh, const float* __restrict__ bU,
    float* __restrict__ EZ, float* __restrict__ ER,
    float* __restrict__ EH, float* __restrict__ EU)
{
    const ushort* Bw; const float* bias; float* out;
    switch(blockIdx.z){
      case 0:  Bw=WzX; bias=bz; out=EZ; break;
      case 1:  Bw=WrB; bias=br; out=ER; break;
      case 2:  Bw=WhX; bias=bh; out=EH; break;
      default: Bw=UXp; bias=bU; out=EU; break;
    }
    pre_body(embb, HP, Bw, bias, out, Vq, 15);
}

__global__ __launch_bounds__(256) void preT_k(
    const ushort* __restrict__ treeb,
    const ushort* __restrict__ WLp, const ushort* __restrict__ ULp,
    const float* __restrict__ bW, float* __restrict__ TP, float* __restrict__ TU)
{
    const ushort* Bw = blockIdx.z ? ULp : WLp;
    const float* bias = blockIdx.z ? nullptr : bW;
    float* out = blockIdx.z ? TU : TP;
    pre_body(treeb, 64, Bw, bias, out, Bq, 2);
}

// ---------- compaction: count / scan / fill ----------
__device__ __forceinline__ bool cmask(int which, int gr,
    const int* __restrict__ valid, const int* __restrict__ dir)
{
    if (which == 0) return (gr < Bq) ? true : (valid[gr-Bq] && dir[gr-Bq]);
    return (gr < TBq) ? (valid[gr] != 0) : true;
}
__global__ void cnt_k(const int* __restrict__ valid, const int* __restrict__ dir,
                      int* __restrict__ cnts)
{
    int which = blockIdx.y;
    int gr = blockIdx.x*256 + threadIdx.x;
    bool m = cmask(which, gr, valid, dir);
    unsigned long long bal = __ballot(m);
    if ((threadIdx.x & 63) == 0)
        atomicAdd(&cnts[which*NPB + blockIdx.x], (int)__popcll(bal));
}
__global__ void scan_k(const int* __restrict__ cnts, int* __restrict__ offs,
                       int* __restrict__ totals)
{
    if (threadIdx.x == 0){
        int a = 0;
        for (int i=0;i<NPB;i++){ offs[i] = a; a += cnts[i]; }
        totals[0] = a;
        int b = 0;
        for (int i=0;i<NPB;i++){ offs[NPB+i] = b; b += cnts[NPB+i]; }
        totals[1] = b;
    }
}
__global__ void fill_k(const int* __restrict__ valid, const int* __restrict__ dir,
                       const int* __restrict__ offs, int* __restrict__ listp,
                       int* __restrict__ lists)
{
    __shared__ int woff[4];
    int which = blockIdx.y;
    int gr = blockIdx.x*256 + threadIdx.x;
    bool m = cmask(which, gr, valid, dir);
    unsigned long long bal = __ballot(m);
    int lane = threadIdx.x & 63, wv = threadIdx.x >> 6;
    if (lane == 0) woff[wv] = (int)__popcll(bal);
    __syncthreads();
    int prev = 0;
    for (int i=0;i<wv;i++) prev += woff[i];
    if (m){
        int rank = prev + (int)__popcll(bal & ((1ull << lane) - 1ull));
        int pos = offs[which*NPB + blockIdx.x] + rank;
        if (which == 0){ if (pos < NPCAP) listp[pos] = gr; }
        else           { if (pos < NSCAP) lists[pos] = gr; }
    }
}

// ---------- scan step part 1: full-machine gather (one task per thread) ----------
// 512 rows x 60 16B-chunks = 30720 tasks over 120 blocks x 256 threads.
// Writes sumh/gated (plain row-major bf16). Coherence across kernels comes
// from launch boundaries.
__global__ __launch_bounds__(256) void gather_k(int t,
    const int* __restrict__ x_wid, const int* __restrict__ h_nei_idx,
    const float* __restrict__ ER,
    const ushort* __restrict__ hbuf, const ushort* __restrict__ uhbuf,
    ushort* __restrict__ sumh, ushort* __restrict__ gated)
{
    const int task = blockIdx.x*256 + threadIdx.x;   // 0..30719
    const int r = task / 60;
    const int c = task - r*60;
    const int j0 = c*8;
    u32x4 so, go;
    if (c < 57){
        const int base = t*Bq + r;
        const int wid = x_wid[base];
        const int* ip = h_nei_idx + (size_t)base*Mq;
        int idx[Mq];
#pragma unroll
        for (int m=0;m<Mq;m++) idx[m] = ip[m];
        float er[8];
        { const float* erp = ER + (size_t)wid*F32S + j0;
          float4 e0 = *(const float4*)erp, e1 = *(const float4*)(erp+4);
          er[0]=e0.x;er[1]=e0.y;er[2]=e0.z;er[3]=e0.w;
          er[4]=e1.x;er[5]=e1.y;er[6]=e1.z;er[7]=e1.w; }
        float sh[8] = {0,0,0,0,0,0,0,0};
        float gt[8] = {0,0,0,0,0,0,0,0};
#pragma unroll
        for (int m=0;m<Mq;m++){
            u32x4 hv = *(const u32x4*)(hbuf  + (size_t)idx[m]*HP + j0);
            u32x4 uv = *(const u32x4*)(uhbuf + (size_t)idx[m]*HP + j0);
#pragma unroll
            for (int e=0;e<8;e++){
                float h = bf2f((ushort)((hv[e>>1] >> ((e&1)*16)) & 0xffff));
                float u = bf2f((ushort)((uv[e>>1] >> ((e&1)*16)) & 0xffff));
                sh[e] += h;
                gt[e] += h * sigmf(er[e] + u);
            }
        }
        so[0]=pk2(sh[0],sh[1]); so[1]=pk2(sh[2],sh[3]);
        so[2]=pk2(sh[4],sh[5]); so[3]=pk2(sh[6],sh[7]);
        go[0]=pk2(gt[0],gt[1]); go[1]=pk2(gt[2],gt[3]);
        go[2]=pk2(gt[4],gt[5]); go[3]=pk2(gt[6],gt[7]);
    } else {
        so = (u32x4){0,0,0,0}; go = (u32x4){0,0,0,0};
    }
    *(u32x4*)(sumh  + (size_t)r*HP + j0) = so;
    *(u32x4*)(gated + (size_t)r*HP + j0) = go;
}

// ---------- scan step part 2: twin GEMM + blend + Ur GEMM (slab-fused) ----------
// 32 blocks x 16-row slab; A-fragments read directly from global sumh/gated
// (each byte read once, L2/L3-resident). nh handoff via LDS (swizzled).
__global__ __launch_bounds__(256, 1) void gemm_step_k(int t,
    const int* __restrict__ x_wid, const int* __restrict__ valid,
    const float* __restrict__ EZ, const float* __restrict__ EH,
    const ushort* __restrict__ WzS, const ushort* __restrict__ WhG, const ushort* __restrict__ UrB,
    const ushort* __restrict__ sumh, const ushort* __restrict__ gated,
    ushort* __restrict__ hbuf, ushort* __restrict__ uhbuf)
{
    __shared__ __align__(16) char nhL[SLAB*1024];
    const int tid = threadIdx.x, lane = tid & 63, wv = tid >> 6;
    const int R0 = blockIdx.x * SLAB;
    const int arow = lane & 15;     // A row / output col-within-tile
    const int kh = lane >> 4;       // k-quarter group / output row group

    // ---- phase B: twin 16x512 GEMM (K=480) + GRU blend ----
    const ushort* aZp = sumh  + (size_t)(R0 + arow)*HP + kh*8;
    const ushort* aGp = gated + (size_t)(R0 + arow)*HP + kh*8;
    f32x4 accZ[8], accH[8];
#pragma unroll
    for (int nt=0; nt<8; ++nt){ accZ[nt]=(f32x4){0,0,0,0}; accH[nt]=(f32x4){0,0,0,0}; }
    for (int kt=0; kt<15; ++kt){
        const int kb = kt*32;
        bf16x8 aZ = *(const bf16x8*)(aZp + kb);
        bf16x8 aG = *(const bf16x8*)(aGp + kb);
#pragma unroll
        for (int nt=0; nt<8; ++nt){
            const int col = wv*128 + nt*16 + arow;
            bf16x8 bZ = *(const bf16x8*)(WzS + (size_t)col*HP + kb + kh*8);
            bf16x8 bG = *(const bf16x8*)(WhG + (size_t)col*HP + kb + kh*8);
            accZ[nt] = __builtin_amdgcn_mfma_f32_16x16x32_bf16(aZ, bZ, accZ[nt], 0, 0, 0);
            accH[nt] = __builtin_amdgcn_mfma_f32_16x16x32_bf16(aG, bG, accH[nt], 0, 0, 0);
        }
    }
#pragma unroll
    for (int nt=0; nt<8; ++nt){
        const int col = wv*128 + nt*16 + arow;   // C/D: col = lane&15 (+tile), row = kh*4+j
        if (col < 480){
#pragma unroll
            for (int j=0; j<4; j++){
                const int r = kh*4 + j;
                const int base = t*Bq + R0 + r;
                ushort o = 0;
                if (col < Hq){
                    const int wid = x_wid[base];
                    float z  = sigmf(accZ[nt][j] + EZ[(size_t)wid*F32S + col]);
                    float ht = tanhfast(accH[nt][j] + EH[(size_t)wid*F32S + col]);
                    float sh = bf2f(sumh[(size_t)(R0 + r)*HP + col]);
                    o = f2bf((1.f - z)*sh + z*ht);
                    if (valid[base]) hbuf[(size_t)(1 + base)*HP + col] = o;
                }
                const int nb = col*2;
                *(ushort*)(nhL + r*1024 + ((nb & 0x3F0) ^ ((r&7)<<4)) + (nb & 0xF)) = o;
            }
        }
    }
    __syncthreads();

    // ---- phase C: uh = nh @ Ur^T (16x512, K=480) ----
    f32x4 accU[8];
#pragma unroll
    for (int nt=0; nt<8; ++nt) accU[nt]=(f32x4){0,0,0,0};
    for (int kt=0; kt<15; ++kt){
        const int aoff = (kt*64 + kh*16) ^ ((arow&7)<<4);
        bf16x8 aN = *(const bf16x8*)(nhL + arow*1024 + aoff);
        const int kb = kt*32 + kh*8;
#pragma unroll
        for (int nt=0; nt<8; ++nt){
            const int col = wv*128 + nt*16 + arow;
            bf16x8 bU = *(const bf16x8*)(UrB + (size_t)col*HP + kb);
            accU[nt] = __builtin_amdgcn_mfma_f32_16x16x32_bf16(aN, bU, accU[nt], 0, 0, 0);
        }
    }
#pragma unroll
    for (int nt=0; nt<8; ++nt){
        const int col = wv*128 + nt*16 + arow;
        if (col < Hq){
#pragma unroll
            for (int j=0; j<4; j++){
                const int r = kh*4 + j;
                const int base = t*Bq + R0 + r;
                if (valid[base]) uhbuf[(size_t)(1 + base)*HP + col] = f2bf(accU[nt][j]);
            }
        }
    }
}

// ---------- pred GEMM1 (compacted rows) ----------
__global__ __launch_bounds__(256) void pred1c_k(const int* __restrict__ np_,
    const int* __restrict__ listp, const ushort* __restrict__ hbuf,
    const float* __restrict__ TP, const ushort* __restrict__ WHp,
    ushort* __restrict__ pv)
{
    const int np = *np_;
    const int row0 = blockIdx.y*128;
    if (row0 >= np) return;
    const int col0 = blockIdx.x*64;
    const int tid = threadIdx.x;
    int i0 = row0 + (tid>>2), i1 = i0 + 64;
    int g0 = (i0 < np) ? listp[i0] : 0;
    int g1 = (i1 < np) ? listp[i1] : 0;
    const ushort* p0 = (g0 < Bq) ? hbuf : hbuf + (size_t)(1 + g0 - Bq)*HP;  // hbuf row0 = zeros
    const ushort* p1 = (g1 < Bq) ? hbuf : hbuf + (size_t)(1 + g1 - Bq)*HP;
    f32x4 acc[4][2];
    mgemm2([&](int which,int k0){ return (which?p1:p0)+k0; }, WHp, HP, 15, col0, acc);
    EPI_PRE
#pragma unroll
    for (int f=0; f<4; f++)
#pragma unroll
      for (int g=0; g<2; g++){
        int col = col0 + wn*32 + g*16 + (lane & 15);
        if (col >= HP) continue;
#pragma unroll
        for (int j=0; j<4; j++){
            int i = row0 + wm*64 + f*16 + ((lane>>4)<<2) + j;
            if (i >= np) continue;
            int gr = listp[i];
            int b = (gr < Bq) ? gr : ((gr - Bq) & (Bq-1));
            float v = 0.f;
            if (col < Hq) v = fmaxf(acc[f][g][j] + TP[(size_t)b*F32S + col], 0.f);
            pv[(size_t)i*HP + col] = f2bf(v);
        }
      }
}

// ---------- pred GEMM2 ----------
__global__ __launch_bounds__(256) void pred2c_k(int cs, const int* __restrict__ np_,
    const ushort* __restrict__ pv, const ushort* __restrict__ WOp,
    const float* __restrict__ bWo, float* __restrict__ scores)
{
    const int np = *np_;
    const int row0 = blockIdx.y*128;
    if (cs + row0 >= np) return;
    const int col0 = blockIdx.x*64;
    const int tid = threadIdx.x;
    const ushort* p0 = pv + (size_t)(cs + row0 + (tid>>2))*HP;
    const ushort* p1 = p0 + (size_t)64*HP;
    f32x4 acc[4][2];
    mgemm2([&](int which,int k0){ return (which?p1:p0)+k0; }, WOp, HP, 15, col0, acc);
    EPI_PRE
#pragma unroll
    for (int f=0; f<4; f++)
#pragma unroll
      for (int g=0; g<2; g++){
        int col = col0 + wn*32 + g*16 + (lane & 15);
        if (col >= Vq) continue;
        float bc = bWo[col];
#pragma unroll
        for (int j=0; j<4; j++){
            int r = row0 + wm*64 + f*16 + ((lane>>4)<<2) + j;
            scores[(size_t)r*832 + col] = acc[f][g][j] + bc;
        }
      }
}

// ---------- pred reduce: wave-per-row ----------
__global__ __launch_bounds__(256) void predred_k(int cs, const int* __restrict__ np_,
    const int* __restrict__ listp, const float* __restrict__ scores,
    const int* __restrict__ pred_wid, const int* __restrict__ root_wid,
    float* __restrict__ accv)
{
    const int np = *np_;
    int nrows = np - cs; if (nrows > CH2) nrows = CH2;
    const int lane = threadIdx.x & 63, wv = threadIdx.x >> 6;
    const int wid_g = blockIdx.x*4 + wv, nw = gridDim.x*4;
    float ce = 0.f, hit = 0.f, cnt = 0.f;
    for (int r = wid_g; r < nrows; r += nw){
        const float* sc = scores + (size_t)r*832;
        int gr = listp[cs + r];
        int tgt = (gr < Bq) ? root_wid[gr] : pred_wid[gr - Bq];
        float vals[13];
        float bv = -INFINITY, tv = 0.f; int bi = 0;
#pragma unroll
        for (int q=0; q<13; q++){
            int j = lane + q*64;
            float v = (j < Vq) ? sc[j] : -INFINITY;
            vals[q] = v;
            if (v > bv){ bv = v; bi = j; }
            if (j == tgt) tv = v;
        }
#pragma unroll
        for (int off=32; off; off>>=1){
            float ov = __shfl_xor(bv, off); int oi = __shfl_xor(bi, off);
            if (ov > bv || (ov == bv && oi < bi)){ bv = ov; bi = oi; }
        }
        float s = 0.f;
#pragma unroll
        for (int q=0; q<13; q++){
            int j = lane + q*64;
            if (j < Vq) s += __expf(vals[q] - bv);
        }
#pragma unroll
        for (int off=32; off; off>>=1) s += __shfl_xor(s, off);
#pragma unroll
        for (int off=32; off; off>>=1) tv += __shfl_xor(tv, off);
        if (lane == 0){
            ce += bv + logf(s) - tv;
            hit += (bi == tgt) ? 1.f : 0.f;
            cnt += 1.f;
        }
    }
    __shared__ float L[3][4];
    if (lane == 0){ L[0][wv] = ce; L[1][wv] = hit; L[2][wv] = cnt; }
    __syncthreads();
    if (threadIdx.x == 0){
        float a = L[0][0]+L[0][1]+L[0][2]+L[0][3];
        float b = L[1][0]+L[1][1]+L[1][2]+L[1][3];
        float c = L[2][0]+L[2][1]+L[2][2]+L[2][3];
        if (c != 0.f){
            atomicAdd(&accv[0], a);
            atomicAdd(&accv[1], b);
            atomicAdd(&accv[2], c);
        }
    }
}

// ---------- stop: cur_o gather (compacted) ----------
__global__ void curo_c(const int* __restrict__ ns_, const int* __restrict__ lists,
                       const int* __restrict__ o_nei_idx, const int* __restrict__ root_o_nei,
                       const ushort* __restrict__ hbuf, ushort* __restrict__ curo)
{
    int i = blockIdx.x;
    if (i >= *ns_) return;
    int gr = lists[i];
    int j0 = threadIdx.x * 4;
    if (j0 >= HP) return;
    int idx[Mq];
    if (gr < TBq){
        int tt = gr >> 9;
#pragma unroll
        for (int m=0;m<Mq;m++){
            int ix = o_nei_idx[(size_t)gr*Mq + m];
            idx[m] = (ix <= tt*Bq) ? ix : 0;   // slots written before step tt; row 0 is zero
        }
    } else {
#pragma unroll
        for (int m=0;m<Mq;m++) idx[m] = root_o_nei[(size_t)(gr-TBq)*Mq + m];
    }
    float s0=0,s1=0,s2=0,s3=0;
#pragma unroll
    for (int m=0;m<Mq;m++){
        uint2 v = *(const uint2*)(hbuf + (size_t)idx[m]*HP + j0);
        s0 += bf2f((ushort)(v.x & 0xffff)); s1 += bf2f((ushort)(v.x >> 16));
        s2 += bf2f((ushort)(v.y & 0xffff)); s3 += bf2f((ushort)(v.y >> 16));
    }
    uint2 o; o.x = pk2(s0, s1); o.y = pk2(s2, s3);
    *(uint2*)(curo + (size_t)i*HP + j0) = o;
}

// ---------- stop GEMM (compacted) + fused Us-dot ----------
__global__ __launch_bounds__(256) void stopc_k(const int* __restrict__ ns_,
    const int* __restrict__ lists, const int* __restrict__ x_wid,
    const int* __restrict__ root_wid, const ushort* __restrict__ curo,
    const ushort* __restrict__ UOp, const float* __restrict__ EU,
    const float* __restrict__ TU, const float* __restrict__ Usf,
    float* __restrict__ ss)
{
    const int ns = *ns_;
    const int row0 = blockIdx.y*128;
    if (row0 >= ns) return;
    const int col0 = blockIdx.x*64;
    const int tid = threadIdx.x;
    const ushort* p0 = curo + (size_t)(row0 + (tid>>2))*HP;
    const ushort* p1 = p0 + (size_t)64*HP;
    f32x4 acc[4][2];
    mgemm2([&](int which,int k0){ return (which?p1:p0)+k0; }, UOp, HP, 15, col0, acc);
    EPI_PRE
#pragma unroll
    for (int f=0; f<4; f++){
#pragma unroll
        for (int j=0; j<4; j++){
            int i = row0 + wm*64 + f*16 + ((lane>>4)<<2) + j;
            float p = 0.f;
            if (i < ns){
                int gr = lists[i];
                int wid = (gr < TBq) ? x_wid[gr] : root_wid[gr - TBq];
                int b   = (gr < TBq) ? (gr & (Bq-1)) : (gr - TBq);
                const float* eu = EU + (size_t)wid*F32S;
                const float* tu = TU + (size_t)b*F32S;
#pragma unroll
                for (int g=0; g<2; g++){
                    int col = col0 + wn*32 + g*16 + (lane & 15);
                    if (col < Hq)
                        p += fmaxf(acc[f][g][j] + eu[col] + tu[col], 0.f) * Usf[col];
                }
            }
            p += __shfl_xor(p, 1); p += __shfl_xor(p, 2);
            p += __shfl_xor(p, 4); p += __shfl_xor(p, 8);
            if ((lane & 15) == 0 && i < ns) atomicAdd(&ss[i], p);
        }
    }
}

__global__ void stopfin_k(const int* __restrict__ ns_, const int* __restrict__ lists,
    const float* __restrict__ ss, const float* __restrict__ bUs,
    const int* __restrict__ direction, float* __restrict__ accv)
{
    const int ns = *ns_;
    int i = blockIdx.x*256 + threadIdx.x;
    float bce = 0.f, hit = 0.f, c = 0.f;
    if (i < ns){
        int gr = lists[i];
        float s = ss[i] + bUs[0];
        float stgt = (gr < TBq) ? (float)direction[gr] : 0.f;
        bce = fmaxf(s,0.f) - s*stgt + log1pf(__expf(-fabsf(s)));
        hit = ((((s >= 0.f) ? 1.f : 0.f) == stgt) ? 1.f : 0.f);
        c = 1.f;
    }
    for (int off=32; off; off>>=1){
        bce += __shfl_down(bce, off);
        hit += __shfl_down(hit, off);
        c   += __shfl_down(c,   off);
    }
    if ((threadIdx.x & 63) == 0 && c != 0.f){
        atomicAdd(&accv[3], bce);
        atomicAdd(&accv[4], hit);
        atomicAdd(&accv[5], c);
    }
}

__global__ void finalize_k(const float* __restrict__ accv, float* __restrict__ out){
    if (threadIdx.x == 0){
        out[0] = accv[0] / (float)Bq;
        out[1] = accv[3] / (float)Bq;
        out[2] = accv[1] / accv[2];
        out[3] = accv[4] / accv[5];
    }
}

extern "C" void kernel_launch(void* const* d_in, const int* in_sizes, int n_in,
                              void* d_out, int out_size, void* d_ws, size_t ws_size,
                              hipStream_t stream) {
    (void)in_sizes; (void)n_in; (void)out_size; (void)ws_size;
    const float* tree_vecs = (const float*)d_in[0];
    const int*   x_wid     = (const int*)d_in[1];
    const int*   pred_wid  = (const int*)d_in[2];
    const int*   root_wid  = (const int*)d_in[3];
    const int*   h_nei_idx = (const int*)d_in[4];
    const int*   o_nei_idx = (const int*)d_in[5];
    const int*   root_o_nei= (const int*)d_in[6];
    const int*   valid     = (const int*)d_in[7];
    const int*   direction = (const int*)d_in[8];
    const float* emb       = (const float*)d_in[9];
    const float* Wz        = (const float*)d_in[10];
    const float* bz        = (const float*)d_in[11];
    const float* Wr        = (const float*)d_in[12];
    const float* br        = (const float*)d_in[13];
    const float* Ur        = (const float*)d_in[14];
    const float* Wh        = (const float*)d_in[15];
    const float* bh        = (const float*)d_in[16];
    const float* Wm        = (const float*)d_in[17];
    const float* bW        = (const float*)d_in[18];
    const float* U         = (const float*)d_in[19];
    const float* bU        = (const float*)d_in[20];
    const float* Wo        = (const float*)d_in[21];
    const float* bWo       = (const float*)d_in[22];
    const float* Us        = (const float*)d_in[23];
    const float* bUs       = (const float*)d_in[24];

    char* w = (char*)d_ws; size_t off = 0;
    auto alloc = [&](size_t bytes)->void*{ void* p = w + off; off += (bytes + 255) & ~(size_t)255; return p; };

    ushort* hbuf  = (ushort*)alloc((size_t)Sq*HP*2);
    ushort* uhbuf = (ushort*)alloc((size_t)Sq*HP*2);
    ushort* embb  = (ushort*)alloc((size_t)896*HP*2);
    ushort* treeb = (ushort*)alloc((size_t)Bq*64*2);
    ushort* WzX   = (ushort*)alloc((size_t)512*HP*2);
    ushort* WzS   = (ushort*)alloc((size_t)512*HP*2);
    ushort* WrB   = (ushort*)alloc((size_t)512*HP*2);
    ushort* WhX   = (ushort*)alloc((size_t)512*HP*2);
    ushort* WhG   = (ushort*)alloc((size_t)512*HP*2);
    ushort* UrB   = (ushort*)alloc((size_t)512*HP*2);
    ushort* WHp   = (ushort*)alloc((size_t)512*HP*2);
    ushort* UXp   = (ushort*)alloc((size_t)512*HP*2);
    ushort* UOp   = (ushort*)alloc((size_t)512*HP*2);
    ushort* WOp   = (ushort*)alloc((size_t)832*HP*2);
    ushort* WLp   = (ushort*)alloc((size_t)512*64*2);
    ushort* ULp   = (ushort*)alloc((size_t)512*64*2);
    float*  EZ    = (float*)alloc((size_t)Vq*F32S*4);
    float*  ER    = (float*)alloc((size_t)Vq*F32S*4);
    float*  EH    = (float*)alloc((size_t)Vq*F32S*4);
    float*  EU    = (float*)alloc((size_t)Vq*F32S*4);
    float*  TP    = (float*)alloc((size_t)Bq*F32S*4);
    float*  TU    = (float*)alloc((size_t)Bq*F32S*4);
    ushort* sumh  = (ushort*)alloc((size_t)Bq*HP*2);
    ushort* gated = (ushort*)alloc((size_t)Bq*HP*2);
    ushort* pv    = (ushort*)alloc((size_t)NPCAP*HP*2);
    float*  scores= (float*)alloc((size_t)CH2*832*4);
    float*  ss    = (float*)alloc((size_t)NSCAP*4);
    int*    listp = (int*)alloc((size_t)NPCAP*4);
    int*    lists = (int*)alloc((size_t)NSCAP*4);
    int*    meta  = (int*)alloc((size_t)(NPB*4 + 2 + 16)*4);
    int*    cnts  = meta;            // [2*NPB]
    int*    offs  = meta + 2*NPB;    // [2*NPB]
    int*    tot   = meta + 4*NPB;    // [2]
    float*  accv  = (float*)(meta + 4*NPB + 2);
    ushort* curo  = pv;              // stop phase reuses pv/scores region

    (void)hipMemsetAsync(hbuf,  0, (size_t)Sq*HP*2, stream);
    (void)hipMemsetAsync(uhbuf, 0, (size_t)Sq*HP*2, stream);
    (void)hipMemsetAsync(ss,    0, (size_t)NSCAP*4, stream);
    (void)hipMemsetAsync(meta,  0, (size_t)(NPB*4 + 2 + 16)*4, stream);

    // ---- conversions (1 launch) ----
    convAll_k<<<dim3(896,14), 128, 0, stream>>>(
        emb, tree_vecs, Wz, Wr, Ur, Wh, Wm, U, Wo,
        embb, treeb, WzX, WzS, WrB, WhX, WhG, UrB, WHp, UXp, UOp, WOp, WLp, ULp);

    // ---- precomputes (2 launches) ----
    preE_k<<<dim3(8,7,4), 256, 0, stream>>>(embb, WzX, WrB, WhX, UXp,
                                            bz, br, bh, bU, EZ, ER, EH, EU);
    preT_k<<<dim3(8,4,2), 256, 0, stream>>>(treeb, WLp, ULp, bW, TP, TU);

    // ---- row compaction ----
    cnt_k <<<dim3(NPB,2), 256, 0, stream>>>(valid, direction, cnts);
    scan_k<<<1, 64, 0, stream>>>(cnts, offs, tot);
    fill_k<<<dim3(NPB,2), 256, 0, stream>>>(valid, direction, offs, listp, lists);

    // ---- sequential scan: gather (full machine) + fused GEMM per step ----
    for (int t=0; t<Tq; t++){
        gather_k   <<<120, 256, 0, stream>>>(t, x_wid, h_nei_idx, ER, hbuf, uhbuf, sumh, gated);
        gemm_step_k<<<Bq/SLAB, 256, 0, stream>>>(t, x_wid, valid, EZ, EH,
                                                 WzS, WhG, UrB, sumh, gated, hbuf, uhbuf);
    }

    // ---- pred phase (compacted) ----
    pred1c_k<<<dim3(8, NPCAP/128), 256, 0, stream>>>(tot, listp, hbuf, TP, WHp, pv);
    for (int c=0; c<NCH2; c++){
        int cs = c*CH2;
        pred2c_k<<<dim3(13, CH2/128), 256, 0, stream>>>(cs, tot, pv, WOp, bWo, scores);
        predred_k<<<256, 256, 0, stream>>>(cs, tot, listp, scores, pred_wid, root_wid, accv);
    }

    // ---- stop phase (compacted) ----
    curo_c<<<NSCAP, 128, 0, stream>>>(tot+1, lists, o_nei_idx, root_o_nei, hbuf, curo);
    stopc_k<<<dim3(8, NSCAP/128), 256, 0, stream>>>(tot+1, lists, x_wid, root_wid,
                                                    curo, UOp, EU, TU, Us, ss);
    stopfin_k<<<NSCAP/256, 256, 0, stream>>>(tot+1, lists, ss, bUs, direction, accv);

    finalize_k<<<1, 64, 0, stream>>>(accv, (float*)d_out);
}

// Round 12
// 1459.156 us; speedup vs baseline: 3.8874x; 2.7081x over previous
//
#include <hip/hip_runtime.h>
#include <math.h>

#define Bq 512
#define Tq 64
#define Hq 450
#define Lq 56
#define Vq 780
#define Mq 8
#define TBq 32768
#define Sq 32770
#define HP 480          // bf16 row stride (mult of 32)
#define F32S 464        // f32 row stride
#define NPB 130         // 130*256 = 33280 rows
#define NPCAP 12288     // compacted pred rows cap
#define NSCAP 20480     // compacted stop rows cap
#define CH2 4096        // pred score chunk rows
#define NCH2 3

using bf16x8 = __attribute__((ext_vector_type(8))) __bf16;
using f32x4  = __attribute__((ext_vector_type(4))) float;
using u32x4  = __attribute__((ext_vector_type(4))) unsigned;

__device__ __forceinline__ ushort f2bf(float f){
    union { float f; unsigned u; } c; c.f = f;
    unsigned u = c.u;
    return (ushort)((u + 0x7FFFu + ((u >> 16) & 1u)) >> 16);
}
__device__ __forceinline__ float bf2f(ushort h){
    union { unsigned u; float f; } c; c.u = ((unsigned)h) << 16;
    return c.f;
}
__device__ __forceinline__ unsigned pk2(float a, float b){
    return (unsigned)f2bf(a) | ((unsigned)f2bf(b) << 16);
}
__device__ __forceinline__ float sigmf(float x){
    return __builtin_amdgcn_rcpf(1.f + __expf(-x));
}
__device__ __forceinline__ float tanhfast(float x){
    float e2 = __expf(2.f * x);
    return 1.f - 2.f * __builtin_amdgcn_rcpf(e2 + 1.f);
}

// ---------- fused converter: 14 jobs by blockIdx.y ----------
__global__ void convAll_k(
    const float* __restrict__ emb, const float* __restrict__ tree,
    const float* __restrict__ Wz, const float* __restrict__ Wr,
    const float* __restrict__ Ur, const float* __restrict__ Wh,
    const float* __restrict__ Wm, const float* __restrict__ U, const float* __restrict__ Wo,
    ushort* embb, ushort* treeb, ushort* WzX, ushort* WzS, ushort* WrB,
    ushort* WhX, ushort* WhG, ushort* UrB, ushort* WHp, ushort* UXp,
    ushort* UOp, ushort* WOp, ushort* WLp, ushort* ULp)
{
    int job = blockIdx.y, n = blockIdx.x;
    const float* src; ushort* dst; int Npad, Nsrc, Ksrc, Kpad, len, off;
    switch(job){
      case 0:  src=emb;  dst=embb; Npad=896; Nsrc=780; Ksrc=450; Kpad=480; len=450; off=0;   break;
      case 1:  src=tree; dst=treeb;Npad=512; Nsrc=512; Ksrc=56;  Kpad=64;  len=56;  off=0;   break;
      case 2:  src=Wz;   dst=WzX;  Npad=512; Nsrc=450; Ksrc=900; Kpad=480; len=450; off=0;   break;
      case 3:  src=Wz;   dst=WzS;  Npad=512; Nsrc=450; Ksrc=900; Kpad=480; len=450; off=450; break;
      case 4:  src=Wr;   dst=WrB;  Npad=512; Nsrc=450; Ksrc=450; Kpad=480; len=450; off=0;   break;
      case 5:  src=Wh;   dst=WhX;  Npad=512; Nsrc=450; Ksrc=900; Kpad=480; len=450; off=0;   break;
      case 6:  src=Wh;   dst=WhG;  Npad=512; Nsrc=450; Ksrc=900; Kpad=480; len=450; off=450; break;
      case 7:  src=Ur;   dst=UrB;  Npad=512; Nsrc=450; Ksrc=450; Kpad=480; len=450; off=0;   break;
      case 8:  src=Wm;   dst=WHp;  Npad=512; Nsrc=450; Ksrc=506; Kpad=480; len=450; off=0;   break;
      case 9:  src=U;    dst=UXp;  Npad=512; Nsrc=450; Ksrc=956; Kpad=480; len=450; off=0;   break;
      case 10: src=U;    dst=UOp;  Npad=512; Nsrc=450; Ksrc=956; Kpad=480; len=450; off=450; break;
      case 11: src=Wo;   dst=WOp;  Npad=832; Nsrc=780; Ksrc=450; Kpad=480; len=450; off=0;   break;
      case 12: src=Wm;   dst=WLp;  Npad=512; Nsrc=450; Ksrc=506; Kpad=64;  len=56;  off=450; break;
      default: src=U;    dst=ULp;  Npad=512; Nsrc=450; Ksrc=956; Kpad=64;  len=56;  off=900; break;
    }
    if (n >= Npad) return;
    for (int k = threadIdx.x; k < Kpad; k += blockDim.x){
        float v = 0.f;
        if (n < Nsrc && k < len) v = src[(size_t)n*Ksrc + off + k];
        dst[(size_t)n*Kpad + k] = f2bf(v);
    }
}

// ---------- double-buffered MFMA GEMM body: C(128x64) tile ----------
template<class APtr>
__device__ __forceinline__ void mgemm2(APtr&& aptr, const ushort* __restrict__ Bw, int ldb,
                                       int KT, int col0, f32x4 acc[4][2])
{
    __shared__ __align__(16) char As[2][128*80];
    __shared__ __align__(16) char Bs[2][64*80];
    const int tid = threadIdx.x;
    const int lane = tid & 63;
    const int w = tid >> 6, wm = w >> 1, wn = w & 1;
    const int ac = (tid & 3) * 8;
    const size_t boff = (size_t)(col0 + (tid >> 2)) * ldb;
    u32x4 ra0, ra1, rb;
    auto ld = [&](int k0){
        ra0 = *(const u32x4*)(aptr(0, k0) + ac);
        ra1 = *(const u32x4*)(aptr(1, k0) + ac);
        rb  = *(const u32x4*)(Bw + boff + k0 + ac);
    };
    const int wr_a0 = (tid>>2)*80 + (tid&3)*16;
    const int wr_a1 = ((tid>>2)+64)*80 + (tid&3)*16;
    const int wr_b  = (tid>>2)*80 + (tid&3)*16;
    const int rd_a  = (wm*64 + (lane&15))*80 + (lane>>4)*16;
    const int rd_b  = (wn*32 + (lane&15))*80 + (lane>>4)*16;
    ld(0);
    *(u32x4*)(As[0]+wr_a0) = ra0; *(u32x4*)(As[0]+wr_a1) = ra1; *(u32x4*)(Bs[0]+wr_b) = rb;
#pragma unroll
    for (int f=0;f<4;f++)
#pragma unroll
        for (int g=0;g<2;g++) acc[f][g] = (f32x4){0.f,0.f,0.f,0.f};
    __syncthreads();
    for (int kt=0; kt<KT; ++kt){
        const int cur = kt & 1;
        if (kt+1 < KT) ld((kt+1)*32);
        bf16x8 bF[2];
#pragma unroll
        for (int g=0; g<2; g++) bF[g] = *(const bf16x8*)(Bs[cur] + rd_b + g*16*80);
#pragma unroll
        for (int f=0; f<4; f++){
            bf16x8 aF = *(const bf16x8*)(As[cur] + rd_a + f*16*80);
#pragma unroll
            for (int g=0; g<2; g++)
                acc[f][g] = __builtin_amdgcn_mfma_f32_16x16x32_bf16(aF, bF[g], acc[f][g], 0, 0, 0);
        }
        if (kt+1 < KT){
            *(u32x4*)(As[cur^1]+wr_a0) = ra0; *(u32x4*)(As[cur^1]+wr_a1) = ra1;
            *(u32x4*)(Bs[cur^1]+wr_b) = rb;
        }
        __syncthreads();
    }
}

#define EPI_PRE  const int lane = threadIdx.x & 63; const int w_ = threadIdx.x >> 6; \
                 const int wm = w_ >> 1, wn = w_ & 1;

// ---------- precompute GEMM body ----------
__device__ __forceinline__ void pre_body(const ushort* __restrict__ A, int lda,
    const ushort* __restrict__ Bw, const float* __restrict__ bias,
    float* __restrict__ out, int Mr, int KT)
{
    const int row0 = blockIdx.y*128, col0 = blockIdx.x*64;
    const int tid = threadIdx.x;
    const ushort* p0 = A + (size_t)(row0 + (tid>>2))*lda;
    const ushort* p1 = p0 + (size_t)64*lda;
    f32x4 acc[4][2];
    mgemm2([&](int which,int k0){ return (which?p1:p0)+k0; }, Bw, lda, KT, col0, acc);
    EPI_PRE
#pragma unroll
    for (int f=0; f<4; f++)
#pragma unroll
      for (int g=0; g<2; g++){
        int col = col0 + wn*32 + g*16 + (lane & 15);
        if (col >= F32S) continue;
        float bb = 0.f;
        if (col < Hq && bias) bb = bias[col];
#pragma unroll
        for (int j=0; j<4; j++){
            int row = row0 + wm*64 + f*16 + ((lane>>4)<<2) + j;
            if (row < Mr) out[(size_t)row*F32S + col] = (col < Hq) ? acc[f][g][j] + bb : 0.f;
        }
      }
}

__global__ __launch_bounds__(256) void preE_k(
    const ushort* __restrict__ embb,
    const ushort* __restrict__ WzX, const ushort* __restrict__ WrB,
    const ushort* __restrict__ WhX, const ushort* __restrict__ UXp,
    const float* __restrict__ bz, const float* __restrict__ br,
    const float* __restrict__ bh, const float* __restrict__ bU,
    float* __restrict__ EZ, float* __restrict__ ER,
    float* __restrict__ EH, float* __restrict__ EU)
{
    const ushort* Bw; const float* bias; float* out;
    switch(blockIdx.z){
      case 0:  Bw=WzX; bias=bz; out=EZ; break;
      case 1:  Bw=WrB; bias=br; out=ER; break;
      case 2:  Bw=WhX; bias=bh; out=EH; break;
      default: Bw=UXp; bias=bU; out=EU; break;
    }
    pre_body(embb, HP, Bw, bias, out, Vq, 15);
}

__global__ __launch_bounds__(256) void preT_k(
    const ushort* __restrict__ treeb,
    const ushort* __restrict__ WLp, const ushort* __restrict__ ULp,
    const float* __restrict__ bW, float* __restrict__ TP, float* __restrict__ TU)
{
    const ushort* Bw = blockIdx.z ? ULp : WLp;
    const float* bias = blockIdx.z ? nullptr : bW;
    float* out = blockIdx.z ? TU : TP;
    pre_body(treeb, 64, Bw, bias, out, Bq, 2);
}

// ---------- compaction for pred/stop: count / scan / fill ----------
__device__ __forceinline__ bool cmask(int which, int gr,
    const int* __restrict__ valid, const int* __restrict__ dir)
{
    if (which == 0) return (gr < Bq) ? true : (valid[gr-Bq] && dir[gr-Bq]);
    return (gr < TBq) ? (valid[gr] != 0) : true;
}
__global__ void cnt_k(const int* __restrict__ valid, const int* __restrict__ dir,
                      int* __restrict__ cnts)
{
    int which = blockIdx.y;
    int gr = blockIdx.x*256 + threadIdx.x;
    bool m = cmask(which, gr, valid, dir);
    unsigned long long bal = __ballot(m);
    if ((threadIdx.x & 63) == 0)
        atomicAdd(&cnts[which*NPB + blockIdx.x], (int)__popcll(bal));
}
__global__ void scan_k(const int* __restrict__ cnts, int* __restrict__ offs,
                       int* __restrict__ totals)
{
    if (threadIdx.x == 0){
        int a = 0;
        for (int i=0;i<NPB;i++){ offs[i] = a; a += cnts[i]; }
        totals[0] = a;
        int b = 0;
        for (int i=0;i<NPB;i++){ offs[NPB+i] = b; b += cnts[NPB+i]; }
        totals[1] = b;
    }
}
__global__ void fill_k(const int* __restrict__ valid, const int* __restrict__ dir,
                       const int* __restrict__ offs, int* __restrict__ listp,
                       int* __restrict__ lists)
{
    __shared__ int woff[4];
    int which = blockIdx.y;
    int gr = blockIdx.x*256 + threadIdx.x;
    bool m = cmask(which, gr, valid, dir);
    unsigned long long bal = __ballot(m);
    int lane = threadIdx.x & 63, wv = threadIdx.x >> 6;
    if (lane == 0) woff[wv] = (int)__popcll(bal);
    __syncthreads();
    int prev = 0;
    for (int i=0;i<wv;i++) prev += woff[i];
    if (m){
        int rank = prev + (int)__popcll(bal & ((1ull << lane) - 1ull));
        int pos = offs[which*NPB + blockIdx.x] + rank;
        if (which == 0){ if (pos < NPCAP) listp[pos] = gr; }
        else           { if (pos < NSCAP) lists[pos] = gr; }
    }
}

// ---------- per-step valid-row lists: vlist[t*Bq + i] = b, vcnt[t] ----------
__global__ void vfill_k(const int* __restrict__ valid,
                        int* __restrict__ vcnt, int* __restrict__ vlist)
{
    __shared__ int woff[8];
    const int t = blockIdx.x;
    const int b = threadIdx.x;              // 512 threads
    bool m = valid[t*Bq + b] != 0;
    unsigned long long bal = __ballot(m);
    int lane = b & 63, wv = b >> 6;
    if (lane == 0) woff[wv] = (int)__popcll(bal);
    __syncthreads();
    int prev = 0;
    for (int i=0;i<wv;i++) prev += woff[i];
    if (m) vlist[t*Bq + prev + (int)__popcll(bal & ((1ull<<lane)-1ull))] = b;
    if (b == 0){
        __syncthreads();
    }
    if (threadIdx.x == 511){
        int tot = 0;
        for (int i=0;i<8;i++) tot += woff[i];
        vcnt[t] = tot;
    }
}

// ---------- scan: gather (compacted valid rows, full machine) ----------
// tasks = vcnt[t] * 57 (16B chunks covering k<456); writes compacted sumhC/gatedC.
__global__ __launch_bounds__(256) void gather_k(int t,
    const int* __restrict__ x_wid, const int* __restrict__ h_nei_idx,
    const float* __restrict__ ER,
    const int* __restrict__ vcnt, const int* __restrict__ vlist,
    const ushort* __restrict__ hbuf, const ushort* __restrict__ uhbuf,
    ushort* __restrict__ sumhC, ushort* __restrict__ gatedC)
{
    const int cnt = vcnt[t];
    const int task = blockIdx.x*256 + threadIdx.x;
    if (task >= cnt*57) return;
    const int i = task / 57;
    const int c = task - i*57;
    const int j0 = c*8;
    const int b = vlist[t*Bq + i];
    const int base = t*Bq + b;
    const int wid = x_wid[base];
    const int* ip = h_nei_idx + (size_t)base*Mq;
    int idx[Mq];
#pragma unroll
    for (int m=0;m<Mq;m++) idx[m] = ip[m];
    float er[8];
    { const float* erp = ER + (size_t)wid*F32S + j0;
      float4 e0 = *(const float4*)erp, e1 = *(const float4*)(erp+4);
      er[0]=e0.x;er[1]=e0.y;er[2]=e0.z;er[3]=e0.w;
      er[4]=e1.x;er[5]=e1.y;er[6]=e1.z;er[7]=e1.w; }
    float sh[8] = {0,0,0,0,0,0,0,0};
    float gt[8] = {0,0,0,0,0,0,0,0};
#pragma unroll
    for (int m=0;m<Mq;m++){
        u32x4 hv = *(const u32x4*)(hbuf  + (size_t)idx[m]*HP + j0);
        u32x4 uv = *(const u32x4*)(uhbuf + (size_t)idx[m]*HP + j0);
#pragma unroll
        for (int e=0;e<8;e++){
            float h = bf2f((ushort)((hv[e>>1] >> ((e&1)*16)) & 0xffff));
            float u = bf2f((ushort)((uv[e>>1] >> ((e&1)*16)) & 0xffff));
            sh[e] += h;
            gt[e] += h * sigmf(er[e] + u);
        }
    }
    u32x4 so, go;
    so[0]=pk2(sh[0],sh[1]); so[1]=pk2(sh[2],sh[3]);
    so[2]=pk2(sh[4],sh[5]); so[3]=pk2(sh[6],sh[7]);
    go[0]=pk2(gt[0],gt[1]); go[1]=pk2(gt[2],gt[3]);
    go[2]=pk2(gt[4],gt[5]); go[3]=pk2(gt[6],gt[7]);
    *(u32x4*)(sumhC  + (size_t)i*HP + j0) = so;
    *(u32x4*)(gatedC + (size_t)i*HP + j0) = go;
}

// ---------- scan: twin GEMM + blend, wide grid (15 col-tiles x 16 row-tiles) ----------
// Rows are compacted (all valid). A/B direct from global; weight K-pads are zero,
// so garbage beyond cnt rows / k>=450 is harmless (outputs discarded / times zero).
__global__ __launch_bounds__(256) void zh_k(int t,
    const int* __restrict__ x_wid,
    const int* __restrict__ vcnt, const int* __restrict__ vlist,
    const float* __restrict__ EZ, const float* __restrict__ EH,
    const ushort* __restrict__ WzS, const ushort* __restrict__ WhG,
    const ushort* __restrict__ sumhC, const ushort* __restrict__ gatedC,
    ushort* __restrict__ nhC, ushort* __restrict__ hbuf)
{
    const int cnt = vcnt[t];
    const int rows0 = blockIdx.y*32;
    if (rows0 >= cnt) return;
    const int cols0 = blockIdx.x*32;
    const int lane = threadIdx.x & 63, w = threadIdx.x >> 6;
    const int wr = w >> 1, wc = w & 1;
    const int ai = rows0 + wr*16 + (lane & 15);       // compacted A row
    const int C  = cols0 + wc*16 + (lane & 15);       // output col
    const int kq = (lane >> 4) * 8;
    const ushort* aZp = sumhC  + (size_t)ai*HP + kq;
    const ushort* aGp = gatedC + (size_t)ai*HP + kq;
    const ushort* bZp = WzS + (size_t)C*HP + kq;
    const ushort* bGp = WhG + (size_t)C*HP + kq;
    f32x4 accZ = (f32x4){0,0,0,0}, accH = (f32x4){0,0,0,0};
#pragma unroll 5
    for (int kt=0; kt<15; ++kt){
        const int kb = kt*32;
        bf16x8 aZ = *(const bf16x8*)(aZp + kb);
        bf16x8 aG = *(const bf16x8*)(aGp + kb);
        bf16x8 bZ = *(const bf16x8*)(bZp + kb);
        bf16x8 bG = *(const bf16x8*)(bGp + kb);
        accZ = __builtin_amdgcn_mfma_f32_16x16x32_bf16(aZ, bZ, accZ, 0, 0, 0);
        accH = __builtin_amdgcn_mfma_f32_16x16x32_bf16(aG, bG, accH, 0, 0, 0);
    }
    // C/D: col = lane&15 (+tile), row = (lane>>4)*4 + j (+tile)
#pragma unroll
    for (int j=0; j<4; j++){
        const int i = rows0 + wr*16 + ((lane>>4)<<2) + j;
        if (i >= cnt) continue;
        const int b = vlist[t*Bq + i];
        const int base = t*Bq + b;
        ushort o = 0;
        if (C < Hq){
            const int wid = x_wid[base];
            float z  = sigmf(accZ[j] + EZ[(size_t)wid*F32S + C]);
            float ht = tanhfast(accH[j] + EH[(size_t)wid*F32S + C]);
            float sh = bf2f(sumhC[(size_t)i*HP + C]);
            o = f2bf((1.f - z)*sh + z*ht);
            hbuf[(size_t)(1 + base)*HP + C] = o;      // all compacted rows valid
        }
        nhC[(size_t)i*HP + C] = o;                    // zero in pad cols
    }
}

// ---------- scan: uh = nh @ Ur^T, wide grid ----------
__global__ __launch_bounds__(256) void ur_k(int t,
    const int* __restrict__ vcnt, const int* __restrict__ vlist,
    const ushort* __restrict__ UrB, const ushort* __restrict__ nhC,
    ushort* __restrict__ uhbuf)
{
    const int cnt = vcnt[t];
    const int rows0 = blockIdx.y*32;
    if (rows0 >= cnt) return;
    const int cols0 = blockIdx.x*32;
    const int lane = threadIdx.x & 63, w = threadIdx.x >> 6;
    const int wr = w >> 1, wc = w & 1;
    const int ai = rows0 + wr*16 + (lane & 15);
    const int C  = cols0 + wc*16 + (lane & 15);
    const int kq = (lane >> 4) * 8;
    const ushort* aNp = nhC + (size_t)ai*HP + kq;
    const ushort* bUp = UrB + (size_t)C*HP + kq;
    f32x4 acc = (f32x4){0,0,0,0};
#pragma unroll 5
    for (int kt=0; kt<15; ++kt){
        const int kb = kt*32;
        bf16x8 aN = *(const bf16x8*)(aNp + kb);
        bf16x8 bU = *(const bf16x8*)(bUp + kb);
        acc = __builtin_amdgcn_mfma_f32_16x16x32_bf16(aN, bU, acc, 0, 0, 0);
    }
    if (C < Hq){
#pragma unroll
        for (int j=0; j<4; j++){
            const int i = rows0 + wr*16 + ((lane>>4)<<2) + j;
            if (i >= cnt) continue;
            const int b = vlist[t*Bq + i];
            uhbuf[(size_t)(1 + t*Bq + b)*HP + C] = f2bf(acc[j]);
        }
    }
}

// ---------- pred GEMM1 (compacted rows) ----------
__global__ __launch_bounds__(256) void pred1c_k(const int* __restrict__ np_,
    const int* __restrict__ listp, const ushort* __restrict__ hbuf,
    const float* __restrict__ TP, const ushort* __restrict__ WHp,
    ushort* __restrict__ pv)
{
    const int np = *np_;
    const int row0 = blockIdx.y*128;
    if (row0 >= np) return;
    const int col0 = blockIdx.x*64;
    const int tid = threadIdx.x;
    int i0 = row0 + (tid>>2), i1 = i0 + 64;
    int g0 = (i0 < np) ? listp[i0] : 0;
    int g1 = (i1 < np) ? listp[i1] : 0;
    const ushort* p0 = (g0 < Bq) ? hbuf : hbuf + (size_t)(1 + g0 - Bq)*HP;  // hbuf row0 = zeros
    const ushort* p1 = (g1 < Bq) ? hbuf : hbuf + (size_t)(1 + g1 - Bq)*HP;
    f32x4 acc[4][2];
    mgemm2([&](int which,int k0){ return (which?p1:p0)+k0; }, WHp, HP, 15, col0, acc);
    EPI_PRE
#pragma unroll
    for (int f=0; f<4; f++)
#pragma unroll
      for (int g=0; g<2; g++){
        int col = col0 + wn*32 + g*16 + (lane & 15);
        if (col >= HP) continue;
#pragma unroll
        for (int j=0; j<4; j++){
            int i = row0 + wm*64 + f*16 + ((lane>>4)<<2) + j;
            if (i >= np) continue;
            int gr = listp[i];
            int b = (gr < Bq) ? gr : ((gr - Bq) & (Bq-1));
            float v = 0.f;
            if (col < Hq) v = fmaxf(acc[f][g][j] + TP[(size_t)b*F32S + col], 0.f);
            pv[(size_t)i*HP + col] = f2bf(v);
        }
      }
}

// ---------- pred GEMM2 ----------
__global__ __launch_bounds__(256) void pred2c_k(int cs, const int* __restrict__ np_,
    const ushort* __restrict__ pv, const ushort* __restrict__ WOp,
    const float* __restrict__ bWo, float* __restrict__ scores)
{
    const int np = *np_;
    const int row0 = blockIdx.y*128;
    if (cs + row0 >= np) return;
    const int col0 = blockIdx.x*64;
    const int tid = threadIdx.x;
    const ushort* p0 = pv + (size_t)(cs + row0 + (tid>>2))*HP;
    const ushort* p1 = p0 + (size_t)64*HP;
    f32x4 acc[4][2];
    mgemm2([&](int which,int k0){ return (which?p1:p0)+k0; }, WOp, HP, 15, col0, acc);
    EPI_PRE
#pragma unroll
    for (int f=0; f<4; f++)
#pragma unroll
      for (int g=0; g<2; g++){
        int col = col0 + wn*32 + g*16 + (lane & 15);
        if (col >= Vq) continue;
        float bc = bWo[col];
#pragma unroll
        for (int j=0; j<4; j++){
            int r = row0 + wm*64 + f*16 + ((lane>>4)<<2) + j;
            scores[(size_t)r*832 + col] = acc[f][g][j] + bc;
        }
      }
}

// ---------- pred reduce: wave-per-row ----------
__global__ __launch_bounds__(256) void predred_k(int cs, const int* __restrict__ np_,
    const int* __restrict__ listp, const float* __restrict__ scores,
    const int* __restrict__ pred_wid, const int* __restrict__ root_wid,
    float* __restrict__ accv)
{
    const int np = *np_;
    int nrows = np - cs; if (nrows > CH2) nrows = CH2;
    const int lane = threadIdx.x & 63, wv = threadIdx.x >> 6;
    const int wid_g = blockIdx.x*4 + wv, nw = gridDim.x*4;
    float ce = 0.f, hit = 0.f, cnt = 0.f;
    for (int r = wid_g; r < nrows; r += nw){
        const float* sc = scores + (size_t)r*832;
        int gr = listp[cs + r];
        int tgt = (gr < Bq) ? root_wid[gr] : pred_wid[gr - Bq];
        float vals[13];
        float bv = -INFINITY, tv = 0.f; int bi = 0;
#pragma unroll
        for (int q=0; q<13; q++){
            int j = lane + q*64;
            float v = (j < Vq) ? sc[j] : -INFINITY;
            vals[q] = v;
            if (v > bv){ bv = v; bi = j; }
            if (j == tgt) tv = v;
        }
#pragma unroll
        for (int off=32; off; off>>=1){
            float ov = __shfl_xor(bv, off); int oi = __shfl_xor(bi, off);
            if (ov > bv || (ov == bv && oi < bi)){ bv = ov; bi = oi; }
        }
        float s = 0.f;
#pragma unroll
        for (int q=0; q<13; q++){
            int j = lane + q*64;
            if (j < Vq) s += __expf(vals[q] - bv);
        }
#pragma unroll
        for (int off=32; off; off>>=1) s += __shfl_xor(s, off);
#pragma unroll
        for (int off=32; off; off>>=1) tv += __shfl_xor(tv, off);
        if (lane == 0){
            ce += bv + logf(s) - tv;
            hit += (bi == tgt) ? 1.f : 0.f;
            cnt += 1.f;
        }
    }
    __shared__ float L[3][4];
    if (lane == 0){ L[0][wv] = ce; L[1][wv] = hit; L[2][wv] = cnt; }
    __syncthreads();
    if (threadIdx.x == 0){
        float a = L[0][0]+L[0][1]+L[0][2]+L[0][3];
        float b = L[1][0]+L[1][1]+L[1][2]+L[1][3];
        float c = L[2][0]+L[2][1]+L[2][2]+L[2][3];
        if (c != 0.f){
            atomicAdd(&accv[0], a);
            atomicAdd(&accv[1], b);
            atomicAdd(&accv[2], c);
        }
    }
}

// ---------- stop: cur_o gather (compacted) ----------
__global__ void curo_c(const int* __restrict__ ns_, const int* __restrict__ lists,
                       const int* __restrict__ o_nei_idx, const int* __restrict__ root_o_nei,
                       const ushort* __restrict__ hbuf, ushort* __restrict__ curo)
{
    int i = blockIdx.x;
    if (i >= *ns_) return;
    int gr = lists[i];
    int j0 = threadIdx.x * 4;
    if (j0 >= HP) return;
    int idx[Mq];
    if (gr < TBq){
        int tt = gr >> 9;
#pragma unroll
        for (int m=0;m<Mq;m++){
            int ix = o_nei_idx[(size_t)gr*Mq + m];
            idx[m] = (ix <= tt*Bq) ? ix : 0;   // slots written before step tt; row 0 is zero
        }
    } else {
#pragma unroll
        for (int m=0;m<Mq;m++) idx[m] = root_o_nei[(size_t)(gr-TBq)*Mq + m];
    }
    float s0=0,s1=0,s2=0,s3=0;
#pragma unroll
    for (int m=0;m<Mq;m++){
        uint2 v = *(const uint2*)(hbuf + (size_t)idx[m]*HP + j0);
        s0 += bf2f((ushort)(v.x & 0xffff)); s1 += bf2f((ushort)(v.x >> 16));
        s2 += bf2f((ushort)(v.y & 0xffff)); s3 += bf2f((ushort)(v.y >> 16));
    }
    uint2 o; o.x = pk2(s0, s1); o.y = pk2(s2, s3);
    *(uint2*)(curo + (size_t)i*HP + j0) = o;
}

// ---------- stop GEMM (compacted) + fused Us-dot ----------
__global__ __launch_bounds__(256) void stopc_k(const int* __restrict__ ns_,
    const int* __restrict__ lists, const int* __restrict__ x_wid,
    const int* __restrict__ root_wid, const ushort* __restrict__ curo,
    const ushort* __restrict__ UOp, const float* __restrict__ EU,
    const float* __restrict__ TU, const float* __restrict__ Usf,
    float* __restrict__ ss)
{
    const int ns = *ns_;
    const int row0 = blockIdx.y*128;
    if (row0 >= ns) return;
    const int col0 = blockIdx.x*64;
    const int tid = threadIdx.x;
    const ushort* p0 = curo + (size_t)(row0 + (tid>>2))*HP;
    const ushort* p1 = p0 + (size_t)64*HP;
    f32x4 acc[4][2];
    mgemm2([&](int which,int k0){ return (which?p1:p0)+k0; }, UOp, HP, 15, col0, acc);
    EPI_PRE
#pragma unroll
    for (int f=0; f<4; f++){
#pragma unroll
        for (int j=0; j<4; j++){
            int i = row0 + wm*64 + f*16 + ((lane>>4)<<2) + j;
            float p = 0.f;
            if (i < ns){
                int gr = lists[i];
                int wid = (gr < TBq) ? x_wid[gr] : root_wid[gr - TBq];
                int b   = (gr < TBq) ? (gr & (Bq-1)) : (gr - TBq);
                const float* eu = EU + (size_t)wid*F32S;
                const float* tu = TU + (size_t)b*F32S;
#pragma unroll
                for (int g=0; g<2; g++){
                    int col = col0 + wn*32 + g*16 + (lane & 15);
                    if (col < Hq)
                        p += fmaxf(acc[f][g][j] + eu[col] + tu[col], 0.f) * Usf[col];
                }
            }
            p += __shfl_xor(p, 1); p += __shfl_xor(p, 2);
            p += __shfl_xor(p, 4); p += __shfl_xor(p, 8);
            if ((lane & 15) == 0 && i < ns) atomicAdd(&ss[i], p);
        }
    }
}

__global__ void stopfin_k(const int* __restrict__ ns_, const int* __restrict__ lists,
    const float* __restrict__ ss, const float* __restrict__ bUs,
    const int* __restrict__ direction, float* __restrict__ accv)
{
    const int ns = *ns_;
    int i = blockIdx.x*256 + threadIdx.x;
    float bce = 0.f, hit = 0.f, c = 0.f;
    if (i < ns){
        int gr = lists[i];
        float s = ss[i] + bUs[0];
        float stgt = (gr < TBq) ? (float)direction[gr] : 0.f;
        bce = fmaxf(s,0.f) - s*stgt + log1pf(__expf(-fabsf(s)));
        hit = ((((s >= 0.f) ? 1.f : 0.f) == stgt) ? 1.f : 0.f);
        c = 1.f;
    }
    for (int off=32; off; off>>=1){
        bce += __shfl_down(bce, off);
        hit += __shfl_down(hit, off);
        c   += __shfl_down(c,   off);
    }
    if ((threadIdx.x & 63) == 0 && c != 0.f){
        atomicAdd(&accv[3], bce);
        atomicAdd(&accv[4], hit);
        atomicAdd(&accv[5], c);
    }
}

__global__ void finalize_k(const float* __restrict__ accv, float* __restrict__ out){
    if (threadIdx.x == 0){
        out[0] = accv[0] / (float)Bq;
        out[1] = accv[3] / (float)Bq;
        out[2] = accv[1] / accv[2];
        out[3] = accv[4] / accv[5];
    }
}

extern "C" void kernel_launch(void* const* d_in, const int* in_sizes, int n_in,
                              void* d_out, int out_size, void* d_ws, size_t ws_size,
                              hipStream_t stream) {
    (void)in_sizes; (void)n_in; (void)out_size; (void)ws_size;
    const float* tree_vecs = (const float*)d_in[0];
    const int*   x_wid     = (const int*)d_in[1];
    const int*   pred_wid  = (const int*)d_in[2];
    const int*   root_wid  = (const int*)d_in[3];
    const int*   h_nei_idx = (const int*)d_in[4];
    const int*   o_nei_idx = (const int*)d_in[5];
    const int*   root_o_nei= (const int*)d_in[6];
    const int*   valid     = (const int*)d_in[7];
    const int*   direction = (const int*)d_in[8];
    const float* emb       = (const float*)d_in[9];
    const float* Wz        = (const float*)d_in[10];
    const float* bz        = (const float*)d_in[11];
    const float* Wr        = (const float*)d_in[12];
    const float* br        = (const float*)d_in[13];
    const float* Ur        = (const float*)d_in[14];
    const float* Wh        = (const float*)d_in[15];
    const float* bh        = (const float*)d_in[16];
    const float* Wm        = (const float*)d_in[17];
    const float* bW        = (const float*)d_in[18];
    const float* U         = (const float*)d_in[19];
    const float* bU        = (const float*)d_in[20];
    const float* Wo        = (const float*)d_in[21];
    const float* bWo       = (const float*)d_in[22];
    const float* Us        = (const float*)d_in[23];
    const float* bUs       = (const float*)d_in[24];

    char* w = (char*)d_ws; size_t off = 0;
    auto alloc = [&](size_t bytes)->void*{ void* p = w + off; off += (bytes + 255) & ~(size_t)255; return p; };

    ushort* hbuf  = (ushort*)alloc((size_t)Sq*HP*2);
    ushort* uhbuf = (ushort*)alloc((size_t)Sq*HP*2);
    ushort* embb  = (ushort*)alloc((size_t)896*HP*2);
    ushort* treeb = (ushort*)alloc((size_t)Bq*64*2);
    ushort* WzX   = (ushort*)alloc((size_t)512*HP*2);
    ushort* WzS   = (ushort*)alloc((size_t)512*HP*2);
    ushort* WrB   = (ushort*)alloc((size_t)512*HP*2);
    ushort* WhX   = (ushort*)alloc((size_t)512*HP*2);
    ushort* WhG   = (ushort*)alloc((size_t)512*HP*2);
    ushort* UrB   = (ushort*)alloc((size_t)512*HP*2);
    ushort* WHp   = (ushort*)alloc((size_t)512*HP*2);
    ushort* UXp   = (ushort*)alloc((size_t)512*HP*2);
    ushort* UOp   = (ushort*)alloc((size_t)512*HP*2);
    ushort* WOp   = (ushort*)alloc((size_t)832*HP*2);
    ushort* WLp   = (ushort*)alloc((size_t)512*64*2);
    ushort* ULp   = (ushort*)alloc((size_t)512*64*2);
    float*  EZ    = (float*)alloc((size_t)Vq*F32S*4);
    float*  ER    = (float*)alloc((size_t)Vq*F32S*4);
    float*  EH    = (float*)alloc((size_t)Vq*F32S*4);
    float*  EU    = (float*)alloc((size_t)Vq*F32S*4);
    float*  TP    = (float*)alloc((size_t)Bq*F32S*4);
    float*  TU    = (float*)alloc((size_t)Bq*F32S*4);
    ushort* sumhC = (ushort*)alloc((size_t)Bq*HP*2);
    ushort* gatedC= (ushort*)alloc((size_t)Bq*HP*2);
    ushort* nhC   = (ushort*)alloc((size_t)Bq*HP*2);
    ushort* pv    = (ushort*)alloc((size_t)NPCAP*HP*2);
    float*  scores= (float*)alloc((size_t)CH2*832*4);
    float*  ss    = (float*)alloc((size_t)NSCAP*4);
    int*    listp = (int*)alloc((size_t)NPCAP*4);
    int*    lists = (int*)alloc((size_t)NSCAP*4);
    int*    vlist = (int*)alloc((size_t)Tq*Bq*4);
    int*    vcnt  = (int*)alloc((size_t)Tq*4);
    int*    meta  = (int*)alloc((size_t)(NPB*4 + 2 + 16)*4);
    int*    cnts  = meta;            // [2*NPB]
    int*    offs  = meta + 2*NPB;    // [2*NPB]
    int*    tot   = meta + 4*NPB;    // [2]
    float*  accv  = (float*)(meta + 4*NPB + 2);
    ushort* curo  = pv;              // stop phase reuses pv/scores region

    (void)hipMemsetAsync(hbuf,  0, (size_t)Sq*HP*2, stream);
    (void)hipMemsetAsync(uhbuf, 0, (size_t)Sq*HP*2, stream);
    (void)hipMemsetAsync(ss,    0, (size_t)NSCAP*4, stream);
    (void)hipMemsetAsync(meta,  0, (size_t)(NPB*4 + 2 + 16)*4, stream);

    // ---- conversions (1 launch) ----
    convAll_k<<<dim3(896,14), 128, 0, stream>>>(
        emb, tree_vecs, Wz, Wr, Ur, Wh, Wm, U, Wo,
        embb, treeb, WzX, WzS, WrB, WhX, WhG, UrB, WHp, UXp, UOp, WOp, WLp, ULp);

    // ---- precomputes (2 launches) ----
    preE_k<<<dim3(8,7,4), 256, 0, stream>>>(embb, WzX, WrB, WhX, UXp,
                                            bz, br, bh, bU, EZ, ER, EH, EU);
    preT_k<<<dim3(8,4,2), 256, 0, stream>>>(treeb, WLp, ULp, bW, TP, TU);

    // ---- row compaction (pred/stop + per-step valid lists) ----
    cnt_k <<<dim3(NPB,2), 256, 0, stream>>>(valid, direction, cnts);
    scan_k<<<1, 64, 0, stream>>>(cnts, offs, tot);
    fill_k<<<dim3(NPB,2), 256, 0, stream>>>(valid, direction, offs, listp, lists);
    vfill_k<<<Tq, 512, 0, stream>>>(valid, vcnt, vlist);

    // ---- sequential scan: 3 wide kernels per step ----
    for (int t=0; t<Tq; t++){
        gather_k<<<115, 256, 0, stream>>>(t, x_wid, h_nei_idx, ER, vcnt, vlist,
                                          hbuf, uhbuf, sumhC, gatedC);
        zh_k<<<dim3(15,16), 256, 0, stream>>>(t, x_wid, vcnt, vlist, EZ, EH,
                                              WzS, WhG, sumhC, gatedC, nhC, hbuf);
        ur_k<<<dim3(15,16), 256, 0, stream>>>(t, vcnt, vlist, UrB, nhC, uhbuf);
    }

    // ---- pred phase (compacted) ----
    pred1c_k<<<dim3(8, NPCAP/128), 256, 0, stream>>>(tot, listp, hbuf, TP, WHp, pv);
    for (int c=0; c<NCH2; c++){
        int cs = c*CH2;
        pred2c_k<<<dim3(13, CH2/128), 256, 0, stream>>>(cs, tot, pv, WOp, bWo, scores);
        predred_k<<<256, 256, 0, stream>>>(cs, tot, listp, scores, pred_wid, root_wid, accv);
    }

    // ---- stop phase (compacted) ----
    curo_c<<<NSCAP, 128, 0, stream>>>(tot+1, lists, o_nei_idx, root_o_nei, hbuf, curo);
    stopc_k<<<dim3(8, NSCAP/128), 256, 0, stream>>>(tot+1, lists, x_wid, root_wid,
                                                    curo, UOp, EU, TU, Us, ss);
    stopfin_k<<<NSCAP/256, 256, 0, stream>>>(tot+1, lists, ss, bUs, direction, accv);

    finalize_k<<<1, 64, 0, stream>>>(accv, (float*)d_out);
}

// Round 13
// 1452.353 us; speedup vs baseline: 3.9056x; 1.0047x over previous
//
#include <hip/hip_runtime.h>
#include <math.h>

#define Bq 512
#define Tq 64
#define Hq 450
#define Lq 56
#define Vq 780
#define Mq 8
#define TBq 32768
#define Sq 32770
#define HP 480          // bf16 row stride (mult of 32)
#define NPB 130         // 130*256 = 33280 rows
#define NPCAP 12288     // compacted pred rows cap
#define NSCAP 20480     // compacted stop rows cap
#define CH2 4096        // pred score chunk rows
#define NCH2 3

using bf16x8 = __attribute__((ext_vector_type(8))) __bf16;
using f32x4  = __attribute__((ext_vector_type(4))) float;
using u32x4  = __attribute__((ext_vector_type(4))) unsigned;

__device__ __forceinline__ ushort f2bf(float f){
    union { float f; unsigned u; } c; c.f = f;
    unsigned u = c.u;
    return (ushort)((u + 0x7FFFu + ((u >> 16) & 1u)) >> 16);
}
__device__ __forceinline__ float bf2f(ushort h){
    union { unsigned u; float f; } c; c.u = ((unsigned)h) << 16;
    return c.f;
}
__device__ __forceinline__ unsigned pk2(float a, float b){
    return (unsigned)f2bf(a) | ((unsigned)f2bf(b) << 16);
}
__device__ __forceinline__ float sigmf(float x){
    return __builtin_amdgcn_rcpf(1.f + __expf(-x));
}
__device__ __forceinline__ float tanhfast(float x){
    float e2 = __expf(2.f * x);
    return 1.f - 2.f * __builtin_amdgcn_rcpf(e2 + 1.f);
}

// ---------- fused converter: 14 jobs by blockIdx.y ----------
__global__ void convAll_k(
    const float* __restrict__ emb, const float* __restrict__ tree,
    const float* __restrict__ Wz, const float* __restrict__ Wr,
    const float* __restrict__ Ur, const float* __restrict__ Wh,
    const float* __restrict__ Wm, const float* __restrict__ U, const float* __restrict__ Wo,
    ushort* embb, ushort* treeb, ushort* WzX, ushort* WzS, ushort* WrB,
    ushort* WhX, ushort* WhG, ushort* UrB, ushort* WHp, ushort* UXp,
    ushort* UOp, ushort* WOp, ushort* WLp, ushort* ULp)
{
    int job = blockIdx.y, n = blockIdx.x;
    const float* src; ushort* dst; int Npad, Nsrc, Ksrc, Kpad, len, off;
    switch(job){
      case 0:  src=emb;  dst=embb; Npad=896; Nsrc=780; Ksrc=450; Kpad=480; len=450; off=0;   break;
      case 1:  src=tree; dst=treeb;Npad=512; Nsrc=512; Ksrc=56;  Kpad=64;  len=56;  off=0;   break;
      case 2:  src=Wz;   dst=WzX;  Npad=512; Nsrc=450; Ksrc=900; Kpad=480; len=450; off=0;   break;
      case 3:  src=Wz;   dst=WzS;  Npad=512; Nsrc=450; Ksrc=900; Kpad=480; len=450; off=450; break;
      case 4:  src=Wr;   dst=WrB;  Npad=512; Nsrc=450; Ksrc=450; Kpad=480; len=450; off=0;   break;
      case 5:  src=Wh;   dst=WhX;  Npad=512; Nsrc=450; Ksrc=900; Kpad=480; len=450; off=0;   break;
      case 6:  src=Wh;   dst=WhG;  Npad=512; Nsrc=450; Ksrc=900; Kpad=480; len=450; off=450; break;
      case 7:  src=Ur;   dst=UrB;  Npad=512; Nsrc=450; Ksrc=450; Kpad=480; len=450; off=0;   break;
      case 8:  src=Wm;   dst=WHp;  Npad=512; Nsrc=450; Ksrc=506; Kpad=480; len=450; off=0;   break;
      case 9:  src=U;    dst=UXp;  Npad=512; Nsrc=450; Ksrc=956; Kpad=480; len=450; off=0;   break;
      case 10: src=U;    dst=UOp;  Npad=512; Nsrc=450; Ksrc=956; Kpad=480; len=450; off=450; break;
      case 11: src=Wo;   dst=WOp;  Npad=832; Nsrc=780; Ksrc=450; Kpad=480; len=450; off=0;   break;
      case 12: src=Wm;   dst=WLp;  Npad=512; Nsrc=450; Ksrc=506; Kpad=64;  len=56;  off=450; break;
      default: src=U;    dst=ULp;  Npad=512; Nsrc=450; Ksrc=956; Kpad=64;  len=56;  off=900; break;
    }
    if (n >= Npad) return;
    for (int k = threadIdx.x; k < Kpad; k += blockDim.x){
        float v = 0.f;
        if (n < Nsrc && k < len) v = src[(size_t)n*Ksrc + off + k];
        dst[(size_t)n*Kpad + k] = f2bf(v);
    }
}

// ---------- double-buffered MFMA GEMM body: C(128x64) tile ----------
template<class APtr>
__device__ __forceinline__ void mgemm2(APtr&& aptr, const ushort* __restrict__ Bw, int ldb,
                                       int KT, int col0, f32x4 acc[4][2])
{
    __shared__ __align__(16) char As[2][128*80];
    __shared__ __align__(16) char Bs[2][64*80];
    const int tid = threadIdx.x;
    const int lane = tid & 63;
    const int w = tid >> 6, wm = w >> 1, wn = w & 1;
    const int ac = (tid & 3) * 8;
    const size_t boff = (size_t)(col0 + (tid >> 2)) * ldb;
    u32x4 ra0, ra1, rb;
    auto ld = [&](int k0){
        ra0 = *(const u32x4*)(aptr(0, k0) + ac);
        ra1 = *(const u32x4*)(aptr(1, k0) + ac);
        rb  = *(const u32x4*)(Bw + boff + k0 + ac);
    };
    const int wr_a0 = (tid>>2)*80 + (tid&3)*16;
    const int wr_a1 = ((tid>>2)+64)*80 + (tid&3)*16;
    const int wr_b  = (tid>>2)*80 + (tid&3)*16;
    const int rd_a  = (wm*64 + (lane&15))*80 + (lane>>4)*16;
    const int rd_b  = (wn*32 + (lane&15))*80 + (lane>>4)*16;
    ld(0);
    *(u32x4*)(As[0]+wr_a0) = ra0; *(u32x4*)(As[0]+wr_a1) = ra1; *(u32x4*)(Bs[0]+wr_b) = rb;
#pragma unroll
    for (int f=0;f<4;f++)
#pragma unroll
        for (int g=0;g<2;g++) acc[f][g] = (f32x4){0.f,0.f,0.f,0.f};
    __syncthreads();
    for (int kt=0; kt<KT; ++kt){
        const int cur = kt & 1;
        if (kt+1 < KT) ld((kt+1)*32);
        bf16x8 bF[2];
#pragma unroll
        for (int g=0; g<2; g++) bF[g] = *(const bf16x8*)(Bs[cur] + rd_b + g*16*80);
#pragma unroll
        for (int f=0; f<4; f++){
            bf16x8 aF = *(const bf16x8*)(As[cur] + rd_a + f*16*80);
#pragma unroll
            for (int g=0; g<2; g++)
                acc[f][g] = __builtin_amdgcn_mfma_f32_16x16x32_bf16(aF, bF[g], acc[f][g], 0, 0, 0);
        }
        if (kt+1 < KT){
            *(u32x4*)(As[cur^1]+wr_a0) = ra0; *(u32x4*)(As[cur^1]+wr_a1) = ra1;
            *(u32x4*)(Bs[cur^1]+wr_b) = rb;
        }
        __syncthreads();
    }
}

#define EPI_PRE  const int lane = threadIdx.x & 63; const int w_ = threadIdx.x >> 6; \
                 const int wm = w_ >> 1, wn = w_ & 1;

// ---------- precompute GEMM body: out bf16 [rows][HP] ----------
__device__ __forceinline__ void pre_body(const ushort* __restrict__ A, int lda,
    const ushort* __restrict__ Bw, const float* __restrict__ bias,
    ushort* __restrict__ out, int Mr, int KT)
{
    const int row0 = blockIdx.y*128, col0 = blockIdx.x*64;
    const int tid = threadIdx.x;
    const ushort* p0 = A + (size_t)(row0 + (tid>>2))*lda;
    const ushort* p1 = p0 + (size_t)64*lda;
    f32x4 acc[4][2];
    mgemm2([&](int which,int k0){ return (which?p1:p0)+k0; }, Bw, lda, KT, col0, acc);
    EPI_PRE
#pragma unroll
    for (int f=0; f<4; f++)
#pragma unroll
      for (int g=0; g<2; g++){
        int col = col0 + wn*32 + g*16 + (lane & 15);
        if (col >= HP) continue;
        float bb = 0.f;
        if (col < Hq && bias) bb = bias[col];
#pragma unroll
        for (int j=0; j<4; j++){
            int row = row0 + wm*64 + f*16 + ((lane>>4)<<2) + j;
            if (row < Mr) out[(size_t)row*HP + col] = (col < Hq) ? f2bf(acc[f][g][j] + bb) : 0;
        }
      }
}

__global__ __launch_bounds__(256) void preE_k(
    const ushort* __restrict__ embb,
    const ushort* __restrict__ WzX, const ushort* __restrict__ WrB,
    const ushort* __restrict__ WhX, const ushort* __restrict__ UXp,
    const float* __restrict__ bz, const float* __restrict__ br,
    const float* __restrict__ bh, const float* __restrict__ bU,
    ushort* __restrict__ EZ, ushort* __restrict__ ER,
    ushort* __restrict__ EH, ushort* __restrict__ EU)
{
    const ushort* Bw; const float* bias; ushort* out;
    switch(blockIdx.z){
      case 0:  Bw=WzX; bias=bz; out=EZ; break;
      case 1:  Bw=WrB; bias=br; out=ER; break;
      case 2:  Bw=WhX; bias=bh; out=EH; break;
      default: Bw=UXp; bias=bU; out=EU; break;
    }
    pre_body(embb, HP, Bw, bias, out, Vq, 15);
}

__global__ __launch_bounds__(256) void preT_k(
    const ushort* __restrict__ treeb,
    const ushort* __restrict__ WLp, const ushort* __restrict__ ULp,
    const float* __restrict__ bW, ushort* __restrict__ TP, ushort* __restrict__ TU)
{
    const ushort* Bw = blockIdx.z ? ULp : WLp;
    const float* bias = blockIdx.z ? nullptr : bW;
    ushort* out = blockIdx.z ? TU : TP;
    pre_body(treeb, 64, Bw, bias, out, Bq, 2);
}

// ---------- compaction for pred/stop: count / scan / fill ----------
__device__ __forceinline__ bool cmask(int which, int gr,
    const int* __restrict__ valid, const int* __restrict__ dir)
{
    if (which == 0) return (gr < Bq) ? true : (valid[gr-Bq] && dir[gr-Bq]);
    return (gr < TBq) ? (valid[gr] != 0) : true;
}
__global__ void cnt_k(const int* __restrict__ valid, const int* __restrict__ dir,
                      int* __restrict__ cnts)
{
    int which = blockIdx.y;
    int gr = blockIdx.x*256 + threadIdx.x;
    bool m = cmask(which, gr, valid, dir);
    unsigned long long bal = __ballot(m);
    if ((threadIdx.x & 63) == 0)
        atomicAdd(&cnts[which*NPB + blockIdx.x], (int)__popcll(bal));
}
__global__ void scan_k(const int* __restrict__ cnts, int* __restrict__ offs,
                       int* __restrict__ totals)
{
    if (threadIdx.x == 0){
        int a = 0;
        for (int i=0;i<NPB;i++){ offs[i] = a; a += cnts[i]; }
        totals[0] = a;
        int b = 0;
        for (int i=0;i<NPB;i++){ offs[NPB+i] = b; b += cnts[NPB+i]; }
        totals[1] = b;
    }
}
__global__ void fill_k(const int* __restrict__ valid, const int* __restrict__ dir,
                       const int* __restrict__ offs, int* __restrict__ listp,
                       int* __restrict__ lists)
{
    __shared__ int woff[4];
    int which = blockIdx.y;
    int gr = blockIdx.x*256 + threadIdx.x;
    bool m = cmask(which, gr, valid, dir);
    unsigned long long bal = __ballot(m);
    int lane = threadIdx.x & 63, wv = threadIdx.x >> 6;
    if (lane == 0) woff[wv] = (int)__popcll(bal);
    __syncthreads();
    int prev = 0;
    for (int i=0;i<wv;i++) prev += woff[i];
    if (m){
        int rank = prev + (int)__popcll(bal & ((1ull << lane) - 1ull));
        int pos = offs[which*NPB + blockIdx.x] + rank;
        if (which == 0){ if (pos < NPCAP) listp[pos] = gr; }
        else           { if (pos < NSCAP) lists[pos] = gr; }
    }
}

// ---------- per-step valid-row lists: vlist[t*Bq + i] = b, vcnt[t] ----------
__global__ void vfill_k(const int* __restrict__ valid,
                        int* __restrict__ vcnt, int* __restrict__ vlist)
{
    __shared__ int woff[8];
    const int t = blockIdx.x;
    const int b = threadIdx.x;              // 512 threads
    bool m = valid[t*Bq + b] != 0;
    unsigned long long bal = __ballot(m);
    int lane = b & 63, wv = b >> 6;
    if (lane == 0) woff[wv] = (int)__popcll(bal);
    __syncthreads();
    int prev = 0;
    for (int i=0;i<wv;i++) prev += woff[i];
    if (m) vlist[t*Bq + prev + (int)__popcll(bal & ((1ull<<lane)-1ull))] = b;
    if (threadIdx.x == 511){
        int tot = 0;
        for (int i=0;i<8;i++) tot += woff[i];
        vcnt[t] = tot;
    }
}

// ---------- scan: gather (compacted valid rows, full machine) ----------
__global__ __launch_bounds__(256) void gather_k(int t,
    const int* __restrict__ x_wid, const int* __restrict__ h_nei_idx,
    const ushort* __restrict__ ER,
    const int* __restrict__ vcnt, const int* __restrict__ vlist,
    const ushort* __restrict__ hbuf, const ushort* __restrict__ uhbuf,
    ushort* __restrict__ sumhC, ushort* __restrict__ gatedC)
{
    const int cnt = vcnt[t];
    const int task = blockIdx.x*256 + threadIdx.x;
    if (task >= cnt*57) return;
    const int i = task / 57;
    const int c = task - i*57;
    const int j0 = c*8;
    const int b = vlist[t*Bq + i];
    const int base = t*Bq + b;
    const int wid = x_wid[base];
    const int* ip = h_nei_idx + (size_t)base*Mq;
    int idx[Mq];
#pragma unroll
    for (int m=0;m<Mq;m++) idx[m] = ip[m];
    float er[8];
    { u32x4 ev = *(const u32x4*)(ER + (size_t)wid*HP + j0);
#pragma unroll
      for (int e=0;e<8;e++) er[e] = bf2f((ushort)((ev[e>>1] >> ((e&1)*16)) & 0xffff)); }
    float sh[8] = {0,0,0,0,0,0,0,0};
    float gt[8] = {0,0,0,0,0,0,0,0};
#pragma unroll
    for (int m=0;m<Mq;m++){
        u32x4 hv = *(const u32x4*)(hbuf  + (size_t)idx[m]*HP + j0);
        u32x4 uv = *(const u32x4*)(uhbuf + (size_t)idx[m]*HP + j0);
#pragma unroll
        for (int e=0;e<8;e++){
            float h = bf2f((ushort)((hv[e>>1] >> ((e&1)*16)) & 0xffff));
            float u = bf2f((ushort)((uv[e>>1] >> ((e&1)*16)) & 0xffff));
            sh[e] += h;
            gt[e] += h * sigmf(er[e] + u);
        }
    }
    u32x4 so, go;
    so[0]=pk2(sh[0],sh[1]); so[1]=pk2(sh[2],sh[3]);
    so[2]=pk2(sh[4],sh[5]); so[3]=pk2(sh[6],sh[7]);
    go[0]=pk2(gt[0],gt[1]); go[1]=pk2(gt[2],gt[3]);
    go[2]=pk2(gt[4],gt[5]); go[3]=pk2(gt[6],gt[7]);
    *(u32x4*)(sumhC  + (size_t)i*HP + j0) = so;
    *(u32x4*)(gatedC + (size_t)i*HP + j0) = go;
}

// ---------- scan: twin GEMM + blend, wide grid (15 col-tiles x 16 row-tiles) ----------
__global__ __launch_bounds__(256) void zh_k(int t,
    const int* __restrict__ x_wid,
    const int* __restrict__ vcnt, const int* __restrict__ vlist,
    const ushort* __restrict__ EZ, const ushort* __restrict__ EH,
    const ushort* __restrict__ WzS, const ushort* __restrict__ WhG,
    const ushort* __restrict__ sumhC, const ushort* __restrict__ gatedC,
    ushort* __restrict__ nhC, ushort* __restrict__ hbuf)
{
    const int cnt = vcnt[t];
    const int rows0 = blockIdx.y*32;
    if (rows0 >= cnt) return;
    const int cols0 = blockIdx.x*32;
    const int lane = threadIdx.x & 63, w = threadIdx.x >> 6;
    const int wr = w >> 1, wc = w & 1;
    const int ai = rows0 + wr*16 + (lane & 15);       // compacted A row
    const int C  = cols0 + wc*16 + (lane & 15);       // output col
    const int kq = (lane >> 4) * 8;
    const ushort* aZp = sumhC  + (size_t)ai*HP + kq;
    const ushort* aGp = gatedC + (size_t)ai*HP + kq;
    const ushort* bZp = WzS + (size_t)C*HP + kq;
    const ushort* bGp = WhG + (size_t)C*HP + kq;
    f32x4 accZ = (f32x4){0,0,0,0}, accH = (f32x4){0,0,0,0};
#pragma unroll 5
    for (int kt=0; kt<15; ++kt){
        const int kb = kt*32;
        bf16x8 aZ = *(const bf16x8*)(aZp + kb);
        bf16x8 aG = *(const bf16x8*)(aGp + kb);
        bf16x8 bZ = *(const bf16x8*)(bZp + kb);
        bf16x8 bG = *(const bf16x8*)(bGp + kb);
        accZ = __builtin_amdgcn_mfma_f32_16x16x32_bf16(aZ, bZ, accZ, 0, 0, 0);
        accH = __builtin_amdgcn_mfma_f32_16x16x32_bf16(aG, bG, accH, 0, 0, 0);
    }
    // C/D: col = lane&15 (+tile), row = (lane>>4)*4 + j (+tile)
#pragma unroll
    for (int j=0; j<4; j++){
        const int i = rows0 + wr*16 + ((lane>>4)<<2) + j;
        if (i >= cnt) continue;
        const int b = vlist[t*Bq + i];
        const int base = t*Bq + b;
        ushort o = 0;
        if (C < Hq){
            const int wid = x_wid[base];
            float z  = sigmf(accZ[j] + bf2f(EZ[(size_t)wid*HP + C]));
            float ht = tanhfast(accH[j] + bf2f(EH[(size_t)wid*HP + C]));
            float sh = bf2f(sumhC[(size_t)i*HP + C]);
            o = f2bf((1.f - z)*sh + z*ht);
            hbuf[(size_t)(1 + base)*HP + C] = o;      // all compacted rows valid
        }
        nhC[(size_t)i*HP + C] = o;                    // zero in pad cols
    }
}

// ---------- scan: uh = nh @ Ur^T, wide grid ----------
__global__ __launch_bounds__(256) void ur_k(int t,
    const int* __restrict__ vcnt, const int* __restrict__ vlist,
    const ushort* __restrict__ UrB, const ushort* __restrict__ nhC,
    ushort* __restrict__ uhbuf)
{
    const int cnt = vcnt[t];
    const int rows0 = blockIdx.y*32;
    if (rows0 >= cnt) return;
    const int cols0 = blockIdx.x*32;
    const int lane = threadIdx.x & 63, w = threadIdx.x >> 6;
    const int wr = w >> 1, wc = w & 1;
    const int ai = rows0 + wr*16 + (lane & 15);
    const int C  = cols0 + wc*16 + (lane & 15);
    const int kq = (lane >> 4) * 8;
    const ushort* aNp = nhC + (size_t)ai*HP + kq;
    const ushort* bUp = UrB + (size_t)C*HP + kq;
    f32x4 acc = (f32x4){0,0,0,0};
#pragma unroll 5
    for (int kt=0; kt<15; ++kt){
        const int kb = kt*32;
        bf16x8 aN = *(const bf16x8*)(aNp + kb);
        bf16x8 bU = *(const bf16x8*)(bUp + kb);
        acc = __builtin_amdgcn_mfma_f32_16x16x32_bf16(aN, bU, acc, 0, 0, 0);
    }
    if (C < Hq){
#pragma unroll
        for (int j=0; j<4; j++){
            const int i = rows0 + wr*16 + ((lane>>4)<<2) + j;
            if (i >= cnt) continue;
            const int b = vlist[t*Bq + i];
            uhbuf[(size_t)(1 + t*Bq + b)*HP + C] = f2bf(acc[j]);
        }
    }
}

// ---------- pred GEMM1 (compacted rows) ----------
__global__ __launch_bounds__(256) void pred1c_k(const int* __restrict__ np_,
    const int* __restrict__ listp, const ushort* __restrict__ hbuf,
    const ushort* __restrict__ TP, const ushort* __restrict__ WHp,
    ushort* __restrict__ pv)
{
    const int np = *np_;
    const int row0 = blockIdx.y*128;
    if (row0 >= np) return;
    const int col0 = blockIdx.x*64;
    const int tid = threadIdx.x;
    int i0 = row0 + (tid>>2), i1 = i0 + 64;
    int g0 = (i0 < np) ? listp[i0] : 0;
    int g1 = (i1 < np) ? listp[i1] : 0;
    const ushort* p0 = (g0 < Bq) ? hbuf : hbuf + (size_t)(1 + g0 - Bq)*HP;  // hbuf row0 = zeros
    const ushort* p1 = (g1 < Bq) ? hbuf : hbuf + (size_t)(1 + g1 - Bq)*HP;
    f32x4 acc[4][2];
    mgemm2([&](int which,int k0){ return (which?p1:p0)+k0; }, WHp, HP, 15, col0, acc);
    EPI_PRE
#pragma unroll
    for (int f=0; f<4; f++)
#pragma unroll
      for (int g=0; g<2; g++){
        int col = col0 + wn*32 + g*16 + (lane & 15);
        if (col >= HP) continue;
#pragma unroll
        for (int j=0; j<4; j++){
            int i = row0 + wm*64 + f*16 + ((lane>>4)<<2) + j;
            if (i >= np) continue;
            int gr = listp[i];
            int b = (gr < Bq) ? gr : ((gr - Bq) & (Bq-1));
            float v = 0.f;
            if (col < Hq) v = fmaxf(acc[f][g][j] + bf2f(TP[(size_t)b*HP + col]), 0.f);
            pv[(size_t)i*HP + col] = f2bf(v);
        }
      }
}

// ---------- pred GEMM2 ----------
__global__ __launch_bounds__(256) void pred2c_k(int cs, const int* __restrict__ np_,
    const ushort* __restrict__ pv, const ushort* __restrict__ WOp,
    const float* __restrict__ bWo, float* __restrict__ scores)
{
    const int np = *np_;
    const int row0 = blockIdx.y*128;
    if (cs + row0 >= np) return;
    const int col0 = blockIdx.x*64;
    const int tid = threadIdx.x;
    const ushort* p0 = pv + (size_t)(cs + row0 + (tid>>2))*HP;
    const ushort* p1 = p0 + (size_t)64*HP;
    f32x4 acc[4][2];
    mgemm2([&](int which,int k0){ return (which?p1:p0)+k0; }, WOp, HP, 15, col0, acc);
    EPI_PRE
#pragma unroll
    for (int f=0; f<4; f++)
#pragma unroll
      for (int g=0; g<2; g++){
        int col = col0 + wn*32 + g*16 + (lane & 15);
        if (col >= Vq) continue;
        float bc = bWo[col];
#pragma unroll
        for (int j=0; j<4; j++){
            int r = row0 + wm*64 + f*16 + ((lane>>4)<<2) + j;
            scores[(size_t)r*832 + col] = acc[f][g][j] + bc;
        }
      }
}

// ---------- pred reduce: wave-per-row ----------
__global__ __launch_bounds__(256) void predred_k(int cs, const int* __restrict__ np_,
    const int* __restrict__ listp, const float* __restrict__ scores,
    const int* __restrict__ pred_wid, const int* __restrict__ root_wid,
    float* __restrict__ accv)
{
    const int np = *np_;
    int nrows = np - cs; if (nrows > CH2) nrows = CH2;
    const int lane = threadIdx.x & 63, wv = threadIdx.x >> 6;
    const int wid_g = blockIdx.x*4 + wv, nw = gridDim.x*4;
    float ce = 0.f, hit = 0.f, cnt = 0.f;
    for (int r = wid_g; r < nrows; r += nw){
        const float* sc = scores + (size_t)r*832;
        int gr = listp[cs + r];
        int tgt = (gr < Bq) ? root_wid[gr] : pred_wid[gr - Bq];
        float vals[13];
        float bv = -INFINITY, tv = 0.f; int bi = 0;
#pragma unroll
        for (int q=0; q<13; q++){
            int j = lane + q*64;
            float v = (j < Vq) ? sc[j] : -INFINITY;
            vals[q] = v;
            if (v > bv){ bv = v; bi = j; }
            if (j == tgt) tv = v;
        }
#pragma unroll
        for (int off=32; off; off>>=1){
            float ov = __shfl_xor(bv, off); int oi = __shfl_xor(bi, off);
            if (ov > bv || (ov == bv && oi < bi)){ bv = ov; bi = oi; }
        }
        float s = 0.f;
#pragma unroll
        for (int q=0; q<13; q++){
            int j = lane + q*64;
            if (j < Vq) s += __expf(vals[q] - bv);
        }
#pragma unroll
        for (int off=32; off; off>>=1) s += __shfl_xor(s, off);
#pragma unroll
        for (int off=32; off; off>>=1) tv += __shfl_xor(tv, off);
        if (lane == 0){
            ce += bv + logf(s) - tv;
            hit += (bi == tgt) ? 1.f : 0.f;
            cnt += 1.f;
        }
    }
    __shared__ float L[3][4];
    if (lane == 0){ L[0][wv] = ce; L[1][wv] = hit; L[2][wv] = cnt; }
    __syncthreads();
    if (threadIdx.x == 0){
        float a = L[0][0]+L[0][1]+L[0][2]+L[0][3];
        float b = L[1][0]+L[1][1]+L[1][2]+L[1][3];
        float c = L[2][0]+L[2][1]+L[2][2]+L[2][3];
        if (c != 0.f){
            atomicAdd(&accv[0], a);
            atomicAdd(&accv[1], b);
            atomicAdd(&accv[2], c);
        }
    }
}

// ---------- stop: cur_o gather (compacted) ----------
__global__ void curo_c(const int* __restrict__ ns_, const int* __restrict__ lists,
                       const int* __restrict__ o_nei_idx, const int* __restrict__ root_o_nei,
                       const ushort* __restrict__ hbuf, ushort* __restrict__ curo)
{
    int i = blockIdx.x;
    if (i >= *ns_) return;
    int gr = lists[i];
    int j0 = threadIdx.x * 4;
    if (j0 >= HP) return;
    int idx[Mq];
    if (gr < TBq){
        int tt = gr >> 9;
#pragma unroll
        for (int m=0;m<Mq;m++){
            int ix = o_nei_idx[(size_t)gr*Mq + m];
            idx[m] = (ix <= tt*Bq) ? ix : 0;   // slots written before step tt; row 0 is zero
        }
    } else {
#pragma unroll
        for (int m=0;m<Mq;m++) idx[m] = root_o_nei[(size_t)(gr-TBq)*Mq + m];
    }
    float s0=0,s1=0,s2=0,s3=0;
#pragma unroll
    for (int m=0;m<Mq;m++){
        uint2 v = *(const uint2*)(hbuf + (size_t)idx[m]*HP + j0);
        s0 += bf2f((ushort)(v.x & 0xffff)); s1 += bf2f((ushort)(v.x >> 16));
        s2 += bf2f((ushort)(v.y & 0xffff)); s3 += bf2f((ushort)(v.y >> 16));
    }
    uint2 o; o.x = pk2(s0, s1); o.y = pk2(s2, s3);
    *(uint2*)(curo + (size_t)i*HP + j0) = o;
}

// ---------- stop GEMM (compacted) + fused Us-dot ----------
__global__ __launch_bounds__(256) void stopc_k(const int* __restrict__ ns_,
    const int* __restrict__ lists, const int* __restrict__ x_wid,
    const int* __restrict__ root_wid, const ushort* __restrict__ curo,
    const ushort* __restrict__ UOp, const ushort* __restrict__ EU,
    const ushort* __restrict__ TU, const float* __restrict__ Usf,
    float* __restrict__ ss)
{
    const int ns = *ns_;
    const int row0 = blockIdx.y*128;
    if (row0 >= ns) return;
    const int col0 = blockIdx.x*64;
    const int tid = threadIdx.x;
    const ushort* p0 = curo + (size_t)(row0 + (tid>>2))*HP;
    const ushort* p1 = p0 + (size_t)64*HP;
    f32x4 acc[4][2];
    mgemm2([&](int which,int k0){ return (which?p1:p0)+k0; }, UOp, HP, 15, col0, acc);
    EPI_PRE
#pragma unroll
    for (int f=0; f<4; f++){
#pragma unroll
        for (int j=0; j<4; j++){
            int i = row0 + wm*64 + f*16 + ((lane>>4)<<2) + j;
            float p = 0.f;
            if (i < ns){
                int gr = lists[i];
                int wid = (gr < TBq) ? x_wid[gr] : root_wid[gr - TBq];
                int b   = (gr < TBq) ? (gr & (Bq-1)) : (gr - TBq);
                const ushort* eu = EU + (size_t)wid*HP;
                const ushort* tu = TU + (size_t)b*HP;
#pragma unroll
                for (int g=0; g<2; g++){
                    int col = col0 + wn*32 + g*16 + (lane & 15);
                    if (col < Hq)
                        p += fmaxf(acc[f][g][j] + bf2f(eu[col]) + bf2f(tu[col]), 0.f) * Usf[col];
                }
            }
            p += __shfl_xor(p, 1); p += __shfl_xor(p, 2);
            p += __shfl_xor(p, 4); p += __shfl_xor(p, 8);
            if ((lane & 15) == 0 && i < ns) atomicAdd(&ss[i], p);
        }
    }
}

__global__ void stopfin_k(const int* __restrict__ ns_, const int* __restrict__ lists,
    const float* __restrict__ ss, const float* __restrict__ bUs,
    const int* __restrict__ direction, float* __restrict__ accv)
{
    const int ns = *ns_;
    int i = blockIdx.x*256 + threadIdx.x;
    float bce = 0.f, hit = 0.f, c = 0.f;
    if (i < ns){
        int gr = lists[i];
        float s = ss[i] + bUs[0];
        float stgt = (gr < TBq) ? (float)direction[gr] : 0.f;
        bce = fmaxf(s,0.f) - s*stgt + log1pf(__expf(-fabsf(s)));
        hit = ((((s >= 0.f) ? 1.f : 0.f) == stgt) ? 1.f : 0.f);
        c = 1.f;
    }
    for (int off=32; off; off>>=1){
        bce += __shfl_down(bce, off);
        hit += __shfl_down(hit, off);
        c   += __shfl_down(c,   off);
    }
    if ((threadIdx.x & 63) == 0 && c != 0.f){
        atomicAdd(&accv[3], bce);
        atomicAdd(&accv[4], hit);
        atomicAdd(&accv[5], c);
    }
}

__global__ void finalize_k(const float* __restrict__ accv, float* __restrict__ out){
    if (threadIdx.x == 0){
        out[0] = accv[0] / (float)Bq;
        out[1] = accv[3] / (float)Bq;
        out[2] = accv[1] / accv[2];
        out[3] = accv[4] / accv[5];
    }
}

extern "C" void kernel_launch(void* const* d_in, const int* in_sizes, int n_in,
                              void* d_out, int out_size, void* d_ws, size_t ws_size,
                              hipStream_t stream) {
    (void)in_sizes; (void)n_in; (void)out_size; (void)ws_size;
    const float* tree_vecs = (const float*)d_in[0];
    const int*   x_wid     = (const int*)d_in[1];
    const int*   pred_wid  = (const int*)d_in[2];
    const int*   root_wid  = (const int*)d_in[3];
    const int*   h_nei_idx = (const int*)d_in[4];
    const int*   o_nei_idx = (const int*)d_in[5];
    const int*   root_o_nei= (const int*)d_in[6];
    const int*   valid     = (const int*)d_in[7];
    const int*   direction = (const int*)d_in[8];
    const float* emb       = (const float*)d_in[9];
    const float* Wz        = (const float*)d_in[10];
    const float* bz        = (const float*)d_in[11];
    const float* Wr        = (const float*)d_in[12];
    const float* br        = (const float*)d_in[13];
    const float* Ur        = (const float*)d_in[14];
    const float* Wh        = (const float*)d_in[15];
    const float* bh        = (const float*)d_in[16];
    const float* Wm        = (const float*)d_in[17];
    const float* bW        = (const float*)d_in[18];
    const float* U         = (const float*)d_in[19];
    const float* bU        = (const float*)d_in[20];
    const float* Wo        = (const float*)d_in[21];
    const float* bWo       = (const float*)d_in[22];
    const float* Us        = (const float*)d_in[23];
    const float* bUs       = (const float*)d_in[24];

    char* w = (char*)d_ws; size_t off = 0;
    auto alloc = [&](size_t bytes)->void*{ void* p = w + off; off += (bytes + 255) & ~(size_t)255; return p; };

    ushort* hbuf  = (ushort*)alloc((size_t)Sq*HP*2);
    ushort* uhbuf = (ushort*)alloc((size_t)Sq*HP*2);
    ushort* embb  = (ushort*)alloc((size_t)896*HP*2);
    ushort* treeb = (ushort*)alloc((size_t)Bq*64*2);
    ushort* WzX   = (ushort*)alloc((size_t)512*HP*2);
    ushort* WzS   = (ushort*)alloc((size_t)512*HP*2);
    ushort* WrB   = (ushort*)alloc((size_t)512*HP*2);
    ushort* WhX   = (ushort*)alloc((size_t)512*HP*2);
    ushort* WhG   = (ushort*)alloc((size_t)512*HP*2);
    ushort* UrB   = (ushort*)alloc((size_t)512*HP*2);
    ushort* WHp   = (ushort*)alloc((size_t)512*HP*2);
    ushort* UXp   = (ushort*)alloc((size_t)512*HP*2);
    ushort* UOp   = (ushort*)alloc((size_t)512*HP*2);
    ushort* WOp   = (ushort*)alloc((size_t)832*HP*2);
    ushort* WLp   = (ushort*)alloc((size_t)512*64*2);
    ushort* ULp   = (ushort*)alloc((size_t)512*64*2);
    ushort* EZ    = (ushort*)alloc((size_t)896*HP*2);
    ushort* ER    = (ushort*)alloc((size_t)896*HP*2);
    ushort* EH    = (ushort*)alloc((size_t)896*HP*2);
    ushort* EU    = (ushort*)alloc((size_t)896*HP*2);
    ushort* TP    = (ushort*)alloc((size_t)Bq*HP*2);
    ushort* TU    = (ushort*)alloc((size_t)Bq*HP*2);
    ushort* sumhC = (ushort*)alloc((size_t)Bq*HP*2);
    ushort* gatedC= (ushort*)alloc((size_t)Bq*HP*2);
    ushort* nhC   = (ushort*)alloc((size_t)Bq*HP*2);
    ushort* pv    = (ushort*)alloc((size_t)NPCAP*HP*2);
    float*  scores= (float*)alloc((size_t)CH2*832*4);
    float*  ss    = (float*)alloc((size_t)NSCAP*4);
    int*    listp = (int*)alloc((size_t)NPCAP*4);
    int*    lists = (int*)alloc((size_t)NSCAP*4);
    int*    vlist = (int*)alloc((size_t)Tq*Bq*4);
    int*    vcnt  = (int*)alloc((size_t)Tq*4);
    int*    meta  = (int*)alloc((size_t)(NPB*4 + 2 + 16)*4);
    int*    cnts  = meta;            // [2*NPB]
    int*    offs  = meta + 2*NPB;    // [2*NPB]
    int*    tot   = meta + 4*NPB;    // [2]
    float*  accv  = (float*)(meta + 4*NPB + 2);
    ushort* curo  = pv;              // stop phase reuses pv/scores region

    (void)hipMemsetAsync(hbuf,  0, (size_t)Sq*HP*2, stream);
    (void)hipMemsetAsync(uhbuf, 0, (size_t)Sq*HP*2, stream);
    (void)hipMemsetAsync(ss,    0, (size_t)NSCAP*4, stream);
    (void)hipMemsetAsync(meta,  0, (size_t)(NPB*4 + 2 + 16)*4, stream);

    // ---- conversions (1 launch) ----
    convAll_k<<<dim3(896,14), 128, 0, stream>>>(
        emb, tree_vecs, Wz, Wr, Ur, Wh, Wm, U, Wo,
        embb, treeb, WzX, WzS, WrB, WhX, WhG, UrB, WHp, UXp, UOp, WOp, WLp, ULp);

    // ---- precomputes (2 launches, bf16 tables) ----
    preE_k<<<dim3(8,7,4), 256, 0, stream>>>(embb, WzX, WrB, WhX, UXp,
                                            bz, br, bh, bU, EZ, ER, EH, EU);
    preT_k<<<dim3(8,4,2), 256, 0, stream>>>(treeb, WLp, ULp, bW, TP, TU);

    // ---- row compaction (pred/stop + per-step valid lists) ----
    cnt_k <<<dim3(NPB,2), 256, 0, stream>>>(valid, direction, cnts);
    scan_k<<<1, 64, 0, stream>>>(cnts, offs, tot);
    fill_k<<<dim3(NPB,2), 256, 0, stream>>>(valid, direction, offs, listp, lists);
    vfill_k<<<Tq, 512, 0, stream>>>(valid, vcnt, vlist);

    // ---- sequential scan: 3 wide kernels per step ----
    for (int t=0; t<Tq; t++){
        gather_k<<<115, 256, 0, stream>>>(t, x_wid, h_nei_idx, ER, vcnt, vlist,
                                          hbuf, uhbuf, sumhC, gatedC);
        zh_k<<<dim3(15,16), 256, 0, stream>>>(t, x_wid, vcnt, vlist, EZ, EH,
                                              WzS, WhG, sumhC, gatedC, nhC, hbuf);
        ur_k<<<dim3(15,16), 256, 0, stream>>>(t, vcnt, vlist, UrB, nhC, uhbuf);
    }

    // ---- pred phase (compacted) ----
    pred1c_k<<<dim3(8, NPCAP/128), 256, 0, stream>>>(tot, listp, hbuf, TP, WHp, pv);
    for (int c=0; c<NCH2; c++){
        int cs = c*CH2;
        pred2c_k<<<dim3(13, CH2/128), 256, 0, stream>>>(cs, tot, pv, WOp, bWo, scores);
        predred_k<<<256, 256, 0, stream>>>(cs, tot, listp, scores, pred_wid, root_wid, accv);
    }

    // ---- stop phase (compacted) ----
    curo_c<<<NSCAP, 128, 0, stream>>>(tot+1, lists, o_nei_idx, root_o_nei, hbuf, curo);
    stopc_k<<<dim3(8, NSCAP/128), 256, 0, stream>>>(tot+1, lists, x_wid, root_wid,
                                                    curo, UOp, EU, TU, Us, ss);
    stopfin_k<<<NSCAP/256, 256, 0, stream>>>(tot+1, lists, ss, bUs, direction, accv);

    finalize_k<<<1, 64, 0, stream>>>(accv, (float*)d_out);
}

// Round 14
// 1351.634 us; speedup vs baseline: 4.1966x; 1.0745x over previous
//
#include <hip/hip_runtime.h>
#include <math.h>

#define Bq 512
#define Tq 64
#define Hq 450
#define Lq 56
#define Vq 780
#define Mq 8
#define TBq 32768
#define Sq 32770
#define HP 480          // bf16 row stride (mult of 32)
#define NPB 130         // 130*256 = 33280 rows
#define NPCAP 12288     // compacted pred rows cap
#define NSCAP 20480     // compacted stop rows cap
#define CH2 6144        // pred score chunk rows
#define NCH2 2

using bf16x8 = __attribute__((ext_vector_type(8))) __bf16;
using f32x4  = __attribute__((ext_vector_type(4))) float;
using u32x4  = __attribute__((ext_vector_type(4))) unsigned;

__device__ __forceinline__ ushort f2bf(float f){
    union { float f; unsigned u; } c; c.f = f;
    unsigned u = c.u;
    return (ushort)((u + 0x7FFFu + ((u >> 16) & 1u)) >> 16);
}
__device__ __forceinline__ float bf2f(ushort h){
    union { unsigned u; float f; } c; c.u = ((unsigned)h) << 16;
    return c.f;
}
__device__ __forceinline__ unsigned pk2(float a, float b){
    return (unsigned)f2bf(a) | ((unsigned)f2bf(b) << 16);
}
__device__ __forceinline__ float sigmf(float x){
    return __builtin_amdgcn_rcpf(1.f + __expf(-x));
}
__device__ __forceinline__ float tanhfast(float x){
    float e2 = __expf(2.f * x);
    return 1.f - 2.f * __builtin_amdgcn_rcpf(e2 + 1.f);
}

// ---------- fused converter: 14 jobs by blockIdx.y ----------
__global__ void convAll_k(
    const float* __restrict__ emb, const float* __restrict__ tree,
    const float* __restrict__ Wz, const float* __restrict__ Wr,
    const float* __restrict__ Ur, const float* __restrict__ Wh,
    const float* __restrict__ Wm, const float* __restrict__ U, const float* __restrict__ Wo,
    ushort* embb, ushort* treeb, ushort* WzX, ushort* WzS, ushort* WrB,
    ushort* WhX, ushort* WhG, ushort* UrB, ushort* WHp, ushort* UXp,
    ushort* UOp, ushort* WOp, ushort* WLp, ushort* ULp)
{
    int job = blockIdx.y, n = blockIdx.x;
    const float* src; ushort* dst; int Npad, Nsrc, Ksrc, Kpad, len, off;
    switch(job){
      case 0:  src=emb;  dst=embb; Npad=896; Nsrc=780; Ksrc=450; Kpad=480; len=450; off=0;   break;
      case 1:  src=tree; dst=treeb;Npad=512; Nsrc=512; Ksrc=56;  Kpad=64;  len=56;  off=0;   break;
      case 2:  src=Wz;   dst=WzX;  Npad=512; Nsrc=450; Ksrc=900; Kpad=480; len=450; off=0;   break;
      case 3:  src=Wz;   dst=WzS;  Npad=512; Nsrc=450; Ksrc=900; Kpad=480; len=450; off=450; break;
      case 4:  src=Wr;   dst=WrB;  Npad=512; Nsrc=450; Ksrc=450; Kpad=480; len=450; off=0;   break;
      case 5:  src=Wh;   dst=WhX;  Npad=512; Nsrc=450; Ksrc=900; Kpad=480; len=450; off=0;   break;
      case 6:  src=Wh;   dst=WhG;  Npad=512; Nsrc=450; Ksrc=900; Kpad=480; len=450; off=450; break;
      case 7:  src=Ur;   dst=UrB;  Npad=512; Nsrc=450; Ksrc=450; Kpad=480; len=450; off=0;   break;
      case 8:  src=Wm;   dst=WHp;  Npad=512; Nsrc=450; Ksrc=506; Kpad=480; len=450; off=0;   break;
      case 9:  src=U;    dst=UXp;  Npad=512; Nsrc=450; Ksrc=956; Kpad=480; len=450; off=0;   break;
      case 10: src=U;    dst=UOp;  Npad=512; Nsrc=450; Ksrc=956; Kpad=480; len=450; off=450; break;
      case 11: src=Wo;   dst=WOp;  Npad=832; Nsrc=780; Ksrc=450; Kpad=480; len=450; off=0;   break;
      case 12: src=Wm;   dst=WLp;  Npad=512; Nsrc=450; Ksrc=506; Kpad=64;  len=56;  off=450; break;
      default: src=U;    dst=ULp;  Npad=512; Nsrc=450; Ksrc=956; Kpad=64;  len=56;  off=900; break;
    }
    if (n >= Npad) return;
    for (int k = threadIdx.x; k < Kpad; k += blockDim.x){
        float v = 0.f;
        if (n < Nsrc && k < len) v = src[(size_t)n*Ksrc + off + k];
        dst[(size_t)n*Kpad + k] = f2bf(v);
    }
}

// ---------- double-buffered MFMA GEMM body: C(128x64) tile ----------
// row0/col0 supplied by caller (row-tile on blockIdx.x for XCD-L2 A reuse)
template<class APtr>
__device__ __forceinline__ void mgemm2(APtr&& aptr, const ushort* __restrict__ Bw, int ldb,
                                       int KT, int col0, f32x4 acc[4][2])
{
    __shared__ __align__(16) char As[2][128*80];
    __shared__ __align__(16) char Bs[2][64*80];
    const int tid = threadIdx.x;
    const int lane = tid & 63;
    const int w = tid >> 6, wm = w >> 1, wn = w & 1;
    const int ac = (tid & 3) * 8;
    const size_t boff = (size_t)(col0 + (tid >> 2)) * ldb;
    u32x4 ra0, ra1, rb;
    auto ld = [&](int k0){
        ra0 = *(const u32x4*)(aptr(0, k0) + ac);
        ra1 = *(const u32x4*)(aptr(1, k0) + ac);
        rb  = *(const u32x4*)(Bw + boff + k0 + ac);
    };
    const int wr_a0 = (tid>>2)*80 + (tid&3)*16;
    const int wr_a1 = ((tid>>2)+64)*80 + (tid&3)*16;
    const int wr_b  = (tid>>2)*80 + (tid&3)*16;
    const int rd_a  = (wm*64 + (lane&15))*80 + (lane>>4)*16;
    const int rd_b  = (wn*32 + (lane&15))*80 + (lane>>4)*16;
    ld(0);
    *(u32x4*)(As[0]+wr_a0) = ra0; *(u32x4*)(As[0]+wr_a1) = ra1; *(u32x4*)(Bs[0]+wr_b) = rb;
#pragma unroll
    for (int f=0;f<4;f++)
#pragma unroll
        for (int g=0;g<2;g++) acc[f][g] = (f32x4){0.f,0.f,0.f,0.f};
    __syncthreads();
    for (int kt=0; kt<KT; ++kt){
        const int cur = kt & 1;
        if (kt+1 < KT) ld((kt+1)*32);
        bf16x8 bF[2];
#pragma unroll
        for (int g=0; g<2; g++) bF[g] = *(const bf16x8*)(Bs[cur] + rd_b + g*16*80);
#pragma unroll
        for (int f=0; f<4; f++){
            bf16x8 aF = *(const bf16x8*)(As[cur] + rd_a + f*16*80);
#pragma unroll
            for (int g=0; g<2; g++)
                acc[f][g] = __builtin_amdgcn_mfma_f32_16x16x32_bf16(aF, bF[g], acc[f][g], 0, 0, 0);
        }
        if (kt+1 < KT){
            *(u32x4*)(As[cur^1]+wr_a0) = ra0; *(u32x4*)(As[cur^1]+wr_a1) = ra1;
            *(u32x4*)(Bs[cur^1]+wr_b) = rb;
        }
        __syncthreads();
    }
}

#define EPI_PRE  const int lane = threadIdx.x & 63; const int w_ = threadIdx.x >> 6; \
                 const int wm = w_ >> 1, wn = w_ & 1;

// ---------- precompute GEMM body: out bf16 [rows][HP] ----------
__device__ __forceinline__ void pre_body(const ushort* __restrict__ A, int lda,
    const ushort* __restrict__ Bw, const float* __restrict__ bias,
    ushort* __restrict__ out, int Mr, int KT)
{
    const int row0 = blockIdx.y*128, col0 = blockIdx.x*64;
    const int tid = threadIdx.x;
    const ushort* p0 = A + (size_t)(row0 + (tid>>2))*lda;
    const ushort* p1 = p0 + (size_t)64*lda;
    f32x4 acc[4][2];
    mgemm2([&](int which,int k0){ return (which?p1:p0)+k0; }, Bw, lda, KT, col0, acc);
    EPI_PRE
#pragma unroll
    for (int f=0; f<4; f++)
#pragma unroll
      for (int g=0; g<2; g++){
        int col = col0 + wn*32 + g*16 + (lane & 15);
        if (col >= HP) continue;
        float bb = 0.f;
        if (col < Hq && bias) bb = bias[col];
#pragma unroll
        for (int j=0; j<4; j++){
            int row = row0 + wm*64 + f*16 + ((lane>>4)<<2) + j;
            if (row < Mr) out[(size_t)row*HP + col] = (col < Hq) ? f2bf(acc[f][g][j] + bb) : 0;
        }
      }
}

__global__ __launch_bounds__(256) void preE_k(
    const ushort* __restrict__ embb,
    const ushort* __restrict__ WzX, const ushort* __restrict__ WrB,
    const ushort* __restrict__ WhX, const ushort* __restrict__ UXp,
    const float* __restrict__ bz, const float* __restrict__ br,
    const float* __restrict__ bh, const float* __restrict__ bU,
    ushort* __restrict__ EZ, ushort* __restrict__ ER,
    ushort* __restrict__ EH, ushort* __restrict__ EU)
{
    const ushort* Bw; const float* bias; ushort* out;
    switch(blockIdx.z){
      case 0:  Bw=WzX; bias=bz; out=EZ; break;
      case 1:  Bw=WrB; bias=br; out=ER; break;
      case 2:  Bw=WhX; bias=bh; out=EH; break;
      default: Bw=UXp; bias=bU; out=EU; break;
    }
    pre_body(embb, HP, Bw, bias, out, Vq, 15);
}

__global__ __launch_bounds__(256) void preT_k(
    const ushort* __restrict__ treeb,
    const ushort* __restrict__ WLp, const ushort* __restrict__ ULp,
    const float* __restrict__ bW, ushort* __restrict__ TP, ushort* __restrict__ TU)
{
    const ushort* Bw = blockIdx.z ? ULp : WLp;
    const float* bias = blockIdx.z ? nullptr : bW;
    ushort* out = blockIdx.z ? TU : TP;
    pre_body(treeb, 64, Bw, bias, out, Bq, 2);
}

// ---------- compaction for pred/stop: count / scan / fill ----------
__device__ __forceinline__ bool cmask(int which, int gr,
    const int* __restrict__ valid, const int* __restrict__ dir)
{
    if (which == 0) return (gr < Bq) ? true : (valid[gr-Bq] && dir[gr-Bq]);
    return (gr < TBq) ? (valid[gr] != 0) : true;
}
__global__ void cnt_k(const int* __restrict__ valid, const int* __restrict__ dir,
                      int* __restrict__ cnts)
{
    int which = blockIdx.y;
    int gr = blockIdx.x*256 + threadIdx.x;
    bool m = cmask(which, gr, valid, dir);
    unsigned long long bal = __ballot(m);
    if ((threadIdx.x & 63) == 0)
        atomicAdd(&cnts[which*NPB + blockIdx.x], (int)__popcll(bal));
}
__global__ void scan_k(const int* __restrict__ cnts, int* __restrict__ offs,
                       int* __restrict__ totals)
{
    if (threadIdx.x == 0){
        int a = 0;
        for (int i=0;i<NPB;i++){ offs[i] = a; a += cnts[i]; }
        totals[0] = a;
        int b = 0;
        for (int i=0;i<NPB;i++){ offs[NPB+i] = b; b += cnts[NPB+i]; }
        totals[1] = b;
    }
}
__global__ void fill_k(const int* __restrict__ valid, const int* __restrict__ dir,
                       const int* __restrict__ offs, int* __restrict__ listp,
                       int* __restrict__ lists)
{
    __shared__ int woff[4];
    int which = blockIdx.y;
    int gr = blockIdx.x*256 + threadIdx.x;
    bool m = cmask(which, gr, valid, dir);
    unsigned long long bal = __ballot(m);
    int lane = threadIdx.x & 63, wv = threadIdx.x >> 6;
    if (lane == 0) woff[wv] = (int)__popcll(bal);
    __syncthreads();
    int prev = 0;
    for (int i=0;i<wv;i++) prev += woff[i];
    if (m){
        int rank = prev + (int)__popcll(bal & ((1ull << lane) - 1ull));
        int pos = offs[which*NPB + blockIdx.x] + rank;
        if (which == 0){ if (pos < NPCAP) listp[pos] = gr; }
        else           { if (pos < NSCAP) lists[pos] = gr; }
    }
}

// ---------- per-step valid-row lists: vlist[t*Bq + i] = b, vcnt[t] ----------
__global__ void vfill_k(const int* __restrict__ valid,
                        int* __restrict__ vcnt, int* __restrict__ vlist)
{
    __shared__ int woff[8];
    const int t = blockIdx.x;
    const int b = threadIdx.x;              // 512 threads
    bool m = valid[t*Bq + b] != 0;
    unsigned long long bal = __ballot(m);
    int lane = b & 63, wv = b >> 6;
    if (lane == 0) woff[wv] = (int)__popcll(bal);
    __syncthreads();
    int prev = 0;
    for (int i=0;i<wv;i++) prev += woff[i];
    if (m) vlist[t*Bq + prev + (int)__popcll(bal & ((1ull<<lane)-1ull))] = b;
    if (threadIdx.x == 511){
        int tot = 0;
        for (int i=0;i<8;i++) tot += woff[i];
        vcnt[t] = tot;
    }
}

// ---------- scan: gather (compacted valid rows, full machine) ----------
__global__ __launch_bounds__(256) void gather_k(int t,
    const int* __restrict__ x_wid, const int* __restrict__ h_nei_idx,
    const ushort* __restrict__ ER,
    const int* __restrict__ vcnt, const int* __restrict__ vlist,
    const ushort* __restrict__ hbuf, const ushort* __restrict__ uhbuf,
    ushort* __restrict__ sumhC, ushort* __restrict__ gatedC)
{
    const int cnt = vcnt[t];
    const int task = blockIdx.x*256 + threadIdx.x;
    if (task >= cnt*57) return;
    const int i = task / 57;
    const int c = task - i*57;
    const int j0 = c*8;
    const int b = vlist[t*Bq + i];
    const int base = t*Bq + b;
    const int wid = x_wid[base];
    const int* ip = h_nei_idx + (size_t)base*Mq;
    int idx[Mq];
#pragma unroll
    for (int m=0;m<Mq;m++) idx[m] = ip[m];
    float er[8];
    { u32x4 ev = *(const u32x4*)(ER + (size_t)wid*HP + j0);
#pragma unroll
      for (int e=0;e<8;e++) er[e] = bf2f((ushort)((ev[e>>1] >> ((e&1)*16)) & 0xffff)); }
    float sh[8] = {0,0,0,0,0,0,0,0};
    float gt[8] = {0,0,0,0,0,0,0,0};
#pragma unroll
    for (int m=0;m<Mq;m++){
        u32x4 hv = *(const u32x4*)(hbuf  + (size_t)idx[m]*HP + j0);
        u32x4 uv = *(const u32x4*)(uhbuf + (size_t)idx[m]*HP + j0);
#pragma unroll
        for (int e=0;e<8;e++){
            float h = bf2f((ushort)((hv[e>>1] >> ((e&1)*16)) & 0xffff));
            float u = bf2f((ushort)((uv[e>>1] >> ((e&1)*16)) & 0xffff));
            sh[e] += h;
            gt[e] += h * sigmf(er[e] + u);
        }
    }
    u32x4 so, go;
    so[0]=pk2(sh[0],sh[1]); so[1]=pk2(sh[2],sh[3]);
    so[2]=pk2(sh[4],sh[5]); so[3]=pk2(sh[6],sh[7]);
    go[0]=pk2(gt[0],gt[1]); go[1]=pk2(gt[2],gt[3]);
    go[2]=pk2(gt[4],gt[5]); go[3]=pk2(gt[6],gt[7]);
    *(u32x4*)(sumhC  + (size_t)i*HP + j0) = so;
    *(u32x4*)(gatedC + (size_t)i*HP + j0) = go;
}

// ---------- scan: twin GEMM + blend; rows on blockIdx.x (16 tiles, %8==0) ----------
__global__ __launch_bounds__(256) void zh_k(int t,
    const int* __restrict__ x_wid,
    const int* __restrict__ vcnt, const int* __restrict__ vlist,
    const ushort* __restrict__ EZ, const ushort* __restrict__ EH,
    const ushort* __restrict__ WzS, const ushort* __restrict__ WhG,
    const ushort* __restrict__ sumhC, const ushort* __restrict__ gatedC,
    ushort* __restrict__ nhC, ushort* __restrict__ hbuf)
{
    const int cnt = vcnt[t];
    const int rows0 = blockIdx.x*32;
    if (rows0 >= cnt) return;
    const int cols0 = blockIdx.y*32;
    const int lane = threadIdx.x & 63, w = threadIdx.x >> 6;
    const int wr = w >> 1, wc = w & 1;
    const int ai = rows0 + wr*16 + (lane & 15);       // compacted A row
    const int C  = cols0 + wc*16 + (lane & 15);       // output col
    const int kq = (lane >> 4) * 8;
    const ushort* aZp = sumhC  + (size_t)ai*HP + kq;
    const ushort* aGp = gatedC + (size_t)ai*HP + kq;
    const ushort* bZp = WzS + (size_t)C*HP + kq;
    const ushort* bGp = WhG + (size_t)C*HP + kq;
    f32x4 accZ = (f32x4){0,0,0,0}, accH = (f32x4){0,0,0,0};
#pragma unroll 5
    for (int kt=0; kt<15; ++kt){
        const int kb = kt*32;
        bf16x8 aZ = *(const bf16x8*)(aZp + kb);
        bf16x8 aG = *(const bf16x8*)(aGp + kb);
        bf16x8 bZ = *(const bf16x8*)(bZp + kb);
        bf16x8 bG = *(const bf16x8*)(bGp + kb);
        accZ = __builtin_amdgcn_mfma_f32_16x16x32_bf16(aZ, bZ, accZ, 0, 0, 0);
        accH = __builtin_amdgcn_mfma_f32_16x16x32_bf16(aG, bG, accH, 0, 0, 0);
    }
    // C/D: col = lane&15 (+tile), row = (lane>>4)*4 + j (+tile)
#pragma unroll
    for (int j=0; j<4; j++){
        const int i = rows0 + wr*16 + ((lane>>4)<<2) + j;
        if (i >= cnt) continue;
        const int b = vlist[t*Bq + i];
        const int base = t*Bq + b;
        ushort o = 0;
        if (C < Hq){
            const int wid = x_wid[base];
            float z  = sigmf(accZ[j] + bf2f(EZ[(size_t)wid*HP + C]));
            float ht = tanhfast(accH[j] + bf2f(EH[(size_t)wid*HP + C]));
            float sh = bf2f(sumhC[(size_t)i*HP + C]);
            o = f2bf((1.f - z)*sh + z*ht);
            hbuf[(size_t)(1 + base)*HP + C] = o;      // all compacted rows valid
        }
        nhC[(size_t)i*HP + C] = o;                    // zero in pad cols
    }
}

// ---------- scan: uh = nh @ Ur^T; rows on blockIdx.x ----------
__global__ __launch_bounds__(256) void ur_k(int t,
    const int* __restrict__ vcnt, const int* __restrict__ vlist,
    const ushort* __restrict__ UrB, const ushort* __restrict__ nhC,
    ushort* __restrict__ uhbuf)
{
    const int cnt = vcnt[t];
    const int rows0 = blockIdx.x*32;
    if (rows0 >= cnt) return;
    const int cols0 = blockIdx.y*32;
    const int lane = threadIdx.x & 63, w = threadIdx.x >> 6;
    const int wr = w >> 1, wc = w & 1;
    const int ai = rows0 + wr*16 + (lane & 15);
    const int C  = cols0 + wc*16 + (lane & 15);
    const int kq = (lane >> 4) * 8;
    const ushort* aNp = nhC + (size_t)ai*HP + kq;
    const ushort* bUp = UrB + (size_t)C*HP + kq;
    f32x4 acc = (f32x4){0,0,0,0};
#pragma unroll 5
    for (int kt=0; kt<15; ++kt){
        const int kb = kt*32;
        bf16x8 aN = *(const bf16x8*)(aNp + kb);
        bf16x8 bU = *(const bf16x8*)(bUp + kb);
        acc = __builtin_amdgcn_mfma_f32_16x16x32_bf16(aN, bU, acc, 0, 0, 0);
    }
    if (C < Hq){
#pragma unroll
        for (int j=0; j<4; j++){
            const int i = rows0 + wr*16 + ((lane>>4)<<2) + j;
            if (i >= cnt) continue;
            const int b = vlist[t*Bq + i];
            uhbuf[(size_t)(1 + t*Bq + b)*HP + C] = f2bf(acc[j]);
        }
    }
}

// ---------- pred GEMM1 (compacted rows); rows on blockIdx.x (96 tiles) ----------
__global__ __launch_bounds__(256) void pred1c_k(const int* __restrict__ np_,
    const int* __restrict__ listp, const ushort* __restrict__ hbuf,
    const ushort* __restrict__ TP, const ushort* __restrict__ WHp,
    ushort* __restrict__ pv)
{
    const int np = *np_;
    const int row0 = blockIdx.x*128;
    if (row0 >= np) return;
    const int col0 = blockIdx.y*64;
    const int tid = threadIdx.x;
    int i0 = row0 + (tid>>2), i1 = i0 + 64;
    int g0 = (i0 < np) ? listp[i0] : 0;
    int g1 = (i1 < np) ? listp[i1] : 0;
    const ushort* p0 = (g0 < Bq) ? hbuf : hbuf + (size_t)(1 + g0 - Bq)*HP;  // hbuf row0 = zeros
    const ushort* p1 = (g1 < Bq) ? hbuf : hbuf + (size_t)(1 + g1 - Bq)*HP;
    f32x4 acc[4][2];
    mgemm2([&](int which,int k0){ return (which?p1:p0)+k0; }, WHp, HP, 15, col0, acc);
    EPI_PRE
#pragma unroll
    for (int f=0; f<4; f++)
#pragma unroll
      for (int g=0; g<2; g++){
        int col = col0 + wn*32 + g*16 + (lane & 15);
        if (col >= HP) continue;
#pragma unroll
        for (int j=0; j<4; j++){
            int i = row0 + wm*64 + f*16 + ((lane>>4)<<2) + j;
            if (i >= np) continue;
            int gr = listp[i];
            int b = (gr < Bq) ? gr : ((gr - Bq) & (Bq-1));
            float v = 0.f;
            if (col < Hq) v = fmaxf(acc[f][g][j] + bf2f(TP[(size_t)b*HP + col]), 0.f);
            pv[(size_t)i*HP + col] = f2bf(v);
        }
      }
}

// ---------- pred GEMM2; rows on blockIdx.x (48 tiles) ----------
__global__ __launch_bounds__(256) void pred2c_k(int cs, const int* __restrict__ np_,
    const ushort* __restrict__ pv, const ushort* __restrict__ WOp,
    const float* __restrict__ bWo, float* __restrict__ scores)
{
    const int np = *np_;
    const int row0 = blockIdx.x*128;
    if (cs + row0 >= np) return;
    const int col0 = blockIdx.y*64;
    const int tid = threadIdx.x;
    const ushort* p0 = pv + (size_t)(cs + row0 + (tid>>2))*HP;
    const ushort* p1 = p0 + (size_t)64*HP;
    f32x4 acc[4][2];
    mgemm2([&](int which,int k0){ return (which?p1:p0)+k0; }, WOp, HP, 15, col0, acc);
    EPI_PRE
#pragma unroll
    for (int f=0; f<4; f++)
#pragma unroll
      for (int g=0; g<2; g++){
        int col = col0 + wn*32 + g*16 + (lane & 15);
        if (col >= Vq) continue;
        float bc = bWo[col];
#pragma unroll
        for (int j=0; j<4; j++){
            int r = row0 + wm*64 + f*16 + ((lane>>4)<<2) + j;
            scores[(size_t)r*832 + col] = acc[f][g][j] + bc;
        }
      }
}

// ---------- pred reduce: wave-per-row ----------
__global__ __launch_bounds__(256) void predred_k(int cs, const int* __restrict__ np_,
    const int* __restrict__ listp, const float* __restrict__ scores,
    const int* __restrict__ pred_wid, const int* __restrict__ root_wid,
    float* __restrict__ accv)
{
    const int np = *np_;
    int nrows = np - cs; if (nrows > CH2) nrows = CH2;
    const int lane = threadIdx.x & 63, wv = threadIdx.x >> 6;
    const int wid_g = blockIdx.x*4 + wv, nw = gridDim.x*4;
    float ce = 0.f, hit = 0.f, cnt = 0.f;
    for (int r = wid_g; r < nrows; r += nw){
        const float* sc = scores + (size_t)r*832;
        int gr = listp[cs + r];
        int tgt = (gr < Bq) ? root_wid[gr] : pred_wid[gr - Bq];
        float vals[13];
        float bv = -INFINITY, tv = 0.f; int bi = 0;
#pragma unroll
        for (int q=0; q<13; q++){
            int j = lane + q*64;
            float v = (j < Vq) ? sc[j] : -INFINITY;
            vals[q] = v;
            if (v > bv){ bv = v; bi = j; }
            if (j == tgt) tv = v;
        }
#pragma unroll
        for (int off=32; off; off>>=1){
            float ov = __shfl_xor(bv, off); int oi = __shfl_xor(bi, off);
            if (ov > bv || (ov == bv && oi < bi)){ bv = ov; bi = oi; }
        }
        float s = 0.f;
#pragma unroll
        for (int q=0; q<13; q++){
            int j = lane + q*64;
            if (j < Vq) s += __expf(vals[q] - bv);
        }
#pragma unroll
        for (int off=32; off; off>>=1) s += __shfl_xor(s, off);
#pragma unroll
        for (int off=32; off; off>>=1) tv += __shfl_xor(tv, off);
        if (lane == 0){
            ce += bv + logf(s) - tv;
            hit += (bi == tgt) ? 1.f : 0.f;
            cnt += 1.f;
        }
    }
    __shared__ float L[3][4];
    if (lane == 0){ L[0][wv] = ce; L[1][wv] = hit; L[2][wv] = cnt; }
    __syncthreads();
    if (threadIdx.x == 0){
        float a = L[0][0]+L[0][1]+L[0][2]+L[0][3];
        float b = L[1][0]+L[1][1]+L[1][2]+L[1][3];
        float c = L[2][0]+L[2][1]+L[2][2]+L[2][3];
        if (c != 0.f){
            atomicAdd(&accv[0], a);
            atomicAdd(&accv[1], b);
            atomicAdd(&accv[2], c);
        }
    }
}

// ---------- stop: cur_o gather (task-parallel, 16B chunks) ----------
__global__ __launch_bounds__(256) void curo_c(const int* __restrict__ ns_,
    const int* __restrict__ lists,
    const int* __restrict__ o_nei_idx, const int* __restrict__ root_o_nei,
    const ushort* __restrict__ hbuf, ushort* __restrict__ curo)
{
    const int ns = *ns_;
    const int task = blockIdx.x*256 + threadIdx.x;
    if (task >= ns*60) return;
    const int i = task / 60;
    const int c = task - i*60;
    const int j0 = c*8;
    const int gr = lists[i];
    int idx[Mq];
    if (gr < TBq){
        int tt = gr >> 9;
#pragma unroll
        for (int m=0;m<Mq;m++){
            int ix = o_nei_idx[(size_t)gr*Mq + m];
            idx[m] = (ix <= tt*Bq) ? ix : 0;   // slots written before step tt; row 0 is zero
        }
    } else {
#pragma unroll
        for (int m=0;m<Mq;m++) idx[m] = root_o_nei[(size_t)(gr-TBq)*Mq + m];
    }
    float sh[8] = {0,0,0,0,0,0,0,0};
#pragma unroll
    for (int m=0;m<Mq;m++){
        u32x4 hv = *(const u32x4*)(hbuf + (size_t)idx[m]*HP + j0);   // pad cols are zero
#pragma unroll
        for (int e=0;e<8;e++)
            sh[e] += bf2f((ushort)((hv[e>>1] >> ((e&1)*16)) & 0xffff));
    }
    u32x4 so;
    so[0]=pk2(sh[0],sh[1]); so[1]=pk2(sh[2],sh[3]);
    so[2]=pk2(sh[4],sh[5]); so[3]=pk2(sh[6],sh[7]);
    *(u32x4*)(curo + (size_t)i*HP + j0) = so;
}

// ---------- stop GEMM (compacted) + fused Us-dot; rows on blockIdx.x (160) ----------
__global__ __launch_bounds__(256) void stopc_k(const int* __restrict__ ns_,
    const int* __restrict__ lists, const int* __restrict__ x_wid,
    const int* __restrict__ root_wid, const ushort* __restrict__ curo,
    const ushort* __restrict__ UOp, const ushort* __restrict__ EU,
    const ushort* __restrict__ TU, const float* __restrict__ Usf,
    float* __restrict__ ss)
{
    const int ns = *ns_;
    const int row0 = blockIdx.x*128;
    if (row0 >= ns) return;
    const int col0 = blockIdx.y*64;
    const int tid = threadIdx.x;
    const ushort* p0 = curo + (size_t)(row0 + (tid>>2))*HP;
    const ushort* p1 = p0 + (size_t)64*HP;
    f32x4 acc[4][2];
    mgemm2([&](int which,int k0){ return (which?p1:p0)+k0; }, UOp, HP, 15, col0, acc);
    EPI_PRE
#pragma unroll
    for (int f=0; f<4; f++){
#pragma unroll
        for (int j=0; j<4; j++){
            int i = row0 + wm*64 + f*16 + ((lane>>4)<<2) + j;
            float p = 0.f;
            if (i < ns){
                int gr = lists[i];
                int wid = (gr < TBq) ? x_wid[gr] : root_wid[gr - TBq];
                int b   = (gr < TBq) ? (gr & (Bq-1)) : (gr - TBq);
                const ushort* eu = EU + (size_t)wid*HP;
                const ushort* tu = TU + (size_t)b*HP;
#pragma unroll
                for (int g=0; g<2; g++){
                    int col = col0 + wn*32 + g*16 + (lane & 15);
                    if (col < Hq)
                        p += fmaxf(acc[f][g][j] + bf2f(eu[col]) + bf2f(tu[col]), 0.f) * Usf[col];
                }
            }
            p += __shfl_xor(p, 1); p += __shfl_xor(p, 2);
            p += __shfl_xor(p, 4); p += __shfl_xor(p, 8);
            if ((lane & 15) == 0 && i < ns) atomicAdd(&ss[i], p);
        }
    }
}

__global__ void stopfin_k(const int* __restrict__ ns_, const int* __restrict__ lists,
    const float* __restrict__ ss, const float* __restrict__ bUs,
    const int* __restrict__ direction, float* __restrict__ accv)
{
    const int ns = *ns_;
    int i = blockIdx.x*256 + threadIdx.x;
    float bce = 0.f, hit = 0.f, c = 0.f;
    if (i < ns){
        int gr = lists[i];
        float s = ss[i] + bUs[0];
        float stgt = (gr < TBq) ? (float)direction[gr] : 0.f;
        bce = fmaxf(s,0.f) - s*stgt + log1pf(__expf(-fabsf(s)));
        hit = ((((s >= 0.f) ? 1.f : 0.f) == stgt) ? 1.f : 0.f);
        c = 1.f;
    }
    for (int off=32; off; off>>=1){
        bce += __shfl_down(bce, off);
        hit += __shfl_down(hit, off);
        c   += __shfl_down(c,   off);
    }
    if ((threadIdx.x & 63) == 0 && c != 0.f){
        atomicAdd(&accv[3], bce);
        atomicAdd(&accv[4], hit);
        atomicAdd(&accv[5], c);
    }
}

__global__ void finalize_k(const float* __restrict__ accv, float* __restrict__ out){
    if (threadIdx.x == 0){
        out[0] = accv[0] / (float)Bq;
        out[1] = accv[3] / (float)Bq;
        out[2] = accv[1] / accv[2];
        out[3] = accv[4] / accv[5];
    }
}

extern "C" void kernel_launch(void* const* d_in, const int* in_sizes, int n_in,
                              void* d_out, int out_size, void* d_ws, size_t ws_size,
                              hipStream_t stream) {
    (void)in_sizes; (void)n_in; (void)out_size; (void)ws_size;
    const float* tree_vecs = (const float*)d_in[0];
    const int*   x_wid     = (const int*)d_in[1];
    const int*   pred_wid  = (const int*)d_in[2];
    const int*   root_wid  = (const int*)d_in[3];
    const int*   h_nei_idx = (const int*)d_in[4];
    const int*   o_nei_idx = (const int*)d_in[5];
    const int*   root_o_nei= (const int*)d_in[6];
    const int*   valid     = (const int*)d_in[7];
    const int*   direction = (const int*)d_in[8];
    const float* emb       = (const float*)d_in[9];
    const float* Wz        = (const float*)d_in[10];
    const float* bz        = (const float*)d_in[11];
    const float* Wr        = (const float*)d_in[12];
    const float* br        = (const float*)d_in[13];
    const float* Ur        = (const float*)d_in[14];
    const float* Wh        = (const float*)d_in[15];
    const float* bh        = (const float*)d_in[16];
    const float* Wm        = (const float*)d_in[17];
    const float* bW        = (const float*)d_in[18];
    const float* U         = (const float*)d_in[19];
    const float* bU        = (const float*)d_in[20];
    const float* Wo        = (const float*)d_in[21];
    const float* bWo       = (const float*)d_in[22];
    const float* Us        = (const float*)d_in[23];
    const float* bUs       = (const float*)d_in[24];

    char* w = (char*)d_ws; size_t off = 0;
    auto alloc = [&](size_t bytes)->void*{ void* p = w + off; off += (bytes + 255) & ~(size_t)255; return p; };

    ushort* hbuf  = (ushort*)alloc((size_t)Sq*HP*2);
    ushort* uhbuf = (ushort*)alloc((size_t)Sq*HP*2);
    ushort* embb  = (ushort*)alloc((size_t)896*HP*2);
    ushort* treeb = (ushort*)alloc((size_t)Bq*64*2);
    ushort* WzX   = (ushort*)alloc((size_t)512*HP*2);
    ushort* WzS   = (ushort*)alloc((size_t)512*HP*2);
    ushort* WrB   = (ushort*)alloc((size_t)512*HP*2);
    ushort* WhX   = (ushort*)alloc((size_t)512*HP*2);
    ushort* WhG   = (ushort*)alloc((size_t)512*HP*2);
    ushort* UrB   = (ushort*)alloc((size_t)512*HP*2);
    ushort* WHp   = (ushort*)alloc((size_t)512*HP*2);
    ushort* UXp   = (ushort*)alloc((size_t)512*HP*2);
    ushort* UOp   = (ushort*)alloc((size_t)512*HP*2);
    ushort* WOp   = (ushort*)alloc((size_t)832*HP*2);
    ushort* WLp   = (ushort*)alloc((size_t)512*64*2);
    ushort* ULp   = (ushort*)alloc((size_t)512*64*2);
    ushort* EZ    = (ushort*)alloc((size_t)896*HP*2);
    ushort* ER    = (ushort*)alloc((size_t)896*HP*2);
    ushort* EH    = (ushort*)alloc((size_t)896*HP*2);
    ushort* EU    = (ushort*)alloc((size_t)896*HP*2);
    ushort* TP    = (ushort*)alloc((size_t)Bq*HP*2);
    ushort* TU    = (ushort*)alloc((size_t)Bq*HP*2);
    ushort* sumhC = (ushort*)alloc((size_t)Bq*HP*2);
    ushort* gatedC= (ushort*)alloc((size_t)Bq*HP*2);
    ushort* nhC   = (ushort*)alloc((size_t)Bq*HP*2);
    ushort* pv    = (ushort*)alloc((size_t)NPCAP*HP*2);
    float*  scores= (float*)alloc((size_t)CH2*832*4);
    float*  ss    = (float*)alloc((size_t)NSCAP*4);
    int*    listp = (int*)alloc((size_t)NPCAP*4);
    int*    lists = (int*)alloc((size_t)NSCAP*4);
    int*    vlist = (int*)alloc((size_t)Tq*Bq*4);
    int*    vcnt  = (int*)alloc((size_t)Tq*4);
    int*    meta  = (int*)alloc((size_t)(NPB*4 + 2 + 16)*4);
    int*    cnts  = meta;            // [2*NPB]
    int*    offs  = meta + 2*NPB;    // [2*NPB]
    int*    tot   = meta + 4*NPB;    // [2]
    float*  accv  = (float*)(meta + 4*NPB + 2);
    ushort* curo  = pv;              // stop phase reuses pv/scores region (31.9MB >= 19.7MB)

    (void)hipMemsetAsync(hbuf,  0, (size_t)Sq*HP*2, stream);
    (void)hipMemsetAsync(uhbuf, 0, (size_t)Sq*HP*2, stream);
    (void)hipMemsetAsync(ss,    0, (size_t)NSCAP*4, stream);
    (void)hipMemsetAsync(meta,  0, (size_t)(NPB*4 + 2 + 16)*4, stream);

    // ---- conversions (1 launch) ----
    convAll_k<<<dim3(896,14), 128, 0, stream>>>(
        emb, tree_vecs, Wz, Wr, Ur, Wh, Wm, U, Wo,
        embb, treeb, WzX, WzS, WrB, WhX, WhG, UrB, WHp, UXp, UOp, WOp, WLp, ULp);

    // ---- precomputes (2 launches, bf16 tables) ----
    preE_k<<<dim3(8,7,4), 256, 0, stream>>>(embb, WzX, WrB, WhX, UXp,
                                            bz, br, bh, bU, EZ, ER, EH, EU);
    preT_k<<<dim3(8,4,2), 256, 0, stream>>>(treeb, WLp, ULp, bW, TP, TU);

    // ---- row compaction (pred/stop + per-step valid lists) ----
    cnt_k <<<dim3(NPB,2), 256, 0, stream>>>(valid, direction, cnts);
    scan_k<<<1, 64, 0, stream>>>(cnts, offs, tot);
    fill_k<<<dim3(NPB,2), 256, 0, stream>>>(valid, direction, offs, listp, lists);
    vfill_k<<<Tq, 512, 0, stream>>>(valid, vcnt, vlist);

    // ---- sequential scan: 3 wide kernels per step ----
    for (int t=0; t<Tq; t++){
        gather_k<<<115, 256, 0, stream>>>(t, x_wid, h_nei_idx, ER, vcnt, vlist,
                                          hbuf, uhbuf, sumhC, gatedC);
        zh_k<<<dim3(16,15), 256, 0, stream>>>(t, x_wid, vcnt, vlist, EZ, EH,
                                              WzS, WhG, sumhC, gatedC, nhC, hbuf);
        ur_k<<<dim3(16,15), 256, 0, stream>>>(t, vcnt, vlist, UrB, nhC, uhbuf);
    }

    // ---- pred phase (compacted) ----
    pred1c_k<<<dim3(NPCAP/128, 8), 256, 0, stream>>>(tot, listp, hbuf, TP, WHp, pv);
    for (int c=0; c<NCH2; c++){
        int cs = c*CH2;
        pred2c_k<<<dim3(CH2/128, 13), 256, 0, stream>>>(cs, tot, pv, WOp, bWo, scores);
        predred_k<<<256, 256, 0, stream>>>(cs, tot, listp, scores, pred_wid, root_wid, accv);
    }

    // ---- stop phase (compacted) ----
    curo_c<<<(NSCAP*60 + 255)/256, 256, 0, stream>>>(tot+1, lists, o_nei_idx, root_o_nei, hbuf, curo);
    stopc_k<<<dim3(NSCAP/128, 8), 256, 0, stream>>>(tot+1, lists, x_wid, root_wid,
                                                    curo, UOp, EU, TU, Us, ss);
    stopfin_k<<<NSCAP/256, 256, 0, stream>>>(tot+1, lists, ss, bUs, direction, accv);

    finalize_k<<<1, 64, 0, stream>>>(accv, (float*)d_out);
}

// Round 15
// 1220.337 us; speedup vs baseline: 4.6482x; 1.1076x over previous
//
#include <hip/hip_runtime.h>
#include <math.h>

#define Bq 512
#define Tq 64
#define Hq 450
#define Lq 56
#define Vq 780
#define Mq 8
#define TBq 32768
#define Sq 32770
#define HP 480          // bf16 row stride (mult of 32)
#define NPB 130         // 130*256 = 33280 rows
#define NPCAP 12288     // compacted pred rows cap
#define NSCAP 20480     // compacted stop rows cap
#define CH2 6144        // pred score chunk rows
#define NCH2 2

using bf16x8 = __attribute__((ext_vector_type(8))) __bf16;
using f32x4  = __attribute__((ext_vector_type(4))) float;
using u32x4  = __attribute__((ext_vector_type(4))) unsigned;

__device__ __forceinline__ ushort f2bf(float f){
    union { float f; unsigned u; } c; c.f = f;
    unsigned u = c.u;
    return (ushort)((u + 0x7FFFu + ((u >> 16) & 1u)) >> 16);
}
__device__ __forceinline__ float bf2f(ushort h){
    union { unsigned u; float f; } c; c.u = ((unsigned)h) << 16;
    return c.f;
}
__device__ __forceinline__ unsigned pk2(float a, float b){
    return (unsigned)f2bf(a) | ((unsigned)f2bf(b) << 16);
}
__device__ __forceinline__ float sigmf(float x){
    return __builtin_amdgcn_rcpf(1.f + __expf(-x));
}
__device__ __forceinline__ float tanhfast(float x){
    float e2 = __expf(2.f * x);
    return 1.f - 2.f * __builtin_amdgcn_rcpf(e2 + 1.f);
}

// ---------- fused converter: 14 jobs by blockIdx.y ----------
__global__ void convAll_k(
    const float* __restrict__ emb, const float* __restrict__ tree,
    const float* __restrict__ Wz, const float* __restrict__ Wr,
    const float* __restrict__ Ur, const float* __restrict__ Wh,
    const float* __restrict__ Wm, const float* __restrict__ U, const float* __restrict__ Wo,
    ushort* embb, ushort* treeb, ushort* WzX, ushort* WzS, ushort* WrB,
    ushort* WhX, ushort* WhG, ushort* UrB, ushort* WHp, ushort* UXp,
    ushort* UOp, ushort* WOp, ushort* WLp, ushort* ULp)
{
    int job = blockIdx.y, n = blockIdx.x;
    const float* src; ushort* dst; int Npad, Nsrc, Ksrc, Kpad, len, off;
    switch(job){
      case 0:  src=emb;  dst=embb; Npad=896; Nsrc=780; Ksrc=450; Kpad=480; len=450; off=0;   break;
      case 1:  src=tree; dst=treeb;Npad=512; Nsrc=512; Ksrc=56;  Kpad=64;  len=56;  off=0;   break;
      case 2:  src=Wz;   dst=WzX;  Npad=512; Nsrc=450; Ksrc=900; Kpad=480; len=450; off=0;   break;
      case 3:  src=Wz;   dst=WzS;  Npad=512; Nsrc=450; Ksrc=900; Kpad=480; len=450; off=450; break;
      case 4:  src=Wr;   dst=WrB;  Npad=512; Nsrc=450; Ksrc=450; Kpad=480; len=450; off=0;   break;
      case 5:  src=Wh;   dst=WhX;  Npad=512; Nsrc=450; Ksrc=900; Kpad=480; len=450; off=0;   break;
      case 6:  src=Wh;   dst=WhG;  Npad=512; Nsrc=450; Ksrc=900; Kpad=480; len=450; off=450; break;
      case 7:  src=Ur;   dst=UrB;  Npad=512; Nsrc=450; Ksrc=450; Kpad=480; len=450; off=0;   break;
      case 8:  src=Wm;   dst=WHp;  Npad=512; Nsrc=450; Ksrc=506; Kpad=480; len=450; off=0;   break;
      case 9:  src=U;    dst=UXp;  Npad=512; Nsrc=450; Ksrc=956; Kpad=480; len=450; off=0;   break;
      case 10: src=U;    dst=UOp;  Npad=512; Nsrc=450; Ksrc=956; Kpad=480; len=450; off=450; break;
      case 11: src=Wo;   dst=WOp;  Npad=832; Nsrc=780; Ksrc=450; Kpad=480; len=450; off=0;   break;
      case 12: src=Wm;   dst=WLp;  Npad=512; Nsrc=450; Ksrc=506; Kpad=64;  len=56;  off=450; break;
      default: src=U;    dst=ULp;  Npad=512; Nsrc=450; Ksrc=956; Kpad=64;  len=56;  off=900; break;
    }
    if (n >= Npad) return;
    for (int k = threadIdx.x; k < Kpad; k += blockDim.x){
        float v = 0.f;
        if (n < Nsrc && k < len) v = src[(size_t)n*Ksrc + off + k];
        dst[(size_t)n*Kpad + k] = f2bf(v);
    }
}

// ---------- double-buffered MFMA GEMM body: C(128x64) tile, SWAPPED operands ----------
// D mapping (swapped): row = row0+wm*64+f*16+(lane&15), col = col0+wn*32+g*16+(lane>>4)*4+j
template<class APtr>
__device__ __forceinline__ void mgemm2(APtr&& aptr, const ushort* __restrict__ Bw, int ldb,
                                       int KT, int col0, f32x4 acc[4][2])
{
    __shared__ __align__(16) char As[2][128*80];
    __shared__ __align__(16) char Bs[2][64*80];
    const int tid = threadIdx.x;
    const int lane = tid & 63;
    const int w = tid >> 6, wm = w >> 1, wn = w & 1;
    const int ac = (tid & 3) * 8;
    const size_t boff = (size_t)(col0 + (tid >> 2)) * ldb;
    u32x4 ra0, ra1, rb;
    auto ld = [&](int k0){
        ra0 = *(const u32x4*)(aptr(0, k0) + ac);
        ra1 = *(const u32x4*)(aptr(1, k0) + ac);
        rb  = *(const u32x4*)(Bw + boff + k0 + ac);
    };
    const int wr_a0 = (tid>>2)*80 + (tid&3)*16;
    const int wr_a1 = ((tid>>2)+64)*80 + (tid&3)*16;
    const int wr_b  = (tid>>2)*80 + (tid&3)*16;
    const int rd_a  = (wm*64 + (lane&15))*80 + (lane>>4)*16;
    const int rd_b  = (wn*32 + (lane&15))*80 + (lane>>4)*16;
    ld(0);
    *(u32x4*)(As[0]+wr_a0) = ra0; *(u32x4*)(As[0]+wr_a1) = ra1; *(u32x4*)(Bs[0]+wr_b) = rb;
#pragma unroll
    for (int f=0;f<4;f++)
#pragma unroll
        for (int g=0;g<2;g++) acc[f][g] = (f32x4){0.f,0.f,0.f,0.f};
    __syncthreads();
    for (int kt=0; kt<KT; ++kt){
        const int cur = kt & 1;
        if (kt+1 < KT) ld((kt+1)*32);
        bf16x8 bF[2];
#pragma unroll
        for (int g=0; g<2; g++) bF[g] = *(const bf16x8*)(Bs[cur] + rd_b + g*16*80);
#pragma unroll
        for (int f=0; f<4; f++){
            bf16x8 aF = *(const bf16x8*)(As[cur] + rd_a + f*16*80);
#pragma unroll
            for (int g=0; g<2; g++)
                acc[f][g] = __builtin_amdgcn_mfma_f32_16x16x32_bf16(bF[g], aF, acc[f][g], 0, 0, 0);
        }
        if (kt+1 < KT){
            *(u32x4*)(As[cur^1]+wr_a0) = ra0; *(u32x4*)(As[cur^1]+wr_a1) = ra1;
            *(u32x4*)(Bs[cur^1]+wr_b) = rb;
        }
        __syncthreads();
    }
}

#define EPI_PRE  const int lane = threadIdx.x & 63; const int w_ = threadIdx.x >> 6; \
                 const int wm = w_ >> 1, wn = w_ & 1;

// ---------- precompute GEMM body: out bf16 [rows][HP] (swapped epilogue) ----------
__device__ __forceinline__ void pre_body(const ushort* __restrict__ A, int lda,
    const ushort* __restrict__ Bw, const float* __restrict__ bias,
    ushort* __restrict__ out, int Mr, int KT)
{
    const int row0 = blockIdx.y*128, col0 = blockIdx.x*64;
    const int tid = threadIdx.x;
    const ushort* p0 = A + (size_t)(row0 + (tid>>2))*lda;
    const ushort* p1 = p0 + (size_t)64*lda;
    f32x4 acc[4][2];
    mgemm2([&](int which,int k0){ return (which?p1:p0)+k0; }, Bw, lda, KT, col0, acc);
    EPI_PRE
#pragma unroll
    for (int f=0; f<4; f++){
        const int row = row0 + wm*64 + f*16 + (lane & 15);
        if (row >= Mr) continue;
#pragma unroll
        for (int g=0; g<2; g++){
            const int C4 = col0 + wn*32 + g*16 + ((lane>>4)<<2);
            if (C4 >= HP) continue;
            ushort o[4];
#pragma unroll
            for (int j=0; j<4; j++){
                int col = C4 + j;
                float bb = (col < Hq && bias) ? bias[col] : 0.f;
                o[j] = (col < Hq) ? f2bf(acc[f][g][j] + bb) : 0;
            }
            uint2 ov; ov.x = (unsigned)o[0] | ((unsigned)o[1]<<16);
            ov.y = (unsigned)o[2] | ((unsigned)o[3]<<16);
            *(uint2*)(out + (size_t)row*HP + C4) = ov;
        }
    }
}

__global__ __launch_bounds__(256) void preE_k(
    const ushort* __restrict__ embb,
    const ushort* __restrict__ WzX, const ushort* __restrict__ WrB,
    const ushort* __restrict__ WhX, const ushort* __restrict__ UXp,
    const float* __restrict__ bz, const float* __restrict__ br,
    const float* __restrict__ bh, const float* __restrict__ bU,
    ushort* __restrict__ EZ, ushort* __restrict__ ER,
    ushort* __restrict__ EH, ushort* __restrict__ EU)
{
    const ushort* Bw; const float* bias; ushort* out;
    switch(blockIdx.z){
      case 0:  Bw=WzX; bias=bz; out=EZ; break;
      case 1:  Bw=WrB; bias=br; out=ER; break;
      case 2:  Bw=WhX; bias=bh; out=EH; break;
      default: Bw=UXp; bias=bU; out=EU; break;
    }
    pre_body(embb, HP, Bw, bias, out, Vq, 15);
}

__global__ __launch_bounds__(256) void preT_k(
    const ushort* __restrict__ treeb,
    const ushort* __restrict__ WLp, const ushort* __restrict__ ULp,
    const float* __restrict__ bW, ushort* __restrict__ TP, ushort* __restrict__ TU)
{
    const ushort* Bw = blockIdx.z ? ULp : WLp;
    const float* bias = blockIdx.z ? nullptr : bW;
    ushort* out = blockIdx.z ? TU : TP;
    pre_body(treeb, 64, Bw, bias, out, Bq, 2);
}

// ---------- compaction for pred/stop: count / scan / fill ----------
__device__ __forceinline__ bool cmask(int which, int gr,
    const int* __restrict__ valid, const int* __restrict__ dir)
{
    if (which == 0) return (gr < Bq) ? true : (valid[gr-Bq] && dir[gr-Bq]);
    return (gr < TBq) ? (valid[gr] != 0) : true;
}
__global__ void cnt_k(const int* __restrict__ valid, const int* __restrict__ dir,
                      int* __restrict__ cnts)
{
    int which = blockIdx.y;
    int gr = blockIdx.x*256 + threadIdx.x;
    bool m = cmask(which, gr, valid, dir);
    unsigned long long bal = __ballot(m);
    if ((threadIdx.x & 63) == 0)
        atomicAdd(&cnts[which*NPB + blockIdx.x], (int)__popcll(bal));
}
__global__ void scan_k(const int* __restrict__ cnts, int* __restrict__ offs,
                       int* __restrict__ totals)
{
    if (threadIdx.x == 0){
        int a = 0;
        for (int i=0;i<NPB;i++){ offs[i] = a; a += cnts[i]; }
        totals[0] = a;
        int b = 0;
        for (int i=0;i<NPB;i++){ offs[NPB+i] = b; b += cnts[NPB+i]; }
        totals[1] = b;
    }
}
__global__ void fill_k(const int* __restrict__ valid, const int* __restrict__ dir,
                       const int* __restrict__ offs, int* __restrict__ listp,
                       int* __restrict__ lists)
{
    __shared__ int woff[4];
    int which = blockIdx.y;
    int gr = blockIdx.x*256 + threadIdx.x;
    bool m = cmask(which, gr, valid, dir);
    unsigned long long bal = __ballot(m);
    int lane = threadIdx.x & 63, wv = threadIdx.x >> 6;
    if (lane == 0) woff[wv] = (int)__popcll(bal);
    __syncthreads();
    int prev = 0;
    for (int i=0;i<wv;i++) prev += woff[i];
    if (m){
        int rank = prev + (int)__popcll(bal & ((1ull << lane) - 1ull));
        int pos = offs[which*NPB + blockIdx.x] + rank;
        if (which == 0){ if (pos < NPCAP) listp[pos] = gr; }
        else           { if (pos < NSCAP) lists[pos] = gr; }
    }
}

// ---------- per-step valid-row lists: vlist[t*Bq + i] = b, vcnt[t] ----------
__global__ void vfill_k(const int* __restrict__ valid,
                        int* __restrict__ vcnt, int* __restrict__ vlist)
{
    __shared__ int woff[8];
    const int t = blockIdx.x;
    const int b = threadIdx.x;              // 512 threads
    bool m = valid[t*Bq + b] != 0;
    unsigned long long bal = __ballot(m);
    int lane = b & 63, wv = b >> 6;
    if (lane == 0) woff[wv] = (int)__popcll(bal);
    __syncthreads();
    int prev = 0;
    for (int i=0;i<wv;i++) prev += woff[i];
    if (m) vlist[t*Bq + prev + (int)__popcll(bal & ((1ull<<lane)-1ull))] = b;
    if (threadIdx.x == 511){
        int tot = 0;
        for (int i=0;i<8;i++) tot += woff[i];
        vcnt[t] = tot;
    }
}

// ---------- scan: gather (compacted valid rows, full machine) ----------
__global__ __launch_bounds__(256) void gather_k(int t,
    const int* __restrict__ x_wid, const int* __restrict__ h_nei_idx,
    const ushort* __restrict__ ER,
    const int* __restrict__ vcnt, const int* __restrict__ vlist,
    const ushort* __restrict__ hbuf, const ushort* __restrict__ uhbuf,
    ushort* __restrict__ sumhC, ushort* __restrict__ gatedC)
{
    const int cnt = vcnt[t];
    const int task = blockIdx.x*256 + threadIdx.x;
    if (task >= cnt*57) return;
    const int i = task / 57;
    const int c = task - i*57;
    const int j0 = c*8;
    const int b = vlist[t*Bq + i];
    const int base = t*Bq + b;
    const int wid = x_wid[base];
    const int* ip = h_nei_idx + (size_t)base*Mq;
    int idx[Mq];
#pragma unroll
    for (int m=0;m<Mq;m++) idx[m] = ip[m];
    float er[8];
    { u32x4 ev = *(const u32x4*)(ER + (size_t)wid*HP + j0);
#pragma unroll
      for (int e=0;e<8;e++) er[e] = bf2f((ushort)((ev[e>>1] >> ((e&1)*16)) & 0xffff)); }
    float sh[8] = {0,0,0,0,0,0,0,0};
    float gt[8] = {0,0,0,0,0,0,0,0};
#pragma unroll
    for (int m=0;m<Mq;m++){
        u32x4 hv = *(const u32x4*)(hbuf  + (size_t)idx[m]*HP + j0);
        u32x4 uv = *(const u32x4*)(uhbuf + (size_t)idx[m]*HP + j0);
#pragma unroll
        for (int e=0;e<8;e++){
            float h = bf2f((ushort)((hv[e>>1] >> ((e&1)*16)) & 0xffff));
            float u = bf2f((ushort)((uv[e>>1] >> ((e&1)*16)) & 0xffff));
            sh[e] += h;
            gt[e] += h * sigmf(er[e] + u);
        }
    }
    u32x4 so, go;
    so[0]=pk2(sh[0],sh[1]); so[1]=pk2(sh[2],sh[3]);
    so[2]=pk2(sh[4],sh[5]); so[3]=pk2(sh[6],sh[7]);
    go[0]=pk2(gt[0],gt[1]); go[1]=pk2(gt[2],gt[3]);
    go[2]=pk2(gt[4],gt[5]); go[3]=pk2(gt[6],gt[7]);
    *(u32x4*)(sumhC  + (size_t)i*HP + j0) = so;
    *(u32x4*)(gatedC + (size_t)i*HP + j0) = go;
}

// ---------- scan: twin GEMM + blend; swapped MFMA, vector epilogue ----------
__global__ __launch_bounds__(256) void zh_k(int t,
    const int* __restrict__ x_wid,
    const int* __restrict__ vcnt, const int* __restrict__ vlist,
    const ushort* __restrict__ EZ, const ushort* __restrict__ EH,
    const ushort* __restrict__ WzS, const ushort* __restrict__ WhG,
    const ushort* __restrict__ sumhC, const ushort* __restrict__ gatedC,
    ushort* __restrict__ nhC, ushort* __restrict__ hbuf)
{
    const int cnt = vcnt[t];
    const int rows0 = blockIdx.x*32;
    if (rows0 >= cnt) return;
    const int cols0 = blockIdx.y*32;
    const int lane = threadIdx.x & 63, w = threadIdx.x >> 6;
    const int wr = w >> 1, wc = w & 1;
    const int ai = rows0 + wr*16 + (lane & 15);       // compacted A row (fragment + output)
    const int Cb = cols0 + wc*16 + (lane & 15);       // weight col (fragment)
    const int kq = (lane >> 4) * 8;
    const ushort* aZp = sumhC  + (size_t)ai*HP + kq;
    const ushort* aGp = gatedC + (size_t)ai*HP + kq;
    const ushort* bZp = WzS + (size_t)Cb*HP + kq;
    const ushort* bGp = WhG + (size_t)Cb*HP + kq;
    f32x4 accZ = (f32x4){0,0,0,0}, accH = (f32x4){0,0,0,0};
#pragma unroll 5
    for (int kt=0; kt<15; ++kt){
        const int kb = kt*32;
        bf16x8 aZ = *(const bf16x8*)(aZp + kb);
        bf16x8 aG = *(const bf16x8*)(aGp + kb);
        bf16x8 bZ = *(const bf16x8*)(bZp + kb);
        bf16x8 bG = *(const bf16x8*)(bGp + kb);
        accZ = __builtin_amdgcn_mfma_f32_16x16x32_bf16(bZ, aZ, accZ, 0, 0, 0);
        accH = __builtin_amdgcn_mfma_f32_16x16x32_bf16(bG, aG, accH, 0, 0, 0);
    }
    // swapped D: this thread owns row ai, 4 consecutive cols C4..C4+3
    if (ai < cnt){
        const int C4 = cols0 + wc*16 + ((lane>>4)<<2);
        const int b = vlist[t*Bq + ai];
        const int base = t*Bq + b;
        const int wid = x_wid[base];
        uint2 ez2 = *(const uint2*)(EZ + (size_t)wid*HP + C4);
        uint2 eh2 = *(const uint2*)(EH + (size_t)wid*HP + C4);
        uint2 sh2 = *(const uint2*)(sumhC + (size_t)ai*HP + C4);
        unsigned ezw[2] = {ez2.x, ez2.y}, ehw[2] = {eh2.x, eh2.y}, shw[2] = {sh2.x, sh2.y};
        ushort o[4];
#pragma unroll
        for (int j=0; j<4; j++){
            const int C = C4 + j;
            float z  = sigmf(accZ[j] + bf2f((ushort)((ezw[j>>1] >> ((j&1)*16)) & 0xffff)));
            float ht = tanhfast(accH[j] + bf2f((ushort)((ehw[j>>1] >> ((j&1)*16)) & 0xffff)));
            float sh = bf2f((ushort)((shw[j>>1] >> ((j&1)*16)) & 0xffff));
            o[j] = (C < Hq) ? f2bf((1.f - z)*sh + z*ht) : 0;
        }
        uint2 ov; ov.x = (unsigned)o[0] | ((unsigned)o[1]<<16);
        ov.y = (unsigned)o[2] | ((unsigned)o[3]<<16);
        *(uint2*)(nhC + (size_t)ai*HP + C4) = ov;
        *(uint2*)(hbuf + (size_t)(1 + base)*HP + C4) = ov;   // pads written as 0 (stay 0)
    }
}

// ---------- scan: uh = nh @ Ur^T; swapped MFMA, vector epilogue ----------
__global__ __launch_bounds__(256) void ur_k(int t,
    const int* __restrict__ vcnt, const int* __restrict__ vlist,
    const ushort* __restrict__ UrB, const ushort* __restrict__ nhC,
    ushort* __restrict__ uhbuf)
{
    const int cnt = vcnt[t];
    const int rows0 = blockIdx.x*32;
    if (rows0 >= cnt) return;
    const int cols0 = blockIdx.y*32;
    const int lane = threadIdx.x & 63, w = threadIdx.x >> 6;
    const int wr = w >> 1, wc = w & 1;
    const int ai = rows0 + wr*16 + (lane & 15);
    const int Cb = cols0 + wc*16 + (lane & 15);
    const int kq = (lane >> 4) * 8;
    const ushort* aNp = nhC + (size_t)ai*HP + kq;
    const ushort* bUp = UrB + (size_t)Cb*HP + kq;
    f32x4 acc = (f32x4){0,0,0,0};
#pragma unroll 5
    for (int kt=0; kt<15; ++kt){
        const int kb = kt*32;
        bf16x8 aN = *(const bf16x8*)(aNp + kb);
        bf16x8 bU = *(const bf16x8*)(bUp + kb);
        acc = __builtin_amdgcn_mfma_f32_16x16x32_bf16(bU, aN, acc, 0, 0, 0);
    }
    if (ai < cnt){
        const int C4 = cols0 + wc*16 + ((lane>>4)<<2);
        const int b = vlist[t*Bq + ai];
        ushort o[4];
#pragma unroll
        for (int j=0; j<4; j++)
            o[j] = (C4 + j < Hq) ? f2bf(acc[j]) : 0;
        uint2 ov; ov.x = (unsigned)o[0] | ((unsigned)o[1]<<16);
        ov.y = (unsigned)o[2] | ((unsigned)o[3]<<16);
        *(uint2*)(uhbuf + (size_t)(1 + t*Bq + b)*HP + C4) = ov;  // pads written as 0
    }
}

// ---------- pred GEMM1 (compacted rows); swapped epilogue ----------
__global__ __launch_bounds__(256) void pred1c_k(const int* __restrict__ np_,
    const int* __restrict__ listp, const ushort* __restrict__ hbuf,
    const ushort* __restrict__ TP, const ushort* __restrict__ WHp,
    ushort* __restrict__ pv)
{
    const int np = *np_;
    const int row0 = blockIdx.x*128;
    if (row0 >= np) return;
    const int col0 = blockIdx.y*64;
    const int tid = threadIdx.x;
    int i0 = row0 + (tid>>2), i1 = i0 + 64;
    int g0 = (i0 < np) ? listp[i0] : 0;
    int g1 = (i1 < np) ? listp[i1] : 0;
    const ushort* p0 = (g0 < Bq) ? hbuf : hbuf + (size_t)(1 + g0 - Bq)*HP;  // hbuf row0 = zeros
    const ushort* p1 = (g1 < Bq) ? hbuf : hbuf + (size_t)(1 + g1 - Bq)*HP;
    f32x4 acc[4][2];
    mgemm2([&](int which,int k0){ return (which?p1:p0)+k0; }, WHp, HP, 15, col0, acc);
    EPI_PRE
#pragma unroll
    for (int f=0; f<4; f++){
        const int i = row0 + wm*64 + f*16 + (lane & 15);
        if (i >= np) continue;
        const int gr = listp[i];
        const int b = (gr < Bq) ? gr : ((gr - Bq) & (Bq-1));
#pragma unroll
        for (int g=0; g<2; g++){
            const int C4 = col0 + wn*32 + g*16 + ((lane>>4)<<2);
            if (C4 >= HP) continue;
            uint2 tp2 = *(const uint2*)(TP + (size_t)b*HP + C4);
            unsigned tpw[2] = {tp2.x, tp2.y};
            ushort o[4];
#pragma unroll
            for (int j=0; j<4; j++){
                float v = fmaxf(acc[f][g][j] + bf2f((ushort)((tpw[j>>1] >> ((j&1)*16)) & 0xffff)), 0.f);
                o[j] = f2bf(v);   // pad cols: acc=0, TP=0 -> relu(0)=0
            }
            uint2 ov; ov.x = (unsigned)o[0] | ((unsigned)o[1]<<16);
            ov.y = (unsigned)o[2] | ((unsigned)o[3]<<16);
            *(uint2*)(pv + (size_t)i*HP + C4) = ov;
        }
    }
}

// ---------- pred GEMM2; swapped epilogue, float4 stores ----------
__global__ __launch_bounds__(256) void pred2c_k(int cs, const int* __restrict__ np_,
    const ushort* __restrict__ pv, const ushort* __restrict__ WOp,
    const float* __restrict__ bWo, float* __restrict__ scores)
{
    const int np = *np_;
    const int row0 = blockIdx.x*128;
    if (cs + row0 >= np) return;
    const int col0 = blockIdx.y*64;
    const int tid = threadIdx.x;
    const ushort* p0 = pv + (size_t)(cs + row0 + (tid>>2))*HP;
    const ushort* p1 = p0 + (size_t)64*HP;
    f32x4 acc[4][2];
    mgemm2([&](int which,int k0){ return (which?p1:p0)+k0; }, WOp, HP, 15, col0, acc);
    EPI_PRE
#pragma unroll
    for (int f=0; f<4; f++){
        const int r = row0 + wm*64 + f*16 + (lane & 15);
#pragma unroll
        for (int g=0; g<2; g++){
            const int C4 = col0 + wn*32 + g*16 + ((lane>>4)<<2);
            float4 ov;
            float* op = (float*)&ov;
#pragma unroll
            for (int j=0; j<4; j++){
                int col = C4 + j;
                op[j] = acc[f][g][j] + ((col < Vq) ? bWo[col] : 0.f);
            }
            *(float4*)(scores + (size_t)r*832 + C4) = ov;
        }
    }
}

// ---------- pred reduce: wave-per-row ----------
__global__ __launch_bounds__(256) void predred_k(int cs, const int* __restrict__ np_,
    const int* __restrict__ listp, const float* __restrict__ scores,
    const int* __restrict__ pred_wid, const int* __restrict__ root_wid,
    float* __restrict__ accv)
{
    const int np = *np_;
    int nrows = np - cs; if (nrows > CH2) nrows = CH2;
    const int lane = threadIdx.x & 63, wv = threadIdx.x >> 6;
    const int wid_g = blockIdx.x*4 + wv, nw = gridDim.x*4;
    float ce = 0.f, hit = 0.f, cnt = 0.f;
    for (int r = wid_g; r < nrows; r += nw){
        const float* sc = scores + (size_t)r*832;
        int gr = listp[cs + r];
        int tgt = (gr < Bq) ? root_wid[gr] : pred_wid[gr - Bq];
        float vals[13];
        float bv = -INFINITY, tv = 0.f; int bi = 0;
#pragma unroll
        for (int q=0; q<13; q++){
            int j = lane + q*64;
            float v = (j < Vq) ? sc[j] : -INFINITY;
            vals[q] = v;
            if (v > bv){ bv = v; bi = j; }
            if (j == tgt) tv = v;
        }
#pragma unroll
        for (int off=32; off; off>>=1){
            float ov = __shfl_xor(bv, off); int oi = __shfl_xor(bi, off);
            if (ov > bv || (ov == bv && oi < bi)){ bv = ov; bi = oi; }
        }
        float s = 0.f;
#pragma unroll
        for (int q=0; q<13; q++){
            int j = lane + q*64;
            if (j < Vq) s += __expf(vals[q] - bv);
        }
#pragma unroll
        for (int off=32; off; off>>=1) s += __shfl_xor(s, off);
#pragma unroll
        for (int off=32; off; off>>=1) tv += __shfl_xor(tv, off);
        if (lane == 0){
            ce += bv + logf(s) - tv;
            hit += (bi == tgt) ? 1.f : 0.f;
            cnt += 1.f;
        }
    }
    __shared__ float L[3][4];
    if (lane == 0){ L[0][wv] = ce; L[1][wv] = hit; L[2][wv] = cnt; }
    __syncthreads();
    if (threadIdx.x == 0){
        float a = L[0][0]+L[0][1]+L[0][2]+L[0][3];
        float b = L[1][0]+L[1][1]+L[1][2]+L[1][3];
        float c = L[2][0]+L[2][1]+L[2][2]+L[2][3];
        if (c != 0.f){
            atomicAdd(&accv[0], a);
            atomicAdd(&accv[1], b);
            atomicAdd(&accv[2], c);
        }
    }
}

// ---------- stop: cur_o gather (task-parallel, 16B chunks; pads stored w/o loads) ----------
__global__ __launch_bounds__(256) void curo_c(const int* __restrict__ ns_,
    const int* __restrict__ lists,
    const int* __restrict__ o_nei_idx, const int* __restrict__ root_o_nei,
    const ushort* __restrict__ hbuf, ushort* __restrict__ curo)
{
    const int ns = *ns_;
    const int task = blockIdx.x*256 + threadIdx.x;
    if (task >= ns*60) return;
    const int i = task / 60;
    const int c = task - i*60;
    const int j0 = c*8;
    if (c >= 57){
        u32x4 z = (u32x4){0,0,0,0};
        *(u32x4*)(curo + (size_t)i*HP + j0) = z;
        return;
    }
    const int gr = lists[i];
    int idx[Mq];
    if (gr < TBq){
        int tt = gr >> 9;
#pragma unroll
        for (int m=0;m<Mq;m++){
            int ix = o_nei_idx[(size_t)gr*Mq + m];
            idx[m] = (ix <= tt*Bq) ? ix : 0;   // slots written before step tt; row 0 is zero
        }
    } else {
#pragma unroll
        for (int m=0;m<Mq;m++) idx[m] = root_o_nei[(size_t)(gr-TBq)*Mq + m];
    }
    float sh[8] = {0,0,0,0,0,0,0,0};
#pragma unroll
    for (int m=0;m<Mq;m++){
        u32x4 hv = *(const u32x4*)(hbuf + (size_t)idx[m]*HP + j0);
#pragma unroll
        for (int e=0;e<8;e++)
            sh[e] += bf2f((ushort)((hv[e>>1] >> ((e&1)*16)) & 0xffff));
    }
    u32x4 so;
    so[0]=pk2(sh[0],sh[1]); so[1]=pk2(sh[2],sh[3]);
    so[2]=pk2(sh[4],sh[5]); so[3]=pk2(sh[6],sh[7]);
    *(u32x4*)(curo + (size_t)i*HP + j0) = so;
}

// ---------- stop GEMM (compacted) + fused Us-dot; swapped epilogue ----------
__global__ __launch_bounds__(256) void stopc_k(const int* __restrict__ ns_,
    const int* __restrict__ lists, const int* __restrict__ x_wid,
    const int* __restrict__ root_wid, const ushort* __restrict__ curo,
    const ushort* __restrict__ UOp, const ushort* __restrict__ EU,
    const ushort* __restrict__ TU, const float* __restrict__ Usf,
    float* __restrict__ ss)
{
    const int ns = *ns_;
    const int row0 = blockIdx.x*128;
    if (row0 >= ns) return;
    const int col0 = blockIdx.y*64;
    const int tid = threadIdx.x;
    const ushort* p0 = curo + (size_t)(row0 + (tid>>2))*HP;
    const ushort* p1 = p0 + (size_t)64*HP;
    f32x4 acc[4][2];
    mgemm2([&](int which,int k0){ return (which?p1:p0)+k0; }, UOp, HP, 15, col0, acc);
    EPI_PRE
#pragma unroll
    for (int f=0; f<4; f++){
        const int i = row0 + wm*64 + f*16 + (lane & 15);
        float p = 0.f;
        if (i < ns){
            const int gr = lists[i];
            const int wid = (gr < TBq) ? x_wid[gr] : root_wid[gr - TBq];
            const int b   = (gr < TBq) ? (gr & (Bq-1)) : (gr - TBq);
#pragma unroll
            for (int g=0; g<2; g++){
                const int C4 = col0 + wn*32 + g*16 + ((lane>>4)<<2);
                if (C4 >= Hq) continue;
                uint2 eu2 = *(const uint2*)(EU + (size_t)wid*HP + C4);
                uint2 tu2 = *(const uint2*)(TU + (size_t)b*HP + C4);
                unsigned euw[2] = {eu2.x, eu2.y}, tuw[2] = {tu2.x, tu2.y};
#pragma unroll
                for (int j=0; j<4; j++){
                    const int col = C4 + j;
                    if (col < Hq){
                        float e = bf2f((ushort)((euw[j>>1] >> ((j&1)*16)) & 0xffff));
                        float u = bf2f((ushort)((tuw[j>>1] >> ((j&1)*16)) & 0xffff));
                        p += fmaxf(acc[f][g][j] + e + u, 0.f) * Usf[col];
                    }
                }
            }
        }
        p += __shfl_xor(p, 16); p += __shfl_xor(p, 32);
        if ((lane >> 4) == 0 && i < ns) atomicAdd(&ss[i], p);
    }
}

__global__ void stopfin_k(const int* __restrict__ ns_, const int* __restrict__ lists,
    const float* __restrict__ ss, const float* __restrict__ bUs,
    const int* __restrict__ direction, float* __restrict__ accv)
{
    const int ns = *ns_;
    int i = blockIdx.x*256 + threadIdx.x;
    float bce = 0.f, hit = 0.f, c = 0.f;
    if (i < ns){
        int gr = lists[i];
        float s = ss[i] + bUs[0];
        float stgt = (gr < TBq) ? (float)direction[gr] : 0.f;
        bce = fmaxf(s,0.f) - s*stgt + log1pf(__expf(-fabsf(s)));
        hit = ((((s >= 0.f) ? 1.f : 0.f) == stgt) ? 1.f : 0.f);
        c = 1.f;
    }
    for (int off=32; off; off>>=1){
        bce += __shfl_down(bce, off);
        hit += __shfl_down(hit, off);
        c   += __shfl_down(c,   off);
    }
    if ((threadIdx.x & 63) == 0 && c != 0.f){
        atomicAdd(&accv[3], bce);
        atomicAdd(&accv[4], hit);
        atomicAdd(&accv[5], c);
    }
}

__global__ void finalize_k(const float* __restrict__ accv, float* __restrict__ out){
    if (threadIdx.x == 0){
        out[0] = accv[0] / (float)Bq;
        out[1] = accv[3] / (float)Bq;
        out[2] = accv[1] / accv[2];
        out[3] = accv[4] / accv[5];
    }
}

extern "C" void kernel_launch(void* const* d_in, const int* in_sizes, int n_in,
                              void* d_out, int out_size, void* d_ws, size_t ws_size,
                              hipStream_t stream) {
    (void)in_sizes; (void)n_in; (void)out_size; (void)ws_size;
    const float* tree_vecs = (const float*)d_in[0];
    const int*   x_wid     = (const int*)d_in[1];
    const int*   pred_wid  = (const int*)d_in[2];
    const int*   root_wid  = (const int*)d_in[3];
    const int*   h_nei_idx = (const int*)d_in[4];
    const int*   o_nei_idx = (const int*)d_in[5];
    const int*   root_o_nei= (const int*)d_in[6];
    const int*   valid     = (const int*)d_in[7];
    const int*   direction = (const int*)d_in[8];
    const float* emb       = (const float*)d_in[9];
    const float* Wz        = (const float*)d_in[10];
    const float* bz        = (const float*)d_in[11];
    const float* Wr        = (const float*)d_in[12];
    const float* br        = (const float*)d_in[13];
    const float* Ur        = (const float*)d_in[14];
    const float* Wh        = (const float*)d_in[15];
    const float* bh        = (const float*)d_in[16];
    const float* Wm        = (const float*)d_in[17];
    const float* bW        = (const float*)d_in[18];
    const float* U         = (const float*)d_in[19];
    const float* bU        = (const float*)d_in[20];
    const float* Wo        = (const float*)d_in[21];
    const float* bWo       = (const float*)d_in[22];
    const float* Us        = (const float*)d_in[23];
    const float* bUs       = (const float*)d_in[24];

    char* w = (char*)d_ws; size_t off = 0;
    auto alloc = [&](size_t bytes)->void*{ void* p = w + off; off += (bytes + 255) & ~(size_t)255; return p; };

    ushort* hbuf  = (ushort*)alloc((size_t)Sq*HP*2);
    ushort* uhbuf = (ushort*)alloc((size_t)Sq*HP*2);
    ushort* embb  = (ushort*)alloc((size_t)896*HP*2);
    ushort* treeb = (ushort*)alloc((size_t)Bq*64*2);
    ushort* WzX   = (ushort*)alloc((size_t)512*HP*2);
    ushort* WzS   = (ushort*)alloc((size_t)512*HP*2);
    ushort* WrB   = (ushort*)alloc((size_t)512*HP*2);
    ushort* WhX   = (ushort*)alloc((size_t)512*HP*2);
    ushort* WhG   = (ushort*)alloc((size_t)512*HP*2);
    ushort* UrB   = (ushort*)alloc((size_t)512*HP*2);
    ushort* WHp   = (ushort*)alloc((size_t)512*HP*2);
    ushort* UXp   = (ushort*)alloc((size_t)512*HP*2);
    ushort* UOp   = (ushort*)alloc((size_t)512*HP*2);
    ushort* WOp   = (ushort*)alloc((size_t)832*HP*2);
    ushort* WLp   = (ushort*)alloc((size_t)512*64*2);
    ushort* ULp   = (ushort*)alloc((size_t)512*64*2);
    ushort* EZ    = (ushort*)alloc((size_t)896*HP*2);
    ushort* ER    = (ushort*)alloc((size_t)896*HP*2);
    ushort* EH    = (ushort*)alloc((size_t)896*HP*2);
    ushort* EU    = (ushort*)alloc((size_t)896*HP*2);
    ushort* TP    = (ushort*)alloc((size_t)Bq*HP*2);
    ushort* TU    = (ushort*)alloc((size_t)Bq*HP*2);
    ushort* sumhC = (ushort*)alloc((size_t)Bq*HP*2);
    ushort* gatedC= (ushort*)alloc((size_t)Bq*HP*2);
    ushort* nhC   = (ushort*)alloc((size_t)Bq*HP*2);
    ushort* pv    = (ushort*)alloc((size_t)NPCAP*HP*2);
    float*  scores= (float*)alloc((size_t)CH2*832*4);
    float*  ss    = (float*)alloc((size_t)NSCAP*4);
    int*    listp = (int*)alloc((size_t)NPCAP*4);
    int*    lists = (int*)alloc((size_t)NSCAP*4);
    int*    vlist = (int*)alloc((size_t)Tq*Bq*4);
    int*    vcnt  = (int*)alloc((size_t)Tq*4);
    int*    meta  = (int*)alloc((size_t)(NPB*4 + 2 + 16)*4);
    int*    cnts  = meta;            // [2*NPB]
    int*    offs  = meta + 2*NPB;    // [2*NPB]
    int*    tot   = meta + 4*NPB;    // [2]
    float*  accv  = (float*)(meta + 4*NPB + 2);
    ushort* curo  = pv;              // stop phase reuses pv/scores region

    (void)hipMemsetAsync(hbuf,  0, (size_t)Sq*HP*2, stream);
    (void)hipMemsetAsync(uhbuf, 0, (size_t)Sq*HP*2, stream);
    (void)hipMemsetAsync(ss,    0, (size_t)NSCAP*4, stream);
    (void)hipMemsetAsync(meta,  0, (size_t)(NPB*4 + 2 + 16)*4, stream);

    // ---- conversions (1 launch) ----
    convAll_k<<<dim3(896,14), 128, 0, stream>>>(
        emb, tree_vecs, Wz, Wr, Ur, Wh, Wm, U, Wo,
        embb, treeb, WzX, WzS, WrB, WhX, WhG, UrB, WHp, UXp, UOp, WOp, WLp, ULp);

    // ---- precomputes (2 launches, bf16 tables) ----
    preE_k<<<dim3(8,7,4), 256, 0, stream>>>(embb, WzX, WrB, WhX, UXp,
                                            bz, br, bh, bU, EZ, ER, EH, EU);
    preT_k<<<dim3(8,4,2), 256, 0, stream>>>(treeb, WLp, ULp, bW, TP, TU);

    // ---- row compaction (pred/stop + per-step valid lists) ----
    cnt_k <<<dim3(NPB,2), 256, 0, stream>>>(valid, direction, cnts);
    scan_k<<<1, 64, 0, stream>>>(cnts, offs, tot);
    fill_k<<<dim3(NPB,2), 256, 0, stream>>>(valid, direction, offs, listp, lists);
    vfill_k<<<Tq, 512, 0, stream>>>(valid, vcnt, vlist);

    // ---- sequential scan: 3 wide kernels per step ----
    for (int t=0; t<Tq; t++){
        gather_k<<<115, 256, 0, stream>>>(t, x_wid, h_nei_idx, ER, vcnt, vlist,
                                          hbuf, uhbuf, sumhC, gatedC);
        zh_k<<<dim3(16,15), 256, 0, stream>>>(t, x_wid, vcnt, vlist, EZ, EH,
                                              WzS, WhG, sumhC, gatedC, nhC, hbuf);
        ur_k<<<dim3(16,15), 256, 0, stream>>>(t, vcnt, vlist, UrB, nhC, uhbuf);
    }

    // ---- pred phase (compacted) ----
    pred1c_k<<<dim3(NPCAP/128, 8), 256, 0, stream>>>(tot, listp, hbuf, TP, WHp, pv);
    for (int c=0; c<NCH2; c++){
        int cs = c*CH2;
        pred2c_k<<<dim3(CH2/128, 13), 256, 0, stream>>>(cs, tot, pv, WOp, bWo, scores);
        predred_k<<<256, 256, 0, stream>>>(cs, tot, listp, scores, pred_wid, root_wid, accv);
    }

    // ---- stop phase (compacted) ----
    curo_c<<<(NSCAP*60 + 255)/256, 256, 0, stream>>>(tot+1, lists, o_nei_idx, root_o_nei, hbuf, curo);
    stopc_k<<<dim3(NSCAP/128, 8), 256, 0, stream>>>(tot+1, lists, x_wid, root_wid,
                                                    curo, UOp, EU, TU, Us, ss);
    stopfin_k<<<NSCAP/256, 256, 0, stream>>>(tot+1, lists, ss, bUs, direction, accv);

    finalize_k<<<1, 64, 0, stream>>>(accv, (float*)d_out);
}

// Round 16
// 1177.735 us; speedup vs baseline: 4.8163x; 1.0362x over previous
//
#include <hip/hip_runtime.h>
#include <math.h>

#define Bq 512
#define Tq 64
#define Hq 450
#define Lq 56
#define Vq 780
#define Mq 8
#define TBq 32768
#define Sq 32770
#define HP 480          // bf16 row stride (mult of 32)
#define NPB 130         // 130*256 = 33280 rows
#define NPCAP 12288     // compacted pred rows cap
#define NSCAP 20480     // compacted stop rows cap
#define CH2 6144        // pred score chunk rows
#define NCH2 2

using bf16x8 = __attribute__((ext_vector_type(8))) __bf16;
using f32x4  = __attribute__((ext_vector_type(4))) float;
using u32x4  = __attribute__((ext_vector_type(4))) unsigned;

__device__ __forceinline__ ushort f2bf(float f){
    union { float f; unsigned u; } c; c.f = f;
    unsigned u = c.u;
    return (ushort)((u + 0x7FFFu + ((u >> 16) & 1u)) >> 16);
}
__device__ __forceinline__ float bf2f(ushort h){
    union { unsigned u; float f; } c; c.u = ((unsigned)h) << 16;
    return c.f;
}
__device__ __forceinline__ unsigned pk2(float a, float b){
    return (unsigned)f2bf(a) | ((unsigned)f2bf(b) << 16);
}
__device__ __forceinline__ float sigmf(float x){
    return __builtin_amdgcn_rcpf(1.f + __expf(-x));
}
__device__ __forceinline__ float tanhfast(float x){
    float e2 = __expf(2.f * x);
    return 1.f - 2.f * __builtin_amdgcn_rcpf(e2 + 1.f);
}

// ---------- fused converter: 14 jobs by blockIdx.y ----------
__global__ void convAll_k(
    const float* __restrict__ emb, const float* __restrict__ tree,
    const float* __restrict__ Wz, const float* __restrict__ Wr,
    const float* __restrict__ Ur, const float* __restrict__ Wh,
    const float* __restrict__ Wm, const float* __restrict__ U, const float* __restrict__ Wo,
    ushort* embb, ushort* treeb, ushort* WzX, ushort* WzS, ushort* WrB,
    ushort* WhX, ushort* WhG, ushort* UrB, ushort* WHp, ushort* UXp,
    ushort* UOp, ushort* WOp, ushort* WLp, ushort* ULp)
{
    int job = blockIdx.y, n = blockIdx.x;
    const float* src; ushort* dst; int Npad, Nsrc, Ksrc, Kpad, len, off;
    switch(job){
      case 0:  src=emb;  dst=embb; Npad=896; Nsrc=780; Ksrc=450; Kpad=480; len=450; off=0;   break;
      case 1:  src=tree; dst=treeb;Npad=512; Nsrc=512; Ksrc=56;  Kpad=64;  len=56;  off=0;   break;
      case 2:  src=Wz;   dst=WzX;  Npad=512; Nsrc=450; Ksrc=900; Kpad=480; len=450; off=0;   break;
      case 3:  src=Wz;   dst=WzS;  Npad=512; Nsrc=450; Ksrc=900; Kpad=480; len=450; off=450; break;
      case 4:  src=Wr;   dst=WrB;  Npad=512; Nsrc=450; Ksrc=450; Kpad=480; len=450; off=0;   break;
      case 5:  src=Wh;   dst=WhX;  Npad=512; Nsrc=450; Ksrc=900; Kpad=480; len=450; off=0;   break;
      case 6:  src=Wh;   dst=WhG;  Npad=512; Nsrc=450; Ksrc=900; Kpad=480; len=450; off=450; break;
      case 7:  src=Ur;   dst=UrB;  Npad=512; Nsrc=450; Ksrc=450; Kpad=480; len=450; off=0;   break;
      case 8:  src=Wm;   dst=WHp;  Npad=512; Nsrc=450; Ksrc=506; Kpad=480; len=450; off=0;   break;
      case 9:  src=U;    dst=UXp;  Npad=512; Nsrc=450; Ksrc=956; Kpad=480; len=450; off=0;   break;
      case 10: src=U;    dst=UOp;  Npad=512; Nsrc=450; Ksrc=956; Kpad=480; len=450; off=450; break;
      case 11: src=Wo;   dst=WOp;  Npad=832; Nsrc=780; Ksrc=450; Kpad=480; len=450; off=0;   break;
      case 12: src=Wm;   dst=WLp;  Npad=512; Nsrc=450; Ksrc=506; Kpad=64;  len=56;  off=450; break;
      default: src=U;    dst=ULp;  Npad=512; Nsrc=450; Ksrc=956; Kpad=64;  len=56;  off=900; break;
    }
    if (n >= Npad) return;
    for (int k = threadIdx.x; k < Kpad; k += blockDim.x){
        float v = 0.f;
        if (n < Nsrc && k < len) v = src[(size_t)n*Ksrc + off + k];
        dst[(size_t)n*Kpad + k] = f2bf(v);
    }
}

// ---------- double-buffered MFMA GEMM body: C(128x64) tile, SWAPPED operands ----------
// D mapping (swapped): row = row0+wm*64+f*16+(lane&15), col = col0+wn*32+g*16+(lane>>4)*4+j
template<class APtr>
__device__ __forceinline__ void mgemm2(APtr&& aptr, const ushort* __restrict__ Bw, int ldb,
                                       int KT, int col0, f32x4 acc[4][2])
{
    __shared__ __align__(16) char As[2][128*80];
    __shared__ __align__(16) char Bs[2][64*80];
    const int tid = threadIdx.x;
    const int lane = tid & 63;
    const int w = tid >> 6, wm = w >> 1, wn = w & 1;
    const int ac = (tid & 3) * 8;
    const size_t boff = (size_t)(col0 + (tid >> 2)) * ldb;
    u32x4 ra0, ra1, rb;
    auto ld = [&](int k0){
        ra0 = *(const u32x4*)(aptr(0, k0) + ac);
        ra1 = *(const u32x4*)(aptr(1, k0) + ac);
        rb  = *(const u32x4*)(Bw + boff + k0 + ac);
    };
    const int wr_a0 = (tid>>2)*80 + (tid&3)*16;
    const int wr_a1 = ((tid>>2)+64)*80 + (tid&3)*16;
    const int wr_b  = (tid>>2)*80 + (tid&3)*16;
    const int rd_a  = (wm*64 + (lane&15))*80 + (lane>>4)*16;
    const int rd_b  = (wn*32 + (lane&15))*80 + (lane>>4)*16;
    ld(0);
    *(u32x4*)(As[0]+wr_a0) = ra0; *(u32x4*)(As[0]+wr_a1) = ra1; *(u32x4*)(Bs[0]+wr_b) = rb;
#pragma unroll
    for (int f=0;f<4;f++)
#pragma unroll
        for (int g=0;g<2;g++) acc[f][g] = (f32x4){0.f,0.f,0.f,0.f};
    __syncthreads();
    for (int kt=0; kt<KT; ++kt){
        const int cur = kt & 1;
        if (kt+1 < KT) ld((kt+1)*32);
        bf16x8 bF[2];
#pragma unroll
        for (int g=0; g<2; g++) bF[g] = *(const bf16x8*)(Bs[cur] + rd_b + g*16*80);
#pragma unroll
        for (int f=0; f<4; f++){
            bf16x8 aF = *(const bf16x8*)(As[cur] + rd_a + f*16*80);
#pragma unroll
            for (int g=0; g<2; g++)
                acc[f][g] = __builtin_amdgcn_mfma_f32_16x16x32_bf16(bF[g], aF, acc[f][g], 0, 0, 0);
        }
        if (kt+1 < KT){
            *(u32x4*)(As[cur^1]+wr_a0) = ra0; *(u32x4*)(As[cur^1]+wr_a1) = ra1;
            *(u32x4*)(Bs[cur^1]+wr_b) = rb;
        }
        __syncthreads();
    }
}

#define EPI_PRE  const int lane = threadIdx.x & 63; const int w_ = threadIdx.x >> 6; \
                 const int wm = w_ >> 1, wn = w_ & 1;

// ---------- precompute GEMM body: out bf16 [rows][HP] (swapped epilogue) ----------
__device__ __forceinline__ void pre_body(const ushort* __restrict__ A, int lda,
    const ushort* __restrict__ Bw, const float* __restrict__ bias,
    ushort* __restrict__ out, int Mr, int KT)
{
    const int row0 = blockIdx.y*128, col0 = blockIdx.x*64;
    const int tid = threadIdx.x;
    const ushort* p0 = A + (size_t)(row0 + (tid>>2))*lda;
    const ushort* p1 = p0 + (size_t)64*lda;
    f32x4 acc[4][2];
    mgemm2([&](int which,int k0){ return (which?p1:p0)+k0; }, Bw, lda, KT, col0, acc);
    EPI_PRE
#pragma unroll
    for (int f=0; f<4; f++){
        const int row = row0 + wm*64 + f*16 + (lane & 15);
        if (row >= Mr) continue;
#pragma unroll
        for (int g=0; g<2; g++){
            const int C4 = col0 + wn*32 + g*16 + ((lane>>4)<<2);
            if (C4 >= HP) continue;
            ushort o[4];
#pragma unroll
            for (int j=0; j<4; j++){
                int col = C4 + j;
                float bb = (col < Hq && bias) ? bias[col] : 0.f;
                o[j] = (col < Hq) ? f2bf(acc[f][g][j] + bb) : 0;
            }
            uint2 ov; ov.x = (unsigned)o[0] | ((unsigned)o[1]<<16);
            ov.y = (unsigned)o[2] | ((unsigned)o[3]<<16);
            *(uint2*)(out + (size_t)row*HP + C4) = ov;
        }
    }
}

__global__ __launch_bounds__(256) void preE_k(
    const ushort* __restrict__ embb,
    const ushort* __restrict__ WzX, const ushort* __restrict__ WrB,
    const ushort* __restrict__ WhX, const ushort* __restrict__ UXp,
    const float* __restrict__ bz, const float* __restrict__ br,
    const float* __restrict__ bh, const float* __restrict__ bU,
    ushort* __restrict__ EZ, ushort* __restrict__ ER,
    ushort* __restrict__ EH, ushort* __restrict__ EU)
{
    const ushort* Bw; const float* bias; ushort* out;
    switch(blockIdx.z){
      case 0:  Bw=WzX; bias=bz; out=EZ; break;
      case 1:  Bw=WrB; bias=br; out=ER; break;
      case 2:  Bw=WhX; bias=bh; out=EH; break;
      default: Bw=UXp; bias=bU; out=EU; break;
    }
    pre_body(embb, HP, Bw, bias, out, Vq, 15);
}

__global__ __launch_bounds__(256) void preT_k(
    const ushort* __restrict__ treeb,
    const ushort* __restrict__ WLp, const ushort* __restrict__ ULp,
    const float* __restrict__ bW, ushort* __restrict__ TP, ushort* __restrict__ TU)
{
    const ushort* Bw = blockIdx.z ? ULp : WLp;
    const float* bias = blockIdx.z ? nullptr : bW;
    ushort* out = blockIdx.z ? TU : TP;
    pre_body(treeb, 64, Bw, bias, out, Bq, 2);
}

// ---------- compaction for pred/stop: count / scan / fill ----------
__device__ __forceinline__ bool cmask(int which, int gr,
    const int* __restrict__ valid, const int* __restrict__ dir)
{
    if (which == 0) return (gr < Bq) ? true : (valid[gr-Bq] && dir[gr-Bq]);
    return (gr < TBq) ? (valid[gr] != 0) : true;
}
__global__ void cnt_k(const int* __restrict__ valid, const int* __restrict__ dir,
                      int* __restrict__ cnts)
{
    int which = blockIdx.y;
    int gr = blockIdx.x*256 + threadIdx.x;
    bool m = cmask(which, gr, valid, dir);
    unsigned long long bal = __ballot(m);
    if ((threadIdx.x & 63) == 0)
        atomicAdd(&cnts[which*NPB + blockIdx.x], (int)__popcll(bal));
}
__global__ void scan_k(const int* __restrict__ cnts, int* __restrict__ offs,
                       int* __restrict__ totals)
{
    if (threadIdx.x == 0){
        int a = 0;
        for (int i=0;i<NPB;i++){ offs[i] = a; a += cnts[i]; }
        totals[0] = a;
        int b = 0;
        for (int i=0;i<NPB;i++){ offs[NPB+i] = b; b += cnts[NPB+i]; }
        totals[1] = b;
    }
}
__global__ void fill_k(const int* __restrict__ valid, const int* __restrict__ dir,
                       const int* __restrict__ offs, int* __restrict__ listp,
                       int* __restrict__ lists)
{
    __shared__ int woff[4];
    int which = blockIdx.y;
    int gr = blockIdx.x*256 + threadIdx.x;
    bool m = cmask(which, gr, valid, dir);
    unsigned long long bal = __ballot(m);
    int lane = threadIdx.x & 63, wv = threadIdx.x >> 6;
    if (lane == 0) woff[wv] = (int)__popcll(bal);
    __syncthreads();
    int prev = 0;
    for (int i=0;i<wv;i++) prev += woff[i];
    if (m){
        int rank = prev + (int)__popcll(bal & ((1ull << lane) - 1ull));
        int pos = offs[which*NPB + blockIdx.x] + rank;
        if (which == 0){ if (pos < NPCAP) listp[pos] = gr; }
        else           { if (pos < NSCAP) lists[pos] = gr; }
    }
}

// ---------- per-step valid-row lists: vlist[t*Bq + i] = b, vcnt[t] ----------
__global__ void vfill_k(const int* __restrict__ valid,
                        int* __restrict__ vcnt, int* __restrict__ vlist)
{
    __shared__ int woff[8];
    const int t = blockIdx.x;
    const int b = threadIdx.x;              // 512 threads
    bool m = valid[t*Bq + b] != 0;
    unsigned long long bal = __ballot(m);
    int lane = b & 63, wv = b >> 6;
    if (lane == 0) woff[wv] = (int)__popcll(bal);
    __syncthreads();
    int prev = 0;
    for (int i=0;i<wv;i++) prev += woff[i];
    if (m) vlist[t*Bq + prev + (int)__popcll(bal & ((1ull<<lane)-1ull))] = b;
    if (threadIdx.x == 511){
        int tot = 0;
        for (int i=0;i<8;i++) tot += woff[i];
        vcnt[t] = tot;
    }
}

// ---------- index redirect: h_idx2[r*M+m] = usable slot or 0 ----------
// Slot s holds live data at reader-step t iff 1<=s<=t*Bq && valid[s-1];
// otherwise reference semantics give 0 == our永zero slot 0. Removes the
// need to zero-fill hbuf/uhbuf (only row 0 stays zeroed).
__global__ void hidx_k(const int* __restrict__ h_nei_idx, const int* __restrict__ valid,
                       int* __restrict__ h_idx2)
{
    const int e = blockIdx.x*256 + threadIdx.x;     // e < TBq*Mq
    const int r = e >> 3;
    const int t = r >> 9;                            // r / Bq
    const int ix = h_nei_idx[e];
    const bool ok = (ix >= 1) && (ix <= t*Bq) && (valid[ix-1] != 0);
    h_idx2[e] = ok ? ix : 0;
}
__global__ void oidx_k(const int* __restrict__ o_nei_idx, const int* __restrict__ root_o_nei,
                       const int* __restrict__ valid, int* __restrict__ o_idx2)
{
    const int e = blockIdx.x*256 + threadIdx.x;     // e < (TBq+Bq)*Mq
    const int i = e >> 3;
    int ix, ok;
    if (i < TBq){
        const int tt = i >> 9;
        ix = o_nei_idx[e];
        ok = (ix >= 1) && (ix <= tt*Bq) && (valid[ix-1] != 0);
    } else {
        ix = root_o_nei[e - TBq*Mq];
        ok = (ix >= 1) && (valid[ix-1] != 0);
    }
    o_idx2[e] = ok ? ix : 0;
}

// ---------- scan: gather (compacted valid rows, full machine) ----------
__global__ __launch_bounds__(256) void gather_k(int t,
    const int* __restrict__ x_wid, const int* __restrict__ h_idx2,
    const ushort* __restrict__ ER,
    const int* __restrict__ vcnt, const int* __restrict__ vlist,
    const ushort* __restrict__ hbuf, const ushort* __restrict__ uhbuf,
    ushort* __restrict__ sumhC, ushort* __restrict__ gatedC)
{
    const int cnt = vcnt[t];
    const int task = blockIdx.x*256 + threadIdx.x;
    if (task >= cnt*57) return;
    const int i = task / 57;
    const int c = task - i*57;
    const int j0 = c*8;
    const int b = vlist[t*Bq + i];
    const int base = t*Bq + b;
    const int wid = x_wid[base];
    const int* ip = h_idx2 + (size_t)base*Mq;
    int idx[Mq];
#pragma unroll
    for (int m=0;m<Mq;m++) idx[m] = ip[m];
    float er[8];
    { u32x4 ev = *(const u32x4*)(ER + (size_t)wid*HP + j0);
#pragma unroll
      for (int e=0;e<8;e++) er[e] = bf2f((ushort)((ev[e>>1] >> ((e&1)*16)) & 0xffff)); }
    float sh[8] = {0,0,0,0,0,0,0,0};
    float gt[8] = {0,0,0,0,0,0,0,0};
#pragma unroll
    for (int m=0;m<Mq;m++){
        u32x4 hv = *(const u32x4*)(hbuf  + (size_t)idx[m]*HP + j0);
        u32x4 uv = *(const u32x4*)(uhbuf + (size_t)idx[m]*HP + j0);
#pragma unroll
        for (int e=0;e<8;e++){
            float h = bf2f((ushort)((hv[e>>1] >> ((e&1)*16)) & 0xffff));
            float u = bf2f((ushort)((uv[e>>1] >> ((e&1)*16)) & 0xffff));
            sh[e] += h;
            gt[e] += h * sigmf(er[e] + u);
        }
    }
    u32x4 so, go;
    so[0]=pk2(sh[0],sh[1]); so[1]=pk2(sh[2],sh[3]);
    so[2]=pk2(sh[4],sh[5]); so[3]=pk2(sh[6],sh[7]);
    go[0]=pk2(gt[0],gt[1]); go[1]=pk2(gt[2],gt[3]);
    go[2]=pk2(gt[4],gt[5]); go[3]=pk2(gt[6],gt[7]);
    *(u32x4*)(sumhC  + (size_t)i*HP + j0) = so;
    *(u32x4*)(gatedC + (size_t)i*HP + j0) = go;
}

// ---------- scan: twin GEMM + blend; swapped MFMA, vector epilogue ----------
__global__ __launch_bounds__(256) void zh_k(int t,
    const int* __restrict__ x_wid,
    const int* __restrict__ vcnt, const int* __restrict__ vlist,
    const ushort* __restrict__ EZ, const ushort* __restrict__ EH,
    const ushort* __restrict__ WzS, const ushort* __restrict__ WhG,
    const ushort* __restrict__ sumhC, const ushort* __restrict__ gatedC,
    ushort* __restrict__ nhC, ushort* __restrict__ hbuf)
{
    const int cnt = vcnt[t];
    const int rows0 = blockIdx.x*32;
    if (rows0 >= cnt) return;
    const int cols0 = blockIdx.y*32;
    const int lane = threadIdx.x & 63, w = threadIdx.x >> 6;
    const int wr = w >> 1, wc = w & 1;
    const int ai = rows0 + wr*16 + (lane & 15);       // compacted A row (fragment + output)
    const int Cb = cols0 + wc*16 + (lane & 15);       // weight col (fragment)
    const int kq = (lane >> 4) * 8;
    const ushort* aZp = sumhC  + (size_t)ai*HP + kq;
    const ushort* aGp = gatedC + (size_t)ai*HP + kq;
    const ushort* bZp = WzS + (size_t)Cb*HP + kq;
    const ushort* bGp = WhG + (size_t)Cb*HP + kq;
    f32x4 accZ = (f32x4){0,0,0,0}, accH = (f32x4){0,0,0,0};
#pragma unroll 5
    for (int kt=0; kt<15; ++kt){
        const int kb = kt*32;
        bf16x8 aZ = *(const bf16x8*)(aZp + kb);
        bf16x8 aG = *(const bf16x8*)(aGp + kb);
        bf16x8 bZ = *(const bf16x8*)(bZp + kb);
        bf16x8 bG = *(const bf16x8*)(bGp + kb);
        accZ = __builtin_amdgcn_mfma_f32_16x16x32_bf16(bZ, aZ, accZ, 0, 0, 0);
        accH = __builtin_amdgcn_mfma_f32_16x16x32_bf16(bG, aG, accH, 0, 0, 0);
    }
    // swapped D: this thread owns row ai, 4 consecutive cols C4..C4+3
    if (ai < cnt){
        const int C4 = cols0 + wc*16 + ((lane>>4)<<2);
        const int b = vlist[t*Bq + ai];
        const int base = t*Bq + b;
        const int wid = x_wid[base];
        uint2 ez2 = *(const uint2*)(EZ + (size_t)wid*HP + C4);
        uint2 eh2 = *(const uint2*)(EH + (size_t)wid*HP + C4);
        uint2 sh2 = *(const uint2*)(sumhC + (size_t)ai*HP + C4);
        unsigned ezw[2] = {ez2.x, ez2.y}, ehw[2] = {eh2.x, eh2.y}, shw[2] = {sh2.x, sh2.y};
        ushort o[4];
#pragma unroll
        for (int j=0; j<4; j++){
            const int C = C4 + j;
            float z  = sigmf(accZ[j] + bf2f((ushort)((ezw[j>>1] >> ((j&1)*16)) & 0xffff)));
            float ht = tanhfast(accH[j] + bf2f((ushort)((ehw[j>>1] >> ((j&1)*16)) & 0xffff)));
            float sh = bf2f((ushort)((shw[j>>1] >> ((j&1)*16)) & 0xffff));
            o[j] = (C < Hq) ? f2bf((1.f - z)*sh + z*ht) : 0;
        }
        uint2 ov; ov.x = (unsigned)o[0] | ((unsigned)o[1]<<16);
        ov.y = (unsigned)o[2] | ((unsigned)o[3]<<16);
        *(uint2*)(nhC + (size_t)ai*HP + C4) = ov;
        *(uint2*)(hbuf + (size_t)(1 + base)*HP + C4) = ov;   // pads written as 0 (stay 0)
    }
}

// ---------- scan: uh = nh @ Ur^T; swapped MFMA, vector epilogue ----------
__global__ __launch_bounds__(256) void ur_k(int t,
    const int* __restrict__ vcnt, const int* __restrict__ vlist,
    const ushort* __restrict__ UrB, const ushort* __restrict__ nhC,
    ushort* __restrict__ uhbuf)
{
    const int cnt = vcnt[t];
    const int rows0 = blockIdx.x*32;
    if (rows0 >= cnt) return;
    const int cols0 = blockIdx.y*32;
    const int lane = threadIdx.x & 63, w = threadIdx.x >> 6;
    const int wr = w >> 1, wc = w & 1;
    const int ai = rows0 + wr*16 + (lane & 15);
    const int Cb = cols0 + wc*16 + (lane & 15);
    const int kq = (lane >> 4) * 8;
    const ushort* aNp = nhC + (size_t)ai*HP + kq;
    const ushort* bUp = UrB + (size_t)Cb*HP + kq;
    f32x4 acc = (f32x4){0,0,0,0};
#pragma unroll 5
    for (int kt=0; kt<15; ++kt){
        const int kb = kt*32;
        bf16x8 aN = *(const bf16x8*)(aNp + kb);
        bf16x8 bU = *(const bf16x8*)(bUp + kb);
        acc = __builtin_amdgcn_mfma_f32_16x16x32_bf16(bU, aN, acc, 0, 0, 0);
    }
    if (ai < cnt){
        const int C4 = cols0 + wc*16 + ((lane>>4)<<2);
        const int b = vlist[t*Bq + ai];
        ushort o[4];
#pragma unroll
        for (int j=0; j<4; j++)
            o[j] = (C4 + j < Hq) ? f2bf(acc[j]) : 0;
        uint2 ov; ov.x = (unsigned)o[0] | ((unsigned)o[1]<<16);
        ov.y = (unsigned)o[2] | ((unsigned)o[3]<<16);
        *(uint2*)(uhbuf + (size_t)(1 + t*Bq + b)*HP + C4) = ov;  // pads written as 0
    }
}

// ---------- pred GEMM1 (compacted rows); swapped epilogue ----------
__global__ __launch_bounds__(256) void pred1c_k(const int* __restrict__ np_,
    const int* __restrict__ listp, const ushort* __restrict__ hbuf,
    const ushort* __restrict__ TP, const ushort* __restrict__ WHp,
    ushort* __restrict__ pv)
{
    const int np = *np_;
    const int row0 = blockIdx.x*128;
    if (row0 >= np) return;
    const int col0 = blockIdx.y*64;
    const int tid = threadIdx.x;
    int i0 = row0 + (tid>>2), i1 = i0 + 64;
    int g0 = (i0 < np) ? listp[i0] : 0;
    int g1 = (i1 < np) ? listp[i1] : 0;
    const ushort* p0 = (g0 < Bq) ? hbuf : hbuf + (size_t)(1 + g0 - Bq)*HP;  // hbuf row0 = zeros
    const ushort* p1 = (g1 < Bq) ? hbuf : hbuf + (size_t)(1 + g1 - Bq)*HP;
    f32x4 acc[4][2];
    mgemm2([&](int which,int k0){ return (which?p1:p0)+k0; }, WHp, HP, 15, col0, acc);
    EPI_PRE
#pragma unroll
    for (int f=0; f<4; f++){
        const int i = row0 + wm*64 + f*16 + (lane & 15);
        if (i >= np) continue;
        const int gr = listp[i];
        const int b = (gr < Bq) ? gr : ((gr - Bq) & (Bq-1));
#pragma unroll
        for (int g=0; g<2; g++){
            const int C4 = col0 + wn*32 + g*16 + ((lane>>4)<<2);
            if (C4 >= HP) continue;
            uint2 tp2 = *(const uint2*)(TP + (size_t)b*HP + C4);
            unsigned tpw[2] = {tp2.x, tp2.y};
            ushort o[4];
#pragma unroll
            for (int j=0; j<4; j++){
                float v = fmaxf(acc[f][g][j] + bf2f((ushort)((tpw[j>>1] >> ((j&1)*16)) & 0xffff)), 0.f);
                o[j] = f2bf(v);   // pad cols: acc=0, TP=0 -> relu(0)=0
            }
            uint2 ov; ov.x = (unsigned)o[0] | ((unsigned)o[1]<<16);
            ov.y = (unsigned)o[2] | ((unsigned)o[3]<<16);
            *(uint2*)(pv + (size_t)i*HP + C4) = ov;
        }
    }
}

// ---------- pred GEMM2; swapped epilogue, float4 stores ----------
__global__ __launch_bounds__(256) void pred2c_k(int cs, const int* __restrict__ np_,
    const ushort* __restrict__ pv, const ushort* __restrict__ WOp,
    const float* __restrict__ bWo, float* __restrict__ scores)
{
    const int np = *np_;
    const int row0 = blockIdx.x*128;
    if (cs + row0 >= np) return;
    const int col0 = blockIdx.y*64;
    const int tid = threadIdx.x;
    const ushort* p0 = pv + (size_t)(cs + row0 + (tid>>2))*HP;
    const ushort* p1 = p0 + (size_t)64*HP;
    f32x4 acc[4][2];
    mgemm2([&](int which,int k0){ return (which?p1:p0)+k0; }, WOp, HP, 15, col0, acc);
    EPI_PRE
#pragma unroll
    for (int f=0; f<4; f++){
        const int r = row0 + wm*64 + f*16 + (lane & 15);
#pragma unroll
        for (int g=0; g<2; g++){
            const int C4 = col0 + wn*32 + g*16 + ((lane>>4)<<2);
            float4 ov;
            float* op = (float*)&ov;
#pragma unroll
            for (int j=0; j<4; j++){
                int col = C4 + j;
                op[j] = acc[f][g][j] + ((col < Vq) ? bWo[col] : 0.f);
            }
            *(float4*)(scores + (size_t)r*832 + C4) = ov;
        }
    }
}

// ---------- pred reduce: wave-per-row ----------
__global__ __launch_bounds__(256) void predred_k(int cs, const int* __restrict__ np_,
    const int* __restrict__ listp, const float* __restrict__ scores,
    const int* __restrict__ pred_wid, const int* __restrict__ root_wid,
    float* __restrict__ accv)
{
    const int np = *np_;
    int nrows = np - cs; if (nrows > CH2) nrows = CH2;
    const int lane = threadIdx.x & 63, wv = threadIdx.x >> 6;
    const int wid_g = blockIdx.x*4 + wv, nw = gridDim.x*4;
    float ce = 0.f, hit = 0.f, cnt = 0.f;
    for (int r = wid_g; r < nrows; r += nw){
        const float* sc = scores + (size_t)r*832;
        int gr = listp[cs + r];
        int tgt = (gr < Bq) ? root_wid[gr] : pred_wid[gr - Bq];
        float vals[13];
        float bv = -INFINITY, tv = 0.f; int bi = 0;
#pragma unroll
        for (int q=0; q<13; q++){
            int j = lane + q*64;
            float v = (j < Vq) ? sc[j] : -INFINITY;
            vals[q] = v;
            if (v > bv){ bv = v; bi = j; }
            if (j == tgt) tv = v;
        }
#pragma unroll
        for (int off=32; off; off>>=1){
            float ov = __shfl_xor(bv, off); int oi = __shfl_xor(bi, off);
            if (ov > bv || (ov == bv && oi < bi)){ bv = ov; bi = oi; }
        }
        float s = 0.f;
#pragma unroll
        for (int q=0; q<13; q++){
            int j = lane + q*64;
            if (j < Vq) s += __expf(vals[q] - bv);
        }
#pragma unroll
        for (int off=32; off; off>>=1) s += __shfl_xor(s, off);
#pragma unroll
        for (int off=32; off; off>>=1) tv += __shfl_xor(tv, off);
        if (lane == 0){
            ce += bv + logf(s) - tv;
            hit += (bi == tgt) ? 1.f : 0.f;
            cnt += 1.f;
        }
    }
    __shared__ float L[3][4];
    if (lane == 0){ L[0][wv] = ce; L[1][wv] = hit; L[2][wv] = cnt; }
    __syncthreads();
    if (threadIdx.x == 0){
        float a = L[0][0]+L[0][1]+L[0][2]+L[0][3];
        float b = L[1][0]+L[1][1]+L[1][2]+L[1][3];
        float c = L[2][0]+L[2][1]+L[2][2]+L[2][3];
        if (c != 0.f){
            atomicAdd(&accv[0], a);
            atomicAdd(&accv[1], b);
            atomicAdd(&accv[2], c);
        }
    }
}

// ---------- stop: cur_o gather (task-parallel, 16B chunks; pads stored w/o loads) ----------
__global__ __launch_bounds__(256) void curo_c(const int* __restrict__ ns_,
    const int* __restrict__ lists, const int* __restrict__ o_idx2,
    const ushort* __restrict__ hbuf, ushort* __restrict__ curo)
{
    const int ns = *ns_;
    const int task = blockIdx.x*256 + threadIdx.x;
    if (task >= ns*60) return;
    const int i = task / 60;
    const int c = task - i*60;
    const int j0 = c*8;
    if (c >= 57){
        u32x4 z = (u32x4){0,0,0,0};
        *(u32x4*)(curo + (size_t)i*HP + j0) = z;
        return;
    }
    const int gr = lists[i];
    const int* ip = o_idx2 + (size_t)gr*Mq;
    int idx[Mq];
#pragma unroll
    for (int m=0;m<Mq;m++) idx[m] = ip[m];
    float sh[8] = {0,0,0,0,0,0,0,0};
#pragma unroll
    for (int m=0;m<Mq;m++){
        u32x4 hv = *(const u32x4*)(hbuf + (size_t)idx[m]*HP + j0);
#pragma unroll
        for (int e=0;e<8;e++)
            sh[e] += bf2f((ushort)((hv[e>>1] >> ((e&1)*16)) & 0xffff));
    }
    u32x4 so;
    so[0]=pk2(sh[0],sh[1]); so[1]=pk2(sh[2],sh[3]);
    so[2]=pk2(sh[4],sh[5]); so[3]=pk2(sh[6],sh[7]);
    *(u32x4*)(curo + (size_t)i*HP + j0) = so;
}

// ---------- stop GEMM (compacted) + fused Us-dot; swapped epilogue ----------
__global__ __launch_bounds__(256) void stopc_k(const int* __restrict__ ns_,
    const int* __restrict__ lists, const int* __restrict__ x_wid,
    const int* __restrict__ root_wid, const ushort* __restrict__ curo,
    const ushort* __restrict__ UOp, const ushort* __restrict__ EU,
    const ushort* __restrict__ TU, const float* __restrict__ Usf,
    float* __restrict__ ss)
{
    const int ns = *ns_;
    const int row0 = blockIdx.x*128;
    if (row0 >= ns) return;
    const int col0 = blockIdx.y*64;
    const int tid = threadIdx.x;
    const ushort* p0 = curo + (size_t)(row0 + (tid>>2))*HP;
    const ushort* p1 = p0 + (size_t)64*HP;
    f32x4 acc[4][2];
    mgemm2([&](int which,int k0){ return (which?p1:p0)+k0; }, UOp, HP, 15, col0, acc);
    EPI_PRE
#pragma unroll
    for (int f=0; f<4; f++){
        const int i = row0 + wm*64 + f*16 + (lane & 15);
        float p = 0.f;
        if (i < ns){
            const int gr = lists[i];
            const int wid = (gr < TBq) ? x_wid[gr] : root_wid[gr - TBq];
            const int b   = (gr < TBq) ? (gr & (Bq-1)) : (gr - TBq);
#pragma unroll
            for (int g=0; g<2; g++){
                const int C4 = col0 + wn*32 + g*16 + ((lane>>4)<<2);
                if (C4 >= Hq) continue;
                uint2 eu2 = *(const uint2*)(EU + (size_t)wid*HP + C4);
                uint2 tu2 = *(const uint2*)(TU + (size_t)b*HP + C4);
                unsigned euw[2] = {eu2.x, eu2.y}, tuw[2] = {tu2.x, tu2.y};
#pragma unroll
                for (int j=0; j<4; j++){
                    const int col = C4 + j;
                    if (col < Hq){
                        float e = bf2f((ushort)((euw[j>>1] >> ((j&1)*16)) & 0xffff));
                        float u = bf2f((ushort)((tuw[j>>1] >> ((j&1)*16)) & 0xffff));
                        p += fmaxf(acc[f][g][j] + e + u, 0.f) * Usf[col];
                    }
                }
            }
        }
        p += __shfl_xor(p, 16); p += __shfl_xor(p, 32);
        if ((lane >> 4) == 0 && i < ns) atomicAdd(&ss[i], p);
    }
}

__global__ void stopfin_k(const int* __restrict__ ns_, const int* __restrict__ lists,
    const float* __restrict__ ss, const float* __restrict__ bUs,
    const int* __restrict__ direction, float* __restrict__ accv)
{
    const int ns = *ns_;
    int i = blockIdx.x*256 + threadIdx.x;
    float bce = 0.f, hit = 0.f, c = 0.f;
    if (i < ns){
        int gr = lists[i];
        float s = ss[i] + bUs[0];
        float stgt = (gr < TBq) ? (float)direction[gr] : 0.f;
        bce = fmaxf(s,0.f) - s*stgt + log1pf(__expf(-fabsf(s)));
        hit = ((((s >= 0.f) ? 1.f : 0.f) == stgt) ? 1.f : 0.f);
        c = 1.f;
    }
    for (int off=32; off; off>>=1){
        bce += __shfl_down(bce, off);
        hit += __shfl_down(hit, off);
        c   += __shfl_down(c,   off);
    }
    if ((threadIdx.x & 63) == 0 && c != 0.f){
        atomicAdd(&accv[3], bce);
        atomicAdd(&accv[4], hit);
        atomicAdd(&accv[5], c);
    }
}

__global__ void finalize_k(const float* __restrict__ accv, float* __restrict__ out){
    if (threadIdx.x == 0){
        out[0] = accv[0] / (float)Bq;
        out[1] = accv[3] / (float)Bq;
        out[2] = accv[1] / accv[2];
        out[3] = accv[4] / accv[5];
    }
}

extern "C" void kernel_launch(void* const* d_in, const int* in_sizes, int n_in,
                              void* d_out, int out_size, void* d_ws, size_t ws_size,
                              hipStream_t stream) {
    (void)in_sizes; (void)n_in; (void)out_size; (void)ws_size;
    const float* tree_vecs = (const float*)d_in[0];
    const int*   x_wid     = (const int*)d_in[1];
    const int*   pred_wid  = (const int*)d_in[2];
    const int*   root_wid  = (const int*)d_in[3];
    const int*   h_nei_idx = (const int*)d_in[4];
    const int*   o_nei_idx = (const int*)d_in[5];
    const int*   root_o_nei= (const int*)d_in[6];
    const int*   valid     = (const int*)d_in[7];
    const int*   direction = (const int*)d_in[8];
    const float* emb       = (const float*)d_in[9];
    const float* Wz        = (const float*)d_in[10];
    const float* bz        = (const float*)d_in[11];
    const float* Wr        = (const float*)d_in[12];
    const float* br        = (const float*)d_in[13];
    const float* Ur        = (const float*)d_in[14];
    const float* Wh        = (const float*)d_in[15];
    const float* bh        = (const float*)d_in[16];
    const float* Wm        = (const float*)d_in[17];
    const float* bW        = (const float*)d_in[18];
    const float* U         = (const float*)d_in[19];
    const float* bU        = (const float*)d_in[20];
    const float* Wo        = (const float*)d_in[21];
    const float* bWo       = (const float*)d_in[22];
    const float* Us        = (const float*)d_in[23];
    const float* bUs       = (const float*)d_in[24];

    char* w = (char*)d_ws; size_t off = 0;
    auto alloc = [&](size_t bytes)->void*{ void* p = w + off; off += (bytes + 255) & ~(size_t)255; return p; };

    ushort* hbuf  = (ushort*)alloc((size_t)Sq*HP*2);
    ushort* uhbuf = (ushort*)alloc((size_t)Sq*HP*2);
    ushort* embb  = (ushort*)alloc((size_t)896*HP*2);
    ushort* treeb = (ushort*)alloc((size_t)Bq*64*2);
    ushort* WzX   = (ushort*)alloc((size_t)512*HP*2);
    ushort* WzS   = (ushort*)alloc((size_t)512*HP*2);
    ushort* WrB   = (ushort*)alloc((size_t)512*HP*2);
    ushort* WhX   = (ushort*)alloc((size_t)512*HP*2);
    ushort* WhG   = (ushort*)alloc((size_t)512*HP*2);
    ushort* UrB   = (ushort*)alloc((size_t)512*HP*2);
    ushort* WHp   = (ushort*)alloc((size_t)512*HP*2);
    ushort* UXp   = (ushort*)alloc((size_t)512*HP*2);
    ushort* UOp   = (ushort*)alloc((size_t)512*HP*2);
    ushort* WOp   = (ushort*)alloc((size_t)832*HP*2);
    ushort* WLp   = (ushort*)alloc((size_t)512*64*2);
    ushort* ULp   = (ushort*)alloc((size_t)512*64*2);
    ushort* EZ    = (ushort*)alloc((size_t)896*HP*2);
    ushort* ER    = (ushort*)alloc((size_t)896*HP*2);
    ushort* EH    = (ushort*)alloc((size_t)896*HP*2);
    ushort* EU    = (ushort*)alloc((size_t)896*HP*2);
    ushort* TP    = (ushort*)alloc((size_t)Bq*HP*2);
    ushort* TU    = (ushort*)alloc((size_t)Bq*HP*2);
    ushort* sumhC = (ushort*)alloc((size_t)Bq*HP*2);
    ushort* gatedC= (ushort*)alloc((size_t)Bq*HP*2);
    ushort* nhC   = (ushort*)alloc((size_t)Bq*HP*2);
    ushort* pv    = (ushort*)alloc((size_t)NPCAP*HP*2);
    float*  scores= (float*)alloc((size_t)CH2*832*4);
    float*  ss    = (float*)alloc((size_t)NSCAP*4);
    int*    listp = (int*)alloc((size_t)NPCAP*4);
    int*    lists = (int*)alloc((size_t)NSCAP*4);
    int*    vlist = (int*)alloc((size_t)Tq*Bq*4);
    int*    vcnt  = (int*)alloc((size_t)Tq*4);
    int*    h_idx2= (int*)alloc((size_t)TBq*Mq*4);
    int*    o_idx2= (int*)alloc((size_t)(TBq+Bq)*Mq*4);
    int*    meta  = (int*)alloc((size_t)(NPB*4 + 2 + 16)*4);
    int*    cnts  = meta;            // [2*NPB]
    int*    offs  = meta + 2*NPB;    // [2*NPB]
    int*    tot   = meta + 4*NPB;    // [2]
    float*  accv  = (float*)(meta + 4*NPB + 2);
    ushort* curo  = pv;              // stop phase reuses pv/scores region

    // only slot 0 of hbuf/uhbuf must be zero (index redirect handles the rest)
    (void)hipMemsetAsync(hbuf,  0, (size_t)HP*2, stream);
    (void)hipMemsetAsync(uhbuf, 0, (size_t)HP*2, stream);
    (void)hipMemsetAsync(ss,    0, (size_t)NSCAP*4, stream);
    (void)hipMemsetAsync(meta,  0, (size_t)(NPB*4 + 2 + 16)*4, stream);

    // ---- conversions (1 launch) ----
    convAll_k<<<dim3(896,14), 128, 0, stream>>>(
        emb, tree_vecs, Wz, Wr, Ur, Wh, Wm, U, Wo,
        embb, treeb, WzX, WzS, WrB, WhX, WhG, UrB, WHp, UXp, UOp, WOp, WLp, ULp);

    // ---- precomputes (2 launches, bf16 tables) ----
    preE_k<<<dim3(8,7,4), 256, 0, stream>>>(embb, WzX, WrB, WhX, UXp,
                                            bz, br, bh, bU, EZ, ER, EH, EU);
    preT_k<<<dim3(8,4,2), 256, 0, stream>>>(treeb, WLp, ULp, bW, TP, TU);

    // ---- row compaction + index redirects ----
    cnt_k <<<dim3(NPB,2), 256, 0, stream>>>(valid, direction, cnts);
    scan_k<<<1, 64, 0, stream>>>(cnts, offs, tot);
    fill_k<<<dim3(NPB,2), 256, 0, stream>>>(valid, direction, offs, listp, lists);
    vfill_k<<<Tq, 512, 0, stream>>>(valid, vcnt, vlist);
    hidx_k<<<TBq*Mq/256, 256, 0, stream>>>(h_nei_idx, valid, h_idx2);
    oidx_k<<<(TBq+Bq)*Mq/256, 256, 0, stream>>>(o_nei_idx, root_o_nei, valid, o_idx2);

    // ---- sequential scan: 3 wide kernels per step ----
    for (int t=0; t<Tq; t++){
        gather_k<<<115, 256, 0, stream>>>(t, x_wid, h_idx2, ER, vcnt, vlist,
                                          hbuf, uhbuf, sumhC, gatedC);
        zh_k<<<dim3(16,15), 256, 0, stream>>>(t, x_wid, vcnt, vlist, EZ, EH,
                                              WzS, WhG, sumhC, gatedC, nhC, hbuf);
        ur_k<<<dim3(16,15), 256, 0, stream>>>(t, vcnt, vlist, UrB, nhC, uhbuf);
    }

    // ---- pred phase (compacted) ----
    pred1c_k<<<dim3(NPCAP/128, 8), 256, 0, stream>>>(tot, listp, hbuf, TP, WHp, pv);
    for (int c=0; c<NCH2; c++){
        int cs = c*CH2;
        pred2c_k<<<dim3(CH2/128, 13), 256, 0, stream>>>(cs, tot, pv, WOp, bWo, scores);
        predred_k<<<256, 256, 0, stream>>>(cs, tot, listp, scores, pred_wid, root_wid, accv);
    }

    // ---- stop phase (compacted) ----
    curo_c<<<(NSCAP*60 + 255)/256, 256, 0, stream>>>(tot+1, lists, o_idx2, hbuf, curo);
    stopc_k<<<dim3(NSCAP/128, 8), 256, 0, stream>>>(tot+1, lists, x_wid, root_wid,
                                                    curo, UOp, EU, TU, Us, ss);
    stopfin_k<<<NSCAP/256, 256, 0, stream>>>(tot+1, lists, ss, bUs, direction, accv);

    finalize_k<<<1, 64, 0, stream>>>(accv, (float*)d_out);
}

// Round 17
// 1154.069 us; speedup vs baseline: 4.9151x; 1.0205x over previous
//
#include <hip/hip_runtime.h>
#include <math.h>

#define Bq 512
#define Tq 64
#define Hq 450
#define Lq 56
#define Vq 780
#define Mq 8
#define TBq 32768
#define Sq 32770
#define HP 480          // bf16 row stride (mult of 32)
#define NPB 130         // 130*256 = 33280 rows
#define NPCAP 12288     // compacted pred rows cap
#define NSCAP 20480     // compacted stop rows cap

using bf16x8 = __attribute__((ext_vector_type(8))) __bf16;
using f32x4  = __attribute__((ext_vector_type(4))) float;
using u32x4  = __attribute__((ext_vector_type(4))) unsigned;

__device__ __forceinline__ ushort f2bf(float f){
    union { float f; unsigned u; } c; c.f = f;
    unsigned u = c.u;
    return (ushort)((u + 0x7FFFu + ((u >> 16) & 1u)) >> 16);
}
__device__ __forceinline__ float bf2f(ushort h){
    union { unsigned u; float f; } c; c.u = ((unsigned)h) << 16;
    return c.f;
}
__device__ __forceinline__ unsigned pk2(float a, float b){
    return (unsigned)f2bf(a) | ((unsigned)f2bf(b) << 16);
}
__device__ __forceinline__ float sigmf(float x){
    return __builtin_amdgcn_rcpf(1.f + __expf(-x));
}
__device__ __forceinline__ float tanhfast(float x){
    float e2 = __expf(2.f * x);
    return 1.f - 2.f * __builtin_amdgcn_rcpf(e2 + 1.f);
}

// ---------- fused converter: 14 jobs by blockIdx.y ----------
__global__ void convAll_k(
    const float* __restrict__ emb, const float* __restrict__ tree,
    const float* __restrict__ Wz, const float* __restrict__ Wr,
    const float* __restrict__ Ur, const float* __restrict__ Wh,
    const float* __restrict__ Wm, const float* __restrict__ U, const float* __restrict__ Wo,
    ushort* embb, ushort* treeb, ushort* WzX, ushort* WzS, ushort* WrB,
    ushort* WhX, ushort* WhG, ushort* UrB, ushort* WHp, ushort* UXp,
    ushort* UOp, ushort* WOp, ushort* WLp, ushort* ULp)
{
    int job = blockIdx.y, n = blockIdx.x;
    const float* src; ushort* dst; int Npad, Nsrc, Ksrc, Kpad, len, off;
    switch(job){
      case 0:  src=emb;  dst=embb; Npad=896; Nsrc=780; Ksrc=450; Kpad=480; len=450; off=0;   break;
      case 1:  src=tree; dst=treeb;Npad=512; Nsrc=512; Ksrc=56;  Kpad=64;  len=56;  off=0;   break;
      case 2:  src=Wz;   dst=WzX;  Npad=512; Nsrc=450; Ksrc=900; Kpad=480; len=450; off=0;   break;
      case 3:  src=Wz;   dst=WzS;  Npad=512; Nsrc=450; Ksrc=900; Kpad=480; len=450; off=450; break;
      case 4:  src=Wr;   dst=WrB;  Npad=512; Nsrc=450; Ksrc=450; Kpad=480; len=450; off=0;   break;
      case 5:  src=Wh;   dst=WhX;  Npad=512; Nsrc=450; Ksrc=900; Kpad=480; len=450; off=0;   break;
      case 6:  src=Wh;   dst=WhG;  Npad=512; Nsrc=450; Ksrc=900; Kpad=480; len=450; off=450; break;
      case 7:  src=Ur;   dst=UrB;  Npad=512; Nsrc=450; Ksrc=450; Kpad=480; len=450; off=0;   break;
      case 8:  src=Wm;   dst=WHp;  Npad=512; Nsrc=450; Ksrc=506; Kpad=480; len=450; off=0;   break;
      case 9:  src=U;    dst=UXp;  Npad=512; Nsrc=450; Ksrc=956; Kpad=480; len=450; off=0;   break;
      case 10: src=U;    dst=UOp;  Npad=512; Nsrc=450; Ksrc=956; Kpad=480; len=450; off=450; break;
      case 11: src=Wo;   dst=WOp;  Npad=832; Nsrc=780; Ksrc=450; Kpad=480; len=450; off=0;   break;
      case 12: src=Wm;   dst=WLp;  Npad=512; Nsrc=450; Ksrc=506; Kpad=64;  len=56;  off=450; break;
      default: src=U;    dst=ULp;  Npad=512; Nsrc=450; Ksrc=956; Kpad=64;  len=56;  off=900; break;
    }
    if (n >= Npad) return;
    for (int k = threadIdx.x; k < Kpad; k += blockDim.x){
        float v = 0.f;
        if (n < Nsrc && k < len) v = src[(size_t)n*Ksrc + off + k];
        dst[(size_t)n*Kpad + k] = f2bf(v);
    }
}

// ---------- double-buffered MFMA GEMM body: C(128x64) tile, SWAPPED operands ----------
// D mapping (swapped): row = row0+wm*64+f*16+(lane&15), col = col0+wn*32+g*16+(lane>>4)*4+j
template<class APtr>
__device__ __forceinline__ void mgemm2(APtr&& aptr, const ushort* __restrict__ Bw, int ldb,
                                       int KT, int col0, f32x4 acc[4][2])
{
    __shared__ __align__(16) char As[2][128*80];
    __shared__ __align__(16) char Bs[2][64*80];
    const int tid = threadIdx.x;
    const int lane = tid & 63;
    const int w = tid >> 6, wm = w >> 1, wn = w & 1;
    const int ac = (tid & 3) * 8;
    const size_t boff = (size_t)(col0 + (tid >> 2)) * ldb;
    u32x4 ra0, ra1, rb;
    auto ld = [&](int k0){
        ra0 = *(const u32x4*)(aptr(0, k0) + ac);
        ra1 = *(const u32x4*)(aptr(1, k0) + ac);
        rb  = *(const u32x4*)(Bw + boff + k0 + ac);
    };
    const int wr_a0 = (tid>>2)*80 + (tid&3)*16;
    const int wr_a1 = ((tid>>2)+64)*80 + (tid&3)*16;
    const int wr_b  = (tid>>2)*80 + (tid&3)*16;
    const int rd_a  = (wm*64 + (lane&15))*80 + (lane>>4)*16;
    const int rd_b  = (wn*32 + (lane&15))*80 + (lane>>4)*16;
    ld(0);
    *(u32x4*)(As[0]+wr_a0) = ra0; *(u32x4*)(As[0]+wr_a1) = ra1; *(u32x4*)(Bs[0]+wr_b) = rb;
#pragma unroll
    for (int f=0;f<4;f++)
#pragma unroll
        for (int g=0;g<2;g++) acc[f][g] = (f32x4){0.f,0.f,0.f,0.f};
    __syncthreads();
    for (int kt=0; kt<KT; ++kt){
        const int cur = kt & 1;
        if (kt+1 < KT) ld((kt+1)*32);
        bf16x8 bF[2];
#pragma unroll
        for (int g=0; g<2; g++) bF[g] = *(const bf16x8*)(Bs[cur] + rd_b + g*16*80);
#pragma unroll
        for (int f=0; f<4; f++){
            bf16x8 aF = *(const bf16x8*)(As[cur] + rd_a + f*16*80);
#pragma unroll
            for (int g=0; g<2; g++)
                acc[f][g] = __builtin_amdgcn_mfma_f32_16x16x32_bf16(bF[g], aF, acc[f][g], 0, 0, 0);
        }
        if (kt+1 < KT){
            *(u32x4*)(As[cur^1]+wr_a0) = ra0; *(u32x4*)(As[cur^1]+wr_a1) = ra1;
            *(u32x4*)(Bs[cur^1]+wr_b) = rb;
        }
        __syncthreads();
    }
}

#define EPI_PRE  const int lane = threadIdx.x & 63; const int w_ = threadIdx.x >> 6; \
                 const int wm = w_ >> 1, wn = w_ & 1;

// ---------- precompute GEMM body: out bf16 [rows][HP] (swapped epilogue) ----------
__device__ __forceinline__ void pre_body(const ushort* __restrict__ A, int lda,
    const ushort* __restrict__ Bw, const float* __restrict__ bias,
    ushort* __restrict__ out, int Mr, int KT)
{
    const int row0 = blockIdx.y*128, col0 = blockIdx.x*64;
    const int tid = threadIdx.x;
    const ushort* p0 = A + (size_t)(row0 + (tid>>2))*lda;
    const ushort* p1 = p0 + (size_t)64*lda;
    f32x4 acc[4][2];
    mgemm2([&](int which,int k0){ return (which?p1:p0)+k0; }, Bw, lda, KT, col0, acc);
    EPI_PRE
#pragma unroll
    for (int f=0; f<4; f++){
        const int row = row0 + wm*64 + f*16 + (lane & 15);
        if (row >= Mr) continue;
#pragma unroll
        for (int g=0; g<2; g++){
            const int C4 = col0 + wn*32 + g*16 + ((lane>>4)<<2);
            if (C4 >= HP) continue;
            ushort o[4];
#pragma unroll
            for (int j=0; j<4; j++){
                int col = C4 + j;
                float bb = (col < Hq && bias) ? bias[col] : 0.f;
                o[j] = (col < Hq) ? f2bf(acc[f][g][j] + bb) : 0;
            }
            uint2 ov; ov.x = (unsigned)o[0] | ((unsigned)o[1]<<16);
            ov.y = (unsigned)o[2] | ((unsigned)o[3]<<16);
            *(uint2*)(out + (size_t)row*HP + C4) = ov;
        }
    }
}

__global__ __launch_bounds__(256) void preE_k(
    const ushort* __restrict__ embb,
    const ushort* __restrict__ WzX, const ushort* __restrict__ WrB,
    const ushort* __restrict__ WhX, const ushort* __restrict__ UXp,
    const float* __restrict__ bz, const float* __restrict__ br,
    const float* __restrict__ bh, const float* __restrict__ bU,
    ushort* __restrict__ EZ, ushort* __restrict__ ER,
    ushort* __restrict__ EH, ushort* __restrict__ EU)
{
    const ushort* Bw; const float* bias; ushort* out;
    switch(blockIdx.z){
      case 0:  Bw=WzX; bias=bz; out=EZ; break;
      case 1:  Bw=WrB; bias=br; out=ER; break;
      case 2:  Bw=WhX; bias=bh; out=EH; break;
      default: Bw=UXp; bias=bU; out=EU; break;
    }
    pre_body(embb, HP, Bw, bias, out, Vq, 15);
}

__global__ __launch_bounds__(256) void preT_k(
    const ushort* __restrict__ treeb,
    const ushort* __restrict__ WLp, const ushort* __restrict__ ULp,
    const float* __restrict__ bW, ushort* __restrict__ TP, ushort* __restrict__ TU)
{
    const ushort* Bw = blockIdx.z ? ULp : WLp;
    const float* bias = blockIdx.z ? nullptr : bW;
    ushort* out = blockIdx.z ? TU : TP;
    pre_body(treeb, 64, Bw, bias, out, Bq, 2);
}

// ---------- compaction for pred/stop: count / scan / fill ----------
__device__ __forceinline__ bool cmask(int which, int gr,
    const int* __restrict__ valid, const int* __restrict__ dir)
{
    if (which == 0) return (gr < Bq) ? true : (valid[gr-Bq] && dir[gr-Bq]);
    return (gr < TBq) ? (valid[gr] != 0) : true;
}
__global__ void cnt_k(const int* __restrict__ valid, const int* __restrict__ dir,
                      int* __restrict__ cnts)
{
    int which = blockIdx.y;
    int gr = blockIdx.x*256 + threadIdx.x;
    bool m = cmask(which, gr, valid, dir);
    unsigned long long bal = __ballot(m);
    if ((threadIdx.x & 63) == 0)
        atomicAdd(&cnts[which*NPB + blockIdx.x], (int)__popcll(bal));
}
__global__ void scan_k(const int* __restrict__ cnts, int* __restrict__ offs,
                       int* __restrict__ totals)
{
    if (threadIdx.x == 0){
        int a = 0;
        for (int i=0;i<NPB;i++){ offs[i] = a; a += cnts[i]; }
        totals[0] = a;
        int b = 0;
        for (int i=0;i<NPB;i++){ offs[NPB+i] = b; b += cnts[NPB+i]; }
        totals[1] = b;
    }
}
__global__ void fill_k(const int* __restrict__ valid, const int* __restrict__ dir,
                       const int* __restrict__ offs, int* __restrict__ listp,
                       int* __restrict__ lists)
{
    __shared__ int woff[4];
    int which = blockIdx.y;
    int gr = blockIdx.x*256 + threadIdx.x;
    bool m = cmask(which, gr, valid, dir);
    unsigned long long bal = __ballot(m);
    int lane = threadIdx.x & 63, wv = threadIdx.x >> 6;
    if (lane == 0) woff[wv] = (int)__popcll(bal);
    __syncthreads();
    int prev = 0;
    for (int i=0;i<wv;i++) prev += woff[i];
    if (m){
        int rank = prev + (int)__popcll(bal & ((1ull << lane) - 1ull));
        int pos = offs[which*NPB + blockIdx.x] + rank;
        if (which == 0){ if (pos < NPCAP) listp[pos] = gr; }
        else           { if (pos < NSCAP) lists[pos] = gr; }
    }
}

// ---------- per-step valid-row lists: vlist[t*Bq + i] = b, vcnt[t] ----------
__global__ void vfill_k(const int* __restrict__ valid,
                        int* __restrict__ vcnt, int* __restrict__ vlist)
{
    __shared__ int woff[8];
    const int t = blockIdx.x;
    const int b = threadIdx.x;              // 512 threads
    bool m = valid[t*Bq + b] != 0;
    unsigned long long bal = __ballot(m);
    int lane = b & 63, wv = b >> 6;
    if (lane == 0) woff[wv] = (int)__popcll(bal);
    __syncthreads();
    int prev = 0;
    for (int i=0;i<wv;i++) prev += woff[i];
    if (m) vlist[t*Bq + prev + (int)__popcll(bal & ((1ull<<lane)-1ull))] = b;
    if (threadIdx.x == 511){
        int tot = 0;
        for (int i=0;i<8;i++) tot += woff[i];
        vcnt[t] = tot;
    }
}

// ---------- index redirect (merged): usable slot or 0 ----------
// Slot s holds live data at reader-step t iff 1<=s<=t*Bq && valid[s-1];
// otherwise reference semantics give 0 == always-zero slot 0.
__global__ void idx2_k(const int* __restrict__ h_nei_idx,
                       const int* __restrict__ o_nei_idx, const int* __restrict__ root_o_nei,
                       const int* __restrict__ valid,
                       int* __restrict__ h_idx2, int* __restrict__ o_idx2)
{
    const int e = blockIdx.x*256 + threadIdx.x;
    if (e < TBq*Mq){
        const int r = e >> 3;
        const int t = r >> 9;
        const int ix = h_nei_idx[e];
        h_idx2[e] = (ix >= 1 && ix <= t*Bq && valid[ix-1] != 0) ? ix : 0;
    }
    if (e < (TBq+Bq)*Mq){
        const int i = e >> 3;
        int ix, ok;
        if (i < TBq){
            const int tt = i >> 9;
            ix = o_nei_idx[e];
            ok = (ix >= 1) && (ix <= tt*Bq) && (valid[ix-1] != 0);
        } else {
            ix = root_o_nei[e - TBq*Mq];
            ok = (ix >= 1) && (valid[ix-1] != 0);
        }
        o_idx2[e] = ok ? ix : 0;
    }
}

// ---------- scan: gather (compacted valid rows, full machine) ----------
__global__ __launch_bounds__(256) void gather_k(int t,
    const int* __restrict__ x_wid, const int* __restrict__ h_idx2,
    const ushort* __restrict__ ER,
    const int* __restrict__ vcnt, const int* __restrict__ vlist,
    const ushort* __restrict__ hbuf, const ushort* __restrict__ uhbuf,
    ushort* __restrict__ sumhC, ushort* __restrict__ gatedC)
{
    const int cnt = vcnt[t];
    const int task = blockIdx.x*256 + threadIdx.x;
    if (task >= cnt*57) return;
    const int i = task / 57;
    const int c = task - i*57;
    const int j0 = c*8;
    const int b = vlist[t*Bq + i];
    const int base = t*Bq + b;
    const int wid = x_wid[base];
    const int* ip = h_idx2 + (size_t)base*Mq;
    int idx[Mq];
#pragma unroll
    for (int m=0;m<Mq;m++) idx[m] = ip[m];
    float er[8];
    { u32x4 ev = *(const u32x4*)(ER + (size_t)wid*HP + j0);
#pragma unroll
      for (int e=0;e<8;e++) er[e] = bf2f((ushort)((ev[e>>1] >> ((e&1)*16)) & 0xffff)); }
    float sh[8] = {0,0,0,0,0,0,0,0};
    float gt[8] = {0,0,0,0,0,0,0,0};
#pragma unroll
    for (int m=0;m<Mq;m++){
        u32x4 hv = *(const u32x4*)(hbuf  + (size_t)idx[m]*HP + j0);
        u32x4 uv = *(const u32x4*)(uhbuf + (size_t)idx[m]*HP + j0);
#pragma unroll
        for (int e=0;e<8;e++){
            float h = bf2f((ushort)((hv[e>>1] >> ((e&1)*16)) & 0xffff));
            float u = bf2f((ushort)((uv[e>>1] >> ((e&1)*16)) & 0xffff));
            sh[e] += h;
            gt[e] += h * sigmf(er[e] + u);
        }
    }
    u32x4 so, go;
    so[0]=pk2(sh[0],sh[1]); so[1]=pk2(sh[2],sh[3]);
    so[2]=pk2(sh[4],sh[5]); so[3]=pk2(sh[6],sh[7]);
    go[0]=pk2(gt[0],gt[1]); go[1]=pk2(gt[2],gt[3]);
    go[2]=pk2(gt[4],gt[5]); go[3]=pk2(gt[6],gt[7]);
    *(u32x4*)(sumhC  + (size_t)i*HP + j0) = so;
    *(u32x4*)(gatedC + (size_t)i*HP + j0) = go;
}

// ---------- scan: twin GEMM + blend; swapped MFMA, vector epilogue ----------
__global__ __launch_bounds__(256) void zh_k(int t,
    const int* __restrict__ x_wid,
    const int* __restrict__ vcnt, const int* __restrict__ vlist,
    const ushort* __restrict__ EZ, const ushort* __restrict__ EH,
    const ushort* __restrict__ WzS, const ushort* __restrict__ WhG,
    const ushort* __restrict__ sumhC, const ushort* __restrict__ gatedC,
    ushort* __restrict__ nhC, ushort* __restrict__ hbuf)
{
    const int cnt = vcnt[t];
    const int rows0 = blockIdx.x*32;
    if (rows0 >= cnt) return;
    const int cols0 = blockIdx.y*32;
    const int lane = threadIdx.x & 63, w = threadIdx.x >> 6;
    const int wr = w >> 1, wc = w & 1;
    const int ai = rows0 + wr*16 + (lane & 15);       // compacted A row (fragment + output)
    const int Cb = cols0 + wc*16 + (lane & 15);       // weight col (fragment)
    const int kq = (lane >> 4) * 8;
    const ushort* aZp = sumhC  + (size_t)ai*HP + kq;
    const ushort* aGp = gatedC + (size_t)ai*HP + kq;
    const ushort* bZp = WzS + (size_t)Cb*HP + kq;
    const ushort* bGp = WhG + (size_t)Cb*HP + kq;
    f32x4 accZ = (f32x4){0,0,0,0}, accH = (f32x4){0,0,0,0};
#pragma unroll 5
    for (int kt=0; kt<15; ++kt){
        const int kb = kt*32;
        bf16x8 aZ = *(const bf16x8*)(aZp + kb);
        bf16x8 aG = *(const bf16x8*)(aGp + kb);
        bf16x8 bZ = *(const bf16x8*)(bZp + kb);
        bf16x8 bG = *(const bf16x8*)(bGp + kb);
        accZ = __builtin_amdgcn_mfma_f32_16x16x32_bf16(bZ, aZ, accZ, 0, 0, 0);
        accH = __builtin_amdgcn_mfma_f32_16x16x32_bf16(bG, aG, accH, 0, 0, 0);
    }
    // swapped D: this thread owns row ai, 4 consecutive cols C4..C4+3
    if (ai < cnt){
        const int C4 = cols0 + wc*16 + ((lane>>4)<<2);
        const int b = vlist[t*Bq + ai];
        const int base = t*Bq + b;
        const int wid = x_wid[base];
        uint2 ez2 = *(const uint2*)(EZ + (size_t)wid*HP + C4);
        uint2 eh2 = *(const uint2*)(EH + (size_t)wid*HP + C4);
        uint2 sh2 = *(const uint2*)(sumhC + (size_t)ai*HP + C4);
        unsigned ezw[2] = {ez2.x, ez2.y}, ehw[2] = {eh2.x, eh2.y}, shw[2] = {sh2.x, sh2.y};
        ushort o[4];
#pragma unroll
        for (int j=0; j<4; j++){
            const int C = C4 + j;
            float z  = sigmf(accZ[j] + bf2f((ushort)((ezw[j>>1] >> ((j&1)*16)) & 0xffff)));
            float ht = tanhfast(accH[j] + bf2f((ushort)((ehw[j>>1] >> ((j&1)*16)) & 0xffff)));
            float sh = bf2f((ushort)((shw[j>>1] >> ((j&1)*16)) & 0xffff));
            o[j] = (C < Hq) ? f2bf((1.f - z)*sh + z*ht) : 0;
        }
        uint2 ov; ov.x = (unsigned)o[0] | ((unsigned)o[1]<<16);
        ov.y = (unsigned)o[2] | ((unsigned)o[3]<<16);
        *(uint2*)(nhC + (size_t)ai*HP + C4) = ov;
        *(uint2*)(hbuf + (size_t)(1 + base)*HP + C4) = ov;   // pads written as 0 (stay 0)
    }
}

// ---------- scan: uh = nh @ Ur^T; swapped MFMA, vector epilogue ----------
__global__ __launch_bounds__(256) void ur_k(int t,
    const int* __restrict__ vcnt, const int* __restrict__ vlist,
    const ushort* __restrict__ UrB, const ushort* __restrict__ nhC,
    ushort* __restrict__ uhbuf)
{
    const int cnt = vcnt[t];
    const int rows0 = blockIdx.x*32;
    if (rows0 >= cnt) return;
    const int cols0 = blockIdx.y*32;
    const int lane = threadIdx.x & 63, w = threadIdx.x >> 6;
    const int wr = w >> 1, wc = w & 1;
    const int ai = rows0 + wr*16 + (lane & 15);
    const int Cb = cols0 + wc*16 + (lane & 15);
    const int kq = (lane >> 4) * 8;
    const ushort* aNp = nhC + (size_t)ai*HP + kq;
    const ushort* bUp = UrB + (size_t)Cb*HP + kq;
    f32x4 acc = (f32x4){0,0,0,0};
#pragma unroll 5
    for (int kt=0; kt<15; ++kt){
        const int kb = kt*32;
        bf16x8 aN = *(const bf16x8*)(aNp + kb);
        bf16x8 bU = *(const bf16x8*)(bUp + kb);
        acc = __builtin_amdgcn_mfma_f32_16x16x32_bf16(bU, aN, acc, 0, 0, 0);
    }
    if (ai < cnt){
        const int C4 = cols0 + wc*16 + ((lane>>4)<<2);
        const int b = vlist[t*Bq + ai];
        ushort o[4];
#pragma unroll
        for (int j=0; j<4; j++)
            o[j] = (C4 + j < Hq) ? f2bf(acc[j]) : 0;
        uint2 ov; ov.x = (unsigned)o[0] | ((unsigned)o[1]<<16);
        ov.y = (unsigned)o[2] | ((unsigned)o[3]<<16);
        *(uint2*)(uhbuf + (size_t)(1 + t*Bq + b)*HP + C4) = ov;  // pads written as 0
    }
}

// ---------- pred GEMM1 (compacted rows); swapped epilogue ----------
__global__ __launch_bounds__(256) void pred1c_k(const int* __restrict__ np_,
    const int* __restrict__ listp, const ushort* __restrict__ hbuf,
    const ushort* __restrict__ TP, const ushort* __restrict__ WHp,
    ushort* __restrict__ pv)
{
    const int np = *np_;
    const int row0 = blockIdx.x*128;
    if (row0 >= np) return;
    const int col0 = blockIdx.y*64;
    const int tid = threadIdx.x;
    int i0 = row0 + (tid>>2), i1 = i0 + 64;
    int g0 = (i0 < np) ? listp[i0] : 0;
    int g1 = (i1 < np) ? listp[i1] : 0;
    const ushort* p0 = (g0 < Bq) ? hbuf : hbuf + (size_t)(1 + g0 - Bq)*HP;  // hbuf row0 = zeros
    const ushort* p1 = (g1 < Bq) ? hbuf : hbuf + (size_t)(1 + g1 - Bq)*HP;
    f32x4 acc[4][2];
    mgemm2([&](int which,int k0){ return (which?p1:p0)+k0; }, WHp, HP, 15, col0, acc);
    EPI_PRE
#pragma unroll
    for (int f=0; f<4; f++){
        const int i = row0 + wm*64 + f*16 + (lane & 15);
        if (i >= np) continue;
        const int gr = listp[i];
        const int b = (gr < Bq) ? gr : ((gr - Bq) & (Bq-1));
#pragma unroll
        for (int g=0; g<2; g++){
            const int C4 = col0 + wn*32 + g*16 + ((lane>>4)<<2);
            if (C4 >= HP) continue;
            uint2 tp2 = *(const uint2*)(TP + (size_t)b*HP + C4);
            unsigned tpw[2] = {tp2.x, tp2.y};
            ushort o[4];
#pragma unroll
            for (int j=0; j<4; j++){
                float v = fmaxf(acc[f][g][j] + bf2f((ushort)((tpw[j>>1] >> ((j&1)*16)) & 0xffff)), 0.f);
                o[j] = f2bf(v);   // pad cols: acc=0, TP=0 -> relu(0)=0
            }
            uint2 ov; ov.x = (unsigned)o[0] | ((unsigned)o[1]<<16);
            ov.y = (unsigned)o[2] | ((unsigned)o[3]<<16);
            *(uint2*)(pv + (size_t)i*HP + C4) = ov;
        }
    }
}

// ---------- pred GEMM2; swapped epilogue, bf16 score stores ----------
__global__ __launch_bounds__(256) void pred2c_k(const int* __restrict__ np_,
    const ushort* __restrict__ pv, const ushort* __restrict__ WOp,
    const float* __restrict__ bWo, ushort* __restrict__ scores)
{
    const int np = *np_;
    const int row0 = blockIdx.x*128;
    if (row0 >= np) return;
    const int col0 = blockIdx.y*64;
    const int tid = threadIdx.x;
    const ushort* p0 = pv + (size_t)(row0 + (tid>>2))*HP;
    const ushort* p1 = p0 + (size_t)64*HP;
    f32x4 acc[4][2];
    mgemm2([&](int which,int k0){ return (which?p1:p0)+k0; }, WOp, HP, 15, col0, acc);
    EPI_PRE
#pragma unroll
    for (int f=0; f<4; f++){
        const int r = row0 + wm*64 + f*16 + (lane & 15);
#pragma unroll
        for (int g=0; g<2; g++){
            const int C4 = col0 + wn*32 + g*16 + ((lane>>4)<<2);
            ushort o[4];
#pragma unroll
            for (int j=0; j<4; j++){
                int col = C4 + j;
                o[j] = f2bf(acc[f][g][j] + ((col < Vq) ? bWo[col] : 0.f));
            }
            uint2 ov; ov.x = (unsigned)o[0] | ((unsigned)o[1]<<16);
            ov.y = (unsigned)o[2] | ((unsigned)o[3]<<16);
            *(uint2*)(scores + (size_t)r*832 + C4) = ov;
        }
    }
}

// ---------- pred reduce: wave-per-row (bf16 scores) ----------
__global__ __launch_bounds__(256) void predred_k(const int* __restrict__ np_,
    const int* __restrict__ listp, const ushort* __restrict__ scores,
    const int* __restrict__ pred_wid, const int* __restrict__ root_wid,
    float* __restrict__ accv)
{
    const int np = *np_;
    const int lane = threadIdx.x & 63, wv = threadIdx.x >> 6;
    const int wid_g = blockIdx.x*4 + wv, nw = gridDim.x*4;
    float ce = 0.f, hit = 0.f, cnt = 0.f;
    for (int r = wid_g; r < np; r += nw){
        const ushort* sc = scores + (size_t)r*832;
        int gr = listp[r];
        int tgt = (gr < Bq) ? root_wid[gr] : pred_wid[gr - Bq];
        float vals[13];
        float bv = -INFINITY, tv = 0.f; int bi = 0;
#pragma unroll
        for (int q=0; q<13; q++){
            int j = lane + q*64;
            float v = (j < Vq) ? bf2f(sc[j]) : -INFINITY;
            vals[q] = v;
            if (v > bv){ bv = v; bi = j; }
            if (j == tgt) tv = v;
        }
#pragma unroll
        for (int off=32; off; off>>=1){
            float ov = __shfl_xor(bv, off); int oi = __shfl_xor(bi, off);
            if (ov > bv || (ov == bv && oi < bi)){ bv = ov; bi = oi; }
        }
        float s = 0.f;
#pragma unroll
        for (int q=0; q<13; q++){
            int j = lane + q*64;
            if (j < Vq) s += __expf(vals[q] - bv);
        }
#pragma unroll
        for (int off=32; off; off>>=1) s += __shfl_xor(s, off);
#pragma unroll
        for (int off=32; off; off>>=1) tv += __shfl_xor(tv, off);
        if (lane == 0){
            ce += bv + logf(s) - tv;
            hit += (bi == tgt) ? 1.f : 0.f;
            cnt += 1.f;
        }
    }
    __shared__ float L[3][4];
    if (lane == 0){ L[0][wv] = ce; L[1][wv] = hit; L[2][wv] = cnt; }
    __syncthreads();
    if (threadIdx.x == 0){
        float a = L[0][0]+L[0][1]+L[0][2]+L[0][3];
        float b = L[1][0]+L[1][1]+L[1][2]+L[1][3];
        float c = L[2][0]+L[2][1]+L[2][2]+L[2][3];
        if (c != 0.f){
            atomicAdd(&accv[0], a);
            atomicAdd(&accv[1], b);
            atomicAdd(&accv[2], c);
        }
    }
}

// ---------- stop: cur_o gather (task-parallel, 16B chunks; pads stored w/o loads) ----------
__global__ __launch_bounds__(256) void curo_c(const int* __restrict__ ns_,
    const int* __restrict__ lists, const int* __restrict__ o_idx2,
    const ushort* __restrict__ hbuf, ushort* __restrict__ curo)
{
    const int ns = *ns_;
    const int task = blockIdx.x*256 + threadIdx.x;
    if (task >= ns*60) return;
    const int i = task / 60;
    const int c = task - i*60;
    const int j0 = c*8;
    if (c >= 57){
        u32x4 z = (u32x4){0,0,0,0};
        *(u32x4*)(curo + (size_t)i*HP + j0) = z;
        return;
    }
    const int gr = lists[i];
    const int* ip = o_idx2 + (size_t)gr*Mq;
    int idx[Mq];
#pragma unroll
    for (int m=0;m<Mq;m++) idx[m] = ip[m];
    float sh[8] = {0,0,0,0,0,0,0,0};
#pragma unroll
    for (int m=0;m<Mq;m++){
        u32x4 hv = *(const u32x4*)(hbuf + (size_t)idx[m]*HP + j0);
#pragma unroll
        for (int e=0;e<8;e++)
            sh[e] += bf2f((ushort)((hv[e>>1] >> ((e&1)*16)) & 0xffff));
    }
    u32x4 so;
    so[0]=pk2(sh[0],sh[1]); so[1]=pk2(sh[2],sh[3]);
    so[2]=pk2(sh[4],sh[5]); so[3]=pk2(sh[6],sh[7]);
    *(u32x4*)(curo + (size_t)i*HP + j0) = so;
}

// ---------- stop GEMM (compacted) + fused Us-dot; swapped epilogue ----------
__global__ __launch_bounds__(256) void stopc_k(const int* __restrict__ ns_,
    const int* __restrict__ lists, const int* __restrict__ x_wid,
    const int* __restrict__ root_wid, const ushort* __restrict__ curo,
    const ushort* __restrict__ UOp, const ushort* __restrict__ EU,
    const ushort* __restrict__ TU, const float* __restrict__ Usf,
    float* __restrict__ ss)
{
    const int ns = *ns_;
    const int row0 = blockIdx.x*128;
    if (row0 >= ns) return;
    const int col0 = blockIdx.y*64;
    const int tid = threadIdx.x;
    const ushort* p0 = curo + (size_t)(row0 + (tid>>2))*HP;
    const ushort* p1 = p0 + (size_t)64*HP;
    f32x4 acc[4][2];
    mgemm2([&](int which,int k0){ return (which?p1:p0)+k0; }, UOp, HP, 15, col0, acc);
    EPI_PRE
#pragma unroll
    for (int f=0; f<4; f++){
        const int i = row0 + wm*64 + f*16 + (lane & 15);
        float p = 0.f;
        if (i < ns){
            const int gr = lists[i];
            const int wid = (gr < TBq) ? x_wid[gr] : root_wid[gr - TBq];
            const int b   = (gr < TBq) ? (gr & (Bq-1)) : (gr - TBq);
#pragma unroll
            for (int g=0; g<2; g++){
                const int C4 = col0 + wn*32 + g*16 + ((lane>>4)<<2);
                if (C4 >= Hq) continue;
                uint2 eu2 = *(const uint2*)(EU + (size_t)wid*HP + C4);
                uint2 tu2 = *(const uint2*)(TU + (size_t)b*HP + C4);
                unsigned euw[2] = {eu2.x, eu2.y}, tuw[2] = {tu2.x, tu2.y};
#pragma unroll
                for (int j=0; j<4; j++){
                    const int col = C4 + j;
                    if (col < Hq){
                        float e = bf2f((ushort)((euw[j>>1] >> ((j&1)*16)) & 0xffff));
                        float u = bf2f((ushort)((tuw[j>>1] >> ((j&1)*16)) & 0xffff));
                        p += fmaxf(acc[f][g][j] + e + u, 0.f) * Usf[col];
                    }
                }
            }
        }
        p += __shfl_xor(p, 16); p += __shfl_xor(p, 32);
        if ((lane >> 4) == 0 && i < ns) atomicAdd(&ss[i], p);
    }
}

__global__ void stopfin_k(const int* __restrict__ ns_, const int* __restrict__ lists,
    const float* __restrict__ ss, const float* __restrict__ bUs,
    const int* __restrict__ direction, float* __restrict__ accv)
{
    const int ns = *ns_;
    int i = blockIdx.x*256 + threadIdx.x;
    float bce = 0.f, hit = 0.f, c = 0.f;
    if (i < ns){
        int gr = lists[i];
        float s = ss[i] + bUs[0];
        float stgt = (gr < TBq) ? (float)direction[gr] : 0.f;
        bce = fmaxf(s,0.f) - s*stgt + log1pf(__expf(-fabsf(s)));
        hit = ((((s >= 0.f) ? 1.f : 0.f) == stgt) ? 1.f : 0.f);
        c = 1.f;
    }
    for (int off=32; off; off>>=1){
        bce += __shfl_down(bce, off);
        hit += __shfl_down(hit, off);
        c   += __shfl_down(c,   off);
    }
    if ((threadIdx.x & 63) == 0 && c != 0.f){
        atomicAdd(&accv[3], bce);
        atomicAdd(&accv[4], hit);
        atomicAdd(&accv[5], c);
    }
}

__global__ void finalize_k(const float* __restrict__ accv, float* __restrict__ out){
    if (threadIdx.x == 0){
        out[0] = accv[0] / (float)Bq;
        out[1] = accv[3] / (float)Bq;
        out[2] = accv[1] / accv[2];
        out[3] = accv[4] / accv[5];
    }
}

extern "C" void kernel_launch(void* const* d_in, const int* in_sizes, int n_in,
                              void* d_out, int out_size, void* d_ws, size_t ws_size,
                              hipStream_t stream) {
    (void)in_sizes; (void)n_in; (void)out_size; (void)ws_size;
    const float* tree_vecs = (const float*)d_in[0];
    const int*   x_wid     = (const int*)d_in[1];
    const int*   pred_wid  = (const int*)d_in[2];
    const int*   root_wid  = (const int*)d_in[3];
    const int*   h_nei_idx = (const int*)d_in[4];
    const int*   o_nei_idx = (const int*)d_in[5];
    const int*   root_o_nei= (const int*)d_in[6];
    const int*   valid     = (const int*)d_in[7];
    const int*   direction = (const int*)d_in[8];
    const float* emb       = (const float*)d_in[9];
    const float* Wz        = (const float*)d_in[10];
    const float* bz        = (const float*)d_in[11];
    const float* Wr        = (const float*)d_in[12];
    const float* br        = (const float*)d_in[13];
    const float* Ur        = (const float*)d_in[14];
    const float* Wh        = (const float*)d_in[15];
    const float* bh        = (const float*)d_in[16];
    const float* Wm        = (const float*)d_in[17];
    const float* bW        = (const float*)d_in[18];
    const float* U         = (const float*)d_in[19];
    const float* bU        = (const float*)d_in[20];
    const float* Wo        = (const float*)d_in[21];
    const float* bWo       = (const float*)d_in[22];
    const float* Us        = (const float*)d_in[23];
    const float* bUs       = (const float*)d_in[24];

    char* w = (char*)d_ws; size_t off = 0;
    auto alloc = [&](size_t bytes)->void*{ void* p = w + off; off += (bytes + 255) & ~(size_t)255; return p; };

    ushort* hbuf  = (ushort*)alloc((size_t)Sq*HP*2);
    ushort* uhbuf = (ushort*)alloc((size_t)Sq*HP*2);
    ushort* embb  = (ushort*)alloc((size_t)896*HP*2);
    ushort* treeb = (ushort*)alloc((size_t)Bq*64*2);
    ushort* WzX   = (ushort*)alloc((size_t)512*HP*2);
    ushort* WzS   = (ushort*)alloc((size_t)512*HP*2);
    ushort* WrB   = (ushort*)alloc((size_t)512*HP*2);
    ushort* WhX   = (ushort*)alloc((size_t)512*HP*2);
    ushort* WhG   = (ushort*)alloc((size_t)512*HP*2);
    ushort* UrB   = (ushort*)alloc((size_t)512*HP*2);
    ushort* WHp   = (ushort*)alloc((size_t)512*HP*2);
    ushort* UXp   = (ushort*)alloc((size_t)512*HP*2);
    ushort* UOp   = (ushort*)alloc((size_t)512*HP*2);
    ushort* WOp   = (ushort*)alloc((size_t)832*HP*2);
    ushort* WLp   = (ushort*)alloc((size_t)512*64*2);
    ushort* ULp   = (ushort*)alloc((size_t)512*64*2);
    ushort* EZ    = (ushort*)alloc((size_t)896*HP*2);
    ushort* ER    = (ushort*)alloc((size_t)896*HP*2);
    ushort* EH    = (ushort*)alloc((size_t)896*HP*2);
    ushort* EU    = (ushort*)alloc((size_t)896*HP*2);
    ushort* TP    = (ushort*)alloc((size_t)Bq*HP*2);
    ushort* TU    = (ushort*)alloc((size_t)Bq*HP*2);
    ushort* sumhC = (ushort*)alloc((size_t)Bq*HP*2);
    ushort* gatedC= (ushort*)alloc((size_t)Bq*HP*2);
    ushort* nhC   = (ushort*)alloc((size_t)Bq*HP*2);
    ushort* pv    = (ushort*)alloc((size_t)NPCAP*HP*2);
    ushort* scores= (ushort*)alloc((size_t)NPCAP*832*2);
    float*  ss    = (float*)alloc((size_t)NSCAP*4);
    int*    listp = (int*)alloc((size_t)NPCAP*4);
    int*    lists = (int*)alloc((size_t)NSCAP*4);
    int*    vlist = (int*)alloc((size_t)Tq*Bq*4);
    int*    vcnt  = (int*)alloc((size_t)Tq*4);
    int*    h_idx2= (int*)alloc((size_t)TBq*Mq*4);
    int*    o_idx2= (int*)alloc((size_t)(TBq+Bq)*Mq*4);
    int*    meta  = (int*)alloc((size_t)(NPB*4 + 2 + 16)*4);
    int*    cnts  = meta;            // [2*NPB]
    int*    offs  = meta + 2*NPB;    // [2*NPB]
    int*    tot   = meta + 4*NPB;    // [2]
    float*  accv  = (float*)(meta + 4*NPB + 2);
    ushort* curo  = pv;              // stop phase reuses pv+scores region (31.9MB >= 19.7MB)

    // only slot 0 of hbuf/uhbuf must be zero (index redirect handles the rest)
    (void)hipMemsetAsync(hbuf,  0, (size_t)HP*2, stream);
    (void)hipMemsetAsync(uhbuf, 0, (size_t)HP*2, stream);
    (void)hipMemsetAsync(ss,    0, (size_t)NSCAP*4, stream);
    (void)hipMemsetAsync(meta,  0, (size_t)(NPB*4 + 2 + 16)*4, stream);

    // ---- conversions (1 launch) ----
    convAll_k<<<dim3(896,14), 128, 0, stream>>>(
        emb, tree_vecs, Wz, Wr, Ur, Wh, Wm, U, Wo,
        embb, treeb, WzX, WzS, WrB, WhX, WhG, UrB, WHp, UXp, UOp, WOp, WLp, ULp);

    // ---- precomputes (2 launches, bf16 tables) ----
    preE_k<<<dim3(8,7,4), 256, 0, stream>>>(embb, WzX, WrB, WhX, UXp,
                                            bz, br, bh, bU, EZ, ER, EH, EU);
    preT_k<<<dim3(8,4,2), 256, 0, stream>>>(treeb, WLp, ULp, bW, TP, TU);

    // ---- row compaction + index redirects ----
    cnt_k <<<dim3(NPB,2), 256, 0, stream>>>(valid, direction, cnts);
    scan_k<<<1, 64, 0, stream>>>(cnts, offs, tot);
    fill_k<<<dim3(NPB,2), 256, 0, stream>>>(valid, direction, offs, listp, lists);
    vfill_k<<<Tq, 512, 0, stream>>>(valid, vcnt, vlist);
    idx2_k<<<((TBq+Bq)*Mq + 255)/256, 256, 0, stream>>>(h_nei_idx, o_nei_idx, root_o_nei,
                                                        valid, h_idx2, o_idx2);

    // ---- sequential scan: 3 wide kernels per step ----
    for (int t=0; t<Tq; t++){
        gather_k<<<115, 256, 0, stream>>>(t, x_wid, h_idx2, ER, vcnt, vlist,
                                          hbuf, uhbuf, sumhC, gatedC);
        zh_k<<<dim3(16,15), 256, 0, stream>>>(t, x_wid, vcnt, vlist, EZ, EH,
                                              WzS, WhG, sumhC, gatedC, nhC, hbuf);
        ur_k<<<dim3(16,15), 256, 0, stream>>>(t, vcnt, vlist, UrB, nhC, uhbuf);
    }

    // ---- pred phase (compacted, single chunk, bf16 scores) ----
    pred1c_k<<<dim3(NPCAP/128, 8), 256, 0, stream>>>(tot, listp, hbuf, TP, WHp, pv);
    pred2c_k<<<dim3(NPCAP/128, 13), 256, 0, stream>>>(tot, pv, WOp, bWo, scores);
    predred_k<<<256, 256, 0, stream>>>(tot, listp, scores, pred_wid, root_wid, accv);

    // ---- stop phase (compacted) ----
    curo_c<<<(NSCAP*60 + 255)/256, 256, 0, stream>>>(tot+1, lists, o_idx2, hbuf, curo);
    stopc_k<<<dim3(NSCAP/128, 8), 256, 0, stream>>>(tot+1, lists, x_wid, root_wid,
                                                    curo, UOp, EU, TU, Us, ss);
    stopfin_k<<<NSCAP/256, 256, 0, stream>>>(tot+1, lists, ss, bUs, direction, accv);

    finalize_k<<<1, 64, 0, stream>>>(accv, (float*)d_out);
}

// Round 18
// 1147.484 us; speedup vs baseline: 4.9433x; 1.0057x over previous
//
#include <hip/hip_runtime.h>
#include <math.h>

#define Bq 512
#define Tq 64
#define Hq 450
#define Lq 56
#define Vq 780
#define Mq 8
#define TBq 32768
#define Sq 32770
#define HP 480          // bf16 row stride (mult of 32)
#define NPB 130         // 130*256 = 33280 rows
#define NPCAP 12288     // compacted pred rows cap
#define NSCAP 20480     // compacted stop rows cap

using bf16x8 = __attribute__((ext_vector_type(8))) __bf16;
using f32x4  = __attribute__((ext_vector_type(4))) float;
using u32x4  = __attribute__((ext_vector_type(4))) unsigned;

__device__ __forceinline__ ushort f2bf(float f){
    union { float f; unsigned u; } c; c.f = f;
    unsigned u = c.u;
    return (ushort)((u + 0x7FFFu + ((u >> 16) & 1u)) >> 16);
}
__device__ __forceinline__ float bf2f(ushort h){
    union { unsigned u; float f; } c; c.u = ((unsigned)h) << 16;
    return c.f;
}
__device__ __forceinline__ unsigned pk2(float a, float b){
    return (unsigned)f2bf(a) | ((unsigned)f2bf(b) << 16);
}
__device__ __forceinline__ float sigmf(float x){
    return __builtin_amdgcn_rcpf(1.f + __expf(-x));
}
__device__ __forceinline__ float tanhfast(float x){
    float e2 = __expf(2.f * x);
    return 1.f - 2.f * __builtin_amdgcn_rcpf(e2 + 1.f);
}

// ---------- fused converter: 16 jobs by blockIdx.y ----------
__global__ void convAll_k(
    const float* __restrict__ emb, const float* __restrict__ tree,
    const float* __restrict__ Wz, const float* __restrict__ Wr,
    const float* __restrict__ Ur, const float* __restrict__ Wh,
    const float* __restrict__ Wm, const float* __restrict__ U, const float* __restrict__ Wo,
    const float* __restrict__ Us, const float* __restrict__ bWo,
    ushort* embb, ushort* treeb, ushort* WzX, ushort* WzS, ushort* WrB,
    ushort* WhX, ushort* WhG, ushort* UrB, ushort* WHp, ushort* UXp,
    ushort* UOp, ushort* WOp, ushort* WLp, ushort* ULp,
    ushort* UsB, ushort* bWoB)
{
    int job = blockIdx.y, n = blockIdx.x;
    const float* src; ushort* dst; int Npad, Nsrc, Ksrc, Kpad, len, off;
    switch(job){
      case 0:  src=emb;  dst=embb; Npad=896; Nsrc=780; Ksrc=450; Kpad=480; len=450; off=0;   break;
      case 1:  src=tree; dst=treeb;Npad=512; Nsrc=512; Ksrc=56;  Kpad=64;  len=56;  off=0;   break;
      case 2:  src=Wz;   dst=WzX;  Npad=512; Nsrc=450; Ksrc=900; Kpad=480; len=450; off=0;   break;
      case 3:  src=Wz;   dst=WzS;  Npad=512; Nsrc=450; Ksrc=900; Kpad=480; len=450; off=450; break;
      case 4:  src=Wr;   dst=WrB;  Npad=512; Nsrc=450; Ksrc=450; Kpad=480; len=450; off=0;   break;
      case 5:  src=Wh;   dst=WhX;  Npad=512; Nsrc=450; Ksrc=900; Kpad=480; len=450; off=0;   break;
      case 6:  src=Wh;   dst=WhG;  Npad=512; Nsrc=450; Ksrc=900; Kpad=480; len=450; off=450; break;
      case 7:  src=Ur;   dst=UrB;  Npad=512; Nsrc=450; Ksrc=450; Kpad=480; len=450; off=0;   break;
      case 8:  src=Wm;   dst=WHp;  Npad=512; Nsrc=450; Ksrc=506; Kpad=480; len=450; off=0;   break;
      case 9:  src=U;    dst=UXp;  Npad=512; Nsrc=450; Ksrc=956; Kpad=480; len=450; off=0;   break;
      case 10: src=U;    dst=UOp;  Npad=512; Nsrc=450; Ksrc=956; Kpad=480; len=450; off=450; break;
      case 11: src=Wo;   dst=WOp;  Npad=832; Nsrc=780; Ksrc=450; Kpad=480; len=450; off=0;   break;
      case 12: src=Wm;   dst=WLp;  Npad=512; Nsrc=450; Ksrc=506; Kpad=64;  len=56;  off=450; break;
      case 13: src=U;    dst=ULp;  Npad=512; Nsrc=450; Ksrc=956; Kpad=64;  len=56;  off=900; break;
      case 14: src=Us;   dst=UsB;  Npad=1;   Nsrc=1;   Ksrc=450; Kpad=480; len=450; off=0;   break;
      default: src=bWo;  dst=bWoB; Npad=1;   Nsrc=1;   Ksrc=780; Kpad=832; len=780; off=0;   break;
    }
    if (n >= Npad) return;
    for (int k = threadIdx.x; k < Kpad; k += blockDim.x){
        float v = 0.f;
        if (n < Nsrc && k < len) v = src[(size_t)n*Ksrc + off + k];
        dst[(size_t)n*Kpad + k] = f2bf(v);
    }
}

// ---------- double-buffered MFMA GEMM body: C(128x64) tile, SWAPPED operands ----------
// D mapping (swapped): row = row0+wm*64+f*16+(lane&15), col = col0+wn*32+g*16+(lane>>4)*4+j
template<class APtr>
__device__ __forceinline__ void mgemm2(APtr&& aptr, const ushort* __restrict__ Bw, int ldb,
                                       int KT, int col0, f32x4 acc[4][2])
{
    __shared__ __align__(16) char As[2][128*80];
    __shared__ __align__(16) char Bs[2][64*80];
    const int tid = threadIdx.x;
    const int lane = tid & 63;
    const int w = tid >> 6, wm = w >> 1, wn = w & 1;
    const int ac = (tid & 3) * 8;
    const size_t boff = (size_t)(col0 + (tid >> 2)) * ldb;
    u32x4 ra0, ra1, rb;
    auto ld = [&](int k0){
        ra0 = *(const u32x4*)(aptr(0, k0) + ac);
        ra1 = *(const u32x4*)(aptr(1, k0) + ac);
        rb  = *(const u32x4*)(Bw + boff + k0 + ac);
    };
    const int wr_a0 = (tid>>2)*80 + (tid&3)*16;
    const int wr_a1 = ((tid>>2)+64)*80 + (tid&3)*16;
    const int wr_b  = (tid>>2)*80 + (tid&3)*16;
    const int rd_a  = (wm*64 + (lane&15))*80 + (lane>>4)*16;
    const int rd_b  = (wn*32 + (lane&15))*80 + (lane>>4)*16;
    ld(0);
    *(u32x4*)(As[0]+wr_a0) = ra0; *(u32x4*)(As[0]+wr_a1) = ra1; *(u32x4*)(Bs[0]+wr_b) = rb;
#pragma unroll
    for (int f=0;f<4;f++)
#pragma unroll
        for (int g=0;g<2;g++) acc[f][g] = (f32x4){0.f,0.f,0.f,0.f};
    __syncthreads();
    for (int kt=0; kt<KT; ++kt){
        const int cur = kt & 1;
        if (kt+1 < KT) ld((kt+1)*32);
        bf16x8 bF[2];
#pragma unroll
        for (int g=0; g<2; g++) bF[g] = *(const bf16x8*)(Bs[cur] + rd_b + g*16*80);
#pragma unroll
        for (int f=0; f<4; f++){
            bf16x8 aF = *(const bf16x8*)(As[cur] + rd_a + f*16*80);
#pragma unroll
            for (int g=0; g<2; g++)
                acc[f][g] = __builtin_amdgcn_mfma_f32_16x16x32_bf16(bF[g], aF, acc[f][g], 0, 0, 0);
        }
        if (kt+1 < KT){
            *(u32x4*)(As[cur^1]+wr_a0) = ra0; *(u32x4*)(As[cur^1]+wr_a1) = ra1;
            *(u32x4*)(Bs[cur^1]+wr_b) = rb;
        }
        __syncthreads();
    }
}

#define EPI_PRE  const int lane = threadIdx.x & 63; const int w_ = threadIdx.x >> 6; \
                 const int wm = w_ >> 1, wn = w_ & 1;

// ---------- precompute GEMMs (merged E and T tables): z = 0..5 ----------
__global__ __launch_bounds__(256) void preAll_k(
    const ushort* __restrict__ embb, const ushort* __restrict__ treeb,
    const ushort* __restrict__ WzX, const ushort* __restrict__ WrB,
    const ushort* __restrict__ WhX, const ushort* __restrict__ UXp,
    const ushort* __restrict__ WLp, const ushort* __restrict__ ULp,
    const float* __restrict__ bz, const float* __restrict__ br,
    const float* __restrict__ bh, const float* __restrict__ bU,
    const float* __restrict__ bW,
    ushort* __restrict__ EZ, ushort* __restrict__ ER,
    ushort* __restrict__ EH, ushort* __restrict__ EU,
    ushort* __restrict__ TP, ushort* __restrict__ TU)
{
    const ushort* A; const ushort* Bw; const float* bias; ushort* out;
    int lda, KT, Mr;
    switch(blockIdx.z){
      case 0:  A=embb; lda=HP; KT=15; Mr=Vq; Bw=WzX; bias=bz; out=EZ; break;
      case 1:  A=embb; lda=HP; KT=15; Mr=Vq; Bw=WrB; bias=br; out=ER; break;
      case 2:  A=embb; lda=HP; KT=15; Mr=Vq; Bw=WhX; bias=bh; out=EH; break;
      case 3:  A=embb; lda=HP; KT=15; Mr=Vq; Bw=UXp; bias=bU; out=EU; break;
      case 4:  A=treeb; lda=64; KT=2; Mr=Bq; Bw=WLp; bias=bW; out=TP; break;
      default: A=treeb; lda=64; KT=2; Mr=Bq; Bw=ULp; bias=nullptr; out=TU; break;
    }
    const int row0 = blockIdx.y*128, col0 = blockIdx.x*64;
    if (row0 >= ((Mr + 127) & ~127)) return;
    const int tid = threadIdx.x;
    const ushort* p0 = A + (size_t)(row0 + (tid>>2))*lda;
    const ushort* p1 = p0 + (size_t)64*lda;
    f32x4 acc[4][2];
    mgemm2([&](int which,int k0){ return (which?p1:p0)+k0; }, Bw, lda, KT, col0, acc);
    EPI_PRE
#pragma unroll
    for (int f=0; f<4; f++){
        const int row = row0 + wm*64 + f*16 + (lane & 15);
        if (row >= Mr) continue;
#pragma unroll
        for (int g=0; g<2; g++){
            const int C4 = col0 + wn*32 + g*16 + ((lane>>4)<<2);
            if (C4 >= HP) continue;
            ushort o[4];
#pragma unroll
            for (int j=0; j<4; j++){
                int col = C4 + j;
                float bb = (col < Hq && bias) ? bias[col] : 0.f;
                o[j] = (col < Hq) ? f2bf(acc[f][g][j] + bb) : 0;
            }
            uint2 ov; ov.x = (unsigned)o[0] | ((unsigned)o[1]<<16);
            ov.y = (unsigned)o[2] | ((unsigned)o[3]<<16);
            *(uint2*)(out + (size_t)row*HP + C4) = ov;
        }
    }
}

// ---------- compaction for pred/stop: count / scan / fill ----------
__device__ __forceinline__ bool cmask(int which, int gr,
    const int* __restrict__ valid, const int* __restrict__ dir)
{
    if (which == 0) return (gr < Bq) ? true : (valid[gr-Bq] && dir[gr-Bq]);
    return (gr < TBq) ? (valid[gr] != 0) : true;
}
__global__ void cnt_k(const int* __restrict__ valid, const int* __restrict__ dir,
                      int* __restrict__ cnts)
{
    int which = blockIdx.y;
    int gr = blockIdx.x*256 + threadIdx.x;
    bool m = cmask(which, gr, valid, dir);
    unsigned long long bal = __ballot(m);
    if ((threadIdx.x & 63) == 0)
        atomicAdd(&cnts[which*NPB + blockIdx.x], (int)__popcll(bal));
}
__global__ void scan_k(const int* __restrict__ cnts, int* __restrict__ offs,
                       int* __restrict__ totals)
{
    if (threadIdx.x == 0){
        int a = 0;
        for (int i=0;i<NPB;i++){ offs[i] = a; a += cnts[i]; }
        totals[0] = a;
        int b = 0;
        for (int i=0;i<NPB;i++){ offs[NPB+i] = b; b += cnts[NPB+i]; }
        totals[1] = b;
    }
}
__global__ void fill_k(const int* __restrict__ valid, const int* __restrict__ dir,
                       const int* __restrict__ offs, int* __restrict__ listp,
                       int* __restrict__ lists)
{
    __shared__ int woff[4];
    int which = blockIdx.y;
    int gr = blockIdx.x*256 + threadIdx.x;
    bool m = cmask(which, gr, valid, dir);
    unsigned long long bal = __ballot(m);
    int lane = threadIdx.x & 63, wv = threadIdx.x >> 6;
    if (lane == 0) woff[wv] = (int)__popcll(bal);
    __syncthreads();
    int prev = 0;
    for (int i=0;i<wv;i++) prev += woff[i];
    if (m){
        int rank = prev + (int)__popcll(bal & ((1ull << lane) - 1ull));
        int pos = offs[which*NPB + blockIdx.x] + rank;
        if (which == 0){ if (pos < NPCAP) listp[pos] = gr; }
        else           { if (pos < NSCAP) lists[pos] = gr; }
    }
}

// ---------- per-step valid-row lists: vlist[t*Bq + i] = b, vcnt[t] ----------
__global__ void vfill_k(const int* __restrict__ valid,
                        int* __restrict__ vcnt, int* __restrict__ vlist)
{
    __shared__ int woff[8];
    const int t = blockIdx.x;
    const int b = threadIdx.x;              // 512 threads
    bool m = valid[t*Bq + b] != 0;
    unsigned long long bal = __ballot(m);
    int lane = b & 63, wv = b >> 6;
    if (lane == 0) woff[wv] = (int)__popcll(bal);
    __syncthreads();
    int prev = 0;
    for (int i=0;i<wv;i++) prev += woff[i];
    if (m) vlist[t*Bq + prev + (int)__popcll(bal & ((1ull<<lane)-1ull))] = b;
    if (threadIdx.x == 511){
        int tot = 0;
        for (int i=0;i<8;i++) tot += woff[i];
        vcnt[t] = tot;
    }
}

// ---------- index redirect (merged): usable slot or 0 ----------
__global__ void idx2_k(const int* __restrict__ h_nei_idx,
                       const int* __restrict__ o_nei_idx, const int* __restrict__ root_o_nei,
                       const int* __restrict__ valid,
                       int* __restrict__ h_idx2, int* __restrict__ o_idx2)
{
    const int e = blockIdx.x*256 + threadIdx.x;
    if (e < TBq*Mq){
        const int r = e >> 3;
        const int t = r >> 9;
        const int ix = h_nei_idx[e];
        h_idx2[e] = (ix >= 1 && ix <= t*Bq && valid[ix-1] != 0) ? ix : 0;
    }
    if (e < (TBq+Bq)*Mq){
        const int i = e >> 3;
        int ix, ok;
        if (i < TBq){
            const int tt = i >> 9;
            ix = o_nei_idx[e];
            ok = (ix >= 1) && (ix <= tt*Bq) && (valid[ix-1] != 0);
        } else {
            ix = root_o_nei[e - TBq*Mq];
            ok = (ix >= 1) && (valid[ix-1] != 0);
        }
        o_idx2[e] = ok ? ix : 0;
    }
}

// ---------- scan: gather (compacted valid rows, full machine) ----------
__global__ __launch_bounds__(256) void gather_k(int t,
    const int* __restrict__ x_wid, const int* __restrict__ h_idx2,
    const ushort* __restrict__ ER,
    const int* __restrict__ vcnt, const int* __restrict__ vlist,
    const ushort* __restrict__ hbuf, const ushort* __restrict__ uhbuf,
    ushort* __restrict__ sumhC, ushort* __restrict__ gatedC)
{
    const int cnt = vcnt[t];
    const int task = blockIdx.x*256 + threadIdx.x;
    if (task >= cnt*57) return;
    const int i = task / 57;
    const int c = task - i*57;
    const int j0 = c*8;
    const int b = vlist[t*Bq + i];
    const int base = t*Bq + b;
    const int wid = x_wid[base];
    const int* ip = h_idx2 + (size_t)base*Mq;
    int idx[Mq];
#pragma unroll
    for (int m=0;m<Mq;m++) idx[m] = ip[m];
    float er[8];
    { u32x4 ev = *(const u32x4*)(ER + (size_t)wid*HP + j0);
#pragma unroll
      for (int e=0;e<8;e++) er[e] = bf2f((ushort)((ev[e>>1] >> ((e&1)*16)) & 0xffff)); }
    float sh[8] = {0,0,0,0,0,0,0,0};
    float gt[8] = {0,0,0,0,0,0,0,0};
#pragma unroll
    for (int m=0;m<Mq;m++){
        u32x4 hv = *(const u32x4*)(hbuf  + (size_t)idx[m]*HP + j0);
        u32x4 uv = *(const u32x4*)(uhbuf + (size_t)idx[m]*HP + j0);
#pragma unroll
        for (int e=0;e<8;e++){
            float h = bf2f((ushort)((hv[e>>1] >> ((e&1)*16)) & 0xffff));
            float u = bf2f((ushort)((uv[e>>1] >> ((e&1)*16)) & 0xffff));
            sh[e] += h;
            gt[e] += h * sigmf(er[e] + u);
        }
    }
    u32x4 so, go;
    so[0]=pk2(sh[0],sh[1]); so[1]=pk2(sh[2],sh[3]);
    so[2]=pk2(sh[4],sh[5]); so[3]=pk2(sh[6],sh[7]);
    go[0]=pk2(gt[0],gt[1]); go[1]=pk2(gt[2],gt[3]);
    go[2]=pk2(gt[4],gt[5]); go[3]=pk2(gt[6],gt[7]);
    *(u32x4*)(sumhC  + (size_t)i*HP + j0) = so;
    *(u32x4*)(gatedC + (size_t)i*HP + j0) = go;
}

// ---------- scan: twin GEMM + blend; swapped MFMA, vector epilogue ----------
__global__ __launch_bounds__(256) void zh_k(int t,
    const int* __restrict__ x_wid,
    const int* __restrict__ vcnt, const int* __restrict__ vlist,
    const ushort* __restrict__ EZ, const ushort* __restrict__ EH,
    const ushort* __restrict__ WzS, const ushort* __restrict__ WhG,
    const ushort* __restrict__ sumhC, const ushort* __restrict__ gatedC,
    ushort* __restrict__ nhC, ushort* __restrict__ hbuf)
{
    const int cnt = vcnt[t];
    const int rows0 = blockIdx.x*32;
    if (rows0 >= cnt) return;
    const int cols0 = blockIdx.y*32;
    const int lane = threadIdx.x & 63, w = threadIdx.x >> 6;
    const int wr = w >> 1, wc = w & 1;
    const int ai = rows0 + wr*16 + (lane & 15);       // compacted A row (fragment + output)
    const int Cb = cols0 + wc*16 + (lane & 15);       // weight col (fragment)
    const int kq = (lane >> 4) * 8;
    const ushort* aZp = sumhC  + (size_t)ai*HP + kq;
    const ushort* aGp = gatedC + (size_t)ai*HP + kq;
    const ushort* bZp = WzS + (size_t)Cb*HP + kq;
    const ushort* bGp = WhG + (size_t)Cb*HP + kq;
    f32x4 accZ = (f32x4){0,0,0,0}, accH = (f32x4){0,0,0,0};
#pragma unroll 5
    for (int kt=0; kt<15; ++kt){
        const int kb = kt*32;
        bf16x8 aZ = *(const bf16x8*)(aZp + kb);
        bf16x8 aG = *(const bf16x8*)(aGp + kb);
        bf16x8 bZ = *(const bf16x8*)(bZp + kb);
        bf16x8 bG = *(const bf16x8*)(bGp + kb);
        accZ = __builtin_amdgcn_mfma_f32_16x16x32_bf16(bZ, aZ, accZ, 0, 0, 0);
        accH = __builtin_amdgcn_mfma_f32_16x16x32_bf16(bG, aG, accH, 0, 0, 0);
    }
    // swapped D: this thread owns row ai, 4 consecutive cols C4..C4+3
    if (ai < cnt){
        const int C4 = cols0 + wc*16 + ((lane>>4)<<2);
        const int b = vlist[t*Bq + ai];
        const int base = t*Bq + b;
        const int wid = x_wid[base];
        uint2 ez2 = *(const uint2*)(EZ + (size_t)wid*HP + C4);
        uint2 eh2 = *(const uint2*)(EH + (size_t)wid*HP + C4);
        uint2 sh2 = *(const uint2*)(sumhC + (size_t)ai*HP + C4);
        unsigned ezw[2] = {ez2.x, ez2.y}, ehw[2] = {eh2.x, eh2.y}, shw[2] = {sh2.x, sh2.y};
        ushort o[4];
#pragma unroll
        for (int j=0; j<4; j++){
            const int C = C4 + j;
            float z  = sigmf(accZ[j] + bf2f((ushort)((ezw[j>>1] >> ((j&1)*16)) & 0xffff)));
            float ht = tanhfast(accH[j] + bf2f((ushort)((ehw[j>>1] >> ((j&1)*16)) & 0xffff)));
            float sh = bf2f((ushort)((shw[j>>1] >> ((j&1)*16)) & 0xffff));
            o[j] = (C < Hq) ? f2bf((1.f - z)*sh + z*ht) : 0;
        }
        uint2 ov; ov.x = (unsigned)o[0] | ((unsigned)o[1]<<16);
        ov.y = (unsigned)o[2] | ((unsigned)o[3]<<16);
        *(uint2*)(nhC + (size_t)ai*HP + C4) = ov;
        *(uint2*)(hbuf + (size_t)(1 + base)*HP + C4) = ov;   // pads written as 0 (stay 0)
    }
}

// ---------- scan: uh = nh @ Ur^T; swapped MFMA, vector epilogue ----------
__global__ __launch_bounds__(256) void ur_k(int t,
    const int* __restrict__ vcnt, const int* __restrict__ vlist,
    const ushort* __restrict__ UrB, const ushort* __restrict__ nhC,
    ushort* __restrict__ uhbuf)
{
    const int cnt = vcnt[t];
    const int rows0 = blockIdx.x*32;
    if (rows0 >= cnt) return;
    const int cols0 = blockIdx.y*32;
    const int lane = threadIdx.x & 63, w = threadIdx.x >> 6;
    const int wr = w >> 1, wc = w & 1;
    const int ai = rows0 + wr*16 + (lane & 15);
    const int Cb = cols0 + wc*16 + (lane & 15);
    const int kq = (lane >> 4) * 8;
    const ushort* aNp = nhC + (size_t)ai*HP + kq;
    const ushort* bUp = UrB + (size_t)Cb*HP + kq;
    f32x4 acc = (f32x4){0,0,0,0};
#pragma unroll 5
    for (int kt=0; kt<15; ++kt){
        const int kb = kt*32;
        bf16x8 aN = *(const bf16x8*)(aNp + kb);
        bf16x8 bU = *(const bf16x8*)(bUp + kb);
        acc = __builtin_amdgcn_mfma_f32_16x16x32_bf16(bU, aN, acc, 0, 0, 0);
    }
    if (ai < cnt){
        const int C4 = cols0 + wc*16 + ((lane>>4)<<2);
        const int b = vlist[t*Bq + ai];
        ushort o[4];
#pragma unroll
        for (int j=0; j<4; j++)
            o[j] = (C4 + j < Hq) ? f2bf(acc[j]) : 0;
        uint2 ov; ov.x = (unsigned)o[0] | ((unsigned)o[1]<<16);
        ov.y = (unsigned)o[2] | ((unsigned)o[3]<<16);
        *(uint2*)(uhbuf + (size_t)(1 + t*Bq + b)*HP + C4) = ov;  // pads written as 0
    }
}

// ---------- pred GEMM1 (compacted rows); swapped epilogue ----------
__global__ __launch_bounds__(256) void pred1c_k(const int* __restrict__ np_,
    const int* __restrict__ listp, const ushort* __restrict__ hbuf,
    const ushort* __restrict__ TP, const ushort* __restrict__ WHp,
    ushort* __restrict__ pv)
{
    const int np = *np_;
    const int row0 = blockIdx.x*128;
    if (row0 >= np) return;
    const int col0 = blockIdx.y*64;
    const int tid = threadIdx.x;
    int i0 = row0 + (tid>>2), i1 = i0 + 64;
    int g0 = (i0 < np) ? listp[i0] : 0;
    int g1 = (i1 < np) ? listp[i1] : 0;
    const ushort* p0 = (g0 < Bq) ? hbuf : hbuf + (size_t)(1 + g0 - Bq)*HP;  // hbuf row0 = zeros
    const ushort* p1 = (g1 < Bq) ? hbuf : hbuf + (size_t)(1 + g1 - Bq)*HP;
    f32x4 acc[4][2];
    mgemm2([&](int which,int k0){ return (which?p1:p0)+k0; }, WHp, HP, 15, col0, acc);
    EPI_PRE
#pragma unroll
    for (int f=0; f<4; f++){
        const int i = row0 + wm*64 + f*16 + (lane & 15);
        if (i >= np) continue;
        const int gr = listp[i];
        const int b = (gr < Bq) ? gr : ((gr - Bq) & (Bq-1));
#pragma unroll
        for (int g=0; g<2; g++){
            const int C4 = col0 + wn*32 + g*16 + ((lane>>4)<<2);
            if (C4 >= HP) continue;
            uint2 tp2 = *(const uint2*)(TP + (size_t)b*HP + C4);
            unsigned tpw[2] = {tp2.x, tp2.y};
            ushort o[4];
#pragma unroll
            for (int j=0; j<4; j++){
                float v = fmaxf(acc[f][g][j] + bf2f((ushort)((tpw[j>>1] >> ((j&1)*16)) & 0xffff)), 0.f);
                o[j] = f2bf(v);   // pad cols: acc=0, TP=0 -> relu(0)=0
            }
            uint2 ov; ov.x = (unsigned)o[0] | ((unsigned)o[1]<<16);
            ov.y = (unsigned)o[2] | ((unsigned)o[3]<<16);
            *(uint2*)(pv + (size_t)i*HP + C4) = ov;
        }
    }
}

// ---------- pred GEMM2; swapped epilogue, bf16 score stores ----------
__global__ __launch_bounds__(256) void pred2c_k(const int* __restrict__ np_,
    const ushort* __restrict__ pv, const ushort* __restrict__ WOp,
    const ushort* __restrict__ bWoB, ushort* __restrict__ scores)
{
    const int np = *np_;
    const int row0 = blockIdx.x*128;
    if (row0 >= np) return;
    const int col0 = blockIdx.y*64;
    const int tid = threadIdx.x;
    const ushort* p0 = pv + (size_t)(row0 + (tid>>2))*HP;
    const ushort* p1 = p0 + (size_t)64*HP;
    f32x4 acc[4][2];
    mgemm2([&](int which,int k0){ return (which?p1:p0)+k0; }, WOp, HP, 15, col0, acc);
    EPI_PRE
#pragma unroll
    for (int f=0; f<4; f++){
        const int r = row0 + wm*64 + f*16 + (lane & 15);
#pragma unroll
        for (int g=0; g<2; g++){
            const int C4 = col0 + wn*32 + g*16 + ((lane>>4)<<2);
            uint2 bw2 = *(const uint2*)(bWoB + C4);
            unsigned bww[2] = {bw2.x, bw2.y};
            ushort o[4];
#pragma unroll
            for (int j=0; j<4; j++){
                float bb = bf2f((ushort)((bww[j>>1] >> ((j&1)*16)) & 0xffff));
                o[j] = f2bf(acc[f][g][j] + bb);
            }
            uint2 ov; ov.x = (unsigned)o[0] | ((unsigned)o[1]<<16);
            ov.y = (unsigned)o[2] | ((unsigned)o[3]<<16);
            *(uint2*)(scores + (size_t)r*832 + C4) = ov;
        }
    }
}

// ---------- pred reduce: wave-per-row (bf16 scores) ----------
__global__ __launch_bounds__(256) void predred_k(const int* __restrict__ np_,
    const int* __restrict__ listp, const ushort* __restrict__ scores,
    const int* __restrict__ pred_wid, const int* __restrict__ root_wid,
    float* __restrict__ accv)
{
    const int np = *np_;
    const int lane = threadIdx.x & 63, wv = threadIdx.x >> 6;
    const int wid_g = blockIdx.x*4 + wv, nw = gridDim.x*4;
    float ce = 0.f, hit = 0.f, cnt = 0.f;
    for (int r = wid_g; r < np; r += nw){
        const ushort* sc = scores + (size_t)r*832;
        int gr = listp[r];
        int tgt = (gr < Bq) ? root_wid[gr] : pred_wid[gr - Bq];
        float vals[13];
        float bv = -INFINITY, tv = 0.f; int bi = 0;
#pragma unroll
        for (int q=0; q<13; q++){
            int j = lane + q*64;
            float v = (j < Vq) ? bf2f(sc[j]) : -INFINITY;
            vals[q] = v;
            if (v > bv){ bv = v; bi = j; }
            if (j == tgt) tv = v;
        }
#pragma unroll
        for (int off=32; off; off>>=1){
            float ov = __shfl_xor(bv, off); int oi = __shfl_xor(bi, off);
            if (ov > bv || (ov == bv && oi < bi)){ bv = ov; bi = oi; }
        }
        float s = 0.f;
#pragma unroll
        for (int q=0; q<13; q++){
            int j = lane + q*64;
            if (j < Vq) s += __expf(vals[q] - bv);
        }
#pragma unroll
        for (int off=32; off; off>>=1) s += __shfl_xor(s, off);
#pragma unroll
        for (int off=32; off; off>>=1) tv += __shfl_xor(tv, off);
        if (lane == 0){
            ce += bv + logf(s) - tv;
            hit += (bi == tgt) ? 1.f : 0.f;
            cnt += 1.f;
        }
    }
    __shared__ float L[3][4];
    if (lane == 0){ L[0][wv] = ce; L[1][wv] = hit; L[2][wv] = cnt; }
    __syncthreads();
    if (threadIdx.x == 0){
        float a = L[0][0]+L[0][1]+L[0][2]+L[0][3];
        float b = L[1][0]+L[1][1]+L[1][2]+L[1][3];
        float c = L[2][0]+L[2][1]+L[2][2]+L[2][3];
        if (c != 0.f){
            atomicAdd(&accv[0], a);
            atomicAdd(&accv[1], b);
            atomicAdd(&accv[2], c);
        }
    }
}

// ---------- stop: cur_o gather (task-parallel, 16B chunks; pads stored w/o loads) ----------
__global__ __launch_bounds__(256) void curo_c(const int* __restrict__ ns_,
    const int* __restrict__ lists, const int* __restrict__ o_idx2,
    const ushort* __restrict__ hbuf, ushort* __restrict__ curo)
{
    const int ns = *ns_;
    const int task = blockIdx.x*256 + threadIdx.x;
    if (task >= ns*60) return;
    const int i = task / 60;
    const int c = task - i*60;
    const int j0 = c*8;
    if (c >= 57){
        u32x4 z = (u32x4){0,0,0,0};
        *(u32x4*)(curo + (size_t)i*HP + j0) = z;
        return;
    }
    const int gr = lists[i];
    const int* ip = o_idx2 + (size_t)gr*Mq;
    int idx[Mq];
#pragma unroll
    for (int m=0;m<Mq;m++) idx[m] = ip[m];
    float sh[8] = {0,0,0,0,0,0,0,0};
#pragma unroll
    for (int m=0;m<Mq;m++){
        u32x4 hv = *(const u32x4*)(hbuf + (size_t)idx[m]*HP + j0);
#pragma unroll
        for (int e=0;e<8;e++)
            sh[e] += bf2f((ushort)((hv[e>>1] >> ((e&1)*16)) & 0xffff));
    }
    u32x4 so;
    so[0]=pk2(sh[0],sh[1]); so[1]=pk2(sh[2],sh[3]);
    so[2]=pk2(sh[4],sh[5]); so[3]=pk2(sh[6],sh[7]);
    *(u32x4*)(curo + (size_t)i*HP + j0) = so;
}

// ---------- stop GEMM (compacted) + fused Us-dot; swapped epilogue ----------
__global__ __launch_bounds__(256) void stopc_k(const int* __restrict__ ns_,
    const int* __restrict__ lists, const int* __restrict__ x_wid,
    const int* __restrict__ root_wid, const ushort* __restrict__ curo,
    const ushort* __restrict__ UOp, const ushort* __restrict__ EU,
    const ushort* __restrict__ TU, const ushort* __restrict__ UsB,
    float* __restrict__ ss)
{
    const int ns = *ns_;
    const int row0 = blockIdx.x*128;
    if (row0 >= ns) return;
    const int col0 = blockIdx.y*64;
    const int tid = threadIdx.x;
    const ushort* p0 = curo + (size_t)(row0 + (tid>>2))*HP;
    const ushort* p1 = p0 + (size_t)64*HP;
    f32x4 acc[4][2];
    mgemm2([&](int which,int k0){ return (which?p1:p0)+k0; }, UOp, HP, 15, col0, acc);
    EPI_PRE
#pragma unroll
    for (int f=0; f<4; f++){
        const int i = row0 + wm*64 + f*16 + (lane & 15);
        float p = 0.f;
        if (i < ns){
            const int gr = lists[i];
            const int wid = (gr < TBq) ? x_wid[gr] : root_wid[gr - TBq];
            const int b   = (gr < TBq) ? (gr & (Bq-1)) : (gr - TBq);
#pragma unroll
            for (int g=0; g<2; g++){
                const int C4 = col0 + wn*32 + g*16 + ((lane>>4)<<2);
                if (C4 >= Hq) continue;
                uint2 eu2 = *(const uint2*)(EU + (size_t)wid*HP + C4);
                uint2 tu2 = *(const uint2*)(TU + (size_t)b*HP + C4);
                uint2 us2 = *(const uint2*)(UsB + C4);
                unsigned euw[2] = {eu2.x, eu2.y}, tuw[2] = {tu2.x, tu2.y}, usw[2] = {us2.x, us2.y};
#pragma unroll
                for (int j=0; j<4; j++){
                    const int col = C4 + j;
                    if (col < Hq){
                        float e = bf2f((ushort)((euw[j>>1] >> ((j&1)*16)) & 0xffff));
                        float u = bf2f((ushort)((tuw[j>>1] >> ((j&1)*16)) & 0xffff));
                        float us = bf2f((ushort)((usw[j>>1] >> ((j&1)*16)) & 0xffff));
                        p += fmaxf(acc[f][g][j] + e + u, 0.f) * us;
                    }
                }
            }
        }
        p += __shfl_xor(p, 16); p += __shfl_xor(p, 32);
        if ((lane >> 4) == 0 && i < ns) atomicAdd(&ss[i], p);
    }
}

__global__ void stopfin_k(const int* __restrict__ ns_, const int* __restrict__ lists,
    const float* __restrict__ ss, const float* __restrict__ bUs,
    const int* __restrict__ direction, float* __restrict__ accv)
{
    const int ns = *ns_;
    int i = blockIdx.x*256 + threadIdx.x;
    float bce = 0.f, hit = 0.f, c = 0.f;
    if (i < ns){
        int gr = lists[i];
        float s = ss[i] + bUs[0];
        float stgt = (gr < TBq) ? (float)direction[gr] : 0.f;
        bce = fmaxf(s,0.f) - s*stgt + log1pf(__expf(-fabsf(s)));
        hit = ((((s >= 0.f) ? 1.f : 0.f) == stgt) ? 1.f : 0.f);
        c = 1.f;
    }
    for (int off=32; off; off>>=1){
        bce += __shfl_down(bce, off);
        hit += __shfl_down(hit, off);
        c   += __shfl_down(c,   off);
    }
    if ((threadIdx.x & 63) == 0 && c != 0.f){
        atomicAdd(&accv[3], bce);
        atomicAdd(&accv[4], hit);
        atomicAdd(&accv[5], c);
    }
}

__global__ void finalize_k(const float* __restrict__ accv, float* __restrict__ out){
    if (threadIdx.x == 0){
        out[0] = accv[0] / (float)Bq;
        out[1] = accv[3] / (float)Bq;
        out[2] = accv[1] / accv[2];
        out[3] = accv[4] / accv[5];
    }
}

extern "C" void kernel_launch(void* const* d_in, const int* in_sizes, int n_in,
                              void* d_out, int out_size, void* d_ws, size_t ws_size,
                              hipStream_t stream) {
    (void)in_sizes; (void)n_in; (void)out_size; (void)ws_size;
    const float* tree_vecs = (const float*)d_in[0];
    const int*   x_wid     = (const int*)d_in[1];
    const int*   pred_wid  = (const int*)d_in[2];
    const int*   root_wid  = (const int*)d_in[3];
    const int*   h_nei_idx = (const int*)d_in[4];
    const int*   o_nei_idx = (const int*)d_in[5];
    const int*   root_o_nei= (const int*)d_in[6];
    const int*   valid     = (const int*)d_in[7];
    const int*   direction = (const int*)d_in[8];
    const float* emb       = (const float*)d_in[9];
    const float* Wz        = (const float*)d_in[10];
    const float* bz        = (const float*)d_in[11];
    const float* Wr        = (const float*)d_in[12];
    const float* br        = (const float*)d_in[13];
    const float* Ur        = (const float*)d_in[14];
    const float* Wh        = (const float*)d_in[15];
    const float* bh        = (const float*)d_in[16];
    const float* Wm        = (const float*)d_in[17];
    const float* bW        = (const float*)d_in[18];
    const float* U         = (const float*)d_in[19];
    const float* bU        = (const float*)d_in[20];
    const float* Wo        = (const float*)d_in[21];
    const float* bWo       = (const float*)d_in[22];
    const float* Us        = (const float*)d_in[23];
    const float* bUs       = (const float*)d_in[24];

    char* w = (char*)d_ws; size_t off = 0;
    auto alloc = [&](size_t bytes)->void*{ void* p = w + off; off += (bytes + 255) & ~(size_t)255; return p; };

    ushort* hbuf  = (ushort*)alloc((size_t)Sq*HP*2);
    ushort* uhbuf = (ushort*)alloc((size_t)Sq*HP*2);
    ushort* embb  = (ushort*)alloc((size_t)896*HP*2);
    ushort* treeb = (ushort*)alloc((size_t)Bq*64*2);
    ushort* WzX   = (ushort*)alloc((size_t)512*HP*2);
    ushort* WzS   = (ushort*)alloc((size_t)512*HP*2);
    ushort* WrB   = (ushort*)alloc((size_t)512*HP*2);
    ushort* WhX   = (ushort*)alloc((size_t)512*HP*2);
    ushort* WhG   = (ushort*)alloc((size_t)512*HP*2);
    ushort* UrB   = (ushort*)alloc((size_t)512*HP*2);
    ushort* WHp   = (ushort*)alloc((size_t)512*HP*2);
    ushort* UXp   = (ushort*)alloc((size_t)512*HP*2);
    ushort* UOp   = (ushort*)alloc((size_t)512*HP*2);
    ushort* WOp   = (ushort*)alloc((size_t)832*HP*2);
    ushort* WLp   = (ushort*)alloc((size_t)512*64*2);
    ushort* ULp   = (ushort*)alloc((size_t)512*64*2);
    ushort* UsB   = (ushort*)alloc((size_t)HP*2);
    ushort* bWoB  = (ushort*)alloc((size_t)832*2);
    ushort* EZ    = (ushort*)alloc((size_t)896*HP*2);
    ushort* ER    = (ushort*)alloc((size_t)896*HP*2);
    ushort* EH    = (ushort*)alloc((size_t)896*HP*2);
    ushort* EU    = (ushort*)alloc((size_t)896*HP*2);
    ushort* TP    = (ushort*)alloc((size_t)Bq*HP*2);
    ushort* TU    = (ushort*)alloc((size_t)Bq*HP*2);
    ushort* sumhC = (ushort*)alloc((size_t)Bq*HP*2);
    ushort* gatedC= (ushort*)alloc((size_t)Bq*HP*2);
    ushort* nhC   = (ushort*)alloc((size_t)Bq*HP*2);
    ushort* pv    = (ushort*)alloc((size_t)NPCAP*HP*2);
    ushort* scores= (ushort*)alloc((size_t)NPCAP*832*2);
    float*  ss    = (float*)alloc((size_t)NSCAP*4);
    int*    listp = (int*)alloc((size_t)NPCAP*4);
    int*    lists = (int*)alloc((size_t)NSCAP*4);
    int*    vlist = (int*)alloc((size_t)Tq*Bq*4);
    int*    vcnt  = (int*)alloc((size_t)Tq*4);
    int*    h_idx2= (int*)alloc((size_t)TBq*Mq*4);
    int*    o_idx2= (int*)alloc((size_t)(TBq+Bq)*Mq*4);
    int*    meta  = (int*)alloc((size_t)(NPB*4 + 2 + 16)*4);
    int*    cnts  = meta;            // [2*NPB]
    int*    offs  = meta + 2*NPB;    // [2*NPB]
    int*    tot   = meta + 4*NPB;    // [2]
    float*  accv  = (float*)(meta + 4*NPB + 2);
    ushort* curo  = pv;              // stop phase reuses pv+scores region

    // only slot 0 of hbuf/uhbuf must be zero (index redirect handles the rest)
    (void)hipMemsetAsync(hbuf,  0, (size_t)HP*2, stream);
    (void)hipMemsetAsync(uhbuf, 0, (size_t)HP*2, stream);
    (void)hipMemsetAsync(ss,    0, (size_t)NSCAP*4, stream);
    (void)hipMemsetAsync(meta,  0, (size_t)(NPB*4 + 2 + 16)*4, stream);

    // ---- conversions (1 launch, 16 jobs) ----
    convAll_k<<<dim3(896,16), 128, 0, stream>>>(
        emb, tree_vecs, Wz, Wr, Ur, Wh, Wm, U, Wo, Us, bWo,
        embb, treeb, WzX, WzS, WrB, WhX, WhG, UrB, WHp, UXp, UOp, WOp, WLp, ULp,
        UsB, bWoB);

    // ---- precomputes (1 launch, bf16 tables) ----
    preAll_k<<<dim3(8,7,6), 256, 0, stream>>>(embb, treeb, WzX, WrB, WhX, UXp, WLp, ULp,
                                              bz, br, bh, bU, bW, EZ, ER, EH, EU, TP, TU);

    // ---- row compaction + index redirects ----
    cnt_k <<<dim3(NPB,2), 256, 0, stream>>>(valid, direction, cnts);
    scan_k<<<1, 64, 0, stream>>>(cnts, offs, tot);
    fill_k<<<dim3(NPB,2), 256, 0, stream>>>(valid, direction, offs, listp, lists);
    vfill_k<<<Tq, 512, 0, stream>>>(valid, vcnt, vlist);
    idx2_k<<<((TBq+Bq)*Mq + 255)/256, 256, 0, stream>>>(h_nei_idx, o_nei_idx, root_o_nei,
                                                        valid, h_idx2, o_idx2);

    // ---- sequential scan: 3 wide kernels per step ----
    for (int t=0; t<Tq; t++){
        gather_k<<<115, 256, 0, stream>>>(t, x_wid, h_idx2, ER, vcnt, vlist,
                                          hbuf, uhbuf, sumhC, gatedC);
        zh_k<<<dim3(16,15), 256, 0, stream>>>(t, x_wid, vcnt, vlist, EZ, EH,
                                              WzS, WhG, sumhC, gatedC, nhC, hbuf);
        ur_k<<<dim3(16,15), 256, 0, stream>>>(t, vcnt, vlist, UrB, nhC, uhbuf);
    }

    // ---- pred phase (compacted, single chunk, bf16 scores) ----
    pred1c_k<<<dim3(NPCAP/128, 8), 256, 0, stream>>>(tot, listp, hbuf, TP, WHp, pv);
    pred2c_k<<<dim3(NPCAP/128, 13), 256, 0, stream>>>(tot, pv, WOp, bWoB, scores);
    predred_k<<<256, 256, 0, stream>>>(tot, listp, scores, pred_wid, root_wid, accv);

    // ---- stop phase (compacted) ----
    curo_c<<<(NSCAP*60 + 255)/256, 256, 0, stream>>>(tot+1, lists, o_idx2, hbuf, curo);
    stopc_k<<<dim3(NSCAP/128, 8), 256, 0, stream>>>(tot+1, lists, x_wid, root_wid,
                                                    curo, UOp, EU, TU, UsB, ss);
    stopfin_k<<<NSCAP/256, 256, 0, stream>>>(tot+1, lists, ss, bUs, direction, accv);

    finalize_k<<<1, 64, 0, stream>>>(accv, (float*)d_out);
}